// Round 1
// 3487.428 us; speedup vs baseline: 1.5287x; 1.5287x over previous
//
#include <hip/hip_runtime.h>
#include <hip/hip_bf16.h>
#include <math.h>

typedef _Float16 fp16;
typedef _Float16 f16x8 __attribute__((ext_vector_type(8)));
typedef float f32x4 __attribute__((ext_vector_type(4)));

#define BB 16
#define PP 12
#define QQ 12
#define NN 2000
#define CC 1024

static __device__ __forceinline__ float ldf(float v) { return v; }
static __device__ __forceinline__ float ldf(fp16 v) { return (float)v; }
static __device__ __forceinline__ void stf(float* p, float v) { *p = v; }
static __device__ __forceinline__ void stf(fp16* p, float v) { *p = (fp16)v; }

// async global->LDS, 16B per lane (wave-uniform LDS base + lane*16)
static __device__ __forceinline__ void gload_lds16(const fp16* g, fp16* l) {
  __builtin_amdgcn_global_load_lds(
      (const __attribute__((address_space(1))) void*)g,
      (__attribute__((address_space(3))) void*)l, 16, 0, 0);
}

// ---------- conversions / repacks ----------
__global__ void k_f2h(fp16* __restrict__ dst, const float* __restrict__ src, long long n) {
  long long i = (long long)blockIdx.x * 256 + threadIdx.x;
  if (i < n) dst[i] = (fp16)src[i];
}

// dcgru weights (512,O): row=f*4+t -> Wt[d][t*128+c] = src[(c*4+t)*O+d]
__global__ void k_gru_repackT(fp16* __restrict__ dst, const float* __restrict__ src, int O) {
  int i = blockIdx.x * 256 + threadIdx.x;
  if (i >= O * 512) return;
  int d = i >> 9;
  int kc = i & 511;
  int t = kc >> 7;
  int c = kc & 127;
  dst[i] = (fp16)src[(c * 4 + t) * O + d];
}

// (64,64) -> T[d][k] fp16
__global__ void k_w2T(fp16* __restrict__ dst, const float* __restrict__ src) {
  int i = blockIdx.x * 256 + threadIdx.x;
  if (i >= 4096) return;
  int d = i >> 6, k = i & 63;
  dst[i] = (fp16)src[k * 64 + d];
}

// ---------- laplacian ----------
__global__ void k_dinv(const float* __restrict__ adj, float* __restrict__ dinv) {
  int row = blockIdx.x;
  float s = 0.f;
  for (int j = threadIdx.x; j < NN; j += 256)
    s += fmaxf(adj[(long long)row * NN + j], adj[(long long)j * NN + row]);
  __shared__ float red[256];
  red[threadIdx.x] = s;
  __syncthreads();
  for (int st = 128; st > 0; st >>= 1) {
    if (threadIdx.x < st) red[threadIdx.x] += red[threadIdx.x + st];
    __syncthreads();
  }
  if (threadIdx.x == 0) {
    float d = red[0];
    dinv[row] = d > 0.f ? 1.0f / sqrtf(d) : 0.f;
  }
}

// writes L with row stride 2048 (zero-padded to K=2048 for maskless mfma4)
__global__ void k_L(const float* __restrict__ adj, const float* __restrict__ dinv,
                    fp16* __restrict__ Lh) {
  long long i = (long long)blockIdx.x * 256 + threadIdx.x;
  if (i >= (long long)NN * NN) return;
  int r = (int)(i / NN), c = (int)(i % NN);
  float a = fmaxf(adj[(long long)r * NN + c], adj[(long long)c * NN + r]);
  Lh[(long long)r * 2048 + c] = (fp16)(-dinv[r] * a * dinv[c]);
}

__global__ void k_subdiag(fp16* __restrict__ M2) {
  int i = blockIdx.x * 256 + threadIdx.x;
  if (i >= NN) return;
  M2[(long long)i * 2048 + i] = (fp16)((float)M2[(long long)i * 2048 + i] - 1.0f);
}

// ---------- gumbel softmax -> fp16 ----------
__global__ void k_gumbel_softmax(const float* __restrict__ ml, const float* __restrict__ gn,
                                 fp16* __restrict__ mZ) {
  int row = blockIdx.x;
  __shared__ float buf[CC];
  __shared__ float red[256];
  int t = threadIdx.x;
  float mx = -1e30f;
  for (int j = t; j < CC; j += 256) {
    float u = gn[(long long)row * CC + j];
    float g = -logf(-logf(u + 1e-20f) + 1e-20f);
    float v = ml[(long long)row * CC + j] + g;
    buf[j] = v;
    mx = fmaxf(mx, v);
  }
  red[t] = mx;
  __syncthreads();
  for (int st = 128; st > 0; st >>= 1) {
    if (t < st) red[t] = fmaxf(red[t], red[t + st]);
    __syncthreads();
  }
  mx = red[0];
  __syncthreads();
  float s = 0.f;
  for (int j = t; j < CC; j += 256) {
    float e = expf(buf[j] - mx);
    buf[j] = e;
    s += e;
  }
  red[t] = s;
  __syncthreads();
  for (int st = 128; st > 0; st >>= 1) {
    if (t < st) red[t] += red[t + st];
    __syncthreads();
  }
  float inv = 1.0f / red[0];
  for (int j = t; j < CC; j += 256) mZ[(long long)row * CC + j] = (fp16)(buf[j] * inv);
}

__global__ void k_te(const int* __restrict__ TE, const float* __restrict__ w1,
                     const float* __restrict__ b1, float* __restrict__ tmp) {
  int i = blockIdx.x * 256 + threadIdx.x;
  if (i >= BB * PP * 64) return;
  int j = i & 63;
  int bp = i >> 6;
  int b = bp / PP, p = bp % PP;
  int te0 = TE[(b * (PP + QQ) + p) * 2 + 0];
  int te1 = TE[(b * (PP + QQ) + p) * 2 + 1];
  float v = w1[te0 * 64 + j] + w1[(7 + te1) * 64 + j] + b1[j];
  tmp[i] = fmaxf(v, 0.f);
}

__global__ void k_addb(float* __restrict__ dst, const float* __restrict__ b, int n) {
  int i = blockIdx.x * 256 + threadIdx.x;
  if (i < n) dst[i] += b[i & 63];
}

__global__ void k_zf1(const float* __restrict__ Z, const float* __restrict__ w1,
                      const float* __restrict__ b1, fp16* __restrict__ tmp) {
  long long i = (long long)blockIdx.x * 256 + threadIdx.x;
  if (i >= (long long)BB * PP * CC * 64) return;
  int j = (int)(i & 63);
  long long row = i >> 6;
  float v = Z[row * 2 + 0] * w1[j] + Z[row * 2 + 1] * w1[64 + j] + b1[j];
  tmp[i] = (fp16)fmaxf(v, 0.f);
}

__global__ void k_add_stez(fp16* __restrict__ Zf, const float* __restrict__ seZ,
                           const float* __restrict__ teZ) {
  long long i = (long long)blockIdx.x * 256 + threadIdx.x;
  if (i >= (long long)BB * PP * CC * 64) return;
  int j = (int)(i & 63);
  long long row = i >> 6;
  int c = (int)(row % CC);
  int bp = (int)(row / CC);
  Zf[i] = (fp16)((float)Zf[i] + seZ[c * 64 + j] + teZ[bp * 64 + j]);
}

// ---------- generic fp32-path GEMM (small ops) ----------
template <typename TA, typename TB, typename TC>
__global__ __launch_bounds__(256) void gemm_t(
    const TA* __restrict__ A, int lda, long long sA,
    const TB* __restrict__ Bm, int ldb, long long sB,
    TC* Cm, int ldc, long long sC,
    const TC* S, long long sS,
    const float* __restrict__ bias,
    int M, int Ncols, int K, float alpha, float beta, int act) {
  int bz = blockIdx.z;
  A += (long long)bz * sA;
  Bm += (long long)bz * sB;
  Cm += (long long)bz * sC;
  if (S) S += (long long)bz * sS;
  const int row0 = blockIdx.x * 64, col0 = blockIdx.y * 64;
  __shared__ float As[16][68];
  __shared__ float Bs[16][68];
  int tid = threadIdx.x, tx = tid & 15, ty = tid >> 4;
  float acc[4][4] = {};
  for (int k0 = 0; k0 < K; k0 += 16) {
#pragma unroll
    for (int j = 0; j < 4; ++j) {
      int e = tid + 256 * j;
      int m = e >> 4, kk = e & 15;
      int gm = row0 + m;
      As[kk][m] = (gm < M) ? ldf(A[(long long)gm * lda + k0 + kk]) : 0.f;
    }
#pragma unroll
    for (int j = 0; j < 4; ++j) {
      int e = tid + 256 * j;
      int kk = e >> 6, n = e & 63;
      int gn = col0 + n;
      Bs[kk][n] = (gn < Ncols) ? ldf(Bm[(long long)(k0 + kk) * ldb + gn]) : 0.f;
    }
    __syncthreads();
#pragma unroll
    for (int kk = 0; kk < 16; ++kk) {
      float a[4], bb[4];
#pragma unroll
      for (int i = 0; i < 4; ++i) a[i] = As[kk][ty * 4 + i];
#pragma unroll
      for (int j = 0; j < 4; ++j) bb[j] = Bs[kk][tx * 4 + j];
#pragma unroll
      for (int i = 0; i < 4; ++i)
#pragma unroll
        for (int j = 0; j < 4; ++j) acc[i][j] = fmaf(a[i], bb[j], acc[i][j]);
    }
    __syncthreads();
  }
#pragma unroll
  for (int i = 0; i < 4; ++i) {
    int r = row0 + ty * 4 + i;
    if (r >= M) continue;
#pragma unroll
    for (int j = 0; j < 4; ++j) {
      int cn = col0 + tx * 4 + j;
      if (cn >= Ncols) continue;
      float v = alpha * acc[i][j];
      if (bias) v += bias[cn];
      if (S) v += beta * ldf(S[(long long)r * ldc + cn]);
      if (act == 1) v = fmaxf(v, 0.f);
      else if (act == 2) v = 1.f / (1.f + expf(-v));
      else if (act == 3) v = tanhf(v);
      stf(&Cm[(long long)r * ldc + cn], v);
    }
  }
}

// ---------- mfma2: DCGRU weight GEMMs with fused GRU epilogues ----------
// MODE 1 (ru):  C=ruT [z][128][NN]; sigmoid; rows<64 also write rh=r*h into rhOut
// MODE 2 (cnd): tanh; h' = u*h + (1-u)*v written in-place into C (=U0 h-rows)
template <int MT, int MODE>
__global__ __launch_bounds__(256) void mfma2(
    const fp16* __restrict__ A, int lda,
    const fp16* __restrict__ B, int ldb, long long bBatch, int bShift, long long bSlab,
    int bHi,
    fp16* __restrict__ C, int ldc, long long cBatch,
    const float* __restrict__ bias,
    fp16* __restrict__ rhOut, const fp16* __restrict__ hIn, long long xStride,
    const fp16* __restrict__ uIn, long long uStride,
    int M, int Ncols, int K, float alpha) {
  __shared__ fp16 As[MT][40];
  __shared__ fp16 Bs[64][40];
  const int z = blockIdx.z;
  const int gm0 = blockIdx.x * MT, n0 = blockIdx.y * 64;
  B += (long long)z * bBatch;
  C += (long long)z * cBatch;
  if (rhOut) rhOut += (long long)z * xStride;
  if (hIn) hIn += (long long)z * xStride;
  if (uIn) uIn += (long long)z * uStride;
  const int tid = threadIdx.x;
  const int lane = tid & 63, wv = tid >> 6;
  const int wr = wv >> 1, wc = wv & 1;
  const int quad = lane >> 4, ln = lane & 15;
  const unsigned bMask = (1u << bShift) - 1u;
  constexpr int WM = MT / 32;
  f32x4 acc[WM][2];
#pragma unroll
  for (int i = 0; i < WM; ++i)
#pragma unroll
    for (int j = 0; j < 2; ++j) acc[i][j] = (f32x4){0.f, 0.f, 0.f, 0.f};

  for (int k0 = 0; k0 < K; k0 += 32) {
#pragma unroll
    for (int i = 0; i < MT / 64; ++i) {
      int c = tid + 256 * i;
      int row = c >> 2, seg = c & 3;
      int gm = gm0 + row;
      int kk0 = k0 + seg * 8;
      const fp16* src = A + (long long)gm * lda + kk0;
      if (gm < M && kk0 + 8 <= K) {
        *(f16x8*)&As[row][seg * 8] = *(const f16x8*)src;
      } else {
#pragma unroll
        for (int j = 0; j < 8; ++j)
          As[row][seg * 8 + j] = (gm < M && kk0 + j < K) ? src[j] : (fp16)0.f;
      }
    }
    {
      int kk = k0 + (tid & 31);
      int ngrp = tid >> 5;
      int slab = (int)((unsigned)kk >> bShift);
      int kin = (int)((unsigned)kk & bMask);
      int col = kin + (kin >= 64 ? bHi : 0);
      int n = n0 + ngrp * 8;
      const fp16* src = B + (long long)slab * bSlab + (long long)col * ldb + n;
      if (kk < K && n + 8 <= Ncols) {
        f16x8 v = *(const f16x8*)src;
#pragma unroll
        for (int j = 0; j < 8; ++j) Bs[ngrp * 8 + j][tid & 31] = v[j];
      } else {
#pragma unroll
        for (int j = 0; j < 8; ++j)
          Bs[ngrp * 8 + j][tid & 31] = (kk < K && n + j < Ncols) ? src[j] : (fp16)0.f;
      }
    }
    __syncthreads();
    f16x8 af[WM], bf[2];
#pragma unroll
    for (int wm = 0; wm < WM; ++wm)
      af[wm] = *(const f16x8*)&As[wr * (MT / 2) + wm * 16 + ln][quad * 8];
#pragma unroll
    for (int wn = 0; wn < 2; ++wn)
      bf[wn] = *(const f16x8*)&Bs[wc * 32 + wn * 16 + ln][quad * 8];
#pragma unroll
    for (int wm = 0; wm < WM; ++wm)
#pragma unroll
      for (int wn = 0; wn < 2; ++wn)
        acc[wm][wn] =
            __builtin_amdgcn_mfma_f32_16x16x32_f16(af[wm], bf[wn], acc[wm][wn], 0, 0, 0);
    __syncthreads();
  }
#pragma unroll
  for (int wm = 0; wm < WM; ++wm) {
#pragma unroll
    for (int wn = 0; wn < 2; ++wn) {
#pragma unroll
      for (int r = 0; r < 4; ++r) {
        int gm = gm0 + wr * (MT / 2) + wm * 16 + quad * 4 + r;
        int gn = n0 + wc * 32 + wn * 16 + ln;
        if (gm < M && gn < Ncols) {
          float v = alpha * acc[wm][wn][r];
          v += bias[gm];
          if (MODE == 1) {
            v = 1.f / (1.f + expf(-v));  // sigmoid
            C[(long long)gm * ldc + gn] = (fp16)v;
            if (gm < 64) {
              float h = (float)hIn[(long long)gm * 2048 + gn];
              rhOut[(long long)gm * 2048 + gn] = (fp16)(v * h);
            }
          } else {
            v = tanhf(v);
            float u = (float)uIn[(long long)(64 + gm) * NN + gn];
            long long ci = (long long)gm * ldc + gn;
            float h = (float)C[ci];
            C[ci] = (fp16)(u * h + (1.f - u) * v);
          }
        }
      }
    }
  }
}

// ---------- mfma3: all-b128 GEMM; M-split and N-split output mapping ----------
template <int MT, int NT>
__global__ __launch_bounds__(256) void mfma3(
    const fp16* __restrict__ A, int lda, long long zA, int aMsh, long long aMslab,
    const fp16* __restrict__ B, int ldb, long long zB,
    fp16* __restrict__ C, int ldc, long long zC, int cMsh, long long cMslab, int cNsh,
    long long cNslab,
    const fp16* __restrict__ S, long long zS, float beta,
    const float* __restrict__ rowBias, long long zRB,
    const float* __restrict__ s2T, int s2ld,
    int M, int Ncols, int K, float alpha, int act) {
  __shared__ fp16 As[MT][40];
  __shared__ fp16 Bs[NT][40];
  const int z = blockIdx.z;
  const int gm0 = blockIdx.x * MT, n0 = blockIdx.y * NT;
  A += (long long)z * zA;
  B += (long long)z * zB;
  C += (long long)z * zC;
  if (S) S += (long long)z * zS;
  const int tid = threadIdx.x;
  const int lane = tid & 63, wv = tid >> 6;
  const int wr = wv >> 1, wc = wv & 1;
  const int quad = lane >> 4, ln = lane & 15;
  const unsigned aMmask = (1u << aMsh) - 1u;
  const unsigned cMmask = (1u << cMsh) - 1u;
  const unsigned cNmask = (1u << cNsh) - 1u;
  constexpr int WM = MT / 32, WN = NT / 32;
  f32x4 acc[WM][WN];
#pragma unroll
  for (int i = 0; i < WM; ++i)
#pragma unroll
    for (int j = 0; j < WN; ++j) acc[i][j] = (f32x4){0.f, 0.f, 0.f, 0.f};

  for (int k0 = 0; k0 < K; k0 += 32) {
#pragma unroll
    for (int i = 0; i < MT / 64; ++i) {
      int c = tid + 256 * i;
      int row = c >> 2, seg = c & 3;
      int gm = gm0 + row;
      int kk0 = k0 + seg * 8;
      const fp16* src = A + ((long long)((unsigned)gm >> aMsh)) * aMslab +
                        (long long)(gm & aMmask) * lda + kk0;
      if (gm < M && kk0 + 8 <= K) {
        *(f16x8*)&As[row][seg * 8] = *(const f16x8*)src;
      } else {
#pragma unroll
        for (int j = 0; j < 8; ++j)
          As[row][seg * 8 + j] = (gm < M && kk0 + j < K) ? src[j] : (fp16)0.f;
      }
    }
#pragma unroll
    for (int i = 0; i < NT / 64; ++i) {
      int c = tid + 256 * i;
      int n = c >> 2, seg = c & 3;
      int gn = n0 + n;
      int kk0 = k0 + seg * 8;
      const fp16* src = B + (long long)gn * ldb + kk0;
      if (gn < Ncols && kk0 + 8 <= K) {
        *(f16x8*)&Bs[n][seg * 8] = *(const f16x8*)src;
      } else {
#pragma unroll
        for (int j = 0; j < 8; ++j)
          Bs[n][seg * 8 + j] = (gn < Ncols && kk0 + j < K) ? src[j] : (fp16)0.f;
      }
    }
    __syncthreads();
    f16x8 af[WM], bf[WN];
#pragma unroll
    for (int wm = 0; wm < WM; ++wm)
      af[wm] = *(const f16x8*)&As[wr * (MT / 2) + wm * 16 + ln][quad * 8];
#pragma unroll
    for (int wn = 0; wn < WN; ++wn)
      bf[wn] = *(const f16x8*)&Bs[wc * (NT / 2) + wn * 16 + ln][quad * 8];
#pragma unroll
    for (int wm = 0; wm < WM; ++wm)
#pragma unroll
      for (int wn = 0; wn < WN; ++wn)
        acc[wm][wn] =
            __builtin_amdgcn_mfma_f32_16x16x32_f16(af[wm], bf[wn], acc[wm][wn], 0, 0, 0);
    __syncthreads();
  }
#pragma unroll
  for (int wm = 0; wm < WM; ++wm) {
#pragma unroll
    for (int wn = 0; wn < WN; ++wn) {
#pragma unroll
      for (int r = 0; r < 4; ++r) {
        int gm = gm0 + wr * (MT / 2) + wm * 16 + quad * 4 + r;
        int gn = n0 + wc * (NT / 2) + wn * 16 + ln;
        if (gm < M && gn < Ncols) {
          float v = alpha * acc[wm][wn][r];
          if (rowBias) v += rowBias[(long long)z * zRB + gm];
          if (s2T) v += s2T[(long long)gn * s2ld + gm];
          long long ci = ((long long)((unsigned)gm >> cMsh)) * cMslab +
                         (long long)(gm & cMmask) * ldc +
                         ((long long)((unsigned)gn >> cNsh)) * cNslab + (gn & cNmask);
          if (S) v += beta * (float)S[ci];
          if (act == 1) v = fmaxf(v, 0.f);
          else if (act == 2) v = 1.f / (1.f + expf(-v));
          else if (act == 3) v = tanhf(v);
          C[ci] = (fp16)v;
        }
      }
    }
  }
}

// ---------- mfma4: maskless m97-structure GEMM for the DCGRU chains ----------
// Requirements: M % MT == 0, Ncols % NT == 0 (full tiles), K % 32 == 0,
// all rows of A/B readable for full K (zero-padded), 16B-aligned rows.
// global_load_lds staging (direct HBM->LDS DMA), double-buffered LDS,
// stage(t+1) issued before compute(t), single __syncthreads per K-step.
// seg-XOR swizzle: source pre-swizzled, ds_read swizzled (involution).
template <int MT, int NT>
__global__ __launch_bounds__(256) void mfma4(
    const fp16* __restrict__ A, int lda, int aMsh, long long aMslab,
    const fp16* __restrict__ B, int ldb,
    fp16* __restrict__ C, int ldc, int cMsh, long long cMslab, int cNsh, long long cNslab,
    int K) {
  __shared__ fp16 As[2][MT * 32];
  __shared__ fp16 Bs[2][NT * 32];
  const int tid = threadIdx.x;
  const int gm0 = blockIdx.x * MT, n0 = blockIdx.y * NT;
  const unsigned aMmask = (1u << aMsh) - 1u;
  const unsigned cMmask = (1u << cMsh) - 1u;
  const unsigned cNmask = (1u << cNsh) - 1u;
  const int lane = tid & 63, wv = tid >> 6;
  const int wr = wv >> 1, wc = wv & 1;
  const int quad = lane >> 4, ln = lane & 15;
  constexpr int WM = MT / 32, WN = NT / 32;

  // per-thread staging source bases (seg pre-swizzled so linear LDS slot c
  // holds logical (row=c>>2, seg=(c&3)^(row&3)))
  const fp16* aSrc[MT / 64];
  const fp16* bSrc[NT / 64];
#pragma unroll
  for (int i = 0; i < MT / 64; ++i) {
    int c = i * 256 + tid;
    int row = c >> 2;
    int lseg = (c & 3) ^ (row & 3);
    int gm = gm0 + row;
    aSrc[i] = A + ((long long)((unsigned)gm >> aMsh)) * aMslab +
              (long long)(gm & aMmask) * lda + lseg * 8;
  }
#pragma unroll
  for (int i = 0; i < NT / 64; ++i) {
    int c = i * 256 + tid;
    int row = c >> 2;
    int lseg = (c & 3) ^ (row & 3);
    bSrc[i] = B + (long long)(n0 + row) * ldb + lseg * 8;
  }

  f32x4 acc[WM][WN];
#pragma unroll
  for (int i = 0; i < WM; ++i)
#pragma unroll
    for (int j = 0; j < WN; ++j) acc[i][j] = (f32x4){0.f, 0.f, 0.f, 0.f};

  const int sw = (quad ^ (ln & 3)) << 3;  // swizzled 8-elem slot for ds_read

  // prologue: stage tile 0 into buf 0
#pragma unroll
  for (int i = 0; i < MT / 64; ++i) gload_lds16(aSrc[i], &As[0][(i * 256 + tid) * 8]);
#pragma unroll
  for (int i = 0; i < NT / 64; ++i) gload_lds16(bSrc[i], &Bs[0][(i * 256 + tid) * 8]);

  const int nk = K >> 5;
  for (int t = 0; t < nk; ++t) {
    const int buf = t & 1;
    __syncthreads();  // drains vmcnt(0): tile t landed; prior reads of buf^1 done
    if (t + 1 < nk) {
      const int k1 = (t + 1) * 32;
#pragma unroll
      for (int i = 0; i < MT / 64; ++i)
        gload_lds16(aSrc[i] + k1, &As[buf ^ 1][(i * 256 + tid) * 8]);
#pragma unroll
      for (int i = 0; i < NT / 64; ++i)
        gload_lds16(bSrc[i] + k1, &Bs[buf ^ 1][(i * 256 + tid) * 8]);
    }
    f16x8 af[WM], bf[WN];
#pragma unroll
    for (int wm = 0; wm < WM; ++wm) {
      int row = wr * (MT / 2) + wm * 16 + ln;
      af[wm] = *(const f16x8*)&As[buf][row * 32 + sw];
    }
#pragma unroll
    for (int wn = 0; wn < WN; ++wn) {
      int row = wc * (NT / 2) + wn * 16 + ln;
      bf[wn] = *(const f16x8*)&Bs[buf][row * 32 + sw];
    }
#pragma unroll
    for (int wm = 0; wm < WM; ++wm)
#pragma unroll
      for (int wn = 0; wn < WN; ++wn)
        acc[wm][wn] =
            __builtin_amdgcn_mfma_f32_16x16x32_f16(af[wm], bf[wn], acc[wm][wn], 0, 0, 0);
  }
#pragma unroll
  for (int wm = 0; wm < WM; ++wm)
#pragma unroll
    for (int wn = 0; wn < WN; ++wn)
#pragma unroll
      for (int r = 0; r < 4; ++r) {
        int gm = gm0 + wr * (MT / 2) + wm * 16 + quad * 4 + r;
        int gn = n0 + wc * (NT / 2) + wn * 16 + ln;
        long long ci = ((long long)((unsigned)gm >> cMsh)) * cMslab +
                       (long long)(gm & cMmask) * ldc +
                       ((long long)((unsigned)gn >> cNsh)) * cNslab + (gn & cNmask);
        C[ci] = (fp16)acc[wm][wn][r];
      }
}

// ---------- k_zxt: ZXt[d][n] = ZmovT@agh2^T (K=1024) + w2T@Tmat^T (K=64)
//            + teXb[z][d] + seX[n][d].  M=64, NT=128 (WN=4!), z in [0,96).
__global__ __launch_bounds__(256) void k_zxt(
    const fp16* __restrict__ A1, const fp16* __restrict__ B1,  // ZmovT, agh2
    const fp16* __restrict__ A2, const fp16* __restrict__ B2,  // w2T, Tmat
    fp16* __restrict__ C, const float* __restrict__ teXb, const float* __restrict__ seX) {
  __shared__ fp16 As[64][40];
  __shared__ fp16 Bs[128][40];
  const int z = blockIdx.z;
  const int n0 = blockIdx.y * 128;
  A1 += (long long)z * 64 * CC;
  B2 += (long long)z * NN * 64;
  C += (long long)z * 64 * NN;
  teXb += (long long)z * 64;
  const int tid = threadIdx.x;
  const int lane = tid & 63, wv = tid >> 6;
  const int wr = wv >> 1, wc = wv & 1;
  const int quad = lane >> 4, ln = lane & 15;
  f32x4 acc[2][4];
#pragma unroll
  for (int i = 0; i < 2; ++i)
#pragma unroll
    for (int j = 0; j < 4; ++j) acc[i][j] = (f32x4){0.f, 0.f, 0.f, 0.f};

  for (int k0 = 0; k0 < 1088; k0 += 32) {
    {
      int c = tid;
      int row = c >> 2, seg = c & 3;
      int kk0 = k0 + seg * 8;
      const fp16* src = (kk0 < 1024) ? (A1 + (long long)row * CC + kk0)
                                     : (A2 + (long long)row * 64 + (kk0 - 1024));
      *(f16x8*)&As[row][seg * 8] = *(const f16x8*)src;
    }
#pragma unroll
    for (int i = 0; i < 2; ++i) {
      int c = tid + 256 * i;
      int n = c >> 2, seg = c & 3;
      int gn = n0 + n;
      int kk0 = k0 + seg * 8;
      const fp16* src = (kk0 < 1024) ? (B1 + (long long)gn * CC + kk0)
                                     : (B2 + (long long)gn * 64 + (kk0 - 1024));
      if (gn < NN) {
        *(f16x8*)&Bs[n][seg * 8] = *(const f16x8*)src;
      } else {
#pragma unroll
        for (int j = 0; j < 8; ++j) Bs[n][seg * 8 + j] = (fp16)0.f;
      }
    }
    __syncthreads();
    f16x8 af[2], bf[4];
#pragma unroll
    for (int wm = 0; wm < 2; ++wm)
      af[wm] = *(const f16x8*)&As[wr * 32 + wm * 16 + ln][quad * 8];
#pragma unroll
    for (int wn = 0; wn < 4; ++wn)
      bf[wn] = *(const f16x8*)&Bs[wc * 64 + wn * 16 + ln][quad * 8];
#pragma unroll
    for (int wm = 0; wm < 2; ++wm)
#pragma unroll
      for (int wn = 0; wn < 4; ++wn)
        acc[wm][wn] =
            __builtin_amdgcn_mfma_f32_16x16x32_f16(af[wm], bf[wn], acc[wm][wn], 0, 0, 0);
    __syncthreads();
  }
#pragma unroll
  for (int wm = 0; wm < 2; ++wm)
#pragma unroll
    for (int wn = 0; wn < 4; ++wn)
#pragma unroll
      for (int r = 0; r < 4; ++r) {
        int gm = wr * 32 + wm * 16 + quad * 4 + r;
        int gn = n0 + wc * 64 + wn * 16 + ln;
        if (gn < NN) {
          float v = acc[wm][wn][r] + teXb[gm] + seX[(long long)gn * 64 + gm];
          C[(long long)gm * NN + gn] = (fp16)v;
        }
      }
}

// ---------- ConvLSTM conv as MFMA ----------
__global__ __launch_bounds__(256) void k_conv_mfma(
    const fp16* __restrict__ Zf, const fp16* __restrict__ h,
    const fp16* __restrict__ wcat, fp16* __restrict__ gates, int p) {
  __shared__ fp16 As[128][40];
  __shared__ fp16 Bs[64][40];
  const int gm0 = blockIdx.x * 128, n0 = blockIdx.y * 64;
  const int tid = threadIdx.x;
  const int lane = tid & 63, wv = tid >> 6;
  const int wr = wv >> 1, wc = wv & 1;
  const int quad = lane >> 4, ln = lane & 15;
  f32x4 acc[4][2];
#pragma unroll
  for (int i = 0; i < 4; ++i)
#pragma unroll
    for (int j = 0; j < 2; ++j) acc[i][j] = (f32x4){0.f, 0.f, 0.f, 0.f};

  for (int kb = 0; kb < 36; ++kb) {
    const int srcsel = kb >= 18;
    const int tap = (kb >> 1) % 9;
    const int half = kb & 1;
    const int dy = tap / 3 - 1, dx = tap % 3 - 1;
#pragma unroll
    for (int i = 0; i < 2; ++i) {
      int c = tid + 256 * i;
      int row = c >> 2, seg = c & 3;
      int m = gm0 + row;
      int b = m >> 10;
      int y = (m >> 5) & 31, x = m & 31;
      int yy = y + dy, xx = x + dx;
      bool valid = ((unsigned)yy < 32u) && ((unsigned)xx < 32u);
      f16x8 v;
      if (valid) {
        long long cell = ((long long)b << 10) + (yy << 5) + xx;
        const fp16* sp =
            srcsel ? (h + cell * 64)
                   : (Zf + ((((long long)(b * PP + p)) << 10) + (yy << 5) + xx) * 64);
        v = *(const f16x8*)(sp + half * 32 + seg * 8);
      } else {
#pragma unroll
        for (int j = 0; j < 8; ++j) v[j] = (fp16)0.f;
      }
      *(f16x8*)&As[row][seg * 8] = v;
    }
    {
      int kk = kb * 32 + (tid & 31);
      int ngrp = tid >> 5;
      int n = n0 + ngrp * 8;
      f16x8 v = *(const f16x8*)(wcat + (long long)kk * 256 + n);
#pragma unroll
      for (int j = 0; j < 8; ++j) Bs[ngrp * 8 + j][tid & 31] = v[j];
    }
    __syncthreads();
    f16x8 af[4], bf[2];
#pragma unroll
    for (int wm = 0; wm < 4; ++wm)
      af[wm] = *(const f16x8*)&As[wr * 64 + wm * 16 + ln][quad * 8];
#pragma unroll
    for (int wn = 0; wn < 2; ++wn)
      bf[wn] = *(const f16x8*)&Bs[wc * 32 + wn * 16 + ln][quad * 8];
#pragma unroll
    for (int wm = 0; wm < 4; ++wm)
#pragma unroll
      for (int wn = 0; wn < 2; ++wn)
        acc[wm][wn] =
            __builtin_amdgcn_mfma_f32_16x16x32_f16(af[wm], bf[wn], acc[wm][wn], 0, 0, 0);
    __syncthreads();
  }
#pragma unroll
  for (int wm = 0; wm < 4; ++wm)
#pragma unroll
    for (int wn = 0; wn < 2; ++wn)
#pragma unroll
      for (int r = 0; r < 4; ++r) {
        int gm = gm0 + wr * 64 + wm * 16 + quad * 4 + r;
        int gn = n0 + wc * 32 + wn * 16 + ln;
        gates[(long long)gm * 256 + gn] = (fp16)acc[wm][wn][r];
      }
}

__global__ void k_clstm_update(const fp16* __restrict__ gates, float* __restrict__ c,
                               fp16* __restrict__ h, fp16* __restrict__ ZclT, int p) {
  long long i = (long long)blockIdx.x * 256 + threadIdx.x;
  if (i >= (long long)BB * CC * 64) return;
  int d = (int)(i & 63);
  long long bc = i >> 6;
  int b = (int)(bc >> 10);
  int cell = (int)(bc & 1023);
  const fp16* g = gates + (((long long)b * CC) + cell) * 256;
  float gi = (float)g[d], gf = (float)g[64 + d], gg = (float)g[128 + d],
        go = (float)g[192 + d];
  float hs_f = fminf(fmaxf(0.2f * gf + 0.5f, 0.f), 1.f);
  float hs_i = fminf(fmaxf(0.2f * gi + 0.5f, 0.f), 1.f);
  float hs_o = fminf(fmaxf(0.2f * go + 0.5f, 0.f), 1.f);
  float cv = hs_f * c[i] + hs_i * tanhf(gg);
  c[i] = cv;
  float hv = hs_o * tanhf(cv);
  h[i] = (fp16)hv;
  ZclT[(((long long)(b * PP + p)) * 64 + d) * CC + cell] = (fp16)hv;
}

__global__ void k_tmat(const float* __restrict__ X, const float* __restrict__ w1,
                       const float* __restrict__ b1, fp16* __restrict__ T, long long nrows) {
  long long i = (long long)blockIdx.x * 256 + threadIdx.x;
  if (i >= nrows * 64) return;
  int j = (int)(i & 63);
  long long row = i >> 6;
  T[i] = (fp16)fmaxf(X[row] * w1[j] + b1[j], 0.f);
}

// ---------- DCGRU elementwise ----------
// fill U0 x-rows (0..63) only; h rows 64..127 are live storage
__global__ void k_u0x(const fp16* __restrict__ ZXt, fp16* __restrict__ U0, int p) {
  long long i = (long long)blockIdx.x * 256 + threadIdx.x;
  if (i >= (long long)BB * 64 * (NN / 8)) return;
  int n8 = (int)(i % (NN / 8));
  int c = (int)((i / (NN / 8)) & 63);
  int b = (int)(i / ((NN / 8) * 64));
  f16x8 v = *(const f16x8*)(ZXt + ((((long long)(b * PP + p)) * 64 + c) * NN) + n8 * 8);
  *(f16x8*)(U0 + ((long long)b * 192 + c) * 2048 + n8 * 8) = v;
}

__global__ void k_trT(const fp16* __restrict__ U0, float* __restrict__ htmp) {
  long long i = (long long)blockIdx.x * 256 + threadIdx.x;
  if (i >= (long long)BB * NN * 64) return;
  int d = (int)(i & 63);
  long long bn = i >> 6;
  int b = (int)(bn / NN);
  int n = (int)(bn % NN);
  htmp[i] = (float)U0[((long long)b * 192 + 64 + d) * 2048 + n];
}

__global__ void k_out(const float* __restrict__ Y, float* __restrict__ out) {
  int i = blockIdx.x * 256 + threadIdx.x;
  if (i >= BB * QQ * NN) return;
  int n = i % NN;
  int bq = i / NN;
  int b = bq / QQ, q = bq % QQ;
  out[i] = Y[((long long)b * NN + n) * 12 + q];
}

// ---------- host helpers ----------
template <typename TA, typename TB, typename TC>
static void launch_gemm(hipStream_t stream, const TA* A, int lda, long long sA,
                        const TB* Bm, int ldb, long long sB, TC* Cm, int ldc, long long sC,
                        const TC* S, long long sS, const float* bias, int M, int Nc, int K,
                        float alpha, float beta, int act, int batch) {
  dim3 g((M + 63) / 64, (Nc + 63) / 64, batch);
  gemm_t<TA, TB, TC><<<g, dim3(256), 0, stream>>>(A, lda, sA, Bm, ldb, sB, Cm, ldc, sC, S,
                                                  sS, bias, M, Nc, K, alpha, beta, act);
}

extern "C" void kernel_launch(void* const* d_in, const int* in_sizes, int n_in,
                              void* d_out, int out_size, void* d_ws, size_t ws_size,
                              hipStream_t stream) {
  char* base = (char*)d_ws;
  size_t off = 0;
  auto alloc_bytes = [&](size_t nb) -> char* {
    char* p = base + off;
    off += (nb + 255) & ~(size_t)255;
    return p;
  };
  auto allocf = [&](size_t n) -> float* { return (float*)alloc_bytes(n * 4); };
  auto alloch = [&](size_t n) -> fp16* { return (fp16*)alloc_bytes(n * 2); };

  const float* X = (const float*)d_in[0];
  const float* Z = (const float*)d_in[1];
  const int* TE = (const int*)d_in[2];
  const float* adj_gg = (const float*)d_in[3];
  const float* adj_gr = (const float*)d_in[4];
  const float* gumbel = (const float*)d_in[5];
  const float* se_x = (const float*)d_in[6];
  const float* se_z = (const float*)d_in[7];
  const float* movement = (const float*)d_in[8];
  auto W = [&](int i) { return (const float*)d_in[i]; };

  // ---- allocations ----
  fp16* wcat = alloch(1152 * 256);
  fp16* gwT = alloch(128 * 512);
  fp16* cwT = alloch(64 * 512);
  fp16* w2T = alloch(64 * 64);
  fp16* w2mT = alloch(64 * 64);
  float* dinv = allocf(NN);
  fp16* LMall = alloch((size_t)6144 * 2048);  // rows padded to 2048 for maskless mfma4
  fp16* mZh = alloch((size_t)CC * CC);
  fp16* agh2 = alloch((size_t)NN * CC);
  float* seZ = allocf(CC * 64);
  float* teZ = allocf(BB * PP * 64);
  float* seX = allocf(NN * 64);
  float* teXb = allocf(BB * PP * 64);
  float* mtmp = allocf(NN * 64);
  float* tetmp = allocf(BB * PP * 64);
  fp16* ruT = alloch((size_t)BB * 128 * NN);  // [b][128][2000]
  // pool (50.33MB): U slabs 4x[16][192][2048] fp16; aliases conv gates/chh/ccc + Zmix/ZmovT
  char* pool = alloc_bytes(50331648);
  fp16* Uall = (fp16*)pool;
  fp16* gates = (fp16*)pool;
  fp16* chh = (fp16*)(pool + 8388608);
  float* ccc = (float*)(pool + 12582912);
  fp16* Zmix = (fp16*)pool;
  fp16* ZmovT = (fp16*)(pool + 25165824);
  // zpool: Zf [bp][1024][64] then ZXt [bp][64][2000]
  fp16* zpool = alloch((size_t)BB * PP * NN * 64);
  fp16* Zf = zpool;
  fp16* ZXt = zpool;
  fp16* Zc = alloch((size_t)BB * PP * CC * 64);  // zf1 scratch -> ZclT -> Tmat -> head scratch

  if (off > ws_size) return;

  const long long uB = 192LL * 2048;
  const long long USL = 16LL * uB;
  fp16* Lh = LMall;
  fp16* M2h = LMall + 2048LL * 2048;
  fp16* M3h = LMall + 4096LL * 2048;

  // ---- precompute ----
  k_f2h<<<dim3(576), dim3(256), 0, stream>>>(wcat, W(39), 576 * 256);
  k_f2h<<<dim3(576), dim3(256), 0, stream>>>(wcat + 576 * 256, W(40), 576 * 256);
  k_gru_repackT<<<dim3(256), dim3(256), 0, stream>>>(gwT, W(41), 128);
  k_gru_repackT<<<dim3(128), dim3(256), 0, stream>>>(cwT, W(43), 64);
  k_w2T<<<dim3(16), dim3(256), 0, stream>>>(w2T, W(31));
  k_w2T<<<dim3(16), dim3(256), 0, stream>>>(w2mT, W(33));
  k_dinv<<<dim3(NN), dim3(256), 0, stream>>>(adj_gg, dinv);
  hipMemsetAsync(LMall, 0, (size_t)6144 * 2048 * 2, stream);
  k_L<<<dim3((NN * NN + 255) / 256), dim3(256), 0, stream>>>(adj_gg, dinv, Lh);
  mfma3<128, 128><<<dim3(16, 16, 1), dim3(256), 0, stream>>>(
      Lh, 2048, 0LL, 31, 0LL, Lh, 2048, 0LL, M2h, 2048, 0LL, 31, 0LL, 31, 0LL,
      (const fp16*)nullptr, 0LL, 0.f, nullptr, 0LL, nullptr, 0, NN, NN, NN, 2.f, 0);
  k_subdiag<<<dim3((NN + 255) / 256), dim3(256), 0, stream>>>(M2h);
  mfma3<128, 128><<<dim3(16, 16, 1), dim3(256), 0, stream>>>(
      Lh, 2048, 0LL, 31, 0LL, M2h, 2048, 0LL, M3h, 2048, 0LL, 31, 0LL, 31, 0LL,
      (const fp16*)Lh, 0LL, -1.f, nullptr, 0LL, nullptr, 0, NN, NN, NN, 2.f, 0);
  k_gumbel_softmax<<<dim3(CC), dim3(256), 0, stream>>>(movement, gumbel, mZh);
  k_f2h<<<dim3((NN * CC + 255) / 256), dim3(256), 0, stream>>>(agh2, adj_gr,
                                                               (long long)NN * CC);

  // ---- STEZ / STEX ----
  launch_gemm(stream, se_z, 64, 0LL, W(17), 64, 0LL, mtmp, 64, 0LL, (float*)nullptr, 0LL,
              W(18), CC, 64, 64, 1.f, 0.f, 1, 1);
  launch_gemm(stream, (const float*)mtmp, 64, 0LL, W(19), 64, 0LL, seZ, 64, 0LL,
              (float*)nullptr, 0LL, W(20), CC, 64, 64, 1.f, 0.f, 0, 1);
  k_te<<<dim3((BB * PP * 64 + 255) / 256), dim3(256), 0, stream>>>(TE, W(21), W(22), tetmp);
  launch_gemm(stream, (const float*)tetmp, 64, 0LL, W(23), 64, 0LL, teZ, 64, 0LL,
              (float*)nullptr, 0LL, W(24), BB * PP, 64, 64, 1.f, 0.f, 0, 1);
  launch_gemm(stream, se_x, 64, 0LL, W(9), 64, 0LL, mtmp, 64, 0LL, (float*)nullptr, 0LL,
              W(10), NN, 64, 64, 1.f, 0.f, 1, 1);
  launch_gemm(stream, (const float*)mtmp, 64, 0LL, W(11), 64, 0LL, seX, 64, 0LL,
              (float*)nullptr, 0LL, W(12), NN, 64, 64, 1.f, 0.f, 0, 1);
  k_te<<<dim3((BB * PP * 64 + 255) / 256), dim3(256), 0, stream>>>(TE, W(13), W(14), tetmp);
  launch_gemm(stream, (const float*)tetmp, 64, 0LL, W(15), 64, 0LL, teXb, 64, 0LL,
              (float*)nullptr, 0LL, W(16), BB * PP, 64, 64, 1.f, 0.f, 0, 1);
  k_addb<<<dim3((BB * PP * 64 + 255) / 256), dim3(256), 0, stream>>>(teXb, W(32),
                                                                     BB * PP * 64);

  // ---- Zf = mlp2(Z) + STEZ ----
  long long nZ = (long long)BB * PP * CC * 64;
  k_zf1<<<dim3((int)((nZ + 255) / 256)), dim3(256), 0, stream>>>(Z, W(25), W(26), Zc);
  launch_gemm(stream, (const fp16*)Zc, 64, 0LL, W(27), 64, 0LL, Zf, 64, 0LL,
              (fp16*)nullptr, 0LL, W(28), BB * PP * CC, 64, 64, 1.f, 0.f, 0, 1);
  k_add_stez<<<dim3((int)((nZ + 255) / 256)), dim3(256), 0, stream>>>(Zf, seZ, teZ);

  // ---- ConvLSTM (writes ZclT into Zc) ----
  hipMemsetAsync(chh, 0, (size_t)BB * CC * 64 * 2, stream);
  hipMemsetAsync(ccc, 0, (size_t)BB * CC * 64 * 4, stream);
  for (int p = 0; p < PP; ++p) {
    k_conv_mfma<<<dim3(BB * CC / 128, 4), dim3(256), 0, stream>>>(Zf, chh, wcat, gates, p);
    k_clstm_update<<<dim3((int)(((long long)BB * CC * 64 + 255) / 256)), dim3(256), 0,
                     stream>>>(gates, ccc, chh, Zc, p);
  }

  // ---- movement m1/m2 ----
  mfma3<128, 64><<<dim3(8, 1, 192), dim3(256), 0, stream>>>(
      mZh, CC, 0LL, 31, 0LL, (const fp16*)Zc, CC, (long long)64 * CC, Zmix, 64,
      (long long)CC * 64, 31, 0LL, 31, 0LL, (const fp16*)nullptr, 0LL, 0.f, nullptr, 0LL,
      nullptr, 0, CC, 64, CC, 1.f, 0);
  mfma3<64, 128><<<dim3(1, 8, 192), dim3(256), 0, stream>>>(
      w2mT, 64, 0LL, 31, 0LL, Zmix, 64, (long long)CC * 64, ZmovT, CC, (long long)64 * CC,
      31, 0LL, 31, 0LL, (const fp16*)nullptr, 0LL, 0.f, W(34), 0LL, nullptr, 0, 64, CC, 64,
      1.f, 1);

  // ---- merged m3+Tmat (fixed WN=4 k_zxt; two z-halves, Tmat in dead Zc) ----
  fp16* Tmat = Zc;
  for (int half = 0; half < 2; ++half) {
    long long z0 = 96LL * half;
    k_tmat<<<dim3((int)((96LL * NN * 64 + 255) / 256)), dim3(256), 0, stream>>>(
        X + z0 * NN, W(29), W(30), Tmat, 96LL * NN);
    k_zxt<<<dim3(1, 16, 96), dim3(256), 0, stream>>>(
        ZmovT + z0 * 64 * CC, agh2, w2T, Tmat, ZXt + z0 * 64 * NN, teXb + z0 * 64, seX);
  }

  // ---- DCGRU (fused epilogues; h lives in U0 rows 64..127) ----
  // chain GEMMs run maskless at K=2048 (U-slab rows and LMall rows zero-padded)
  fp16* U0 = Uall;
  fp16* U1 = Uall + USL;
  hipMemsetAsync(U0, 0, (size_t)USL * 2, stream);  // zero slab 0 (incl. K pad cols)
  const long long nU0x = (long long)BB * 64 * (NN / 8);
  for (int p = 0; p < PP; ++p) {
    // U0 x-rows <- ZXt_p ; h rows 64..127 hold h_{p-1}
    k_u0x<<<dim3((int)((nU0x + 255) / 256)), dim3(256), 0, stream>>>(ZXt, U0, p);
    // gate+h chain: [T1|T2|T3](rows 0..127) = U0[x|h] @ [L|M2|M3]  (mfma4, K=2048)
    mfma4<128, 128><<<dim3(16, 48), dim3(256), 0, stream>>>(
        U0, 2048, 7, uB, LMall, 2048, U1, 2048, 7, uB, 11, USL, 2048);
    // ruT = sigmoid(gwT @ chebs); epilogue writes rh = r*h into U0 rows 128..191
    mfma2<128, 1><<<dim3(1, 32, BB), dim3(256), 0, stream>>>(
        gwT, 512, Uall, 2048, uB, 7, USL, 0, ruT, NN, (long long)128 * NN, W(42),
        U0 + 128 * 2048, U0 + 64 * 2048, uB, (const fp16*)nullptr, 0LL, 128, NN, 512, 1.f);
    // cand rh chain -> U1..U3 rows 128..191  (mfma4, K=2048)
    mfma4<64, 128><<<dim3(16, 48), dim3(256), 0, stream>>>(
        U0 + 128 * 2048, 2048, 6, uB, LMall, 2048, U1 + 128 * 2048, 2048, 6, uB, 11, USL,
        2048);
    // cnd GEMM; epilogue does h' = u*h + (1-u)*tanh(v) in place in U0 rows 64..127
    mfma2<64, 2><<<dim3(1, 32, BB), dim3(256), 0, stream>>>(
        cwT, 512, Uall, 2048, uB, 7, USL, 64, U0 + 64 * 2048, 2048, uB, W(44),
        (fp16*)nullptr, (const fp16*)nullptr, 0LL, (const fp16*)ruT, (long long)128 * NN,
        64, NN, 512, 1.f);
  }

  // ---- output head (all scratch in dead Zc; U0 untouched until read) ----
  float* htmp = (float*)Zc;                       // 8.19 MB
  float* out1 = (float*)(Zc + 5120000);           // byte 10.24 MB, 8.19 MB
  float* out2 = (float*)(Zc + 10240000);          // byte 20.48 MB, 1.54 MB
  k_trT<<<dim3((int)(((long long)BB * NN * 64 + 255) / 256)), dim3(256), 0, stream>>>(U0,
                                                                                      htmp);
  launch_gemm(stream, (const float*)htmp, 64, 0LL, W(35), 64, 0LL, out1, 64, 0LL,
              (float*)nullptr, 0LL, W(36), BB * NN, 64, 64, 1.f, 0.f, 1, 1);
  launch_gemm(stream, (const float*)out1, 64, 0LL, W(37), 12, 0LL, out2, 12, 0LL,
              (float*)nullptr, 0LL, W(38), BB * NN, 12, 64, 1.f, 0.f, 0, 1);
  k_out<<<dim3((BB * QQ * NN + 255) / 256), dim3(256), 0, stream>>>(out2, (float*)d_out);
}

// Round 2
// 3314.391 us; speedup vs baseline: 1.6085x; 1.0522x over previous
//
#include <hip/hip_runtime.h>
#include <hip/hip_bf16.h>
#include <math.h>

typedef _Float16 fp16;
typedef _Float16 f16x8 __attribute__((ext_vector_type(8)));
typedef float f32x4 __attribute__((ext_vector_type(4)));

#define BB 16
#define PP 12
#define QQ 12
#define NN 2000
#define CC 1024

static __device__ __forceinline__ float ldf(float v) { return v; }
static __device__ __forceinline__ float ldf(fp16 v) { return (float)v; }
static __device__ __forceinline__ void stf(float* p, float v) { *p = v; }
static __device__ __forceinline__ void stf(fp16* p, float v) { *p = (fp16)v; }

// async global->LDS, 16B per lane (wave-uniform LDS base + lane*16)
static __device__ __forceinline__ void gload_lds16(const fp16* g, fp16* l) {
  __builtin_amdgcn_global_load_lds(
      (const __attribute__((address_space(1))) void*)g,
      (__attribute__((address_space(3))) void*)l, 16, 0, 0);
}

// ---------- conversions / repacks ----------
__global__ void k_f2h(fp16* __restrict__ dst, const float* __restrict__ src, long long n) {
  long long i = (long long)blockIdx.x * 256 + threadIdx.x;
  if (i < n) dst[i] = (fp16)src[i];
}

// wcatT[n][kk] = wcat[kk][n], kk<576 from W39, else W40 (each [576][256])
__global__ void k_wcatT(fp16* __restrict__ dst, const float* __restrict__ w39,
                        const float* __restrict__ w40) {
  int i = blockIdx.x * 256 + threadIdx.x;
  if (i >= 1152 * 256) return;
  int n = i & 255, kk = i >> 8;
  float v = (kk < 576) ? w39[kk * 256 + n] : w40[(kk - 576) * 256 + n];
  dst[(long long)n * 1152 + kk] = (fp16)v;
}

// dcgru weights (512,O): row=f*4+t -> Wt[d][t*128+c] = src[(c*4+t)*O+d]
__global__ void k_gru_repackT(fp16* __restrict__ dst, const float* __restrict__ src, int O) {
  int i = blockIdx.x * 256 + threadIdx.x;
  if (i >= O * 512) return;
  int d = i >> 9;
  int kc = i & 511;
  int t = kc >> 7;
  int c = kc & 127;
  dst[i] = (fp16)src[(c * 4 + t) * O + d];
}

// (64,64) -> T[d][k] fp16
__global__ void k_w2T(fp16* __restrict__ dst, const float* __restrict__ src) {
  int i = blockIdx.x * 256 + threadIdx.x;
  if (i >= 4096) return;
  int d = i >> 6, k = i & 63;
  dst[i] = (fp16)src[k * 64 + d];
}

// ---------- laplacian ----------
__global__ void k_dinv(const float* __restrict__ adj, float* __restrict__ dinv) {
  int row = blockIdx.x;
  float s = 0.f;
  for (int j = threadIdx.x; j < NN; j += 256)
    s += fmaxf(adj[(long long)row * NN + j], adj[(long long)j * NN + row]);
  __shared__ float red[256];
  red[threadIdx.x] = s;
  __syncthreads();
  for (int st = 128; st > 0; st >>= 1) {
    if (threadIdx.x < st) red[threadIdx.x] += red[threadIdx.x + st];
    __syncthreads();
  }
  if (threadIdx.x == 0) {
    float d = red[0];
    dinv[row] = d > 0.f ? 1.0f / sqrtf(d) : 0.f;
  }
}

// writes L with row stride 2048 (zero-padded for maskless mfma4)
__global__ void k_L(const float* __restrict__ adj, const float* __restrict__ dinv,
                    fp16* __restrict__ Lh) {
  long long i = (long long)blockIdx.x * 256 + threadIdx.x;
  if (i >= (long long)NN * NN) return;
  int r = (int)(i / NN), c = (int)(i % NN);
  float a = fmaxf(adj[(long long)r * NN + c], adj[(long long)c * NN + r]);
  Lh[(long long)r * 2048 + c] = (fp16)(-dinv[r] * a * dinv[c]);
}

__global__ void k_subdiag(fp16* __restrict__ M2) {
  int i = blockIdx.x * 256 + threadIdx.x;
  if (i >= NN) return;
  M2[(long long)i * 2048 + i] = (fp16)((float)M2[(long long)i * 2048 + i] - 1.0f);
}

// ---------- gumbel softmax -> fp16 ----------
__global__ void k_gumbel_softmax(const float* __restrict__ ml, const float* __restrict__ gn,
                                 fp16* __restrict__ mZ) {
  int row = blockIdx.x;
  __shared__ float buf[CC];
  __shared__ float red[256];
  int t = threadIdx.x;
  float mx = -1e30f;
  for (int j = t; j < CC; j += 256) {
    float u = gn[(long long)row * CC + j];
    float g = -logf(-logf(u + 1e-20f) + 1e-20f);
    float v = ml[(long long)row * CC + j] + g;
    buf[j] = v;
    mx = fmaxf(mx, v);
  }
  red[t] = mx;
  __syncthreads();
  for (int st = 128; st > 0; st >>= 1) {
    if (t < st) red[t] = fmaxf(red[t], red[t + st]);
    __syncthreads();
  }
  mx = red[0];
  __syncthreads();
  float s = 0.f;
  for (int j = t; j < CC; j += 256) {
    float e = expf(buf[j] - mx);
    buf[j] = e;
    s += e;
  }
  red[t] = s;
  __syncthreads();
  for (int st = 128; st > 0; st >>= 1) {
    if (t < st) red[t] += red[t + st];
    __syncthreads();
  }
  float inv = 1.0f / red[0];
  for (int j = t; j < CC; j += 256) mZ[(long long)row * CC + j] = (fp16)(buf[j] * inv);
}

__global__ void k_te(const int* __restrict__ TE, const float* __restrict__ w1,
                     const float* __restrict__ b1, float* __restrict__ tmp) {
  int i = blockIdx.x * 256 + threadIdx.x;
  if (i >= BB * PP * 64) return;
  int j = i & 63;
  int bp = i >> 6;
  int b = bp / PP, p = bp % PP;
  int te0 = TE[(b * (PP + QQ) + p) * 2 + 0];
  int te1 = TE[(b * (PP + QQ) + p) * 2 + 1];
  float v = w1[te0 * 64 + j] + w1[(7 + te1) * 64 + j] + b1[j];
  tmp[i] = fmaxf(v, 0.f);
}

__global__ void k_addb(float* __restrict__ dst, const float* __restrict__ b, int n) {
  int i = blockIdx.x * 256 + threadIdx.x;
  if (i < n) dst[i] += b[i & 63];
}

__global__ void k_zf1(const float* __restrict__ Z, const float* __restrict__ w1,
                      const float* __restrict__ b1, fp16* __restrict__ tmp) {
  long long i = (long long)blockIdx.x * 256 + threadIdx.x;
  if (i >= (long long)BB * PP * CC * 64) return;
  int j = (int)(i & 63);
  long long row = i >> 6;
  float v = Z[row * 2 + 0] * w1[j] + Z[row * 2 + 1] * w1[64 + j] + b1[j];
  tmp[i] = (fp16)fmaxf(v, 0.f);
}

__global__ void k_add_stez(fp16* __restrict__ Zf, const float* __restrict__ seZ,
                           const float* __restrict__ teZ) {
  long long i = (long long)blockIdx.x * 256 + threadIdx.x;
  if (i >= (long long)BB * PP * CC * 64) return;
  int j = (int)(i & 63);
  long long row = i >> 6;
  int c = (int)(row % CC);
  int bp = (int)(row / CC);
  Zf[i] = (fp16)((float)Zf[i] + seZ[c * 64 + j] + teZ[bp * 64 + j]);
}

// ---------- generic fp32-path GEMM (small ops) ----------
template <typename TA, typename TB, typename TC>
__global__ __launch_bounds__(256) void gemm_t(
    const TA* __restrict__ A, int lda, long long sA,
    const TB* __restrict__ Bm, int ldb, long long sB,
    TC* Cm, int ldc, long long sC,
    const TC* S, long long sS,
    const float* __restrict__ bias,
    int M, int Ncols, int K, float alpha, float beta, int act) {
  int bz = blockIdx.z;
  A += (long long)bz * sA;
  Bm += (long long)bz * sB;
  Cm += (long long)bz * sC;
  if (S) S += (long long)bz * sS;
  const int row0 = blockIdx.x * 64, col0 = blockIdx.y * 64;
  __shared__ float As[16][68];
  __shared__ float Bs[16][68];
  int tid = threadIdx.x, tx = tid & 15, ty = tid >> 4;
  float acc[4][4] = {};
  for (int k0 = 0; k0 < K; k0 += 16) {
#pragma unroll
    for (int j = 0; j < 4; ++j) {
      int e = tid + 256 * j;
      int m = e >> 4, kk = e & 15;
      int gm = row0 + m;
      As[kk][m] = (gm < M) ? ldf(A[(long long)gm * lda + k0 + kk]) : 0.f;
    }
#pragma unroll
    for (int j = 0; j < 4; ++j) {
      int e = tid + 256 * j;
      int kk = e >> 6, n = e & 63;
      int gn = col0 + n;
      Bs[kk][n] = (gn < Ncols) ? ldf(Bm[(long long)(k0 + kk) * ldb + gn]) : 0.f;
    }
    __syncthreads();
#pragma unroll
    for (int kk = 0; kk < 16; ++kk) {
      float a[4], bb[4];
#pragma unroll
      for (int i = 0; i < 4; ++i) a[i] = As[kk][ty * 4 + i];
#pragma unroll
      for (int j = 0; j < 4; ++j) bb[j] = Bs[kk][tx * 4 + j];
#pragma unroll
      for (int i = 0; i < 4; ++i)
#pragma unroll
        for (int j = 0; j < 4; ++j) acc[i][j] = fmaf(a[i], bb[j], acc[i][j]);
    }
    __syncthreads();
  }
#pragma unroll
  for (int i = 0; i < 4; ++i) {
    int r = row0 + ty * 4 + i;
    if (r >= M) continue;
#pragma unroll
    for (int j = 0; j < 4; ++j) {
      int cn = col0 + tx * 4 + j;
      if (cn >= Ncols) continue;
      float v = alpha * acc[i][j];
      if (bias) v += bias[cn];
      if (S) v += beta * ldf(S[(long long)r * ldc + cn]);
      if (act == 1) v = fmaxf(v, 0.f);
      else if (act == 2) v = 1.f / (1.f + expf(-v));
      else if (act == 3) v = tanhf(v);
      stf(&Cm[(long long)r * ldc + cn], v);
    }
  }
}

// ---------- mfma2: DCGRU weight GEMMs with fused GRU epilogues ----------
// MODE 1 (ru):  C=ruT [z][128][NN]; sigmoid; rows<64 also write rh=r*h into rhOut
// MODE 2 (cnd): tanh; h' = u*h + (1-u)*v written in-place into C (=U0 h-rows)
// xB: if non-null, slab-0 cols<64 (the x features) are read from xB (ZXt, ld=2048)
template <int MT, int MODE>
__global__ __launch_bounds__(256) void mfma2(
    const fp16* __restrict__ A, int lda,
    const fp16* __restrict__ B, int ldb, long long bBatch, int bShift, long long bSlab,
    int bHi,
    fp16* __restrict__ C, int ldc, long long cBatch,
    const float* __restrict__ bias,
    fp16* __restrict__ rhOut, const fp16* __restrict__ hIn, long long xStride,
    const fp16* __restrict__ uIn, long long uStride,
    const fp16* __restrict__ xB, long long xZ,
    int M, int Ncols, int K, float alpha) {
  __shared__ fp16 As[MT][40];
  __shared__ fp16 Bs[64][40];
  const int z = blockIdx.z;
  const int gm0 = blockIdx.x * MT, n0 = blockIdx.y * 64;
  B += (long long)z * bBatch;
  C += (long long)z * cBatch;
  if (rhOut) rhOut += (long long)z * xStride;
  if (hIn) hIn += (long long)z * xStride;
  if (uIn) uIn += (long long)z * uStride;
  if (xB) xB += (long long)z * xZ;
  const int tid = threadIdx.x;
  const int lane = tid & 63, wv = tid >> 6;
  const int wr = wv >> 1, wc = wv & 1;
  const int quad = lane >> 4, ln = lane & 15;
  const unsigned bMask = (1u << bShift) - 1u;
  constexpr int WM = MT / 32;
  f32x4 acc[WM][2];
#pragma unroll
  for (int i = 0; i < WM; ++i)
#pragma unroll
    for (int j = 0; j < 2; ++j) acc[i][j] = (f32x4){0.f, 0.f, 0.f, 0.f};

  for (int k0 = 0; k0 < K; k0 += 32) {
#pragma unroll
    for (int i = 0; i < MT / 64; ++i) {
      int c = tid + 256 * i;
      int row = c >> 2, seg = c & 3;
      int gm = gm0 + row;
      int kk0 = k0 + seg * 8;
      const fp16* src = A + (long long)gm * lda + kk0;
      if (gm < M && kk0 + 8 <= K) {
        *(f16x8*)&As[row][seg * 8] = *(const f16x8*)src;
      } else {
#pragma unroll
        for (int j = 0; j < 8; ++j)
          As[row][seg * 8 + j] = (gm < M && kk0 + j < K) ? src[j] : (fp16)0.f;
      }
    }
    {
      int kk = k0 + (tid & 31);
      int ngrp = tid >> 5;
      int slab = (int)((unsigned)kk >> bShift);
      int kin = (int)((unsigned)kk & bMask);
      int col = kin + (kin >= 64 ? bHi : 0);
      int n = n0 + ngrp * 8;
      const fp16* src;
      if (xB && slab == 0 && kin < 64)
        src = xB + (long long)kin * 2048 + n;
      else
        src = B + (long long)slab * bSlab + (long long)col * ldb + n;
      if (kk < K && n + 8 <= Ncols) {
        f16x8 v = *(const f16x8*)src;
#pragma unroll
        for (int j = 0; j < 8; ++j) Bs[ngrp * 8 + j][tid & 31] = v[j];
      } else {
#pragma unroll
        for (int j = 0; j < 8; ++j)
          Bs[ngrp * 8 + j][tid & 31] = (kk < K && n + j < Ncols) ? src[j] : (fp16)0.f;
      }
    }
    __syncthreads();
    f16x8 af[WM], bf[2];
#pragma unroll
    for (int wm = 0; wm < WM; ++wm)
      af[wm] = *(const f16x8*)&As[wr * (MT / 2) + wm * 16 + ln][quad * 8];
#pragma unroll
    for (int wn = 0; wn < 2; ++wn)
      bf[wn] = *(const f16x8*)&Bs[wc * 32 + wn * 16 + ln][quad * 8];
#pragma unroll
    for (int wm = 0; wm < WM; ++wm)
#pragma unroll
      for (int wn = 0; wn < 2; ++wn)
        acc[wm][wn] =
            __builtin_amdgcn_mfma_f32_16x16x32_f16(af[wm], bf[wn], acc[wm][wn], 0, 0, 0);
    __syncthreads();
  }
#pragma unroll
  for (int wm = 0; wm < WM; ++wm) {
#pragma unroll
    for (int wn = 0; wn < 2; ++wn) {
#pragma unroll
      for (int r = 0; r < 4; ++r) {
        int gm = gm0 + wr * (MT / 2) + wm * 16 + quad * 4 + r;
        int gn = n0 + wc * 32 + wn * 16 + ln;
        if (gm < M && gn < Ncols) {
          float v = alpha * acc[wm][wn][r];
          v += bias[gm];
          if (MODE == 1) {
            v = 1.f / (1.f + expf(-v));  // sigmoid
            C[(long long)gm * ldc + gn] = (fp16)v;
            if (gm < 64) {
              float h = (float)hIn[(long long)gm * 2048 + gn];
              rhOut[(long long)gm * 2048 + gn] = (fp16)(v * h);
            }
          } else {
            v = tanhf(v);
            float u = (float)uIn[(long long)(64 + gm) * NN + gn];
            long long ci = (long long)gm * ldc + gn;
            float h = (float)C[ci];
            C[ci] = (fp16)(u * h + (1.f - u) * v);
          }
        }
      }
    }
  }
}

// ---------- mfma3: all-b128 GEMM (kept for movement m2) ----------
template <int MT, int NT>
__global__ __launch_bounds__(256) void mfma3(
    const fp16* __restrict__ A, int lda, long long zA, int aMsh, long long aMslab,
    const fp16* __restrict__ B, int ldb, long long zB,
    fp16* __restrict__ C, int ldc, long long zC, int cMsh, long long cMslab, int cNsh,
    long long cNslab,
    const fp16* __restrict__ S, long long zS, float beta,
    const float* __restrict__ rowBias, long long zRB,
    const float* __restrict__ s2T, int s2ld,
    int M, int Ncols, int K, float alpha, int act) {
  __shared__ fp16 As[MT][40];
  __shared__ fp16 Bs[NT][40];
  const int z = blockIdx.z;
  const int gm0 = blockIdx.x * MT, n0 = blockIdx.y * NT;
  A += (long long)z * zA;
  B += (long long)z * zB;
  C += (long long)z * zC;
  if (S) S += (long long)z * zS;
  const int tid = threadIdx.x;
  const int lane = tid & 63, wv = tid >> 6;
  const int wr = wv >> 1, wc = wv & 1;
  const int quad = lane >> 4, ln = lane & 15;
  const unsigned aMmask = (1u << aMsh) - 1u;
  const unsigned cMmask = (1u << cMsh) - 1u;
  const unsigned cNmask = (1u << cNsh) - 1u;
  constexpr int WM = MT / 32, WN = NT / 32;
  f32x4 acc[WM][WN];
#pragma unroll
  for (int i = 0; i < WM; ++i)
#pragma unroll
    for (int j = 0; j < WN; ++j) acc[i][j] = (f32x4){0.f, 0.f, 0.f, 0.f};

  for (int k0 = 0; k0 < K; k0 += 32) {
#pragma unroll
    for (int i = 0; i < MT / 64; ++i) {
      int c = tid + 256 * i;
      int row = c >> 2, seg = c & 3;
      int gm = gm0 + row;
      int kk0 = k0 + seg * 8;
      const fp16* src = A + ((long long)((unsigned)gm >> aMsh)) * aMslab +
                        (long long)(gm & aMmask) * lda + kk0;
      if (gm < M && kk0 + 8 <= K) {
        *(f16x8*)&As[row][seg * 8] = *(const f16x8*)src;
      } else {
#pragma unroll
        for (int j = 0; j < 8; ++j)
          As[row][seg * 8 + j] = (gm < M && kk0 + j < K) ? src[j] : (fp16)0.f;
      }
    }
#pragma unroll
    for (int i = 0; i < NT / 64; ++i) {
      int c = tid + 256 * i;
      int n = c >> 2, seg = c & 3;
      int gn = n0 + n;
      int kk0 = k0 + seg * 8;
      const fp16* src = B + (long long)gn * ldb + kk0;
      if (gn < Ncols && kk0 + 8 <= K) {
        *(f16x8*)&Bs[n][seg * 8] = *(const f16x8*)src;
      } else {
#pragma unroll
        for (int j = 0; j < 8; ++j)
          Bs[n][seg * 8 + j] = (gn < Ncols && kk0 + j < K) ? src[j] : (fp16)0.f;
      }
    }
    __syncthreads();
    f16x8 af[WM], bf[WN];
#pragma unroll
    for (int wm = 0; wm < WM; ++wm)
      af[wm] = *(const f16x8*)&As[wr * (MT / 2) + wm * 16 + ln][quad * 8];
#pragma unroll
    for (int wn = 0; wn < WN; ++wn)
      bf[wn] = *(const f16x8*)&Bs[wc * (NT / 2) + wn * 16 + ln][quad * 8];
#pragma unroll
    for (int wm = 0; wm < WM; ++wm)
#pragma unroll
      for (int wn = 0; wn < WN; ++wn)
        acc[wm][wn] =
            __builtin_amdgcn_mfma_f32_16x16x32_f16(af[wm], bf[wn], acc[wm][wn], 0, 0, 0);
    __syncthreads();
  }
#pragma unroll
  for (int wm = 0; wm < WM; ++wm) {
#pragma unroll
    for (int wn = 0; wn < WN; ++wn) {
#pragma unroll
      for (int r = 0; r < 4; ++r) {
        int gm = gm0 + wr * (MT / 2) + wm * 16 + quad * 4 + r;
        int gn = n0 + wc * (NT / 2) + wn * 16 + ln;
        if (gm < M && gn < Ncols) {
          float v = alpha * acc[wm][wn][r];
          if (rowBias) v += rowBias[(long long)z * zRB + gm];
          if (s2T) v += s2T[(long long)gn * s2ld + gm];
          long long ci = ((long long)((unsigned)gm >> cMsh)) * cMslab +
                         (long long)(gm & cMmask) * ldc +
                         ((long long)((unsigned)gn >> cNsh)) * cNslab + (gn & cNmask);
          if (S) v += beta * (float)S[ci];
          if (act == 1) v = fmaxf(v, 0.f);
          else if (act == 2) v = 1.f / (1.f + expf(-v));
          else if (act == 3) v = tanhf(v);
          C[ci] = (fp16)v;
        }
      }
    }
  }
}

// ---------- mfma4: maskless gload_lds GEMM, dual-base A descriptor ----------
// Requirements: M % MT == 0, Ncols % NT == 0, K % 32 == 0, rows readable for
// full K (zero-padded), 16B-aligned rows.
// A row gm: b = gm>>rsh; wi = gm & mask(rsh); sel = wi>>ssh; r = wi & mask(ssh);
//   addr = (sel ? base1 + b*z1 : base0 + b*z0) + r*lda
// Epilogue: C = alpha*acc + beta*S (S optional, same ci mapping).
template <int MT, int NT>
__global__ __launch_bounds__(256) void mfma4(
    const fp16* __restrict__ base0, const fp16* __restrict__ base1, int rsh, int ssh,
    long long z0, long long z1, int lda,
    const fp16* __restrict__ B, int ldb, long long zB,
    fp16* __restrict__ C, int ldc, long long zC, int cMsh, long long cMslab, int cNsh,
    long long cNslab,
    const fp16* __restrict__ S, float alpha, float beta, int K) {
  __shared__ fp16 As[2][MT * 32];
  __shared__ fp16 Bs[2][NT * 32];
  const int tid = threadIdx.x;
  const int z = blockIdx.z;
  const int gm0 = blockIdx.x * MT, n0 = blockIdx.y * NT;
  B += (long long)z * zB;
  C += (long long)z * zC;
  if (S) S += (long long)z * zC;
  const unsigned cMmask = (1u << cMsh) - 1u;
  const unsigned cNmask = (1u << cNsh) - 1u;
  const int lane = tid & 63, wv = tid >> 6;
  const int wr = wv >> 1, wc = wv & 1;
  const int quad = lane >> 4, ln = lane & 15;
  constexpr int WM = MT / 32, WN = NT / 32;

  // per-thread staging source bases (seg pre-swizzled so linear LDS slot c
  // holds logical (row=c>>2, seg=(c&3)^(row&3)))
  const fp16* aSrc[MT / 64];
  const fp16* bSrc[NT / 64];
#pragma unroll
  for (int i = 0; i < MT / 64; ++i) {
    int c = i * 256 + tid;
    int row = c >> 2;
    int lseg = (c & 3) ^ (row & 3);
    int gm = gm0 + row;
    unsigned b = (unsigned)gm >> rsh;
    unsigned wi = (unsigned)gm & ((1u << rsh) - 1u);
    unsigned sel = wi >> ssh;
    unsigned r = wi & ((1u << ssh) - 1u);
    const fp16* ab = sel ? (base1 + (long long)b * z1) : (base0 + (long long)b * z0);
    aSrc[i] = ab + (long long)r * lda + lseg * 8;
  }
#pragma unroll
  for (int i = 0; i < NT / 64; ++i) {
    int c = i * 256 + tid;
    int row = c >> 2;
    int lseg = (c & 3) ^ (row & 3);
    bSrc[i] = B + (long long)(n0 + row) * ldb + lseg * 8;
  }

  f32x4 acc[WM][WN];
#pragma unroll
  for (int i = 0; i < WM; ++i)
#pragma unroll
    for (int j = 0; j < WN; ++j) acc[i][j] = (f32x4){0.f, 0.f, 0.f, 0.f};

  const int sw = (quad ^ (ln & 3)) << 3;  // swizzled 8-elem slot for ds_read

  // prologue: stage tile 0 into buf 0
#pragma unroll
  for (int i = 0; i < MT / 64; ++i) gload_lds16(aSrc[i], &As[0][(i * 256 + tid) * 8]);
#pragma unroll
  for (int i = 0; i < NT / 64; ++i) gload_lds16(bSrc[i], &Bs[0][(i * 256 + tid) * 8]);

  const int nk = K >> 5;
  for (int t = 0; t < nk; ++t) {
    const int buf = t & 1;
    __syncthreads();  // drains vmcnt(0): tile t landed; prior reads of buf^1 done
    if (t + 1 < nk) {
      const int k1 = (t + 1) * 32;
#pragma unroll
      for (int i = 0; i < MT / 64; ++i)
        gload_lds16(aSrc[i] + k1, &As[buf ^ 1][(i * 256 + tid) * 8]);
#pragma unroll
      for (int i = 0; i < NT / 64; ++i)
        gload_lds16(bSrc[i] + k1, &Bs[buf ^ 1][(i * 256 + tid) * 8]);
    }
    f16x8 af[WM], bf[WN];
#pragma unroll
    for (int wm = 0; wm < WM; ++wm) {
      int row = wr * (MT / 2) + wm * 16 + ln;
      af[wm] = *(const f16x8*)&As[buf][row * 32 + sw];
    }
#pragma unroll
    for (int wn = 0; wn < WN; ++wn) {
      int row = wc * (NT / 2) + wn * 16 + ln;
      bf[wn] = *(const f16x8*)&Bs[buf][row * 32 + sw];
    }
#pragma unroll
    for (int wm = 0; wm < WM; ++wm)
#pragma unroll
      for (int wn = 0; wn < WN; ++wn)
        acc[wm][wn] =
            __builtin_amdgcn_mfma_f32_16x16x32_f16(af[wm], bf[wn], acc[wm][wn], 0, 0, 0);
  }
#pragma unroll
  for (int wm = 0; wm < WM; ++wm)
#pragma unroll
    for (int wn = 0; wn < WN; ++wn)
#pragma unroll
      for (int r = 0; r < 4; ++r) {
        int gm = gm0 + wr * (MT / 2) + wm * 16 + quad * 4 + r;
        int gn = n0 + wc * (NT / 2) + wn * 16 + ln;
        long long ci = ((long long)((unsigned)gm >> cMsh)) * cMslab +
                       (long long)(gm & cMmask) * ldc +
                       ((long long)((unsigned)gn >> cNsh)) * cNslab + (gn & cNmask);
        float v = alpha * acc[wm][wn][r];
        if (S) v += beta * (float)S[ci];
        C[ci] = (fp16)v;
      }
}

// ---------- k_zxt: ZXt[d][n] = ZmovT@agh2^T (K=1024) + w2T@Tmat^T (K=64)
//            + teXb[z][d] + seX[n][d].  M=64, NT=128 (WN=4!), z in [0,96).
//            C rows padded to 2048 (ld=2048).
__global__ __launch_bounds__(256) void k_zxt(
    const fp16* __restrict__ A1, const fp16* __restrict__ B1,  // ZmovT, agh2
    const fp16* __restrict__ A2, const fp16* __restrict__ B2,  // w2T, Tmat
    fp16* __restrict__ C, const float* __restrict__ teXb, const float* __restrict__ seX) {
  __shared__ fp16 As[64][40];
  __shared__ fp16 Bs[128][40];
  const int z = blockIdx.z;
  const int n0 = blockIdx.y * 128;
  A1 += (long long)z * 64 * CC;
  B2 += (long long)z * NN * 64;
  C += (long long)z * 64 * 2048;
  teXb += (long long)z * 64;
  const int tid = threadIdx.x;
  const int lane = tid & 63, wv = tid >> 6;
  const int wr = wv >> 1, wc = wv & 1;
  const int quad = lane >> 4, ln = lane & 15;
  f32x4 acc[2][4];
#pragma unroll
  for (int i = 0; i < 2; ++i)
#pragma unroll
    for (int j = 0; j < 4; ++j) acc[i][j] = (f32x4){0.f, 0.f, 0.f, 0.f};

  for (int k0 = 0; k0 < 1088; k0 += 32) {
    {
      int c = tid;
      int row = c >> 2, seg = c & 3;
      int kk0 = k0 + seg * 8;
      const fp16* src = (kk0 < 1024) ? (A1 + (long long)row * CC + kk0)
                                     : (A2 + (long long)row * 64 + (kk0 - 1024));
      *(f16x8*)&As[row][seg * 8] = *(const f16x8*)src;
    }
#pragma unroll
    for (int i = 0; i < 2; ++i) {
      int c = tid + 256 * i;
      int n = c >> 2, seg = c & 3;
      int gn = n0 + n;
      int kk0 = k0 + seg * 8;
      const fp16* src = (kk0 < 1024) ? (B1 + (long long)gn * CC + kk0)
                                     : (B2 + (long long)gn * 64 + (kk0 - 1024));
      if (gn < NN) {
        *(f16x8*)&Bs[n][seg * 8] = *(const f16x8*)src;
      } else {
#pragma unroll
        for (int j = 0; j < 8; ++j) Bs[n][seg * 8 + j] = (fp16)0.f;
      }
    }
    __syncthreads();
    f16x8 af[2], bf[4];
#pragma unroll
    for (int wm = 0; wm < 2; ++wm)
      af[wm] = *(const f16x8*)&As[wr * 32 + wm * 16 + ln][quad * 8];
#pragma unroll
    for (int wn = 0; wn < 4; ++wn)
      bf[wn] = *(const f16x8*)&Bs[wc * 64 + wn * 16 + ln][quad * 8];
#pragma unroll
    for (int wm = 0; wm < 2; ++wm)
#pragma unroll
      for (int wn = 0; wn < 4; ++wn)
        acc[wm][wn] =
            __builtin_amdgcn_mfma_f32_16x16x32_f16(af[wm], bf[wn], acc[wm][wn], 0, 0, 0);
    __syncthreads();
  }
#pragma unroll
  for (int wm = 0; wm < 2; ++wm)
#pragma unroll
    for (int wn = 0; wn < 4; ++wn)
#pragma unroll
      for (int r = 0; r < 4; ++r) {
        int gm = wr * 32 + wm * 16 + quad * 4 + r;
        int gn = n0 + wc * 64 + wn * 16 + ln;
        if (gn < NN) {
          float v = acc[wm][wn][r] + teXb[gm] + seX[(long long)gn * 64 + gm];
          C[(long long)gm * 2048 + gn] = (fp16)v;
        }
      }
}

// ---------- ConvLSTM conv as MFMA (B from pre-transposed wcatT[n][k]) ----------
__global__ __launch_bounds__(256) void k_conv_mfma(
    const fp16* __restrict__ Zf, const fp16* __restrict__ h,
    const fp16* __restrict__ wcatT, fp16* __restrict__ gates, int p) {
  __shared__ fp16 As[128][40];
  __shared__ fp16 Bs[64][40];
  const int gm0 = blockIdx.x * 128, n0 = blockIdx.y * 64;
  const int tid = threadIdx.x;
  const int lane = tid & 63, wv = tid >> 6;
  const int wr = wv >> 1, wc = wv & 1;
  const int quad = lane >> 4, ln = lane & 15;
  f32x4 acc[4][2];
#pragma unroll
  for (int i = 0; i < 4; ++i)
#pragma unroll
    for (int j = 0; j < 2; ++j) acc[i][j] = (f32x4){0.f, 0.f, 0.f, 0.f};

  for (int kb = 0; kb < 36; ++kb) {
    const int srcsel = kb >= 18;
    const int tap = (kb >> 1) % 9;
    const int half = kb & 1;
    const int dy = tap / 3 - 1, dx = tap % 3 - 1;
#pragma unroll
    for (int i = 0; i < 2; ++i) {
      int c = tid + 256 * i;
      int row = c >> 2, seg = c & 3;
      int m = gm0 + row;
      int b = m >> 10;
      int y = (m >> 5) & 31, x = m & 31;
      int yy = y + dy, xx = x + dx;
      bool valid = ((unsigned)yy < 32u) && ((unsigned)xx < 32u);
      f16x8 v;
      if (valid) {
        long long cell = ((long long)b << 10) + (yy << 5) + xx;
        const fp16* sp =
            srcsel ? (h + cell * 64)
                   : (Zf + ((((long long)(b * PP + p)) << 10) + (yy << 5) + xx) * 64);
        v = *(const f16x8*)(sp + half * 32 + seg * 8);
      } else {
#pragma unroll
        for (int j = 0; j < 8; ++j) v[j] = (fp16)0.f;
      }
      *(f16x8*)&As[row][seg * 8] = v;
    }
    {
      int n = tid >> 2, seg = tid & 3;
      *(f16x8*)&Bs[n][seg * 8] =
          *(const f16x8*)(wcatT + (long long)(n0 + n) * 1152 + kb * 32 + seg * 8);
    }
    __syncthreads();
    f16x8 af[4], bf[2];
#pragma unroll
    for (int wm = 0; wm < 4; ++wm)
      af[wm] = *(const f16x8*)&As[wr * 64 + wm * 16 + ln][quad * 8];
#pragma unroll
    for (int wn = 0; wn < 2; ++wn)
      bf[wn] = *(const f16x8*)&Bs[wc * 32 + wn * 16 + ln][quad * 8];
#pragma unroll
    for (int wm = 0; wm < 4; ++wm)
#pragma unroll
      for (int wn = 0; wn < 2; ++wn)
        acc[wm][wn] =
            __builtin_amdgcn_mfma_f32_16x16x32_f16(af[wm], bf[wn], acc[wm][wn], 0, 0, 0);
    __syncthreads();
  }
#pragma unroll
  for (int wm = 0; wm < 4; ++wm)
#pragma unroll
    for (int wn = 0; wn < 2; ++wn)
#pragma unroll
      for (int r = 0; r < 4; ++r) {
        int gm = gm0 + wr * 64 + wm * 16 + quad * 4 + r;
        int gn = n0 + wc * 32 + wn * 16 + ln;
        gates[(long long)gm * 256 + gn] = (fp16)acc[wm][wn][r];
      }
}

__global__ void k_clstm_update(const fp16* __restrict__ gates, float* __restrict__ c,
                               fp16* __restrict__ h, fp16* __restrict__ ZclT, int p) {
  long long i = (long long)blockIdx.x * 256 + threadIdx.x;
  if (i >= (long long)BB * CC * 64) return;
  int d = (int)(i & 63);
  long long bc = i >> 6;
  int b = (int)(bc >> 10);
  int cell = (int)(bc & 1023);
  const fp16* g = gates + (((long long)b * CC) + cell) * 256;
  float gi = (float)g[d], gf = (float)g[64 + d], gg = (float)g[128 + d],
        go = (float)g[192 + d];
  float hs_f = fminf(fmaxf(0.2f * gf + 0.5f, 0.f), 1.f);
  float hs_i = fminf(fmaxf(0.2f * gi + 0.5f, 0.f), 1.f);
  float hs_o = fminf(fmaxf(0.2f * go + 0.5f, 0.f), 1.f);
  float cv = hs_f * c[i] + hs_i * tanhf(gg);
  c[i] = cv;
  float hv = hs_o * tanhf(cv);
  h[i] = (fp16)hv;
  ZclT[(((long long)(b * PP + p)) * 64 + d) * CC + cell] = (fp16)hv;
}

__global__ void k_tmat(const float* __restrict__ X, const float* __restrict__ w1,
                       const float* __restrict__ b1, fp16* __restrict__ T, long long nrows) {
  long long i = (long long)blockIdx.x * 256 + threadIdx.x;
  if (i >= nrows * 64) return;
  int j = (int)(i & 63);
  long long row = i >> 6;
  T[i] = (fp16)fmaxf(X[row] * w1[j] + b1[j], 0.f);
}

__global__ void k_trT(const fp16* __restrict__ U0, float* __restrict__ htmp) {
  long long i = (long long)blockIdx.x * 256 + threadIdx.x;
  if (i >= (long long)BB * NN * 64) return;
  int d = (int)(i & 63);
  long long bn = i >> 6;
  int b = (int)(bn / NN);
  int n = (int)(bn % NN);
  htmp[i] = (float)U0[((long long)b * 192 + 64 + d) * 2048 + n];
}

__global__ void k_out(const float* __restrict__ Y, float* __restrict__ out) {
  int i = blockIdx.x * 256 + threadIdx.x;
  if (i >= BB * QQ * NN) return;
  int n = i % NN;
  int bq = i / NN;
  int b = bq / QQ, q = bq % QQ;
  out[i] = Y[((long long)b * NN + n) * 12 + q];
}

// ---------- host helpers ----------
template <typename TA, typename TB, typename TC>
static void launch_gemm(hipStream_t stream, const TA* A, int lda, long long sA,
                        const TB* Bm, int ldb, long long sB, TC* Cm, int ldc, long long sC,
                        const TC* S, long long sS, const float* bias, int M, int Nc, int K,
                        float alpha, float beta, int act, int batch) {
  dim3 g((M + 63) / 64, (Nc + 63) / 64, batch);
  gemm_t<TA, TB, TC><<<g, dim3(256), 0, stream>>>(A, lda, sA, Bm, ldb, sB, Cm, ldc, sC, S,
                                                  sS, bias, M, Nc, K, alpha, beta, act);
}

extern "C" void kernel_launch(void* const* d_in, const int* in_sizes, int n_in,
                              void* d_out, int out_size, void* d_ws, size_t ws_size,
                              hipStream_t stream) {
  char* base = (char*)d_ws;
  size_t off = 0;
  auto alloc_bytes = [&](size_t nb) -> char* {
    char* p = base + off;
    off += (nb + 255) & ~(size_t)255;
    return p;
  };
  auto allocf = [&](size_t n) -> float* { return (float*)alloc_bytes(n * 4); };
  auto alloch = [&](size_t n) -> fp16* { return (fp16*)alloc_bytes(n * 2); };

  const float* X = (const float*)d_in[0];
  const float* Z = (const float*)d_in[1];
  const int* TE = (const int*)d_in[2];
  const float* adj_gg = (const float*)d_in[3];
  const float* adj_gr = (const float*)d_in[4];
  const float* gumbel = (const float*)d_in[5];
  const float* se_x = (const float*)d_in[6];
  const float* se_z = (const float*)d_in[7];
  const float* movement = (const float*)d_in[8];
  auto W = [&](int i) { return (const float*)d_in[i]; };

  // ---- allocations ----
  fp16* wcatT = alloch((size_t)256 * 1152);  // [n][k] pre-transposed conv weights
  fp16* gwT = alloch(128 * 512);
  fp16* cwT = alloch(64 * 512);
  fp16* w2T = alloch(64 * 64);
  fp16* w2mT = alloch(64 * 64);
  float* dinv = allocf(NN);
  fp16* LMall = alloch((size_t)6144 * 2048);  // rows padded to 2048 for maskless mfma4
  fp16* mZh = alloch((size_t)CC * CC);
  fp16* agh2 = alloch((size_t)NN * CC);
  float* seZ = allocf(CC * 64);
  float* teZ = allocf(BB * PP * 64);
  float* seX = allocf(NN * 64);
  float* teXb = allocf(BB * PP * 64);
  float* mtmp = allocf(NN * 64);
  float* tetmp = allocf(BB * PP * 64);
  fp16* ruT = alloch((size_t)BB * 128 * NN);  // [b][128][2000]
  // pool (50.33MB): U slabs 4x[16][192][2048] fp16; aliases conv gates/chh/ccc + Zmix/ZmovT
  char* pool = alloc_bytes(50331648);
  fp16* Uall = (fp16*)pool;
  fp16* gates = (fp16*)pool;
  fp16* chh = (fp16*)(pool + 8388608);
  float* ccc = (float*)(pool + 12582912);
  fp16* Zmix = (fp16*)pool;
  fp16* ZmovT = (fp16*)(pool + 25165824);
  // zpool: Zf [bp][1024][64] then ZXt [bp][64][2048] (rows padded to 2048)
  fp16* zpool = alloch((size_t)BB * PP * 64 * 2048);
  fp16* Zf = zpool;
  fp16* ZXt = zpool;
  fp16* Zc = alloch((size_t)BB * PP * CC * 64);  // zf1 scratch -> ZclT -> Tmat -> head scratch

  if (off > ws_size) return;

  const long long uB = 192LL * 2048;
  const long long USL = 16LL * uB;
  const long long ZXB = 12LL * 64 * 2048;  // per-batch stride of ZXt
  fp16* Lh = LMall;
  fp16* M2h = LMall + 2048LL * 2048;
  fp16* M3h = LMall + 4096LL * 2048;
  const int KCH = 2016;  // chain K (2000 padded to x32; cols 2000..2015 zero)

  // ---- precompute ----
  k_wcatT<<<dim3(1152), dim3(256), 0, stream>>>(wcatT, W(39), W(40));
  k_gru_repackT<<<dim3(256), dim3(256), 0, stream>>>(gwT, W(41), 128);
  k_gru_repackT<<<dim3(128), dim3(256), 0, stream>>>(cwT, W(43), 64);
  k_w2T<<<dim3(16), dim3(256), 0, stream>>>(w2T, W(31));
  k_w2T<<<dim3(16), dim3(256), 0, stream>>>(w2mT, W(33));
  k_dinv<<<dim3(NN), dim3(256), 0, stream>>>(adj_gg, dinv);
  hipMemsetAsync(LMall, 0, (size_t)6144 * 2048 * 2, stream);
  k_L<<<dim3((NN * NN + 255) / 256), dim3(256), 0, stream>>>(adj_gg, dinv, Lh);
  // M2 = 2*L@L (maskless mfma4, padded), then diag -= 1
  mfma4<64, 128><<<dim3(32, 16, 1), dim3(256), 0, stream>>>(
      Lh, Lh, 31, 31, 0LL, 0LL, 2048, Lh, 2048, 0LL, M2h, 2048, 0LL, 31, 0LL, 31, 0LL,
      (const fp16*)nullptr, 2.f, 0.f, KCH);
  k_subdiag<<<dim3((NN + 255) / 256), dim3(256), 0, stream>>>(M2h);
  // M3 = 2*L@M2 - L
  mfma4<64, 128><<<dim3(32, 16, 1), dim3(256), 0, stream>>>(
      Lh, Lh, 31, 31, 0LL, 0LL, 2048, M2h, 2048, 0LL, M3h, 2048, 0LL, 31, 0LL, 31, 0LL,
      (const fp16*)Lh, 2.f, -1.f, KCH);
  k_gumbel_softmax<<<dim3(CC), dim3(256), 0, stream>>>(movement, gumbel, mZh);
  k_f2h<<<dim3((NN * CC + 255) / 256), dim3(256), 0, stream>>>(agh2, adj_gr,
                                                               (long long)NN * CC);

  // ---- STEZ / STEX ----
  launch_gemm(stream, se_z, 64, 0LL, W(17), 64, 0LL, mtmp, 64, 0LL, (float*)nullptr, 0LL,
              W(18), CC, 64, 64, 1.f, 0.f, 1, 1);
  launch_gemm(stream, (const float*)mtmp, 64, 0LL, W(19), 64, 0LL, seZ, 64, 0LL,
              (float*)nullptr, 0LL, W(20), CC, 64, 64, 1.f, 0.f, 0, 1);
  k_te<<<dim3((BB * PP * 64 + 255) / 256), dim3(256), 0, stream>>>(TE, W(21), W(22), tetmp);
  launch_gemm(stream, (const float*)tetmp, 64, 0LL, W(23), 64, 0LL, teZ, 64, 0LL,
              (float*)nullptr, 0LL, W(24), BB * PP, 64, 64, 1.f, 0.f, 0, 1);
  launch_gemm(stream, se_x, 64, 0LL, W(9), 64, 0LL, mtmp, 64, 0LL, (float*)nullptr, 0LL,
              W(10), NN, 64, 64, 1.f, 0.f, 1, 1);
  launch_gemm(stream, (const float*)mtmp, 64, 0LL, W(11), 64, 0LL, seX, 64, 0LL,
              (float*)nullptr, 0LL, W(12), NN, 64, 64, 1.f, 0.f, 0, 1);
  k_te<<<dim3((BB * PP * 64 + 255) / 256), dim3(256), 0, stream>>>(TE, W(13), W(14), tetmp);
  launch_gemm(stream, (const float*)tetmp, 64, 0LL, W(15), 64, 0LL, teXb, 64, 0LL,
              (float*)nullptr, 0LL, W(16), BB * PP, 64, 64, 1.f, 0.f, 0, 1);
  k_addb<<<dim3((BB * PP * 64 + 255) / 256), dim3(256), 0, stream>>>(teXb, W(32),
                                                                     BB * PP * 64);

  // ---- Zf = mlp2(Z) + STEZ ----
  long long nZ = (long long)BB * PP * CC * 64;
  k_zf1<<<dim3((int)((nZ + 255) / 256)), dim3(256), 0, stream>>>(Z, W(25), W(26), Zc);
  launch_gemm(stream, (const fp16*)Zc, 64, 0LL, W(27), 64, 0LL, Zf, 64, 0LL,
              (fp16*)nullptr, 0LL, W(28), BB * PP * CC, 64, 64, 1.f, 0.f, 0, 1);
  k_add_stez<<<dim3((int)((nZ + 255) / 256)), dim3(256), 0, stream>>>(Zf, seZ, teZ);

  // ---- ConvLSTM (writes ZclT into Zc) ----
  hipMemsetAsync(chh, 0, (size_t)BB * CC * 64 * 2, stream);
  hipMemsetAsync(ccc, 0, (size_t)BB * CC * 64 * 4, stream);
  for (int p = 0; p < PP; ++p) {
    k_conv_mfma<<<dim3(BB * CC / 128, 4), dim3(256), 0, stream>>>(Zf, chh, wcatT, gates, p);
    k_clstm_update<<<dim3((int)(((long long)BB * CC * 64 + 255) / 256)), dim3(256), 0,
                     stream>>>(gates, ccc, chh, Zc, p);
  }

  // Zf is dead now: zero zpool so ZXt pad cols (2000..2047) are zero
  hipMemsetAsync(zpool, 0, (size_t)BB * PP * 64 * 2048 * 2, stream);

  // ---- movement m1 (mfma4, z-batched) / m2 ----
  mfma4<128, 64><<<dim3(8, 1, 192), dim3(256), 0, stream>>>(
      mZh, mZh, 31, 31, 0LL, 0LL, CC, (const fp16*)Zc, CC, (long long)64 * CC, Zmix, 64,
      (long long)CC * 64, 31, 0LL, 31, 0LL, (const fp16*)nullptr, 1.f, 0.f, CC);
  mfma3<64, 128><<<dim3(1, 8, 192), dim3(256), 0, stream>>>(
      w2mT, 64, 0LL, 31, 0LL, Zmix, 64, (long long)CC * 64, ZmovT, CC, (long long)64 * CC,
      31, 0LL, 31, 0LL, (const fp16*)nullptr, 0LL, 0.f, W(34), 0LL, nullptr, 0, 64, CC, 64,
      1.f, 1);

  // ---- merged m3+Tmat (two z-halves, Tmat in dead Zc; ZXt rows padded) ----
  fp16* Tmat = Zc;
  for (int half = 0; half < 2; ++half) {
    long long z0 = 96LL * half;
    k_tmat<<<dim3((int)((96LL * NN * 64 + 255) / 256)), dim3(256), 0, stream>>>(
        X + z0 * NN, W(29), W(30), Tmat, 96LL * NN);
    k_zxt<<<dim3(1, 16, 96), dim3(256), 0, stream>>>(
        ZmovT + z0 * 64 * CC, agh2, w2T, Tmat, ZXt + z0 * 64 * 2048, teXb + z0 * 64, seX);
  }

  // ---- DCGRU (fused epilogues; h lives in U0 rows 64..127; x read from ZXt) ----
  fp16* U0 = Uall;
  fp16* U1 = Uall + USL;
  hipMemsetAsync(U0, 0, (size_t)USL * 2, stream);  // zero slab 0 (h/rh rows + pads)
  for (int p = 0; p < PP; ++p) {
    const fp16* xP = ZXt + (long long)p * 64 * 2048;
    // gate+h chain: [T1|T2|T3](rows 0..127) = [x(ZXt)|h(U0)] @ [L|M2|M3]
    mfma4<128, 128><<<dim3(16, 48, 1), dim3(256), 0, stream>>>(
        xP, U0 + 64 * 2048, 7, 6, ZXB, uB, 2048, LMall, 2048, 0LL, U1, 2048, 0LL, 7, uB,
        11, USL, (const fp16*)nullptr, 1.f, 0.f, KCH);
    // ruT = sigmoid(gwT @ chebs); epilogue writes rh = r*h into U0 rows 128..191
    mfma2<128, 1><<<dim3(1, 32, BB), dim3(256), 0, stream>>>(
        gwT, 512, Uall, 2048, uB, 7, USL, 0, ruT, NN, (long long)128 * NN, W(42),
        U0 + 128 * 2048, U0 + 64 * 2048, uB, (const fp16*)nullptr, 0LL, xP, ZXB, 128, NN,
        512, 1.f);
    // cand rh chain -> U1..U3 rows 128..191
    mfma4<64, 128><<<dim3(16, 48, 1), dim3(256), 0, stream>>>(
        U0 + 128 * 2048, U0, 6, 31, uB, 0LL, 2048, LMall, 2048, 0LL, U1 + 128 * 2048, 2048,
        0LL, 6, uB, 11, USL, (const fp16*)nullptr, 1.f, 0.f, KCH);
    // cnd GEMM; epilogue does h' = u*h + (1-u)*tanh(v) in place in U0 rows 64..127
    mfma2<64, 2><<<dim3(1, 32, BB), dim3(256), 0, stream>>>(
        cwT, 512, Uall, 2048, uB, 7, USL, 64, U0 + 64 * 2048, 2048, uB, W(44),
        (fp16*)nullptr, (const fp16*)nullptr, 0LL, (const fp16*)ruT, (long long)128 * NN,
        xP, ZXB, 64, NN, 512, 1.f);
  }

  // ---- output head (all scratch in dead Zc; U0 untouched until read) ----
  float* htmp = (float*)Zc;                       // 8.19 MB
  float* out1 = (float*)(Zc + 5120000);           // byte 10.24 MB, 8.19 MB
  float* out2 = (float*)(Zc + 10240000);          // byte 20.48 MB, 1.54 MB
  k_trT<<<dim3((int)(((long long)BB * NN * 64 + 255) / 256)), dim3(256), 0, stream>>>(U0,
                                                                                      htmp);
  launch_gemm(stream, (const float*)htmp, 64, 0LL, W(35), 64, 0LL, out1, 64, 0LL,
              (float*)nullptr, 0LL, W(36), BB * NN, 64, 64, 1.f, 0.f, 1, 1);
  launch_gemm(stream, (const float*)out1, 64, 0LL, W(37), 12, 0LL, out2, 12, 0LL,
              (float*)nullptr, 0LL, W(38), BB * NN, 12, 64, 1.f, 0.f, 0, 1);
  k_out<<<dim3((BB * QQ * NN + 255) / 256), dim3(256), 0, stream>>>(out2, (float*)d_out);
}

// Round 3
// 3220.344 us; speedup vs baseline: 1.6555x; 1.0292x over previous
//
#include <hip/hip_runtime.h>
#include <hip/hip_bf16.h>
#include <math.h>

typedef _Float16 fp16;
typedef _Float16 f16x8 __attribute__((ext_vector_type(8)));
typedef float f32x4 __attribute__((ext_vector_type(4)));

#define BB 16
#define PP 12
#define QQ 12
#define NN 2000
#define CC 1024
#define GP 34   // padded grid side (32 + halo)
#define GP2 1156

static __device__ __forceinline__ float ldf(float v) { return v; }
static __device__ __forceinline__ float ldf(fp16 v) { return (float)v; }
static __device__ __forceinline__ void stf(float* p, float v) { *p = v; }
static __device__ __forceinline__ void stf(fp16* p, float v) { *p = (fp16)v; }

// async global->LDS, 16B per lane (wave-uniform LDS base + lane*16)
static __device__ __forceinline__ void gload_lds16(const fp16* g, fp16* l) {
  __builtin_amdgcn_global_load_lds(
      (const __attribute__((address_space(1))) void*)g,
      (__attribute__((address_space(3))) void*)l, 16, 0, 0);
}

// ---------- conversions / repacks ----------
__global__ void k_f2h(fp16* __restrict__ dst, const float* __restrict__ src, long long n) {
  long long i = (long long)blockIdx.x * 256 + threadIdx.x;
  if (i < n) dst[i] = (fp16)src[i];
}

// wcatT[n][kk] = wcat[kk][n], kk<576 from W39, else W40 (each [576][256])
__global__ void k_wcatT(fp16* __restrict__ dst, const float* __restrict__ w39,
                        const float* __restrict__ w40) {
  int i = blockIdx.x * 256 + threadIdx.x;
  if (i >= 1152 * 256) return;
  int n = i & 255, kk = i >> 8;
  float v = (kk < 576) ? w39[kk * 256 + n] : w40[(kk - 576) * 256 + n];
  dst[(long long)n * 1152 + kk] = (fp16)v;
}

// dcgru weights (512,O): row=f*4+t -> Wt[d][t*128+c] = src[(c*4+t)*O+d]
__global__ void k_gru_repackT(fp16* __restrict__ dst, const float* __restrict__ src, int O) {
  int i = blockIdx.x * 256 + threadIdx.x;
  if (i >= O * 512) return;
  int d = i >> 9;
  int kc = i & 511;
  int t = kc >> 7;
  int c = kc & 127;
  dst[i] = (fp16)src[(c * 4 + t) * O + d];
}

// (64,64) -> T[d][k] fp16
__global__ void k_w2T(fp16* __restrict__ dst, const float* __restrict__ src) {
  int i = blockIdx.x * 256 + threadIdx.x;
  if (i >= 4096) return;
  int d = i >> 6, k = i & 63;
  dst[i] = (fp16)src[k * 64 + d];
}

// ---------- laplacian ----------
__global__ void k_dinv(const float* __restrict__ adj, float* __restrict__ dinv) {
  int row = blockIdx.x;
  float s = 0.f;
  for (int j = threadIdx.x; j < NN; j += 256)
    s += fmaxf(adj[(long long)row * NN + j], adj[(long long)j * NN + row]);
  __shared__ float red[256];
  red[threadIdx.x] = s;
  __syncthreads();
  for (int st = 128; st > 0; st >>= 1) {
    if (threadIdx.x < st) red[threadIdx.x] += red[threadIdx.x + st];
    __syncthreads();
  }
  if (threadIdx.x == 0) {
    float d = red[0];
    dinv[row] = d > 0.f ? 1.0f / sqrtf(d) : 0.f;
  }
}

// writes L with row stride 2048 (zero-padded for maskless mfma4)
__global__ void k_L(const float* __restrict__ adj, const float* __restrict__ dinv,
                    fp16* __restrict__ Lh) {
  long long i = (long long)blockIdx.x * 256 + threadIdx.x;
  if (i >= (long long)NN * NN) return;
  int r = (int)(i / NN), c = (int)(i % NN);
  float a = fmaxf(adj[(long long)r * NN + c], adj[(long long)c * NN + r]);
  Lh[(long long)r * 2048 + c] = (fp16)(-dinv[r] * a * dinv[c]);
}

__global__ void k_subdiag(fp16* __restrict__ M2) {
  int i = blockIdx.x * 256 + threadIdx.x;
  if (i >= NN) return;
  M2[(long long)i * 2048 + i] = (fp16)((float)M2[(long long)i * 2048 + i] - 1.0f);
}

// ---------- gumbel softmax -> fp16 ----------
__global__ void k_gumbel_softmax(const float* __restrict__ ml, const float* __restrict__ gn,
                                 fp16* __restrict__ mZ) {
  int row = blockIdx.x;
  __shared__ float buf[CC];
  __shared__ float red[256];
  int t = threadIdx.x;
  float mx = -1e30f;
  for (int j = t; j < CC; j += 256) {
    float u = gn[(long long)row * CC + j];
    float g = -logf(-logf(u + 1e-20f) + 1e-20f);
    float v = ml[(long long)row * CC + j] + g;
    buf[j] = v;
    mx = fmaxf(mx, v);
  }
  red[t] = mx;
  __syncthreads();
  for (int st = 128; st > 0; st >>= 1) {
    if (t < st) red[t] = fmaxf(red[t], red[t + st]);
    __syncthreads();
  }
  mx = red[0];
  __syncthreads();
  float s = 0.f;
  for (int j = t; j < CC; j += 256) {
    float e = expf(buf[j] - mx);
    buf[j] = e;
    s += e;
  }
  red[t] = s;
  __syncthreads();
  for (int st = 128; st > 0; st >>= 1) {
    if (t < st) red[t] += red[t + st];
    __syncthreads();
  }
  float inv = 1.0f / red[0];
  for (int j = t; j < CC; j += 256) mZ[(long long)row * CC + j] = (fp16)(buf[j] * inv);
}

__global__ void k_te(const int* __restrict__ TE, const float* __restrict__ w1,
                     const float* __restrict__ b1, float* __restrict__ tmp) {
  int i = blockIdx.x * 256 + threadIdx.x;
  if (i >= BB * PP * 64) return;
  int j = i & 63;
  int bp = i >> 6;
  int b = bp / PP, p = bp % PP;
  int te0 = TE[(b * (PP + QQ) + p) * 2 + 0];
  int te1 = TE[(b * (PP + QQ) + p) * 2 + 1];
  float v = w1[te0 * 64 + j] + w1[(7 + te1) * 64 + j] + b1[j];
  tmp[i] = fmaxf(v, 0.f);
}

__global__ void k_addb(float* __restrict__ dst, const float* __restrict__ b, int n) {
  int i = blockIdx.x * 256 + threadIdx.x;
  if (i < n) dst[i] += b[i & 63];
}

__global__ void k_zf1(const float* __restrict__ Z, const float* __restrict__ w1,
                      const float* __restrict__ b1, fp16* __restrict__ tmp) {
  long long i = (long long)blockIdx.x * 256 + threadIdx.x;
  if (i >= (long long)BB * PP * CC * 64) return;
  int j = (int)(i & 63);
  long long row = i >> 6;
  float v = Z[row * 2 + 0] * w1[j] + Z[row * 2 + 1] * w1[64 + j] + b1[j];
  tmp[i] = (fp16)fmaxf(v, 0.f);
}

// scatter Zf (unpadded) + STEZ into padded 34x34 grid layout
__global__ void k_add_stez(fp16* __restrict__ dst, const fp16* __restrict__ src,
                           const float* __restrict__ seZ, const float* __restrict__ teZ) {
  long long i = (long long)blockIdx.x * 256 + threadIdx.x;
  if (i >= (long long)BB * PP * CC * 64) return;
  int j = (int)(i & 63);
  long long row = i >> 6;
  int c = (int)(row & 1023);
  int bp = (int)(row >> 10);
  int pc = ((c >> 5) + 1) * GP + (c & 31) + 1;
  dst[((long long)bp * GP2 + pc) * 64 + j] =
      (fp16)((float)src[i] + seZ[c * 64 + j] + teZ[bp * 64 + j]);
}

// ---------- generic fp32-path GEMM (small ops) ----------
template <typename TA, typename TB, typename TC>
__global__ __launch_bounds__(256) void gemm_t(
    const TA* __restrict__ A, int lda, long long sA,
    const TB* __restrict__ Bm, int ldb, long long sB,
    TC* Cm, int ldc, long long sC,
    const TC* S, long long sS,
    const float* __restrict__ bias,
    int M, int Ncols, int K, float alpha, float beta, int act) {
  int bz = blockIdx.z;
  A += (long long)bz * sA;
  Bm += (long long)bz * sB;
  Cm += (long long)bz * sC;
  if (S) S += (long long)bz * sS;
  const int row0 = blockIdx.x * 64, col0 = blockIdx.y * 64;
  __shared__ float As[16][68];
  __shared__ float Bs[16][68];
  int tid = threadIdx.x, tx = tid & 15, ty = tid >> 4;
  float acc[4][4] = {};
  for (int k0 = 0; k0 < K; k0 += 16) {
#pragma unroll
    for (int j = 0; j < 4; ++j) {
      int e = tid + 256 * j;
      int m = e >> 4, kk = e & 15;
      int gm = row0 + m;
      As[kk][m] = (gm < M) ? ldf(A[(long long)gm * lda + k0 + kk]) : 0.f;
    }
#pragma unroll
    for (int j = 0; j < 4; ++j) {
      int e = tid + 256 * j;
      int kk = e >> 6, n = e & 63;
      int gn = col0 + n;
      Bs[kk][n] = (gn < Ncols) ? ldf(Bm[(long long)(k0 + kk) * ldb + gn]) : 0.f;
    }
    __syncthreads();
#pragma unroll
    for (int kk = 0; kk < 16; ++kk) {
      float a[4], bb[4];
#pragma unroll
      for (int i = 0; i < 4; ++i) a[i] = As[kk][ty * 4 + i];
#pragma unroll
      for (int j = 0; j < 4; ++j) bb[j] = Bs[kk][tx * 4 + j];
#pragma unroll
      for (int i = 0; i < 4; ++i)
#pragma unroll
        for (int j = 0; j < 4; ++j) acc[i][j] = fmaf(a[i], bb[j], acc[i][j]);
    }
    __syncthreads();
  }
#pragma unroll
  for (int i = 0; i < 4; ++i) {
    int r = row0 + ty * 4 + i;
    if (r >= M) continue;
#pragma unroll
    for (int j = 0; j < 4; ++j) {
      int cn = col0 + tx * 4 + j;
      if (cn >= Ncols) continue;
      float v = alpha * acc[i][j];
      if (bias) v += bias[cn];
      if (S) v += beta * ldf(S[(long long)r * ldc + cn]);
      if (act == 1) v = fmaxf(v, 0.f);
      else if (act == 2) v = 1.f / (1.f + expf(-v));
      else if (act == 3) v = tanhf(v);
      stf(&Cm[(long long)r * ldc + cn], v);
    }
  }
}

// ---------- mfma2: DCGRU weight GEMMs with fused GRU epilogues ----------
// MODE 1 (ru):  C=ruT [z][128][NN]; sigmoid; rows<64 also write rh=r*h into rhOut
// MODE 2 (cnd): tanh; h' = u*h + (1-u)*v written in-place into C (=U0 h-rows)
// xB: if non-null, slab-0 cols<64 (the x features) are read from xB (ZXt, ld=2048)
template <int MT, int MODE>
__global__ __launch_bounds__(256) void mfma2(
    const fp16* __restrict__ A, int lda,
    const fp16* __restrict__ B, int ldb, long long bBatch, int bShift, long long bSlab,
    int bHi,
    fp16* __restrict__ C, int ldc, long long cBatch,
    const float* __restrict__ bias,
    fp16* __restrict__ rhOut, const fp16* __restrict__ hIn, long long xStride,
    const fp16* __restrict__ uIn, long long uStride,
    const fp16* __restrict__ xB, long long xZ,
    int M, int Ncols, int K, float alpha) {
  __shared__ fp16 As[MT][40];
  __shared__ fp16 Bs[64][40];
  const int z = blockIdx.z;
  const int gm0 = blockIdx.x * MT, n0 = blockIdx.y * 64;
  B += (long long)z * bBatch;
  C += (long long)z * cBatch;
  if (rhOut) rhOut += (long long)z * xStride;
  if (hIn) hIn += (long long)z * xStride;
  if (uIn) uIn += (long long)z * uStride;
  if (xB) xB += (long long)z * xZ;
  const int tid = threadIdx.x;
  const int lane = tid & 63, wv = tid >> 6;
  const int wr = wv >> 1, wc = wv & 1;
  const int quad = lane >> 4, ln = lane & 15;
  const unsigned bMask = (1u << bShift) - 1u;
  constexpr int WM = MT / 32;
  f32x4 acc[WM][2];
#pragma unroll
  for (int i = 0; i < WM; ++i)
#pragma unroll
    for (int j = 0; j < 2; ++j) acc[i][j] = (f32x4){0.f, 0.f, 0.f, 0.f};

  for (int k0 = 0; k0 < K; k0 += 32) {
#pragma unroll
    for (int i = 0; i < MT / 64; ++i) {
      int c = tid + 256 * i;
      int row = c >> 2, seg = c & 3;
      int gm = gm0 + row;
      int kk0 = k0 + seg * 8;
      const fp16* src = A + (long long)gm * lda + kk0;
      if (gm < M && kk0 + 8 <= K) {
        *(f16x8*)&As[row][seg * 8] = *(const f16x8*)src;
      } else {
#pragma unroll
        for (int j = 0; j < 8; ++j)
          As[row][seg * 8 + j] = (gm < M && kk0 + j < K) ? src[j] : (fp16)0.f;
      }
    }
    {
      int kk = k0 + (tid & 31);
      int ngrp = tid >> 5;
      int slab = (int)((unsigned)kk >> bShift);
      int kin = (int)((unsigned)kk & bMask);
      int col = kin + (kin >= 64 ? bHi : 0);
      int n = n0 + ngrp * 8;
      const fp16* src;
      if (xB && slab == 0 && kin < 64)
        src = xB + (long long)kin * 2048 + n;
      else
        src = B + (long long)slab * bSlab + (long long)col * ldb + n;
      if (kk < K && n + 8 <= Ncols) {
        f16x8 v = *(const f16x8*)src;
#pragma unroll
        for (int j = 0; j < 8; ++j) Bs[ngrp * 8 + j][tid & 31] = v[j];
      } else {
#pragma unroll
        for (int j = 0; j < 8; ++j)
          Bs[ngrp * 8 + j][tid & 31] = (kk < K && n + j < Ncols) ? src[j] : (fp16)0.f;
      }
    }
    __syncthreads();
    f16x8 af[WM], bf[2];
#pragma unroll
    for (int wm = 0; wm < WM; ++wm)
      af[wm] = *(const f16x8*)&As[wr * (MT / 2) + wm * 16 + ln][quad * 8];
#pragma unroll
    for (int wn = 0; wn < 2; ++wn)
      bf[wn] = *(const f16x8*)&Bs[wc * 32 + wn * 16 + ln][quad * 8];
#pragma unroll
    for (int wm = 0; wm < WM; ++wm)
#pragma unroll
      for (int wn = 0; wn < 2; ++wn)
        acc[wm][wn] =
            __builtin_amdgcn_mfma_f32_16x16x32_f16(af[wm], bf[wn], acc[wm][wn], 0, 0, 0);
    __syncthreads();
  }
#pragma unroll
  for (int wm = 0; wm < WM; ++wm) {
#pragma unroll
    for (int wn = 0; wn < 2; ++wn) {
#pragma unroll
      for (int r = 0; r < 4; ++r) {
        int gm = gm0 + wr * (MT / 2) + wm * 16 + quad * 4 + r;
        int gn = n0 + wc * 32 + wn * 16 + ln;
        if (gm < M && gn < Ncols) {
          float v = alpha * acc[wm][wn][r];
          v += bias[gm];
          if (MODE == 1) {
            v = 1.f / (1.f + expf(-v));  // sigmoid
            C[(long long)gm * ldc + gn] = (fp16)v;
            if (gm < 64) {
              float h = (float)hIn[(long long)gm * 2048 + gn];
              rhOut[(long long)gm * 2048 + gn] = (fp16)(v * h);
            }
          } else {
            v = tanhf(v);
            float u = (float)uIn[(long long)(64 + gm) * NN + gn];
            long long ci = (long long)gm * ldc + gn;
            float h = (float)C[ci];
            C[ci] = (fp16)(u * h + (1.f - u) * v);
          }
        }
      }
    }
  }
}

// ---------- mfma3: all-b128 GEMM (kept for movement m2) ----------
template <int MT, int NT>
__global__ __launch_bounds__(256) void mfma3(
    const fp16* __restrict__ A, int lda, long long zA, int aMsh, long long aMslab,
    const fp16* __restrict__ B, int ldb, long long zB,
    fp16* __restrict__ C, int ldc, long long zC, int cMsh, long long cMslab, int cNsh,
    long long cNslab,
    const fp16* __restrict__ S, long long zS, float beta,
    const float* __restrict__ rowBias, long long zRB,
    const float* __restrict__ s2T, int s2ld,
    int M, int Ncols, int K, float alpha, int act) {
  __shared__ fp16 As[MT][40];
  __shared__ fp16 Bs[NT][40];
  const int z = blockIdx.z;
  const int gm0 = blockIdx.x * MT, n0 = blockIdx.y * NT;
  A += (long long)z * zA;
  B += (long long)z * zB;
  C += (long long)z * zC;
  if (S) S += (long long)z * zS;
  const int tid = threadIdx.x;
  const int lane = tid & 63, wv = tid >> 6;
  const int wr = wv >> 1, wc = wv & 1;
  const int quad = lane >> 4, ln = lane & 15;
  const unsigned aMmask = (1u << aMsh) - 1u;
  const unsigned cMmask = (1u << cMsh) - 1u;
  const unsigned cNmask = (1u << cNsh) - 1u;
  constexpr int WM = MT / 32, WN = NT / 32;
  f32x4 acc[WM][WN];
#pragma unroll
  for (int i = 0; i < WM; ++i)
#pragma unroll
    for (int j = 0; j < WN; ++j) acc[i][j] = (f32x4){0.f, 0.f, 0.f, 0.f};

  for (int k0 = 0; k0 < K; k0 += 32) {
#pragma unroll
    for (int i = 0; i < MT / 64; ++i) {
      int c = tid + 256 * i;
      int row = c >> 2, seg = c & 3;
      int gm = gm0 + row;
      int kk0 = k0 + seg * 8;
      const fp16* src = A + ((long long)((unsigned)gm >> aMsh)) * aMslab +
                        (long long)(gm & aMmask) * lda + kk0;
      if (gm < M && kk0 + 8 <= K) {
        *(f16x8*)&As[row][seg * 8] = *(const f16x8*)src;
      } else {
#pragma unroll
        for (int j = 0; j < 8; ++j)
          As[row][seg * 8 + j] = (gm < M && kk0 + j < K) ? src[j] : (fp16)0.f;
      }
    }
#pragma unroll
    for (int i = 0; i < NT / 64; ++i) {
      int c = tid + 256 * i;
      int n = c >> 2, seg = c & 3;
      int gn = n0 + n;
      int kk0 = k0 + seg * 8;
      const fp16* src = B + (long long)gn * ldb + kk0;
      if (gn < Ncols && kk0 + 8 <= K) {
        *(f16x8*)&Bs[n][seg * 8] = *(const f16x8*)src;
      } else {
#pragma unroll
        for (int j = 0; j < 8; ++j)
          Bs[n][seg * 8 + j] = (gn < Ncols && kk0 + j < K) ? src[j] : (fp16)0.f;
      }
    }
    __syncthreads();
    f16x8 af[WM], bf[WN];
#pragma unroll
    for (int wm = 0; wm < WM; ++wm)
      af[wm] = *(const f16x8*)&As[wr * (MT / 2) + wm * 16 + ln][quad * 8];
#pragma unroll
    for (int wn = 0; wn < WN; ++wn)
      bf[wn] = *(const f16x8*)&Bs[wc * (NT / 2) + wn * 16 + ln][quad * 8];
#pragma unroll
    for (int wm = 0; wm < WM; ++wm)
#pragma unroll
      for (int wn = 0; wn < WN; ++wn)
        acc[wm][wn] =
            __builtin_amdgcn_mfma_f32_16x16x32_f16(af[wm], bf[wn], acc[wm][wn], 0, 0, 0);
    __syncthreads();
  }
#pragma unroll
  for (int wm = 0; wm < WM; ++wm) {
#pragma unroll
    for (int wn = 0; wn < WN; ++wn) {
#pragma unroll
      for (int r = 0; r < 4; ++r) {
        int gm = gm0 + wr * (MT / 2) + wm * 16 + quad * 4 + r;
        int gn = n0 + wc * (NT / 2) + wn * 16 + ln;
        if (gm < M && gn < Ncols) {
          float v = alpha * acc[wm][wn][r];
          if (rowBias) v += rowBias[(long long)z * zRB + gm];
          if (s2T) v += s2T[(long long)gn * s2ld + gm];
          long long ci = ((long long)((unsigned)gm >> cMsh)) * cMslab +
                         (long long)(gm & cMmask) * ldc +
                         ((long long)((unsigned)gn >> cNsh)) * cNslab + (gn & cNmask);
          if (S) v += beta * (float)S[ci];
          if (act == 1) v = fmaxf(v, 0.f);
          else if (act == 2) v = 1.f / (1.f + expf(-v));
          else if (act == 3) v = tanhf(v);
          C[ci] = (fp16)v;
        }
      }
    }
  }
}

// ---------- mfma4: maskless gload_lds GEMM, dual-base A descriptor ----------
template <int MT, int NT>
__global__ __launch_bounds__(256) void mfma4(
    const fp16* __restrict__ base0, const fp16* __restrict__ base1, int rsh, int ssh,
    long long z0, long long z1, int lda,
    const fp16* __restrict__ B, int ldb, long long zB,
    fp16* __restrict__ C, int ldc, long long zC, int cMsh, long long cMslab, int cNsh,
    long long cNslab,
    const fp16* __restrict__ S, float alpha, float beta, int K) {
  __shared__ fp16 As[2][MT * 32];
  __shared__ fp16 Bs[2][NT * 32];
  const int tid = threadIdx.x;
  const int z = blockIdx.z;
  const int gm0 = blockIdx.x * MT, n0 = blockIdx.y * NT;
  B += (long long)z * zB;
  C += (long long)z * zC;
  if (S) S += (long long)z * zC;
  const unsigned cMmask = (1u << cMsh) - 1u;
  const unsigned cNmask = (1u << cNsh) - 1u;
  const int lane = tid & 63, wv = tid >> 6;
  const int wr = wv >> 1, wc = wv & 1;
  const int quad = lane >> 4, ln = lane & 15;
  constexpr int WM = MT / 32, WN = NT / 32;

  const fp16* aSrc[MT / 64];
  const fp16* bSrc[NT / 64];
#pragma unroll
  for (int i = 0; i < MT / 64; ++i) {
    int c = i * 256 + tid;
    int row = c >> 2;
    int lseg = (c & 3) ^ (row & 3);
    int gm = gm0 + row;
    unsigned b = (unsigned)gm >> rsh;
    unsigned wi = (unsigned)gm & ((1u << rsh) - 1u);
    unsigned sel = wi >> ssh;
    unsigned r = wi & ((1u << ssh) - 1u);
    const fp16* ab = sel ? (base1 + (long long)b * z1) : (base0 + (long long)b * z0);
    aSrc[i] = ab + (long long)r * lda + lseg * 8;
  }
#pragma unroll
  for (int i = 0; i < NT / 64; ++i) {
    int c = i * 256 + tid;
    int row = c >> 2;
    int lseg = (c & 3) ^ (row & 3);
    bSrc[i] = B + (long long)(n0 + row) * ldb + lseg * 8;
  }

  f32x4 acc[WM][WN];
#pragma unroll
  for (int i = 0; i < WM; ++i)
#pragma unroll
    for (int j = 0; j < WN; ++j) acc[i][j] = (f32x4){0.f, 0.f, 0.f, 0.f};

  const int sw = (quad ^ (ln & 3)) << 3;

#pragma unroll
  for (int i = 0; i < MT / 64; ++i) gload_lds16(aSrc[i], &As[0][(i * 256 + tid) * 8]);
#pragma unroll
  for (int i = 0; i < NT / 64; ++i) gload_lds16(bSrc[i], &Bs[0][(i * 256 + tid) * 8]);

  const int nk = K >> 5;
  for (int t = 0; t < nk; ++t) {
    const int buf = t & 1;
    __syncthreads();
    if (t + 1 < nk) {
      const int k1 = (t + 1) * 32;
#pragma unroll
      for (int i = 0; i < MT / 64; ++i)
        gload_lds16(aSrc[i] + k1, &As[buf ^ 1][(i * 256 + tid) * 8]);
#pragma unroll
      for (int i = 0; i < NT / 64; ++i)
        gload_lds16(bSrc[i] + k1, &Bs[buf ^ 1][(i * 256 + tid) * 8]);
    }
    f16x8 af[WM], bf[WN];
#pragma unroll
    for (int wm = 0; wm < WM; ++wm) {
      int row = wr * (MT / 2) + wm * 16 + ln;
      af[wm] = *(const f16x8*)&As[buf][row * 32 + sw];
    }
#pragma unroll
    for (int wn = 0; wn < WN; ++wn) {
      int row = wc * (NT / 2) + wn * 16 + ln;
      bf[wn] = *(const f16x8*)&Bs[buf][row * 32 + sw];
    }
#pragma unroll
    for (int wm = 0; wm < WM; ++wm)
#pragma unroll
      for (int wn = 0; wn < WN; ++wn)
        acc[wm][wn] =
            __builtin_amdgcn_mfma_f32_16x16x32_f16(af[wm], bf[wn], acc[wm][wn], 0, 0, 0);
  }
#pragma unroll
  for (int wm = 0; wm < WM; ++wm)
#pragma unroll
    for (int wn = 0; wn < WN; ++wn)
#pragma unroll
      for (int r = 0; r < 4; ++r) {
        int gm = gm0 + wr * (MT / 2) + wm * 16 + quad * 4 + r;
        int gn = n0 + wc * (NT / 2) + wn * 16 + ln;
        long long ci = ((long long)((unsigned)gm >> cMsh)) * cMslab +
                       (long long)(gm & cMmask) * ldc +
                       ((long long)((unsigned)gn >> cNsh)) * cNslab + (gn & cNmask);
        float v = alpha * acc[wm][wn][r];
        if (S) v += beta * (float)S[ci];
        C[ci] = (fp16)v;
      }
}

// ---------- k_zxt4: maskless mfma4-style, K-concat [1024 | 64] ----------
// ZXt[z][d][n] = ZmovT[z]@agh2^T + w2T@Tmat[z]^T + teXb[z][d] + seX[n][d]
// M=64 (MT=64), N=2048 (NT=128), K=1088 (34 tiles; split at tile 32).
// agh2 padded to 2048 rows; Tmat 2048 rows per z (pad rows garbage -> cols>=NN
// get written 0). C ld=2048.
__global__ __launch_bounds__(256) void k_zxt4(
    const fp16* __restrict__ A1, const fp16* __restrict__ B1,  // ZmovT, agh2 (2048 rows)
    const fp16* __restrict__ A2, const fp16* __restrict__ B2,  // w2T, Tmat[z][2048][64]
    fp16* __restrict__ C, const float* __restrict__ teXb, const float* __restrict__ seX) {
  __shared__ fp16 As[2][64 * 32];
  __shared__ fp16 Bs[2][128 * 32];
  const int z = blockIdx.z;
  const int n0 = blockIdx.y * 128;
  A1 += (long long)z * 64 * 1024;
  B2 += (long long)z * 2048 * 64;
  C += (long long)z * 64 * 2048;
  teXb += z * 64;
  const int tid = threadIdx.x;
  const int lane = tid & 63, wv = tid >> 6;
  const int wr = wv >> 1, wc = wv & 1;
  const int quad = lane >> 4, ln = lane & 15;

  const fp16 *a1p, *a2p;
  {
    int row = tid >> 2;
    int lseg = (tid & 3) ^ (row & 3);
    a1p = A1 + (long long)row * 1024 + lseg * 8;
    a2p = A2 + (long long)row * 64 + lseg * 8;
  }
  const fp16 *b1p[2], *b2p[2];
#pragma unroll
  for (int i = 0; i < 2; ++i) {
    int c = tid + 256 * i;
    int row = c >> 2;
    int lseg = (c & 3) ^ (row & 3);
    b1p[i] = B1 + (long long)(n0 + row) * 1024 + lseg * 8;
    b2p[i] = B2 + (long long)(n0 + row) * 64 + lseg * 8;
  }
  f32x4 acc[2][4];
#pragma unroll
  for (int i = 0; i < 2; ++i)
#pragma unroll
    for (int j = 0; j < 4; ++j) acc[i][j] = (f32x4){0.f, 0.f, 0.f, 0.f};

  auto stage = [&](int t, int buf) {
    if (t < 32) {
      int k1 = t * 32;
      gload_lds16(a1p + k1, &As[buf][tid * 8]);
#pragma unroll
      for (int i = 0; i < 2; ++i)
        gload_lds16(b1p[i] + k1, &Bs[buf][(i * 256 + tid) * 8]);
    } else {
      int k1 = (t - 32) * 32;
      gload_lds16(a2p + k1, &As[buf][tid * 8]);
#pragma unroll
      for (int i = 0; i < 2; ++i)
        gload_lds16(b2p[i] + k1, &Bs[buf][(i * 256 + tid) * 8]);
    }
  };
  stage(0, 0);
  const int sw = (quad ^ (ln & 3)) << 3;
  for (int t = 0; t < 34; ++t) {
    const int buf = t & 1;
    __syncthreads();
    if (t + 1 < 34) stage(t + 1, buf ^ 1);
    f16x8 af[2], bf[4];
#pragma unroll
    for (int wm = 0; wm < 2; ++wm) {
      int row = wr * 32 + wm * 16 + ln;
      af[wm] = *(const f16x8*)&As[buf][row * 32 + sw];
    }
#pragma unroll
    for (int wn = 0; wn < 4; ++wn) {
      int row = wc * 64 + wn * 16 + ln;
      bf[wn] = *(const f16x8*)&Bs[buf][row * 32 + sw];
    }
#pragma unroll
    for (int wm = 0; wm < 2; ++wm)
#pragma unroll
      for (int wn = 0; wn < 4; ++wn)
        acc[wm][wn] =
            __builtin_amdgcn_mfma_f32_16x16x32_f16(af[wm], bf[wn], acc[wm][wn], 0, 0, 0);
  }
#pragma unroll
  for (int wm = 0; wm < 2; ++wm)
#pragma unroll
    for (int wn = 0; wn < 4; ++wn)
#pragma unroll
      for (int r = 0; r < 4; ++r) {
        int gm = wr * 32 + wm * 16 + quad * 4 + r;
        int gn = n0 + wc * 64 + wn * 16 + ln;
        float v = (gn < NN) ? (acc[wm][wn][r] + teXb[gm] + seX[(long long)gn * 64 + gm])
                            : 0.f;
        C[(long long)gm * 2048 + gn] = (fp16)v;
      }
}

// ---------- ConvLSTM conv, mfma4-style with zero-padded 34x34 halo ----------
// A rows m = b*1024 + cell; per k-tile t: tap/half/src select (uniform).
// Zfp: [bp][1156][64] padded, hp: [b][1156][64] padded (halo zeros).
__global__ __launch_bounds__(256) void k_conv4(
    const fp16* __restrict__ Zfp, const fp16* __restrict__ hp,
    const fp16* __restrict__ wcatT, fp16* __restrict__ gates, int p) {
  __shared__ fp16 As[2][128 * 32];
  __shared__ fp16 Bs[2][64 * 32];
  const int gm0 = blockIdx.x * 128, n0 = blockIdx.y * 64;
  const int tid = threadIdx.x;
  const int lane = tid & 63, wv = tid >> 6;
  const int wr = wv >> 1, wc = wv & 1;
  const int quad = lane >> 4, ln = lane & 15;

  long long aZ[2], aH[2];
#pragma unroll
  for (int i = 0; i < 2; ++i) {
    int c = tid + 256 * i;
    int row = c >> 2;
    int lseg = (c & 3) ^ (row & 3);
    int m = gm0 + row;
    int b = m >> 10, y = (m >> 5) & 31, x = m & 31;
    int pc = (y + 1) * GP + (x + 1);
    aZ[i] = ((long long)(b * PP + p) * GP2 + pc) * 64 + lseg * 8;
    aH[i] = ((long long)b * GP2 + pc) * 64 + lseg * 8;
  }
  const fp16* bBase;
  {
    int row = tid >> 2;
    int lseg = (tid & 3) ^ (row & 3);
    bBase = wcatT + (long long)(n0 + row) * 1152 + lseg * 8;
  }
  f32x4 acc[4][2];
#pragma unroll
  for (int i = 0; i < 4; ++i)
#pragma unroll
    for (int j = 0; j < 2; ++j) acc[i][j] = (f32x4){0.f, 0.f, 0.f, 0.f};

  auto stage = [&](int t, int buf) {
    int tap = (t >> 1) % 9, half = t & 1;
    int srcsel = t >= 18;
    int off = ((tap / 3 - 1) * GP + (tap % 3 - 1)) * 64 + half * 32;
#pragma unroll
    for (int i = 0; i < 2; ++i) {
      const fp16* src = srcsel ? (hp + aH[i] + off) : (Zfp + aZ[i] + off);
      gload_lds16(src, &As[buf][(i * 256 + tid) * 8]);
    }
    gload_lds16(bBase + t * 32, &Bs[buf][tid * 8]);
  };
  stage(0, 0);
  const int sw = (quad ^ (ln & 3)) << 3;
  for (int t = 0; t < 36; ++t) {
    const int buf = t & 1;
    __syncthreads();
    if (t + 1 < 36) stage(t + 1, buf ^ 1);
    f16x8 af[4], bf[2];
#pragma unroll
    for (int wm = 0; wm < 4; ++wm) {
      int row = wr * 64 + wm * 16 + ln;
      af[wm] = *(const f16x8*)&As[buf][row * 32 + sw];
    }
#pragma unroll
    for (int wn = 0; wn < 2; ++wn) {
      int row = wc * 32 + wn * 16 + ln;
      bf[wn] = *(const f16x8*)&Bs[buf][row * 32 + sw];
    }
#pragma unroll
    for (int wm = 0; wm < 4; ++wm)
#pragma unroll
      for (int wn = 0; wn < 2; ++wn)
        acc[wm][wn] =
            __builtin_amdgcn_mfma_f32_16x16x32_f16(af[wm], bf[wn], acc[wm][wn], 0, 0, 0);
  }
#pragma unroll
  for (int wm = 0; wm < 4; ++wm)
#pragma unroll
    for (int wn = 0; wn < 2; ++wn)
#pragma unroll
      for (int r = 0; r < 4; ++r) {
        int gm = gm0 + wr * 64 + wm * 16 + quad * 4 + r;
        int gn = n0 + wc * 32 + wn * 16 + ln;
        gates[(long long)gm * 256 + gn] = (fp16)acc[wm][wn][r];
      }
}

__global__ void k_clstm_update(const fp16* __restrict__ gates, float* __restrict__ c,
                               fp16* __restrict__ h, fp16* __restrict__ ZclT, int p) {
  long long i = (long long)blockIdx.x * 256 + threadIdx.x;
  if (i >= (long long)BB * CC * 64) return;
  int d = (int)(i & 63);
  long long bc = i >> 6;
  int b = (int)(bc >> 10);
  int cell = (int)(bc & 1023);
  const fp16* g = gates + (((long long)b * CC) + cell) * 256;
  float gi = (float)g[d], gf = (float)g[64 + d], gg = (float)g[128 + d],
        go = (float)g[192 + d];
  float hs_f = fminf(fmaxf(0.2f * gf + 0.5f, 0.f), 1.f);
  float hs_i = fminf(fmaxf(0.2f * gi + 0.5f, 0.f), 1.f);
  float hs_o = fminf(fmaxf(0.2f * go + 0.5f, 0.f), 1.f);
  float cv = hs_f * c[i] + hs_i * tanhf(gg);
  c[i] = cv;
  float hv = hs_o * tanhf(cv);
  int pc = ((cell >> 5) + 1) * GP + (cell & 31) + 1;
  h[((long long)b * GP2 + pc) * 64 + d] = (fp16)hv;
  ZclT[(((long long)(b * PP + p)) * 64 + d) * CC + cell] = (fp16)hv;
}

// Tmat[z][n][64] with 2048-row stride per z (pad rows garbage, cols>=NN zeroed later)
__global__ void k_tmat(const float* __restrict__ X, const float* __restrict__ w1,
                       const float* __restrict__ b1, fp16* __restrict__ T, long long nrows) {
  long long i = (long long)blockIdx.x * 256 + threadIdx.x;
  if (i >= nrows * 64) return;
  int j = (int)(i & 63);
  long long row = i >> 6;
  int z = (int)(row / NN);
  int n = (int)(row - (long long)z * NN);
  T[(((long long)z * 2048) + n) * 64 + j] = (fp16)fmaxf(X[row] * w1[j] + b1[j], 0.f);
}

__global__ void k_trT(const fp16* __restrict__ U0, float* __restrict__ htmp) {
  long long i = (long long)blockIdx.x * 256 + threadIdx.x;
  if (i >= (long long)BB * NN * 64) return;
  int d = (int)(i & 63);
  long long bn = i >> 6;
  int b = (int)(bn / NN);
  int n = (int)(bn % NN);
  htmp[i] = (float)U0[((long long)b * 192 + 64 + d) * 2048 + n];
}

__global__ void k_out(const float* __restrict__ Y, float* __restrict__ out) {
  int i = blockIdx.x * 256 + threadIdx.x;
  if (i >= BB * QQ * NN) return;
  int n = i % NN;
  int bq = i / NN;
  int b = bq / QQ, q = bq % QQ;
  out[i] = Y[((long long)b * NN + n) * 12 + q];
}

// ---------- host helpers ----------
template <typename TA, typename TB, typename TC>
static void launch_gemm(hipStream_t stream, const TA* A, int lda, long long sA,
                        const TB* Bm, int ldb, long long sB, TC* Cm, int ldc, long long sC,
                        const TC* S, long long sS, const float* bias, int M, int Nc, int K,
                        float alpha, float beta, int act, int batch) {
  dim3 g((M + 63) / 64, (Nc + 63) / 64, batch);
  gemm_t<TA, TB, TC><<<g, dim3(256), 0, stream>>>(A, lda, sA, Bm, ldb, sB, Cm, ldc, sC, S,
                                                  sS, bias, M, Nc, K, alpha, beta, act);
}

extern "C" void kernel_launch(void* const* d_in, const int* in_sizes, int n_in,
                              void* d_out, int out_size, void* d_ws, size_t ws_size,
                              hipStream_t stream) {
  char* base = (char*)d_ws;
  size_t off = 0;
  auto alloc_bytes = [&](size_t nb) -> char* {
    char* p = base + off;
    off += (nb + 255) & ~(size_t)255;
    return p;
  };
  auto allocf = [&](size_t n) -> float* { return (float*)alloc_bytes(n * 4); };
  auto alloch = [&](size_t n) -> fp16* { return (fp16*)alloc_bytes(n * 2); };

  const float* X = (const float*)d_in[0];
  const float* Z = (const float*)d_in[1];
  const int* TE = (const int*)d_in[2];
  const float* adj_gg = (const float*)d_in[3];
  const float* adj_gr = (const float*)d_in[4];
  const float* gumbel = (const float*)d_in[5];
  const float* se_x = (const float*)d_in[6];
  const float* se_z = (const float*)d_in[7];
  const float* movement = (const float*)d_in[8];
  auto W = [&](int i) { return (const float*)d_in[i]; };

  // ---- allocations ----
  fp16* wcatT = alloch((size_t)256 * 1152);  // [n][k] pre-transposed conv weights
  fp16* gwT = alloch(128 * 512);
  fp16* cwT = alloch(64 * 512);
  fp16* w2T = alloch(64 * 64);
  fp16* w2mT = alloch(64 * 64);
  float* dinv = allocf(NN);
  fp16* LMall = alloch((size_t)6144 * 2048);  // rows padded to 2048 for maskless mfma4
  fp16* mZh = alloch((size_t)CC * CC);
  fp16* agh2 = alloch((size_t)2048 * CC);  // padded to 2048 rows
  float* seZ = allocf(CC * 64);
  float* teZ = allocf(BB * PP * 64);
  float* seX = allocf(NN * 64);
  float* teXb = allocf(BB * PP * 64);
  float* mtmp = allocf(NN * 64);
  float* tetmp = allocf(BB * PP * 64);
  fp16* ruT = alloch((size_t)BB * 128 * NN);  // [b][128][2000]
  // pool (50.33MB): U slabs 4x[16][192][2048] fp16; aliases Zftmp/gates/chh/ccc + Zmix/ZmovT
  char* pool = alloc_bytes(50331648);
  fp16* Uall = (fp16*)pool;
  fp16* Zftmp = (fp16*)pool;  // unpadded Zf scratch (25.2MB), dead before gates
  fp16* gates = (fp16*)pool;
  fp16* chh = (fp16*)(pool + 8388608);   // padded h [16][1156][64] (2.37MB)
  float* ccc = (float*)(pool + 12582912);
  fp16* Zmix = (fp16*)pool;
  fp16* ZmovT = (fp16*)(pool + 25165824);
  // zpool: Zf_pad [bp][1156][64] (28.4MB) then ZXt [bp][64][2048]
  fp16* zpool = alloch((size_t)BB * PP * 64 * 2048);
  fp16* Zfp = zpool;
  fp16* ZXt = zpool;
  fp16* Zc = alloch((size_t)BB * PP * CC * 64);  // zf1 scratch -> ZclT -> Tmat -> head scratch

  if (off > ws_size) return;

  const long long uB = 192LL * 2048;
  const long long USL = 16LL * uB;
  const long long ZXB = 12LL * 64 * 2048;  // per-batch stride of ZXt
  fp16* Lh = LMall;
  fp16* M2h = LMall + 2048LL * 2048;
  fp16* M3h = LMall + 4096LL * 2048;
  const int KCH = 2016;  // chain K (2000 padded to x32; cols 2000..2015 zero)

  // ---- precompute ----
  k_wcatT<<<dim3(1152), dim3(256), 0, stream>>>(wcatT, W(39), W(40));
  k_gru_repackT<<<dim3(256), dim3(256), 0, stream>>>(gwT, W(41), 128);
  k_gru_repackT<<<dim3(128), dim3(256), 0, stream>>>(cwT, W(43), 64);
  k_w2T<<<dim3(16), dim3(256), 0, stream>>>(w2T, W(31));
  k_w2T<<<dim3(16), dim3(256), 0, stream>>>(w2mT, W(33));
  k_dinv<<<dim3(NN), dim3(256), 0, stream>>>(adj_gg, dinv);
  hipMemsetAsync(LMall, 0, (size_t)6144 * 2048 * 2, stream);
  k_L<<<dim3((NN * NN + 255) / 256), dim3(256), 0, stream>>>(adj_gg, dinv, Lh);
  mfma4<64, 128><<<dim3(32, 16, 1), dim3(256), 0, stream>>>(
      Lh, Lh, 31, 31, 0LL, 0LL, 2048, Lh, 2048, 0LL, M2h, 2048, 0LL, 31, 0LL, 31, 0LL,
      (const fp16*)nullptr, 2.f, 0.f, KCH);
  k_subdiag<<<dim3((NN + 255) / 256), dim3(256), 0, stream>>>(M2h);
  mfma4<64, 128><<<dim3(32, 16, 1), dim3(256), 0, stream>>>(
      Lh, Lh, 31, 31, 0LL, 0LL, 2048, M2h, 2048, 0LL, M3h, 2048, 0LL, 31, 0LL, 31, 0LL,
      (const fp16*)Lh, 2.f, -1.f, KCH);
  k_gumbel_softmax<<<dim3(CC), dim3(256), 0, stream>>>(movement, gumbel, mZh);
  k_f2h<<<dim3((NN * CC + 255) / 256), dim3(256), 0, stream>>>(agh2, adj_gr,
                                                               (long long)NN * CC);
  hipMemsetAsync(agh2 + (size_t)NN * CC, 0, (size_t)(2048 - NN) * CC * 2, stream);

  // ---- STEZ / STEX ----
  launch_gemm(stream, se_z, 64, 0LL, W(17), 64, 0LL, mtmp, 64, 0LL, (float*)nullptr, 0LL,
              W(18), CC, 64, 64, 1.f, 0.f, 1, 1);
  launch_gemm(stream, (const float*)mtmp, 64, 0LL, W(19), 64, 0LL, seZ, 64, 0LL,
              (float*)nullptr, 0LL, W(20), CC, 64, 64, 1.f, 0.f, 0, 1);
  k_te<<<dim3((BB * PP * 64 + 255) / 256), dim3(256), 0, stream>>>(TE, W(21), W(22), tetmp);
  launch_gemm(stream, (const float*)tetmp, 64, 0LL, W(23), 64, 0LL, teZ, 64, 0LL,
              (float*)nullptr, 0LL, W(24), BB * PP, 64, 64, 1.f, 0.f, 0, 1);
  launch_gemm(stream, se_x, 64, 0LL, W(9), 64, 0LL, mtmp, 64, 0LL, (float*)nullptr, 0LL,
              W(10), NN, 64, 64, 1.f, 0.f, 1, 1);
  launch_gemm(stream, (const float*)mtmp, 64, 0LL, W(11), 64, 0LL, seX, 64, 0LL,
              (float*)nullptr, 0LL, W(12), NN, 64, 64, 1.f, 0.f, 0, 1);
  k_te<<<dim3((BB * PP * 64 + 255) / 256), dim3(256), 0, stream>>>(TE, W(13), W(14), tetmp);
  launch_gemm(stream, (const float*)tetmp, 64, 0LL, W(15), 64, 0LL, teXb, 64, 0LL,
              (float*)nullptr, 0LL, W(16), BB * PP, 64, 64, 1.f, 0.f, 0, 1);
  k_addb<<<dim3((BB * PP * 64 + 255) / 256), dim3(256), 0, stream>>>(teXb, W(32),
                                                                     BB * PP * 64);

  // ---- Zf = mlp2(Z) + STEZ, scattered into padded 34x34 layout ----
  long long nZ = (long long)BB * PP * CC * 64;
  k_zf1<<<dim3((int)((nZ + 255) / 256)), dim3(256), 0, stream>>>(Z, W(25), W(26), Zc);
  launch_gemm(stream, (const fp16*)Zc, 64, 0LL, W(27), 64, 0LL, Zftmp, 64, 0LL,
              (fp16*)nullptr, 0LL, W(28), BB * PP * CC, 64, 64, 1.f, 0.f, 0, 1);
  hipMemsetAsync(zpool, 0, (size_t)BB * PP * GP2 * 64 * 2, stream);  // zero Zf_pad (halo)
  k_add_stez<<<dim3((int)((nZ + 255) / 256)), dim3(256), 0, stream>>>(Zfp, Zftmp, seZ, teZ);

  // ---- ConvLSTM (writes ZclT into Zc; h in padded chh) ----
  hipMemsetAsync(chh, 0, (size_t)BB * GP2 * 64 * 2, stream);
  hipMemsetAsync(ccc, 0, (size_t)BB * CC * 64 * 4, stream);
  for (int p = 0; p < PP; ++p) {
    k_conv4<<<dim3(BB * CC / 128, 4), dim3(256), 0, stream>>>(Zfp, chh, wcatT, gates, p);
    k_clstm_update<<<dim3((int)(((long long)BB * CC * 64 + 255) / 256)), dim3(256), 0,
                     stream>>>(gates, ccc, chh, Zc, p);
  }

  // ---- movement m1 (mfma4, z-batched) / m2 ----
  mfma4<128, 64><<<dim3(8, 1, 192), dim3(256), 0, stream>>>(
      mZh, mZh, 31, 31, 0LL, 0LL, CC, (const fp16*)Zc, CC, (long long)64 * CC, Zmix, 64,
      (long long)CC * 64, 31, 0LL, 31, 0LL, (const fp16*)nullptr, 1.f, 0.f, CC);
  mfma3<64, 128><<<dim3(1, 8, 192), dim3(256), 0, stream>>>(
      w2mT, 64, 0LL, 31, 0LL, Zmix, 64, (long long)CC * 64, ZmovT, CC, (long long)64 * CC,
      31, 0LL, 31, 0LL, (const fp16*)nullptr, 0LL, 0.f, W(34), 0LL, nullptr, 0, 64, CC, 64,
      1.f, 1);

  // ---- merged m3+Tmat (two z-halves; Tmat padded to 2048 rows/z in dead Zc) ----
  fp16* Tmat = Zc;
  for (int half = 0; half < 2; ++half) {
    long long z0 = 96LL * half;
    k_tmat<<<dim3((int)((96LL * NN * 64 + 255) / 256)), dim3(256), 0, stream>>>(
        X + z0 * NN, W(29), W(30), Tmat, 96LL * NN);
    k_zxt4<<<dim3(1, 16, 96), dim3(256), 0, stream>>>(
        ZmovT + z0 * 64 * CC, agh2, w2T, Tmat, ZXt + z0 * 64 * 2048, teXb + z0 * 64, seX);
  }

  // ---- DCGRU (fused epilogues; h lives in U0 rows 64..127; x read from ZXt) ----
  fp16* U0 = Uall;
  fp16* U1 = Uall + USL;
  hipMemsetAsync(U0, 0, (size_t)USL * 2, stream);  // zero slab 0 (h/rh rows + pads)
  for (int p = 0; p < PP; ++p) {
    const fp16* xP = ZXt + (long long)p * 64 * 2048;
    // gate+h chain: [T1|T2|T3](rows 0..127) = [x(ZXt)|h(U0)] @ [L|M2|M3]
    mfma4<128, 128><<<dim3(16, 48, 1), dim3(256), 0, stream>>>(
        xP, U0 + 64 * 2048, 7, 6, ZXB, uB, 2048, LMall, 2048, 0LL, U1, 2048, 0LL, 7, uB,
        11, USL, (const fp16*)nullptr, 1.f, 0.f, KCH);
    // ruT = sigmoid(gwT @ chebs); epilogue writes rh = r*h into U0 rows 128..191
    mfma2<128, 1><<<dim3(1, 32, BB), dim3(256), 0, stream>>>(
        gwT, 512, Uall, 2048, uB, 7, USL, 0, ruT, NN, (long long)128 * NN, W(42),
        U0 + 128 * 2048, U0 + 64 * 2048, uB, (const fp16*)nullptr, 0LL, xP, ZXB, 128, NN,
        512, 1.f);
    // cand rh chain -> U1..U3 rows 128..191
    mfma4<64, 128><<<dim3(16, 48, 1), dim3(256), 0, stream>>>(
        U0 + 128 * 2048, U0, 6, 31, uB, 0LL, 2048, LMall, 2048, 0LL, U1 + 128 * 2048, 2048,
        0LL, 6, uB, 11, USL, (const fp16*)nullptr, 1.f, 0.f, KCH);
    // cnd GEMM; epilogue does h' = u*h + (1-u)*tanh(v) in place in U0 rows 64..127
    mfma2<64, 2><<<dim3(1, 32, BB), dim3(256), 0, stream>>>(
        cwT, 512, Uall, 2048, uB, 7, USL, 64, U0 + 64 * 2048, 2048, uB, W(44),
        (fp16*)nullptr, (const fp16*)nullptr, 0LL, (const fp16*)ruT, (long long)128 * NN,
        xP, ZXB, 64, NN, 512, 1.f);
  }

  // ---- output head (all scratch in dead Zc; U0 untouched until read) ----
  float* htmp = (float*)Zc;                       // 8.19 MB
  float* out1 = (float*)(Zc + 5120000);           // byte 10.24 MB, 8.19 MB
  float* out2 = (float*)(Zc + 10240000);          // byte 20.48 MB, 1.54 MB
  k_trT<<<dim3((int)(((long long)BB * NN * 64 + 255) / 256)), dim3(256), 0, stream>>>(U0,
                                                                                      htmp);
  launch_gemm(stream, (const float*)htmp, 64, 0LL, W(35), 64, 0LL, out1, 64, 0LL,
              (float*)nullptr, 0LL, W(36), BB * NN, 64, 64, 1.f, 0.f, 1, 1);
  launch_gemm(stream, (const float*)out1, 64, 0LL, W(37), 12, 0LL, out2, 12, 0LL,
              (float*)nullptr, 0LL, W(38), BB * NN, 12, 64, 1.f, 0.f, 0, 1);
  k_out<<<dim3((BB * QQ * NN + 255) / 256), dim3(256), 0, stream>>>(out2, (float*)d_out);
}

// Round 4
// 3118.319 us; speedup vs baseline: 1.7096x; 1.0327x over previous
//
#include <hip/hip_runtime.h>
#include <hip/hip_bf16.h>
#include <math.h>

typedef _Float16 fp16;
typedef _Float16 f16x8 __attribute__((ext_vector_type(8)));
typedef float f32x4 __attribute__((ext_vector_type(4)));

#define BB 16
#define PP 12
#define QQ 12
#define NN 2000
#define CC 1024
#define GP 34   // padded grid side (32 + halo)
#define GP2 1156

static __device__ __forceinline__ float ldf(float v) { return v; }
static __device__ __forceinline__ float ldf(fp16 v) { return (float)v; }
static __device__ __forceinline__ void stf(float* p, float v) { *p = v; }
static __device__ __forceinline__ void stf(fp16* p, float v) { *p = (fp16)v; }

// async global->LDS, 16B per lane (wave-uniform LDS base + lane*16)
static __device__ __forceinline__ void gload_lds16(const fp16* g, fp16* l) {
  __builtin_amdgcn_global_load_lds(
      (const __attribute__((address_space(1))) void*)g,
      (__attribute__((address_space(3))) void*)l, 16, 0, 0);
}

// ---------- conversions / repacks ----------
__global__ void k_f2h(fp16* __restrict__ dst, const float* __restrict__ src, long long n) {
  long long i = (long long)blockIdx.x * 256 + threadIdx.x;
  if (i < n) dst[i] = (fp16)src[i];
}

// wcatT[n][kk] = wcat[kk][n], kk<576 from W39, else W40 (each [576][256])
__global__ void k_wcatT(fp16* __restrict__ dst, const float* __restrict__ w39,
                        const float* __restrict__ w40) {
  int i = blockIdx.x * 256 + threadIdx.x;
  if (i >= 1152 * 256) return;
  int n = i & 255, kk = i >> 8;
  float v = (kk < 576) ? w39[kk * 256 + n] : w40[(kk - 576) * 256 + n];
  dst[(long long)n * 1152 + kk] = (fp16)v;
}

// dcgru weights (512,O): row=f*4+t -> Wt[d][t*128+c] = src[(c*4+t)*O+d]
__global__ void k_gru_repackT(fp16* __restrict__ dst, const float* __restrict__ src, int O) {
  int i = blockIdx.x * 256 + threadIdx.x;
  if (i >= O * 512) return;
  int d = i >> 9;
  int kc = i & 511;
  int t = kc >> 7;
  int c = kc & 127;
  dst[i] = (fp16)src[(c * 4 + t) * O + d];
}

// (64,64) -> T[d][k] fp16
__global__ void k_w2T(fp16* __restrict__ dst, const float* __restrict__ src) {
  int i = blockIdx.x * 256 + threadIdx.x;
  if (i >= 4096) return;
  int d = i >> 6, k = i & 63;
  dst[i] = (fp16)src[k * 64 + d];
}

// ---------- laplacian ----------
__global__ void k_dinv(const float* __restrict__ adj, float* __restrict__ dinv) {
  int row = blockIdx.x;
  float s = 0.f;
  for (int j = threadIdx.x; j < NN; j += 256)
    s += fmaxf(adj[(long long)row * NN + j], adj[(long long)j * NN + row]);
  __shared__ float red[256];
  red[threadIdx.x] = s;
  __syncthreads();
  for (int st = 128; st > 0; st >>= 1) {
    if (threadIdx.x < st) red[threadIdx.x] += red[threadIdx.x + st];
    __syncthreads();
  }
  if (threadIdx.x == 0) {
    float d = red[0];
    dinv[row] = d > 0.f ? 1.0f / sqrtf(d) : 0.f;
  }
}

// writes L with row stride 2048 (zero-padded for maskless mfma4)
__global__ void k_L(const float* __restrict__ adj, const float* __restrict__ dinv,
                    fp16* __restrict__ Lh) {
  long long i = (long long)blockIdx.x * 256 + threadIdx.x;
  if (i >= (long long)NN * NN) return;
  int r = (int)(i / NN), c = (int)(i % NN);
  float a = fmaxf(adj[(long long)r * NN + c], adj[(long long)c * NN + r]);
  Lh[(long long)r * 2048 + c] = (fp16)(-dinv[r] * a * dinv[c]);
}

__global__ void k_subdiag(fp16* __restrict__ M2) {
  int i = blockIdx.x * 256 + threadIdx.x;
  if (i >= NN) return;
  M2[(long long)i * 2048 + i] = (fp16)((float)M2[(long long)i * 2048 + i] - 1.0f);
}

// ---------- gumbel softmax -> fp16 ----------
__global__ void k_gumbel_softmax(const float* __restrict__ ml, const float* __restrict__ gn,
                                 fp16* __restrict__ mZ) {
  int row = blockIdx.x;
  __shared__ float buf[CC];
  __shared__ float red[256];
  int t = threadIdx.x;
  float mx = -1e30f;
  for (int j = t; j < CC; j += 256) {
    float u = gn[(long long)row * CC + j];
    float g = -logf(-logf(u + 1e-20f) + 1e-20f);
    float v = ml[(long long)row * CC + j] + g;
    buf[j] = v;
    mx = fmaxf(mx, v);
  }
  red[t] = mx;
  __syncthreads();
  for (int st = 128; st > 0; st >>= 1) {
    if (t < st) red[t] = fmaxf(red[t], red[t + st]);
    __syncthreads();
  }
  mx = red[0];
  __syncthreads();
  float s = 0.f;
  for (int j = t; j < CC; j += 256) {
    float e = expf(buf[j] - mx);
    buf[j] = e;
    s += e;
  }
  red[t] = s;
  __syncthreads();
  for (int st = 128; st > 0; st >>= 1) {
    if (t < st) red[t] += red[t + st];
    __syncthreads();
  }
  float inv = 1.0f / red[0];
  for (int j = t; j < CC; j += 256) mZ[(long long)row * CC + j] = (fp16)(buf[j] * inv);
}

__global__ void k_te(const int* __restrict__ TE, const float* __restrict__ w1,
                     const float* __restrict__ b1, float* __restrict__ tmp) {
  int i = blockIdx.x * 256 + threadIdx.x;
  if (i >= BB * PP * 64) return;
  int j = i & 63;
  int bp = i >> 6;
  int b = bp / PP, p = bp % PP;
  int te0 = TE[(b * (PP + QQ) + p) * 2 + 0];
  int te1 = TE[(b * (PP + QQ) + p) * 2 + 1];
  float v = w1[te0 * 64 + j] + w1[(7 + te1) * 64 + j] + b1[j];
  tmp[i] = fmaxf(v, 0.f);
}

__global__ void k_addb(float* __restrict__ dst, const float* __restrict__ b, int n) {
  int i = blockIdx.x * 256 + threadIdx.x;
  if (i < n) dst[i] += b[i & 63];
}

__global__ void k_zf1(const float* __restrict__ Z, const float* __restrict__ w1,
                      const float* __restrict__ b1, fp16* __restrict__ tmp) {
  long long i = (long long)blockIdx.x * 256 + threadIdx.x;
  if (i >= (long long)BB * PP * CC * 64) return;
  int j = (int)(i & 63);
  long long row = i >> 6;
  float v = Z[row * 2 + 0] * w1[j] + Z[row * 2 + 1] * w1[64 + j] + b1[j];
  tmp[i] = (fp16)fmaxf(v, 0.f);
}

// scatter Zf (unpadded) + STEZ into padded 34x34 grid layout
__global__ void k_add_stez(fp16* __restrict__ dst, const fp16* __restrict__ src,
                           const float* __restrict__ seZ, const float* __restrict__ teZ) {
  long long i = (long long)blockIdx.x * 256 + threadIdx.x;
  if (i >= (long long)BB * PP * CC * 64) return;
  int j = (int)(i & 63);
  long long row = i >> 6;
  int c = (int)(row & 1023);
  int bp = (int)(row >> 10);
  int pc = ((c >> 5) + 1) * GP + (c & 31) + 1;
  dst[((long long)bp * GP2 + pc) * 64 + j] =
      (fp16)((float)src[i] + seZ[c * 64 + j] + teZ[bp * 64 + j]);
}

// ---------- generic fp32-path GEMM (small ops) ----------
template <typename TA, typename TB, typename TC>
__global__ __launch_bounds__(256) void gemm_t(
    const TA* __restrict__ A, int lda, long long sA,
    const TB* __restrict__ Bm, int ldb, long long sB,
    TC* Cm, int ldc, long long sC,
    const TC* S, long long sS,
    const float* __restrict__ bias,
    int M, int Ncols, int K, float alpha, float beta, int act) {
  int bz = blockIdx.z;
  A += (long long)bz * sA;
  Bm += (long long)bz * sB;
  Cm += (long long)bz * sC;
  if (S) S += (long long)bz * sS;
  const int row0 = blockIdx.x * 64, col0 = blockIdx.y * 64;
  __shared__ float As[16][68];
  __shared__ float Bs[16][68];
  int tid = threadIdx.x, tx = tid & 15, ty = tid >> 4;
  float acc[4][4] = {};
  for (int k0 = 0; k0 < K; k0 += 16) {
#pragma unroll
    for (int j = 0; j < 4; ++j) {
      int e = tid + 256 * j;
      int m = e >> 4, kk = e & 15;
      int gm = row0 + m;
      As[kk][m] = (gm < M) ? ldf(A[(long long)gm * lda + k0 + kk]) : 0.f;
    }
#pragma unroll
    for (int j = 0; j < 4; ++j) {
      int e = tid + 256 * j;
      int kk = e >> 6, n = e & 63;
      int gn = col0 + n;
      Bs[kk][n] = (gn < Ncols) ? ldf(Bm[(long long)(k0 + kk) * ldb + gn]) : 0.f;
    }
    __syncthreads();
#pragma unroll
    for (int kk = 0; kk < 16; ++kk) {
      float a[4], bb[4];
#pragma unroll
      for (int i = 0; i < 4; ++i) a[i] = As[kk][ty * 4 + i];
#pragma unroll
      for (int j = 0; j < 4; ++j) bb[j] = Bs[kk][tx * 4 + j];
#pragma unroll
      for (int i = 0; i < 4; ++i)
#pragma unroll
        for (int j = 0; j < 4; ++j) acc[i][j] = fmaf(a[i], bb[j], acc[i][j]);
    }
    __syncthreads();
  }
#pragma unroll
  for (int i = 0; i < 4; ++i) {
    int r = row0 + ty * 4 + i;
    if (r >= M) continue;
#pragma unroll
    for (int j = 0; j < 4; ++j) {
      int cn = col0 + tx * 4 + j;
      if (cn >= Ncols) continue;
      float v = alpha * acc[i][j];
      if (bias) v += bias[cn];
      if (S) v += beta * ldf(S[(long long)r * ldc + cn]);
      if (act == 1) v = fmaxf(v, 0.f);
      else if (act == 2) v = 1.f / (1.f + expf(-v));
      else if (act == 3) v = tanhf(v);
      stf(&Cm[(long long)r * ldc + cn], v);
    }
  }
}

// ---------- mfma5: DCGRU weight GEMMs, Tn-layout chebs, fused GRU epilogues ----------
// K=512 = 4 slabs of 128. slab0 = live xh rows (x from xB/ZXt, h/rh from U0 rows),
// transpose-scatter staging. slabs 1..3 = Tn (gate chebs, inner z*128) / Tn2 (cand
// chebs, inner z*64) -> vectorized b128 staging.
// MODE 1 (ru):  C=ruT [z][128][NN]; sigmoid; rows<64 also write rh=r*h into rhOut
// MODE 2 (cnd): tanh; h' = u*h + (1-u)*v written in-place into C (=U0 h-rows)
template <int MT, int MODE>
__global__ __launch_bounds__(256) void mfma5(
    const fp16* __restrict__ A, int lda,
    const fp16* __restrict__ U0base, long long uZ, int bHi,
    const fp16* __restrict__ xB, long long xZ,
    const fp16* __restrict__ Tn, long long TnSlab,
    const fp16* __restrict__ Tn2, long long Tn2Slab,
    fp16* __restrict__ C, int ldc, long long cBatch,
    const float* __restrict__ bias,
    fp16* __restrict__ rhOut, const fp16* __restrict__ hIn,
    const fp16* __restrict__ uIn, long long uStride,
    int M, int Ncols, int K) {
  __shared__ fp16 As[MT][40];
  __shared__ fp16 Bs[64][40];
  const int z = blockIdx.z;
  const int gm0 = blockIdx.x * MT, n0 = blockIdx.y * 64;
  const fp16* U0z = U0base + (long long)z * uZ;
  const fp16* xBz = xB + (long long)z * xZ;
  C += (long long)z * cBatch;
  if (rhOut) rhOut += (long long)z * uZ;
  if (hIn) hIn += (long long)z * uZ;
  if (uIn) uIn += (long long)z * uStride;
  const int tid = threadIdx.x;
  const int lane = tid & 63, wv = tid >> 6;
  const int wr = wv >> 1, wc = wv & 1;
  const int quad = lane >> 4, ln = lane & 15;
  constexpr int WM = MT / 32;
  f32x4 acc[WM][2];
#pragma unroll
  for (int i = 0; i < WM; ++i)
#pragma unroll
    for (int j = 0; j < 2; ++j) acc[i][j] = (f32x4){0.f, 0.f, 0.f, 0.f};

  for (int k0 = 0; k0 < K; k0 += 32) {
#pragma unroll
    for (int i = 0; i < MT / 64; ++i) {
      int c = tid + 256 * i;
      int row = c >> 2, seg = c & 3;
      *(f16x8*)&As[row][seg * 8] =
          *(const f16x8*)(A + (long long)(gm0 + row) * lda + k0 + seg * 8);
    }
    {
      int slab = k0 >> 7;
      if (slab == 0) {
        int kin = k0 + (tid & 31);
        int ngrp = tid >> 5;
        int n = n0 + ngrp * 8;
        const fp16* src = (kin < 64) ? (xBz + (long long)kin * 2048 + n)
                                     : (U0z + (long long)(kin + bHi) * 2048 + n);
        f16x8 v = *(const f16x8*)src;
#pragma unroll
        for (int j = 0; j < 8; ++j) Bs[ngrp * 8 + j][tid & 31] = v[j];
      } else {
        int n = tid >> 2, seg = tid & 3;
        int kin0 = (k0 & 127) + seg * 8;
        long long node = n0 + n;
        const fp16* src;
        if (MODE == 1 || kin0 < 64)
          src = Tn + (long long)(slab - 1) * TnSlab + node * 2048 + z * 128 + kin0;
        else
          src = Tn2 + (long long)(slab - 1) * Tn2Slab + node * 1024 + z * 64 + (kin0 - 64);
        *(f16x8*)&Bs[n][seg * 8] = *(const f16x8*)src;
      }
    }
    __syncthreads();
    f16x8 af[WM], bf[2];
#pragma unroll
    for (int wm = 0; wm < WM; ++wm)
      af[wm] = *(const f16x8*)&As[wr * (MT / 2) + wm * 16 + ln][quad * 8];
#pragma unroll
    for (int wn = 0; wn < 2; ++wn)
      bf[wn] = *(const f16x8*)&Bs[wc * 32 + wn * 16 + ln][quad * 8];
#pragma unroll
    for (int wm = 0; wm < WM; ++wm)
#pragma unroll
      for (int wn = 0; wn < 2; ++wn)
        acc[wm][wn] =
            __builtin_amdgcn_mfma_f32_16x16x32_f16(af[wm], bf[wn], acc[wm][wn], 0, 0, 0);
    __syncthreads();
  }
#pragma unroll
  for (int wm = 0; wm < WM; ++wm) {
#pragma unroll
    for (int wn = 0; wn < 2; ++wn) {
#pragma unroll
      for (int r = 0; r < 4; ++r) {
        int gm = gm0 + wr * (MT / 2) + wm * 16 + quad * 4 + r;
        int gn = n0 + wc * 32 + wn * 16 + ln;
        if (gm < M && gn < Ncols) {
          float v = acc[wm][wn][r];
          v += bias[gm];
          if (MODE == 1) {
            v = 1.f / (1.f + expf(-v));  // sigmoid
            C[(long long)gm * ldc + gn] = (fp16)v;
            if (gm < 64) {
              float h = (float)hIn[(long long)gm * 2048 + gn];
              rhOut[(long long)gm * 2048 + gn] = (fp16)(v * h);
            }
          } else {
            v = tanhf(v);
            float u = (float)uIn[(long long)(64 + gm) * NN + gn];
            long long ci = (long long)gm * ldc + gn;
            float h = (float)C[ci];
            C[ci] = (fp16)(u * h + (1.f - u) * v);
          }
        }
      }
    }
  }
}

// ---------- mfma3: all-b128 GEMM (kept for movement m2) ----------
template <int MT, int NT>
__global__ __launch_bounds__(256) void mfma3(
    const fp16* __restrict__ A, int lda, long long zA, int aMsh, long long aMslab,
    const fp16* __restrict__ B, int ldb, long long zB,
    fp16* __restrict__ C, int ldc, long long zC, int cMsh, long long cMslab, int cNsh,
    long long cNslab,
    const fp16* __restrict__ S, long long zS, float beta,
    const float* __restrict__ rowBias, long long zRB,
    const float* __restrict__ s2T, int s2ld,
    int M, int Ncols, int K, float alpha, int act) {
  __shared__ fp16 As[MT][40];
  __shared__ fp16 Bs[NT][40];
  const int z = blockIdx.z;
  const int gm0 = blockIdx.x * MT, n0 = blockIdx.y * NT;
  A += (long long)z * zA;
  B += (long long)z * zB;
  C += (long long)z * zC;
  if (S) S += (long long)z * zS;
  const int tid = threadIdx.x;
  const int lane = tid & 63, wv = tid >> 6;
  const int wr = wv >> 1, wc = wv & 1;
  const int quad = lane >> 4, ln = lane & 15;
  const unsigned aMmask = (1u << aMsh) - 1u;
  const unsigned cMmask = (1u << cMsh) - 1u;
  const unsigned cNmask = (1u << cNsh) - 1u;
  constexpr int WM = MT / 32, WN = NT / 32;
  f32x4 acc[WM][WN];
#pragma unroll
  for (int i = 0; i < WM; ++i)
#pragma unroll
    for (int j = 0; j < WN; ++j) acc[i][j] = (f32x4){0.f, 0.f, 0.f, 0.f};

  for (int k0 = 0; k0 < K; k0 += 32) {
#pragma unroll
    for (int i = 0; i < MT / 64; ++i) {
      int c = tid + 256 * i;
      int row = c >> 2, seg = c & 3;
      int gm = gm0 + row;
      int kk0 = k0 + seg * 8;
      const fp16* src = A + ((long long)((unsigned)gm >> aMsh)) * aMslab +
                        (long long)(gm & aMmask) * lda + kk0;
      if (gm < M && kk0 + 8 <= K) {
        *(f16x8*)&As[row][seg * 8] = *(const f16x8*)src;
      } else {
#pragma unroll
        for (int j = 0; j < 8; ++j)
          As[row][seg * 8 + j] = (gm < M && kk0 + j < K) ? src[j] : (fp16)0.f;
      }
    }
#pragma unroll
    for (int i = 0; i < NT / 64; ++i) {
      int c = tid + 256 * i;
      int n = c >> 2, seg = c & 3;
      int gn = n0 + n;
      int kk0 = k0 + seg * 8;
      const fp16* src = B + (long long)gn * ldb + kk0;
      if (gn < Ncols && kk0 + 8 <= K) {
        *(f16x8*)&Bs[n][seg * 8] = *(const f16x8*)src;
      } else {
#pragma unroll
        for (int j = 0; j < 8; ++j)
          Bs[n][seg * 8 + j] = (gn < Ncols && kk0 + j < K) ? src[j] : (fp16)0.f;
      }
    }
    __syncthreads();
    f16x8 af[WM], bf[WN];
#pragma unroll
    for (int wm = 0; wm < WM; ++wm)
      af[wm] = *(const f16x8*)&As[wr * (MT / 2) + wm * 16 + ln][quad * 8];
#pragma unroll
    for (int wn = 0; wn < WN; ++wn)
      bf[wn] = *(const f16x8*)&Bs[wc * (NT / 2) + wn * 16 + ln][quad * 8];
#pragma unroll
    for (int wm = 0; wm < WM; ++wm)
#pragma unroll
      for (int wn = 0; wn < WN; ++wn)
        acc[wm][wn] =
            __builtin_amdgcn_mfma_f32_16x16x32_f16(af[wm], bf[wn], acc[wm][wn], 0, 0, 0);
    __syncthreads();
  }
#pragma unroll
  for (int wm = 0; wm < WM; ++wm) {
#pragma unroll
    for (int wn = 0; wn < WN; ++wn) {
#pragma unroll
      for (int r = 0; r < 4; ++r) {
        int gm = gm0 + wr * (MT / 2) + wm * 16 + quad * 4 + r;
        int gn = n0 + wc * (NT / 2) + wn * 16 + ln;
        if (gm < M && gn < Ncols) {
          float v = alpha * acc[wm][wn][r];
          if (rowBias) v += rowBias[(long long)z * zRB + gm];
          if (s2T) v += s2T[(long long)gn * s2ld + gm];
          long long ci = ((long long)((unsigned)gm >> cMsh)) * cMslab +
                         (long long)(gm & cMmask) * ldc +
                         ((long long)((unsigned)gn >> cNsh)) * cNslab + (gn & cNmask);
          if (S) v += beta * (float)S[ci];
          if (act == 1) v = fmaxf(v, 0.f);
          else if (act == 2) v = 1.f / (1.f + expf(-v));
          else if (act == 3) v = tanhf(v);
          C[ci] = (fp16)v;
        }
      }
    }
  }
}

// ---------- mfma4: maskless gload_lds GEMM, dual-base A descriptor ----------
template <int MT, int NT>
__global__ __launch_bounds__(256) void mfma4(
    const fp16* __restrict__ base0, const fp16* __restrict__ base1, int rsh, int ssh,
    long long z0, long long z1, int lda,
    const fp16* __restrict__ B, int ldb, long long zB,
    fp16* __restrict__ C, int ldc, long long zC, int cMsh, long long cMslab, int cNsh,
    long long cNslab,
    const fp16* __restrict__ S, float alpha, float beta, int K) {
  __shared__ fp16 As[2][MT * 32];
  __shared__ fp16 Bs[2][NT * 32];
  const int tid = threadIdx.x;
  const int z = blockIdx.z;
  const int gm0 = blockIdx.x * MT, n0 = blockIdx.y * NT;
  B += (long long)z * zB;
  C += (long long)z * zC;
  if (S) S += (long long)z * zC;
  const unsigned cMmask = (1u << cMsh) - 1u;
  const unsigned cNmask = (1u << cNsh) - 1u;
  const int lane = tid & 63, wv = tid >> 6;
  const int wr = wv >> 1, wc = wv & 1;
  const int quad = lane >> 4, ln = lane & 15;
  constexpr int WM = MT / 32, WN = NT / 32;

  const fp16* aSrc[MT / 64];
  const fp16* bSrc[NT / 64];
#pragma unroll
  for (int i = 0; i < MT / 64; ++i) {
    int c = i * 256 + tid;
    int row = c >> 2;
    int lseg = (c & 3) ^ (row & 3);
    int gm = gm0 + row;
    unsigned b = (unsigned)gm >> rsh;
    unsigned wi = (unsigned)gm & ((1u << rsh) - 1u);
    unsigned sel = wi >> ssh;
    unsigned r = wi & ((1u << ssh) - 1u);
    const fp16* ab = sel ? (base1 + (long long)b * z1) : (base0 + (long long)b * z0);
    aSrc[i] = ab + (long long)r * lda + lseg * 8;
  }
#pragma unroll
  for (int i = 0; i < NT / 64; ++i) {
    int c = i * 256 + tid;
    int row = c >> 2;
    int lseg = (c & 3) ^ (row & 3);
    bSrc[i] = B + (long long)(n0 + row) * ldb + lseg * 8;
  }

  f32x4 acc[WM][WN];
#pragma unroll
  for (int i = 0; i < WM; ++i)
#pragma unroll
    for (int j = 0; j < WN; ++j) acc[i][j] = (f32x4){0.f, 0.f, 0.f, 0.f};

  const int sw = (quad ^ (ln & 3)) << 3;

#pragma unroll
  for (int i = 0; i < MT / 64; ++i) gload_lds16(aSrc[i], &As[0][(i * 256 + tid) * 8]);
#pragma unroll
  for (int i = 0; i < NT / 64; ++i) gload_lds16(bSrc[i], &Bs[0][(i * 256 + tid) * 8]);

  const int nk = K >> 5;
  for (int t = 0; t < nk; ++t) {
    const int buf = t & 1;
    __syncthreads();
    if (t + 1 < nk) {
      const int k1 = (t + 1) * 32;
#pragma unroll
      for (int i = 0; i < MT / 64; ++i)
        gload_lds16(aSrc[i] + k1, &As[buf ^ 1][(i * 256 + tid) * 8]);
#pragma unroll
      for (int i = 0; i < NT / 64; ++i)
        gload_lds16(bSrc[i] + k1, &Bs[buf ^ 1][(i * 256 + tid) * 8]);
    }
    f16x8 af[WM], bf[WN];
#pragma unroll
    for (int wm = 0; wm < WM; ++wm) {
      int row = wr * (MT / 2) + wm * 16 + ln;
      af[wm] = *(const f16x8*)&As[buf][row * 32 + sw];
    }
#pragma unroll
    for (int wn = 0; wn < WN; ++wn) {
      int row = wc * (NT / 2) + wn * 16 + ln;
      bf[wn] = *(const f16x8*)&Bs[buf][row * 32 + sw];
    }
#pragma unroll
    for (int wm = 0; wm < WM; ++wm)
#pragma unroll
      for (int wn = 0; wn < WN; ++wn)
        acc[wm][wn] =
            __builtin_amdgcn_mfma_f32_16x16x32_f16(af[wm], bf[wn], acc[wm][wn], 0, 0, 0);
  }
#pragma unroll
  for (int wm = 0; wm < WM; ++wm)
#pragma unroll
    for (int wn = 0; wn < WN; ++wn)
#pragma unroll
      for (int r = 0; r < 4; ++r) {
        int gm = gm0 + wr * (MT / 2) + wm * 16 + quad * 4 + r;
        int gn = n0 + wc * (NT / 2) + wn * 16 + ln;
        long long ci = ((long long)((unsigned)gm >> cMsh)) * cMslab +
                       (long long)(gm & cMmask) * ldc +
                       ((long long)((unsigned)gn >> cNsh)) * cNslab + (gn & cNmask);
        float v = alpha * acc[wm][wn][r];
        if (S) v += beta * (float)S[ci];
        C[ci] = (fp16)v;
      }
}

// ---------- mfma6: maskless gload_lds GEMM, dual-base B descriptor ----------
// A = shared M-side matrix (LMall). B row gn: b=gn>>rsh; wi=gn&mask; sel=wi>>ssh;
// r=wi&mask(ssh); addr = (sel?b1+b*z1:b0+b*z0) + r*ldb.
// C: ci = (gm>>cMsh)*cMslab + (gm&cMmask)*ldc + gn  (node-major Tn layout).
template <int MT, int NT>
__global__ __launch_bounds__(256) void mfma6(
    const fp16* __restrict__ A, int lda,
    const fp16* __restrict__ b0, const fp16* __restrict__ b1, int rsh, int ssh,
    long long z0, long long z1, int ldb,
    fp16* __restrict__ C, int ldc, int cMsh, long long cMslab,
    int K) {
  __shared__ fp16 As[2][MT * 32];
  __shared__ fp16 Bs[2][NT * 32];
  const int tid = threadIdx.x;
  const int gm0 = blockIdx.x * MT, n0 = blockIdx.y * NT;
  const unsigned cMmask = (1u << cMsh) - 1u;
  const int lane = tid & 63, wv = tid >> 6;
  const int wr = wv >> 1, wc = wv & 1;
  const int quad = lane >> 4, ln = lane & 15;
  constexpr int WM = MT / 32, WN = NT / 32;

  const fp16* aSrc[MT / 64];
  const fp16* bSrc[NT / 64];
#pragma unroll
  for (int i = 0; i < MT / 64; ++i) {
    int c = i * 256 + tid;
    int row = c >> 2;
    int lseg = (c & 3) ^ (row & 3);
    aSrc[i] = A + (long long)(gm0 + row) * lda + lseg * 8;
  }
#pragma unroll
  for (int i = 0; i < NT / 64; ++i) {
    int c = i * 256 + tid;
    int row = c >> 2;
    int lseg = (c & 3) ^ (row & 3);
    int gn = n0 + row;
    unsigned b = (unsigned)gn >> rsh;
    unsigned wi = (unsigned)gn & ((1u << rsh) - 1u);
    unsigned sel = wi >> ssh;
    unsigned r = wi & ((1u << ssh) - 1u);
    const fp16* bb = sel ? (b1 + (long long)b * z1) : (b0 + (long long)b * z0);
    bSrc[i] = bb + (long long)r * ldb + lseg * 8;
  }

  f32x4 acc[WM][WN];
#pragma unroll
  for (int i = 0; i < WM; ++i)
#pragma unroll
    for (int j = 0; j < WN; ++j) acc[i][j] = (f32x4){0.f, 0.f, 0.f, 0.f};

  const int sw = (quad ^ (ln & 3)) << 3;

#pragma unroll
  for (int i = 0; i < MT / 64; ++i) gload_lds16(aSrc[i], &As[0][(i * 256 + tid) * 8]);
#pragma unroll
  for (int i = 0; i < NT / 64; ++i) gload_lds16(bSrc[i], &Bs[0][(i * 256 + tid) * 8]);

  const int nk = K >> 5;
  for (int t = 0; t < nk; ++t) {
    const int buf = t & 1;
    __syncthreads();
    if (t + 1 < nk) {
      const int k1 = (t + 1) * 32;
#pragma unroll
      for (int i = 0; i < MT / 64; ++i)
        gload_lds16(aSrc[i] + k1, &As[buf ^ 1][(i * 256 + tid) * 8]);
#pragma unroll
      for (int i = 0; i < NT / 64; ++i)
        gload_lds16(bSrc[i] + k1, &Bs[buf ^ 1][(i * 256 + tid) * 8]);
    }
    f16x8 af[WM], bf[WN];
#pragma unroll
    for (int wm = 0; wm < WM; ++wm) {
      int row = wr * (MT / 2) + wm * 16 + ln;
      af[wm] = *(const f16x8*)&As[buf][row * 32 + sw];
    }
#pragma unroll
    for (int wn = 0; wn < WN; ++wn) {
      int row = wc * (NT / 2) + wn * 16 + ln;
      bf[wn] = *(const f16x8*)&Bs[buf][row * 32 + sw];
    }
#pragma unroll
    for (int wm = 0; wm < WM; ++wm)
#pragma unroll
      for (int wn = 0; wn < WN; ++wn)
        acc[wm][wn] =
            __builtin_amdgcn_mfma_f32_16x16x32_f16(af[wm], bf[wn], acc[wm][wn], 0, 0, 0);
  }
#pragma unroll
  for (int wm = 0; wm < WM; ++wm)
#pragma unroll
    for (int wn = 0; wn < WN; ++wn)
#pragma unroll
      for (int r = 0; r < 4; ++r) {
        int gm = gm0 + wr * (MT / 2) + wm * 16 + quad * 4 + r;
        int gn = n0 + wc * (NT / 2) + wn * 16 + ln;
        long long ci = ((long long)((unsigned)gm >> cMsh)) * cMslab +
                       (long long)(gm & cMmask) * ldc + gn;
        C[ci] = (fp16)acc[wm][wn][r];
      }
}

// ---------- k_zxtfin: ZXt[z][d][n] += w2T@Tmat[z]^T + teXb + seX; zero pad cols ----------
// M=64, NT=128, K=64 (single-shot, no double buffer). z local to half (0..95).
__global__ __launch_bounds__(256) void k_zxtfin(
    const fp16* __restrict__ w2T, const fp16* __restrict__ Tmat,
    fp16* __restrict__ ZXt, const float* __restrict__ teXb, const float* __restrict__ seX) {
  __shared__ fp16 As[64][72];
  __shared__ fp16 Bs[128][72];
  const int z = blockIdx.z;
  const int n0 = blockIdx.y * 128;
  const fp16* Tz = Tmat + (long long)z * 2048 * 64;
  fp16* Cz = ZXt + (long long)z * 64 * 2048;
  const float* tb = teXb + z * 64;
  const int tid = threadIdx.x;
  const int lane = tid & 63, wv = tid >> 6;
  const int wr = wv >> 1, wc = wv & 1;
  const int quad = lane >> 4, ln = lane & 15;
#pragma unroll
  for (int i = 0; i < 2; ++i) {
    int c = tid + 256 * i;
    int row = c >> 3, seg = c & 7;
    *(f16x8*)&As[row][seg * 8] = *(const f16x8*)(w2T + row * 64 + seg * 8);
  }
#pragma unroll
  for (int i = 0; i < 4; ++i) {
    int c = tid + 256 * i;
    int row = c >> 3, seg = c & 7;
    *(f16x8*)&Bs[row][seg * 8] =
        *(const f16x8*)(Tz + (long long)(n0 + row) * 64 + seg * 8);
  }
  __syncthreads();
  f32x4 acc[2][4];
#pragma unroll
  for (int i = 0; i < 2; ++i)
#pragma unroll
    for (int j = 0; j < 4; ++j) acc[i][j] = (f32x4){0.f, 0.f, 0.f, 0.f};
#pragma unroll
  for (int kt = 0; kt < 2; ++kt) {
    f16x8 af[2], bf[4];
#pragma unroll
    for (int wm = 0; wm < 2; ++wm)
      af[wm] = *(const f16x8*)&As[wr * 32 + wm * 16 + ln][kt * 32 + quad * 8];
#pragma unroll
    for (int wn = 0; wn < 4; ++wn)
      bf[wn] = *(const f16x8*)&Bs[wc * 64 + wn * 16 + ln][kt * 32 + quad * 8];
#pragma unroll
    for (int wm = 0; wm < 2; ++wm)
#pragma unroll
      for (int wn = 0; wn < 4; ++wn)
        acc[wm][wn] =
            __builtin_amdgcn_mfma_f32_16x16x32_f16(af[wm], bf[wn], acc[wm][wn], 0, 0, 0);
  }
#pragma unroll
  for (int wm = 0; wm < 2; ++wm)
#pragma unroll
    for (int wn = 0; wn < 4; ++wn)
#pragma unroll
      for (int r = 0; r < 4; ++r) {
        int gm = wr * 32 + wm * 16 + quad * 4 + r;
        int gn = n0 + wc * 64 + wn * 16 + ln;
        long long ci = (long long)gm * 2048 + gn;
        float v = 0.f;
        if (gn < NN)
          v = acc[wm][wn][r] + (float)Cz[ci] + tb[gm] + seX[(long long)gn * 64 + gm];
        Cz[ci] = (fp16)v;
      }
}

// ---------- ConvLSTM conv, mfma4-style with zero-padded 34x34 halo ----------
__global__ __launch_bounds__(256) void k_conv4(
    const fp16* __restrict__ Zfp, const fp16* __restrict__ hp,
    const fp16* __restrict__ wcatT, fp16* __restrict__ gates, int p) {
  __shared__ fp16 As[2][128 * 32];
  __shared__ fp16 Bs[2][64 * 32];
  const int gm0 = blockIdx.x * 128, n0 = blockIdx.y * 64;
  const int tid = threadIdx.x;
  const int lane = tid & 63, wv = tid >> 6;
  const int wr = wv >> 1, wc = wv & 1;
  const int quad = lane >> 4, ln = lane & 15;

  long long aZ[2], aH[2];
#pragma unroll
  for (int i = 0; i < 2; ++i) {
    int c = tid + 256 * i;
    int row = c >> 2;
    int lseg = (c & 3) ^ (row & 3);
    int m = gm0 + row;
    int b = m >> 10, y = (m >> 5) & 31, x = m & 31;
    int pc = (y + 1) * GP + (x + 1);
    aZ[i] = ((long long)(b * PP + p) * GP2 + pc) * 64 + lseg * 8;
    aH[i] = ((long long)b * GP2 + pc) * 64 + lseg * 8;
  }
  const fp16* bBase;
  {
    int row = tid >> 2;
    int lseg = (tid & 3) ^ (row & 3);
    bBase = wcatT + (long long)(n0 + row) * 1152 + lseg * 8;
  }
  f32x4 acc[4][2];
#pragma unroll
  for (int i = 0; i < 4; ++i)
#pragma unroll
    for (int j = 0; j < 2; ++j) acc[i][j] = (f32x4){0.f, 0.f, 0.f, 0.f};

  auto stage = [&](int t, int buf) {
    int tap = (t >> 1) % 9, half = t & 1;
    int srcsel = t >= 18;
    int off = ((tap / 3 - 1) * GP + (tap % 3 - 1)) * 64 + half * 32;
#pragma unroll
    for (int i = 0; i < 2; ++i) {
      const fp16* src = srcsel ? (hp + aH[i] + off) : (Zfp + aZ[i] + off);
      gload_lds16(src, &As[buf][(i * 256 + tid) * 8]);
    }
    gload_lds16(bBase + t * 32, &Bs[buf][tid * 8]);
  };
  stage(0, 0);
  const int sw = (quad ^ (ln & 3)) << 3;
  for (int t = 0; t < 36; ++t) {
    const int buf = t & 1;
    __syncthreads();
    if (t + 1 < 36) stage(t + 1, buf ^ 1);
    f16x8 af[4], bf[2];
#pragma unroll
    for (int wm = 0; wm < 4; ++wm) {
      int row = wr * 64 + wm * 16 + ln;
      af[wm] = *(const f16x8*)&As[buf][row * 32 + sw];
    }
#pragma unroll
    for (int wn = 0; wn < 2; ++wn) {
      int row = wc * 32 + wn * 16 + ln;
      bf[wn] = *(const f16x8*)&Bs[buf][row * 32 + sw];
    }
#pragma unroll
    for (int wm = 0; wm < 4; ++wm)
#pragma unroll
      for (int wn = 0; wn < 2; ++wn)
        acc[wm][wn] =
            __builtin_amdgcn_mfma_f32_16x16x32_f16(af[wm], bf[wn], acc[wm][wn], 0, 0, 0);
  }
#pragma unroll
  for (int wm = 0; wm < 4; ++wm)
#pragma unroll
    for (int wn = 0; wn < 2; ++wn)
#pragma unroll
      for (int r = 0; r < 4; ++r) {
        int gm = gm0 + wr * 64 + wm * 16 + quad * 4 + r;
        int gn = n0 + wc * 32 + wn * 16 + ln;
        gates[(long long)gm * 256 + gn] = (fp16)acc[wm][wn][r];
      }
}

__global__ void k_clstm_update(const fp16* __restrict__ gates, float* __restrict__ c,
                               fp16* __restrict__ h, fp16* __restrict__ ZclT, int p) {
  long long i = (long long)blockIdx.x * 256 + threadIdx.x;
  if (i >= (long long)BB * CC * 64) return;
  int d = (int)(i & 63);
  long long bc = i >> 6;
  int b = (int)(bc >> 10);
  int cell = (int)(bc & 1023);
  const fp16* g = gates + (((long long)b * CC) + cell) * 256;
  float gi = (float)g[d], gf = (float)g[64 + d], gg = (float)g[128 + d],
        go = (float)g[192 + d];
  float hs_f = fminf(fmaxf(0.2f * gf + 0.5f, 0.f), 1.f);
  float hs_i = fminf(fmaxf(0.2f * gi + 0.5f, 0.f), 1.f);
  float hs_o = fminf(fmaxf(0.2f * go + 0.5f, 0.f), 1.f);
  float cv = hs_f * c[i] + hs_i * tanhf(gg);
  c[i] = cv;
  float hv = hs_o * tanhf(cv);
  int pc = ((cell >> 5) + 1) * GP + (cell & 31) + 1;
  h[((long long)b * GP2 + pc) * 64 + d] = (fp16)hv;
  ZclT[(((long long)(b * PP + p)) * 64 + d) * CC + cell] = (fp16)hv;
}

// Tmat[z][n][64] with 2048-row stride per z (pad rows garbage; finisher ignores)
__global__ void k_tmat(const float* __restrict__ X, const float* __restrict__ w1,
                       const float* __restrict__ b1, fp16* __restrict__ T, long long nrows) {
  long long i = (long long)blockIdx.x * 256 + threadIdx.x;
  if (i >= nrows * 64) return;
  int j = (int)(i & 63);
  long long row = i >> 6;
  int z = (int)(row / NN);
  int n = (int)(row - (long long)z * NN);
  T[(((long long)z * 2048) + n) * 64 + j] = (fp16)fmaxf(X[row] * w1[j] + b1[j], 0.f);
}

__global__ void k_trT(const fp16* __restrict__ U0, float* __restrict__ htmp) {
  long long i = (long long)blockIdx.x * 256 + threadIdx.x;
  if (i >= (long long)BB * NN * 64) return;
  int d = (int)(i & 63);
  long long bn = i >> 6;
  int b = (int)(bn / NN);
  int n = (int)(bn % NN);
  htmp[i] = (float)U0[((long long)b * 192 + 64 + d) * 2048 + n];
}

__global__ void k_out(const float* __restrict__ Y, float* __restrict__ out) {
  int i = blockIdx.x * 256 + threadIdx.x;
  if (i >= BB * QQ * NN) return;
  int n = i % NN;
  int bq = i / NN;
  int b = bq / QQ, q = bq % QQ;
  out[i] = Y[((long long)b * NN + n) * 12 + q];
}

// ---------- host helpers ----------
template <typename TA, typename TB, typename TC>
static void launch_gemm(hipStream_t stream, const TA* A, int lda, long long sA,
                        const TB* Bm, int ldb, long long sB, TC* Cm, int ldc, long long sC,
                        const TC* S, long long sS, const float* bias, int M, int Nc, int K,
                        float alpha, float beta, int act, int batch) {
  dim3 g((M + 63) / 64, (Nc + 63) / 64, batch);
  gemm_t<TA, TB, TC><<<g, dim3(256), 0, stream>>>(A, lda, sA, Bm, ldb, sB, Cm, ldc, sC, S,
                                                  sS, bias, M, Nc, K, alpha, beta, act);
}

extern "C" void kernel_launch(void* const* d_in, const int* in_sizes, int n_in,
                              void* d_out, int out_size, void* d_ws, size_t ws_size,
                              hipStream_t stream) {
  char* base = (char*)d_ws;
  size_t off = 0;
  auto alloc_bytes = [&](size_t nb) -> char* {
    char* p = base + off;
    off += (nb + 255) & ~(size_t)255;
    return p;
  };
  auto allocf = [&](size_t n) -> float* { return (float*)alloc_bytes(n * 4); };
  auto alloch = [&](size_t n) -> fp16* { return (fp16*)alloc_bytes(n * 2); };

  const float* X = (const float*)d_in[0];
  const float* Z = (const float*)d_in[1];
  const int* TE = (const int*)d_in[2];
  const float* adj_gg = (const float*)d_in[3];
  const float* adj_gr = (const float*)d_in[4];
  const float* gumbel = (const float*)d_in[5];
  const float* se_x = (const float*)d_in[6];
  const float* se_z = (const float*)d_in[7];
  const float* movement = (const float*)d_in[8];
  auto W = [&](int i) { return (const float*)d_in[i]; };

  // ---- allocations ----
  fp16* wcatT = alloch((size_t)256 * 1152);  // [n][k] pre-transposed conv weights
  fp16* gwT = alloch(128 * 512);
  fp16* cwT = alloch(64 * 512);
  fp16* w2T = alloch(64 * 64);
  fp16* w2mT = alloch(64 * 64);
  float* dinv = allocf(NN);
  fp16* LMall = alloch((size_t)6144 * 2048);  // rows padded to 2048 for maskless mfma4/6
  fp16* mZh = alloch((size_t)CC * CC);
  fp16* agh2 = alloch((size_t)2048 * CC);  // padded to 2048 rows (pad rows zero)
  float* seZ = allocf(CC * 64);
  float* teZ = allocf(BB * PP * 64);
  float* seX = allocf(NN * 64);
  float* teXb = allocf(BB * PP * 64);
  float* mtmp = allocf(NN * 64);
  float* tetmp = allocf(BB * PP * 64);
  fp16* ruT = alloch((size_t)BB * 128 * NN);  // [b][128][2000]
  // pool (4*USL = 50.33MB):
  //  phase A: conv gates[0..8.4M] / chh(pad h)[+8.39M] / ccc[+12.58M]
  //  phase B: Zmix[0..25.2M], ZmovT[+25.17M..50.33M]
  //  phase C: U0[0..12.58M] | Tn (3 gate-cheb slabs, 25.17M) | Tn2 (3 cand slabs, 12.58M)
  char* pool = alloc_bytes(50331648);
  fp16* Uall = (fp16*)pool;
  fp16* gates = (fp16*)pool;
  fp16* chh = (fp16*)(pool + 8388608);   // padded h [16][1156][64]
  float* ccc = (float*)(pool + 12582912);
  fp16* Zmix = (fp16*)pool;
  fp16* ZmovT = (fp16*)(pool + 25165824);
  // zpool: Zf_pad [bp][1156][64] (28.4MB) then ZXt [bp][64][2048]
  fp16* zpool = alloch((size_t)BB * PP * 64 * 2048);
  fp16* Zfp = zpool;
  fp16* ZXt = zpool;
  fp16* Zc = alloch((size_t)BB * PP * CC * 64);  // zf1 scratch -> ZclT -> Tmat -> head scratch

  if (off > ws_size) return;

  const long long uB = 192LL * 2048;
  const long long USL = 16LL * uB;
  const long long ZXB = 12LL * 64 * 2048;  // per-batch stride of ZXt
  fp16* Lh = LMall;
  fp16* M2h = LMall + 2048LL * 2048;
  fp16* M3h = LMall + 4096LL * 2048;
  const int KCH = 2016;  // chain K (2000 padded to x32; cols 2000..2015 zero)

  // ---- precompute ----
  k_wcatT<<<dim3(1152), dim3(256), 0, stream>>>(wcatT, W(39), W(40));
  k_gru_repackT<<<dim3(256), dim3(256), 0, stream>>>(gwT, W(41), 128);
  k_gru_repackT<<<dim3(128), dim3(256), 0, stream>>>(cwT, W(43), 64);
  k_w2T<<<dim3(16), dim3(256), 0, stream>>>(w2T, W(31));
  k_w2T<<<dim3(16), dim3(256), 0, stream>>>(w2mT, W(33));
  k_dinv<<<dim3(NN), dim3(256), 0, stream>>>(adj_gg, dinv);
  hipMemsetAsync(LMall, 0, (size_t)6144 * 2048 * 2, stream);
  k_L<<<dim3((NN * NN + 255) / 256), dim3(256), 0, stream>>>(adj_gg, dinv, Lh);
  mfma4<64, 128><<<dim3(32, 16, 1), dim3(256), 0, stream>>>(
      Lh, Lh, 31, 31, 0LL, 0LL, 2048, Lh, 2048, 0LL, M2h, 2048, 0LL, 31, 0LL, 31, 0LL,
      (const fp16*)nullptr, 2.f, 0.f, KCH);
  k_subdiag<<<dim3((NN + 255) / 256), dim3(256), 0, stream>>>(M2h);
  mfma4<64, 128><<<dim3(32, 16, 1), dim3(256), 0, stream>>>(
      Lh, Lh, 31, 31, 0LL, 0LL, 2048, M2h, 2048, 0LL, M3h, 2048, 0LL, 31, 0LL, 31, 0LL,
      (const fp16*)Lh, 2.f, -1.f, KCH);
  k_gumbel_softmax<<<dim3(CC), dim3(256), 0, stream>>>(movement, gumbel, mZh);
  k_f2h<<<dim3((NN * CC + 255) / 256), dim3(256), 0, stream>>>(agh2, adj_gr,
                                                               (long long)NN * CC);
  hipMemsetAsync(agh2 + (size_t)NN * CC, 0, (size_t)(2048 - NN) * CC * 2, stream);

  // ---- STEZ / STEX ----
  launch_gemm(stream, se_z, 64, 0LL, W(17), 64, 0LL, mtmp, 64, 0LL, (float*)nullptr, 0LL,
              W(18), CC, 64, 64, 1.f, 0.f, 1, 1);
  launch_gemm(stream, (const float*)mtmp, 64, 0LL, W(19), 64, 0LL, seZ, 64, 0LL,
              (float*)nullptr, 0LL, W(20), CC, 64, 64, 1.f, 0.f, 0, 1);
  k_te<<<dim3((BB * PP * 64 + 255) / 256), dim3(256), 0, stream>>>(TE, W(21), W(22), tetmp);
  launch_gemm(stream, (const float*)tetmp, 64, 0LL, W(23), 64, 0LL, teZ, 64, 0LL,
              (float*)nullptr, 0LL, W(24), BB * PP, 64, 64, 1.f, 0.f, 0, 1);
  launch_gemm(stream, se_x, 64, 0LL, W(9), 64, 0LL, mtmp, 64, 0LL, (float*)nullptr, 0LL,
              W(10), NN, 64, 64, 1.f, 0.f, 1, 1);
  launch_gemm(stream, (const float*)mtmp, 64, 0LL, W(11), 64, 0LL, seX, 64, 0LL,
              (float*)nullptr, 0LL, W(12), NN, 64, 64, 1.f, 0.f, 0, 1);
  k_te<<<dim3((BB * PP * 64 + 255) / 256), dim3(256), 0, stream>>>(TE, W(13), W(14), tetmp);
  launch_gemm(stream, (const float*)tetmp, 64, 0LL, W(15), 64, 0LL, teXb, 64, 0LL,
              (float*)nullptr, 0LL, W(16), BB * PP, 64, 64, 1.f, 0.f, 0, 1);
  k_addb<<<dim3((BB * PP * 64 + 255) / 256), dim3(256), 0, stream>>>(teXb, W(32),
                                                                     BB * PP * 64);

  // ---- Zf = mlp2(Z) + STEZ, scattered into padded 34x34 layout ----
  long long nZ = (long long)BB * PP * CC * 64;
  k_zf1<<<dim3((int)((nZ + 255) / 256)), dim3(256), 0, stream>>>(Z, W(25), W(26), Zc);
  // Zf (unpadded) scratch goes in ruT+? -> use pool front (dead): Zftmp = Uall
  launch_gemm(stream, (const fp16*)Zc, 64, 0LL, W(27), 64, 0LL, (fp16*)pool, 64, 0LL,
              (fp16*)nullptr, 0LL, W(28), BB * PP * CC, 64, 64, 1.f, 0.f, 0, 1);
  hipMemsetAsync(zpool, 0, (size_t)BB * PP * GP2 * 64 * 2, stream);  // zero Zf_pad (halo)
  k_add_stez<<<dim3((int)((nZ + 255) / 256)), dim3(256), 0, stream>>>(Zfp, (fp16*)pool,
                                                                      seZ, teZ);
  // NOTE: conv gates alias pool[0..8.4MB] = Zftmp — Zftmp is consumed by k_add_stez
  // before the first k_conv4 writes gates.

  // ---- ConvLSTM (writes ZclT into Zc; h in padded chh) ----
  hipMemsetAsync(chh, 0, (size_t)BB * GP2 * 64 * 2, stream);
  hipMemsetAsync(ccc, 0, (size_t)BB * CC * 64 * 4, stream);
  for (int p = 0; p < PP; ++p) {
    k_conv4<<<dim3(BB * CC / 128, 4), dim3(256), 0, stream>>>(Zfp, chh, wcatT, gates, p);
    k_clstm_update<<<dim3((int)(((long long)BB * CC * 64 + 255) / 256)), dim3(256), 0,
                     stream>>>(gates, ccc, chh, Zc, p);
  }

  // ---- movement m1 (mfma4, z-batched) / m2 ----
  mfma4<128, 64><<<dim3(8, 1, 192), dim3(256), 0, stream>>>(
      mZh, mZh, 31, 31, 0LL, 0LL, CC, (const fp16*)Zc, CC, (long long)64 * CC, Zmix, 64,
      (long long)CC * 64, 31, 0LL, 31, 0LL, (const fp16*)nullptr, 1.f, 0.f, CC);
  mfma3<64, 128><<<dim3(1, 8, 192), dim3(256), 0, stream>>>(
      w2mT, 64, 0LL, 31, 0LL, Zmix, 64, (long long)CC * 64, ZmovT, CC, (long long)64 * CC,
      31, 0LL, 31, 0LL, (const fp16*)nullptr, 0LL, 0.f, W(34), 0LL, nullptr, 0, 64, CC, 64,
      1.f, 1);

  // ---- zxt term1: one big GEMM, M = 192*64 = 12288 rows of ZmovT ----
  mfma4<128, 128><<<dim3(96, 16, 1), dim3(256), 0, stream>>>(
      ZmovT, ZmovT, 31, 31, 0LL, 0LL, 1024, agh2, 1024, 0LL, ZXt, 2048, 0LL, 31, 0LL, 31,
      0LL, (const fp16*)nullptr, 1.f, 0.f, 1024);

  // ---- zxt term2 + biases (two halves; Tmat padded to 2048 rows/z in dead Zc) ----
  fp16* Tmat = Zc;
  for (int half = 0; half < 2; ++half) {
    long long z0 = 96LL * half;
    k_tmat<<<dim3((int)((96LL * NN * 64 + 255) / 256)), dim3(256), 0, stream>>>(
        X + z0 * NN, W(29), W(30), Tmat, 96LL * NN);
    k_zxtfin<<<dim3(1, 16, 96), dim3(256), 0, stream>>>(
        w2T, Tmat, ZXt + z0 * 64 * 2048, teXb + z0 * 64, seX);
  }

  // ---- DCGRU (Tn-layout chebs; h lives in U0 rows 64..127; x read from ZXt) ----
  fp16* U0 = Uall;
  fp16* Tn = Uall + USL;        // 3 slabs [2048 n][16*128]
  fp16* Tn2 = Uall + 3 * USL;   // 3 slabs [2048 n][16*64]
  const long long TnSlab = 2048LL * 2048;
  const long long Tn2Slab = 2048LL * 1024;
  hipMemsetAsync(U0, 0, (size_t)USL * 2, stream);  // zero slab 0 (h/rh rows + pads)
  for (int p = 0; p < PP; ++p) {
    const fp16* xP = ZXt + (long long)p * 64 * 2048;
    // gate chebs: Tn[s][n][z*128+row] = LM_s @ [x|h]^T
    mfma6<128, 128><<<dim3(48, 16), dim3(256), 0, stream>>>(
        LMall, 2048, xP, U0 + 64 * 2048, 7, 6, ZXB, uB, 2048, Tn, 2048, 11, TnSlab, KCH);
    // ruT = sigmoid(gwT @ chebs); epilogue writes rh = r*h into U0 rows 128..191
    mfma5<128, 1><<<dim3(1, 32, BB), dim3(256), 0, stream>>>(
        gwT, 512, U0, uB, 0, xP, ZXB, Tn, TnSlab, (const fp16*)nullptr, 0LL, ruT, NN,
        (long long)128 * NN, W(42), U0 + 128 * 2048, U0 + 64 * 2048,
        (const fp16*)nullptr, 0LL, 128, NN, 512);
    // cand chebs: Tn2[s][n][z*64+row] = LM_s @ rh^T
    mfma6<128, 128><<<dim3(48, 8), dim3(256), 0, stream>>>(
        LMall, 2048, U0 + 128 * 2048, U0 + 128 * 2048, 6, 6, uB, uB, 2048, Tn2, 1024, 11,
        Tn2Slab, KCH);
    // cnd GEMM; epilogue does h' = u*h + (1-u)*tanh(v) in place in U0 rows 64..127
    mfma5<64, 2><<<dim3(1, 32, BB), dim3(256), 0, stream>>>(
        cwT, 512, U0, uB, 64, xP, ZXB, Tn, TnSlab, Tn2, Tn2Slab, U0 + 64 * 2048, 2048, uB,
        W(44), (fp16*)nullptr, (const fp16*)nullptr, (const fp16*)ruT, (long long)128 * NN,
        64, NN, 512);
  }

  // ---- output head (all scratch in dead Zc; U0 untouched until read) ----
  float* htmp = (float*)Zc;                       // 8.19 MB
  float* out1 = (float*)(Zc + 5120000);           // byte 10.24 MB, 8.19 MB
  float* out2 = (float*)(Zc + 10240000);          // byte 20.48 MB, 1.54 MB
  k_trT<<<dim3((int)(((long long)BB * NN * 64 + 255) / 256)), dim3(256), 0, stream>>>(U0,
                                                                                      htmp);
  launch_gemm(stream, (const float*)htmp, 64, 0LL, W(35), 64, 0LL, out1, 64, 0LL,
              (float*)nullptr, 0LL, W(36), BB * NN, 64, 64, 1.f, 0.f, 1, 1);
  launch_gemm(stream, (const float*)out1, 64, 0LL, W(37), 12, 0LL, out2, 12, 0LL,
              (float*)nullptr, 0LL, W(38), BB * NN, 12, 64, 1.f, 0.f, 0, 1);
  k_out<<<dim3((BB * QQ * NN + 255) / 256), dim3(256), 0, stream>>>(out2, (float*)d_out);
}

// Round 5
// 2998.108 us; speedup vs baseline: 1.7782x; 1.0401x over previous
//
#include <hip/hip_runtime.h>
#include <hip/hip_bf16.h>
#include <math.h>

typedef _Float16 fp16;
typedef _Float16 f16x8 __attribute__((ext_vector_type(8)));
typedef float f32x4 __attribute__((ext_vector_type(4)));

#define BB 16
#define PP 12
#define QQ 12
#define NN 2000
#define CC 1024
#define GP 34   // padded grid side (32 + halo)
#define GP2 1156

static __device__ __forceinline__ float ldf(float v) { return v; }
static __device__ __forceinline__ float ldf(fp16 v) { return (float)v; }
static __device__ __forceinline__ void stf(float* p, float v) { *p = v; }
static __device__ __forceinline__ void stf(fp16* p, float v) { *p = (fp16)v; }

// async global->LDS, 16B per lane (wave-uniform LDS base + lane*16)
static __device__ __forceinline__ void gload_lds16(const fp16* g, fp16* l) {
  __builtin_amdgcn_global_load_lds(
      (const __attribute__((address_space(1))) void*)g,
      (__attribute__((address_space(3))) void*)l, 16, 0, 0);
}

// ---------- conversions / repacks ----------
__global__ void k_f2h(fp16* __restrict__ dst, const float* __restrict__ src, long long n) {
  long long i = (long long)blockIdx.x * 256 + threadIdx.x;
  if (i < n) dst[i] = (fp16)src[i];
}

// wcatT[n][kk] = wcat[kk][n], kk<576 from W39, else W40 (each [576][256])
__global__ void k_wcatT(fp16* __restrict__ dst, const float* __restrict__ w39,
                        const float* __restrict__ w40) {
  int i = blockIdx.x * 256 + threadIdx.x;
  if (i >= 1152 * 256) return;
  int n = i & 255, kk = i >> 8;
  float v = (kk < 576) ? w39[kk * 256 + n] : w40[(kk - 576) * 256 + n];
  dst[(long long)n * 1152 + kk] = (fp16)v;
}

// dcgru weights (512,O): row=f*4+t -> Wt[d][t*128+c] = src[(c*4+t)*O+d]
__global__ void k_gru_repackT(fp16* __restrict__ dst, const float* __restrict__ src, int O) {
  int i = blockIdx.x * 256 + threadIdx.x;
  if (i >= O * 512) return;
  int d = i >> 9;
  int kc = i & 511;
  int t = kc >> 7;
  int c = kc & 127;
  dst[i] = (fp16)src[(c * 4 + t) * O + d];
}

// (64,64) -> T[d][k] fp16
__global__ void k_w2T(fp16* __restrict__ dst, const float* __restrict__ src) {
  int i = blockIdx.x * 256 + threadIdx.x;
  if (i >= 4096) return;
  int d = i >> 6, k = i & 63;
  dst[i] = (fp16)src[k * 64 + d];
}

// ---------- laplacian ----------
__global__ void k_dinv(const float* __restrict__ adj, float* __restrict__ dinv) {
  int row = blockIdx.x;
  float s = 0.f;
  for (int j = threadIdx.x; j < NN; j += 256)
    s += fmaxf(adj[(long long)row * NN + j], adj[(long long)j * NN + row]);
  __shared__ float red[256];
  red[threadIdx.x] = s;
  __syncthreads();
  for (int st = 128; st > 0; st >>= 1) {
    if (threadIdx.x < st) red[threadIdx.x] += red[threadIdx.x + st];
    __syncthreads();
  }
  if (threadIdx.x == 0) {
    float d = red[0];
    dinv[row] = d > 0.f ? 1.0f / sqrtf(d) : 0.f;
  }
}

// writes L with row stride 2048 (zero-padded for maskless mfma4)
__global__ void k_L(const float* __restrict__ adj, const float* __restrict__ dinv,
                    fp16* __restrict__ Lh) {
  long long i = (long long)blockIdx.x * 256 + threadIdx.x;
  if (i >= (long long)NN * NN) return;
  int r = (int)(i / NN), c = (int)(i % NN);
  float a = fmaxf(adj[(long long)r * NN + c], adj[(long long)c * NN + r]);
  Lh[(long long)r * 2048 + c] = (fp16)(-dinv[r] * a * dinv[c]);
}

__global__ void k_subdiag(fp16* __restrict__ M2) {
  int i = blockIdx.x * 256 + threadIdx.x;
  if (i >= NN) return;
  M2[(long long)i * 2048 + i] = (fp16)((float)M2[(long long)i * 2048 + i] - 1.0f);
}

// ---------- gumbel softmax -> fp16 ----------
__global__ void k_gumbel_softmax(const float* __restrict__ ml, const float* __restrict__ gn,
                                 fp16* __restrict__ mZ) {
  int row = blockIdx.x;
  __shared__ float buf[CC];
  __shared__ float red[256];
  int t = threadIdx.x;
  float mx = -1e30f;
  for (int j = t; j < CC; j += 256) {
    float u = gn[(long long)row * CC + j];
    float g = -logf(-logf(u + 1e-20f) + 1e-20f);
    float v = ml[(long long)row * CC + j] + g;
    buf[j] = v;
    mx = fmaxf(mx, v);
  }
  red[t] = mx;
  __syncthreads();
  for (int st = 128; st > 0; st >>= 1) {
    if (t < st) red[t] = fmaxf(red[t], red[t + st]);
    __syncthreads();
  }
  mx = red[0];
  __syncthreads();
  float s = 0.f;
  for (int j = t; j < CC; j += 256) {
    float e = expf(buf[j] - mx);
    buf[j] = e;
    s += e;
  }
  red[t] = s;
  __syncthreads();
  for (int st = 128; st > 0; st >>= 1) {
    if (t < st) red[t] += red[t + st];
    __syncthreads();
  }
  float inv = 1.0f / red[0];
  for (int j = t; j < CC; j += 256) mZ[(long long)row * CC + j] = (fp16)(buf[j] * inv);
}

__global__ void k_te(const int* __restrict__ TE, const float* __restrict__ w1,
                     const float* __restrict__ b1, float* __restrict__ tmp) {
  int i = blockIdx.x * 256 + threadIdx.x;
  if (i >= BB * PP * 64) return;
  int j = i & 63;
  int bp = i >> 6;
  int b = bp / PP, p = bp % PP;
  int te0 = TE[(b * (PP + QQ) + p) * 2 + 0];
  int te1 = TE[(b * (PP + QQ) + p) * 2 + 1];
  float v = w1[te0 * 64 + j] + w1[(7 + te1) * 64 + j] + b1[j];
  tmp[i] = fmaxf(v, 0.f);
}

__global__ void k_addb(float* __restrict__ dst, const float* __restrict__ b, int n) {
  int i = blockIdx.x * 256 + threadIdx.x;
  if (i < n) dst[i] += b[i & 63];
}

__global__ void k_zf1(const float* __restrict__ Z, const float* __restrict__ w1,
                      const float* __restrict__ b1, fp16* __restrict__ tmp) {
  long long i = (long long)blockIdx.x * 256 + threadIdx.x;
  if (i >= (long long)BB * PP * CC * 64) return;
  int j = (int)(i & 63);
  long long row = i >> 6;
  float v = Z[row * 2 + 0] * w1[j] + Z[row * 2 + 1] * w1[64 + j] + b1[j];
  tmp[i] = (fp16)fmaxf(v, 0.f);
}

// scatter Zf (unpadded) + STEZ into padded 34x34 grid layout
__global__ void k_add_stez(fp16* __restrict__ dst, const fp16* __restrict__ src,
                           const float* __restrict__ seZ, const float* __restrict__ teZ) {
  long long i = (long long)blockIdx.x * 256 + threadIdx.x;
  if (i >= (long long)BB * PP * CC * 64) return;
  int j = (int)(i & 63);
  long long row = i >> 6;
  int c = (int)(row & 1023);
  int bp = (int)(row >> 10);
  int pc = ((c >> 5) + 1) * GP + (c & 31) + 1;
  dst[((long long)bp * GP2 + pc) * 64 + j] =
      (fp16)((float)src[i] + seZ[c * 64 + j] + teZ[bp * 64 + j]);
}

// ---------- generic fp32-path GEMM (small ops) ----------
template <typename TA, typename TB, typename TC>
__global__ __launch_bounds__(256) void gemm_t(
    const TA* __restrict__ A, int lda, long long sA,
    const TB* __restrict__ Bm, int ldb, long long sB,
    TC* Cm, int ldc, long long sC,
    const TC* S, long long sS,
    const float* __restrict__ bias,
    int M, int Ncols, int K, float alpha, float beta, int act) {
  int bz = blockIdx.z;
  A += (long long)bz * sA;
  Bm += (long long)bz * sB;
  Cm += (long long)bz * sC;
  if (S) S += (long long)bz * sS;
  const int row0 = blockIdx.x * 64, col0 = blockIdx.y * 64;
  __shared__ float As[16][68];
  __shared__ float Bs[16][68];
  int tid = threadIdx.x, tx = tid & 15, ty = tid >> 4;
  float acc[4][4] = {};
  for (int k0 = 0; k0 < K; k0 += 16) {
#pragma unroll
    for (int j = 0; j < 4; ++j) {
      int e = tid + 256 * j;
      int m = e >> 4, kk = e & 15;
      int gm = row0 + m;
      As[kk][m] = (gm < M) ? ldf(A[(long long)gm * lda + k0 + kk]) : 0.f;
    }
#pragma unroll
    for (int j = 0; j < 4; ++j) {
      int e = tid + 256 * j;
      int kk = e >> 6, n = e & 63;
      int gn = col0 + n;
      Bs[kk][n] = (gn < Ncols) ? ldf(Bm[(long long)(k0 + kk) * ldb + gn]) : 0.f;
    }
    __syncthreads();
#pragma unroll
    for (int kk = 0; kk < 16; ++kk) {
      float a[4], bb[4];
#pragma unroll
      for (int i = 0; i < 4; ++i) a[i] = As[kk][ty * 4 + i];
#pragma unroll
      for (int j = 0; j < 4; ++j) bb[j] = Bs[kk][tx * 4 + j];
#pragma unroll
      for (int i = 0; i < 4; ++i)
#pragma unroll
        for (int j = 0; j < 4; ++j) acc[i][j] = fmaf(a[i], bb[j], acc[i][j]);
    }
    __syncthreads();
  }
#pragma unroll
  for (int i = 0; i < 4; ++i) {
    int r = row0 + ty * 4 + i;
    if (r >= M) continue;
#pragma unroll
    for (int j = 0; j < 4; ++j) {
      int cn = col0 + tx * 4 + j;
      if (cn >= Ncols) continue;
      float v = alpha * acc[i][j];
      if (bias) v += bias[cn];
      if (S) v += beta * ldf(S[(long long)r * ldc + cn]);
      if (act == 1) v = fmaxf(v, 0.f);
      else if (act == 2) v = 1.f / (1.f + expf(-v));
      else if (act == 3) v = tanhf(v);
      stf(&Cm[(long long)r * ldc + cn], v);
    }
  }
}

// ---------- mfma7: DCGRU weight GEMMs, mfma4-structure, fused GRU epilogues ----------
// K=512 fixed = 16 k-steps. Double-buffered LDS, gload_lds staging for A and for
// cheb slabs 1..3; slab0 (live xh) transpose-scatter directly into swizzled layout.
// B k-slab s>=1: kin<64 from Xc (x-chebs), kin>=64 from Hc (h/rh-chebs).
// MODE 1 (ru):  C=ruT [z][128][NN]; sigmoid; rows<64 also write rh=r*h into rhOut
// MODE 2 (cnd): tanh; h' = u*h + (1-u)*v written in-place into C (=U0 h-rows)
template <int MT, int MODE>
__global__ __launch_bounds__(256) void mfma7(
    const fp16* __restrict__ A,                       // weights MT x 512
    const fp16* __restrict__ U0base, long long uZ, int bHi,
    const fp16* __restrict__ xB, long long xZ,        // ZXt slab0 x rows (ld 2048)
    const fp16* __restrict__ Xc, long long XcSlab, int Xcld, int Xczmul,
    const fp16* __restrict__ Hc, long long HcSlab, int Hcld, int Hczmul,
    fp16* __restrict__ C, int ldc, long long cBatch,
    const float* __restrict__ bias,
    fp16* __restrict__ rhOut, const fp16* __restrict__ hIn,
    const fp16* __restrict__ uIn, long long uStride,
    int M, int Ncols) {
  __shared__ fp16 As[2][MT * 32];
  __shared__ fp16 Bs[2][64 * 32];
  const int z = blockIdx.z;
  const int n0 = blockIdx.y * 64;
  const fp16* U0z = U0base + (long long)z * uZ;
  const fp16* xBz = xB + (long long)z * xZ;
  C += (long long)z * cBatch;
  if (rhOut) rhOut += (long long)z * uZ;
  if (hIn) hIn += (long long)z * uZ;
  if (uIn) uIn += (long long)z * uStride;
  const int tid = threadIdx.x;
  const int lane = tid & 63, wv = tid >> 6;
  const int wr = wv >> 1, wc = wv & 1;
  const int quad = lane >> 4, ln = lane & 15;
  constexpr int WM = MT / 32;

  // A staging sources (seg pre-swizzled)
  const fp16* aSrc[MT / 64];
#pragma unroll
  for (int i = 0; i < MT / 64; ++i) {
    int c = i * 256 + tid;
    int row = c >> 2;
    int lseg = (c & 3) ^ (row & 3);
    aSrc[i] = A + (long long)row * 512 + lseg * 8;
  }
  // B slab>=1 per-thread geometry
  const int brow = tid >> 2;
  const int blseg = (tid & 3) ^ (brow & 3);
  const long long bnode = n0 + brow;

  f32x4 acc[WM][2];
#pragma unroll
  for (int i = 0; i < WM; ++i)
#pragma unroll
    for (int j = 0; j < 2; ++j) acc[i][j] = (f32x4){0.f, 0.f, 0.f, 0.f};

  auto stage = [&](int t, int buf) {
    const int k0 = t * 32;
#pragma unroll
    for (int i = 0; i < MT / 64; ++i)
      gload_lds16(aSrc[i] + k0, &As[buf][(i * 256 + tid) * 8]);
    if (k0 < 128) {
      // slab0: xh transpose-scatter into swizzled layout
      int kin = k0 + (tid & 31);
      int ngrp = tid >> 5;
      int n = n0 + ngrp * 8;
      const fp16* src = (kin < 64) ? (xBz + (long long)kin * 2048 + n)
                                   : (U0z + (long long)(kin + bHi) * 2048 + n);
      f16x8 v = *(const f16x8*)src;
      int kk = tid & 31;
#pragma unroll
      for (int j = 0; j < 8; ++j) {
        int rn = ngrp * 8 + j;
        Bs[buf][rn * 32 + ((((kk >> 3) ^ (rn & 3)) << 3) | (kk & 7))] = v[j];
      }
    } else {
      int slab = k0 >> 7;
      int kin = (k0 & 127) + blseg * 8;
      const fp16* src;
      if (kin < 64)
        src = Xc + (long long)(slab - 1) * XcSlab + bnode * Xcld +
              (long long)z * Xczmul + kin;
      else
        src = Hc + (long long)(slab - 1) * HcSlab + bnode * Hcld +
              (long long)z * Hczmul + (kin - 64);
      gload_lds16(src, &Bs[buf][tid * 8]);
    }
  };

  const int sw = (quad ^ (ln & 3)) << 3;
  stage(0, 0);
  for (int t = 0; t < 16; ++t) {
    const int buf = t & 1;
    __syncthreads();
    if (t + 1 < 16) stage(t + 1, buf ^ 1);
    f16x8 af[WM], bf[2];
#pragma unroll
    for (int wm = 0; wm < WM; ++wm) {
      int row = wr * (MT / 2) + wm * 16 + ln;
      af[wm] = *(const f16x8*)&As[buf][row * 32 + sw];
    }
#pragma unroll
    for (int wn = 0; wn < 2; ++wn) {
      int row = wc * 32 + wn * 16 + ln;
      bf[wn] = *(const f16x8*)&Bs[buf][row * 32 + sw];
    }
#pragma unroll
    for (int wm = 0; wm < WM; ++wm)
#pragma unroll
      for (int wn = 0; wn < 2; ++wn)
        acc[wm][wn] =
            __builtin_amdgcn_mfma_f32_16x16x32_f16(af[wm], bf[wn], acc[wm][wn], 0, 0, 0);
  }
#pragma unroll
  for (int wm = 0; wm < WM; ++wm) {
#pragma unroll
    for (int wn = 0; wn < 2; ++wn) {
#pragma unroll
      for (int r = 0; r < 4; ++r) {
        int gm = wr * (MT / 2) + wm * 16 + quad * 4 + r;
        int gn = n0 + wc * 32 + wn * 16 + ln;
        if (gm < M && gn < Ncols) {
          float v = acc[wm][wn][r];
          v += bias[gm];
          if (MODE == 1) {
            v = 1.f / (1.f + expf(-v));  // sigmoid
            C[(long long)gm * ldc + gn] = (fp16)v;
            if (gm < 64) {
              float h = (float)hIn[(long long)gm * 2048 + gn];
              rhOut[(long long)gm * 2048 + gn] = (fp16)(v * h);
            }
          } else {
            v = tanhf(v);
            float u = (float)uIn[(long long)(64 + gm) * NN + gn];
            long long ci = (long long)gm * ldc + gn;
            float h = (float)C[ci];
            C[ci] = (fp16)(u * h + (1.f - u) * v);
          }
        }
      }
    }
  }
}

// ---------- mfma3: all-b128 GEMM (kept for movement m2) ----------
template <int MT, int NT>
__global__ __launch_bounds__(256) void mfma3(
    const fp16* __restrict__ A, int lda, long long zA, int aMsh, long long aMslab,
    const fp16* __restrict__ B, int ldb, long long zB,
    fp16* __restrict__ C, int ldc, long long zC, int cMsh, long long cMslab, int cNsh,
    long long cNslab,
    const fp16* __restrict__ S, long long zS, float beta,
    const float* __restrict__ rowBias, long long zRB,
    const float* __restrict__ s2T, int s2ld,
    int M, int Ncols, int K, float alpha, int act) {
  __shared__ fp16 As[MT][40];
  __shared__ fp16 Bs[NT][40];
  const int z = blockIdx.z;
  const int gm0 = blockIdx.x * MT, n0 = blockIdx.y * NT;
  A += (long long)z * zA;
  B += (long long)z * zB;
  C += (long long)z * zC;
  if (S) S += (long long)z * zS;
  const int tid = threadIdx.x;
  const int lane = tid & 63, wv = tid >> 6;
  const int wr = wv >> 1, wc = wv & 1;
  const int quad = lane >> 4, ln = lane & 15;
  const unsigned aMmask = (1u << aMsh) - 1u;
  const unsigned cMmask = (1u << cMsh) - 1u;
  const unsigned cNmask = (1u << cNsh) - 1u;
  constexpr int WM = MT / 32, WN = NT / 32;
  f32x4 acc[WM][WN];
#pragma unroll
  for (int i = 0; i < WM; ++i)
#pragma unroll
    for (int j = 0; j < WN; ++j) acc[i][j] = (f32x4){0.f, 0.f, 0.f, 0.f};

  for (int k0 = 0; k0 < K; k0 += 32) {
#pragma unroll
    for (int i = 0; i < MT / 64; ++i) {
      int c = tid + 256 * i;
      int row = c >> 2, seg = c & 3;
      int gm = gm0 + row;
      int kk0 = k0 + seg * 8;
      const fp16* src = A + ((long long)((unsigned)gm >> aMsh)) * aMslab +
                        (long long)(gm & aMmask) * lda + kk0;
      if (gm < M && kk0 + 8 <= K) {
        *(f16x8*)&As[row][seg * 8] = *(const f16x8*)src;
      } else {
#pragma unroll
        for (int j = 0; j < 8; ++j)
          As[row][seg * 8 + j] = (gm < M && kk0 + j < K) ? src[j] : (fp16)0.f;
      }
    }
#pragma unroll
    for (int i = 0; i < NT / 64; ++i) {
      int c = tid + 256 * i;
      int n = c >> 2, seg = c & 3;
      int gn = n0 + n;
      int kk0 = k0 + seg * 8;
      const fp16* src = B + (long long)gn * ldb + kk0;
      if (gn < Ncols && kk0 + 8 <= K) {
        *(f16x8*)&Bs[n][seg * 8] = *(const f16x8*)src;
      } else {
#pragma unroll
        for (int j = 0; j < 8; ++j)
          Bs[n][seg * 8 + j] = (gn < Ncols && kk0 + j < K) ? src[j] : (fp16)0.f;
      }
    }
    __syncthreads();
    f16x8 af[WM], bf[WN];
#pragma unroll
    for (int wm = 0; wm < WM; ++wm)
      af[wm] = *(const f16x8*)&As[wr * (MT / 2) + wm * 16 + ln][quad * 8];
#pragma unroll
    for (int wn = 0; wn < WN; ++wn)
      bf[wn] = *(const f16x8*)&Bs[wc * (NT / 2) + wn * 16 + ln][quad * 8];
#pragma unroll
    for (int wm = 0; wm < WM; ++wm)
#pragma unroll
      for (int wn = 0; wn < WN; ++wn)
        acc[wm][wn] =
            __builtin_amdgcn_mfma_f32_16x16x32_f16(af[wm], bf[wn], acc[wm][wn], 0, 0, 0);
    __syncthreads();
  }
#pragma unroll
  for (int wm = 0; wm < WM; ++wm) {
#pragma unroll
    for (int wn = 0; wn < WN; ++wn) {
#pragma unroll
      for (int r = 0; r < 4; ++r) {
        int gm = gm0 + wr * (MT / 2) + wm * 16 + quad * 4 + r;
        int gn = n0 + wc * (NT / 2) + wn * 16 + ln;
        if (gm < M && gn < Ncols) {
          float v = alpha * acc[wm][wn][r];
          if (rowBias) v += rowBias[(long long)z * zRB + gm];
          if (s2T) v += s2T[(long long)gn * s2ld + gm];
          long long ci = ((long long)((unsigned)gm >> cMsh)) * cMslab +
                         (long long)(gm & cMmask) * ldc +
                         ((long long)((unsigned)gn >> cNsh)) * cNslab + (gn & cNmask);
          if (S) v += beta * (float)S[ci];
          if (act == 1) v = fmaxf(v, 0.f);
          else if (act == 2) v = 1.f / (1.f + expf(-v));
          else if (act == 3) v = tanhf(v);
          C[ci] = (fp16)v;
        }
      }
    }
  }
}

// ---------- mfma4: maskless gload_lds GEMM, dual-base A descriptor ----------
template <int MT, int NT>
__global__ __launch_bounds__(256) void mfma4(
    const fp16* __restrict__ base0, const fp16* __restrict__ base1, int rsh, int ssh,
    long long z0, long long z1, int lda,
    const fp16* __restrict__ B, int ldb, long long zB,
    fp16* __restrict__ C, int ldc, long long zC, int cMsh, long long cMslab, int cNsh,
    long long cNslab,
    const fp16* __restrict__ S, float alpha, float beta, int K) {
  __shared__ fp16 As[2][MT * 32];
  __shared__ fp16 Bs[2][NT * 32];
  const int tid = threadIdx.x;
  const int z = blockIdx.z;
  const int gm0 = blockIdx.x * MT, n0 = blockIdx.y * NT;
  B += (long long)z * zB;
  C += (long long)z * zC;
  if (S) S += (long long)z * zC;
  const unsigned cMmask = (1u << cMsh) - 1u;
  const unsigned cNmask = (1u << cNsh) - 1u;
  const int lane = tid & 63, wv = tid >> 6;
  const int wr = wv >> 1, wc = wv & 1;
  const int quad = lane >> 4, ln = lane & 15;
  constexpr int WM = MT / 32, WN = NT / 32;

  const fp16* aSrc[MT / 64];
  const fp16* bSrc[NT / 64];
#pragma unroll
  for (int i = 0; i < MT / 64; ++i) {
    int c = i * 256 + tid;
    int row = c >> 2;
    int lseg = (c & 3) ^ (row & 3);
    int gm = gm0 + row;
    unsigned b = (unsigned)gm >> rsh;
    unsigned wi = (unsigned)gm & ((1u << rsh) - 1u);
    unsigned sel = wi >> ssh;
    unsigned r = wi & ((1u << ssh) - 1u);
    const fp16* ab = sel ? (base1 + (long long)b * z1) : (base0 + (long long)b * z0);
    aSrc[i] = ab + (long long)r * lda + lseg * 8;
  }
#pragma unroll
  for (int i = 0; i < NT / 64; ++i) {
    int c = i * 256 + tid;
    int row = c >> 2;
    int lseg = (c & 3) ^ (row & 3);
    bSrc[i] = B + (long long)(n0 + row) * ldb + lseg * 8;
  }

  f32x4 acc[WM][WN];
#pragma unroll
  for (int i = 0; i < WM; ++i)
#pragma unroll
    for (int j = 0; j < WN; ++j) acc[i][j] = (f32x4){0.f, 0.f, 0.f, 0.f};

  const int sw = (quad ^ (ln & 3)) << 3;

#pragma unroll
  for (int i = 0; i < MT / 64; ++i) gload_lds16(aSrc[i], &As[0][(i * 256 + tid) * 8]);
#pragma unroll
  for (int i = 0; i < NT / 64; ++i) gload_lds16(bSrc[i], &Bs[0][(i * 256 + tid) * 8]);

  const int nk = K >> 5;
  for (int t = 0; t < nk; ++t) {
    const int buf = t & 1;
    __syncthreads();
    if (t + 1 < nk) {
      const int k1 = (t + 1) * 32;
#pragma unroll
      for (int i = 0; i < MT / 64; ++i)
        gload_lds16(aSrc[i] + k1, &As[buf ^ 1][(i * 256 + tid) * 8]);
#pragma unroll
      for (int i = 0; i < NT / 64; ++i)
        gload_lds16(bSrc[i] + k1, &Bs[buf ^ 1][(i * 256 + tid) * 8]);
    }
    f16x8 af[WM], bf[WN];
#pragma unroll
    for (int wm = 0; wm < WM; ++wm) {
      int row = wr * (MT / 2) + wm * 16 + ln;
      af[wm] = *(const f16x8*)&As[buf][row * 32 + sw];
    }
#pragma unroll
    for (int wn = 0; wn < WN; ++wn) {
      int row = wc * (NT / 2) + wn * 16 + ln;
      bf[wn] = *(const f16x8*)&Bs[buf][row * 32 + sw];
    }
#pragma unroll
    for (int wm = 0; wm < WM; ++wm)
#pragma unroll
      for (int wn = 0; wn < WN; ++wn)
        acc[wm][wn] =
            __builtin_amdgcn_mfma_f32_16x16x32_f16(af[wm], bf[wn], acc[wm][wn], 0, 0, 0);
  }
#pragma unroll
  for (int wm = 0; wm < WM; ++wm)
#pragma unroll
    for (int wn = 0; wn < WN; ++wn)
#pragma unroll
      for (int r = 0; r < 4; ++r) {
        int gm = gm0 + wr * (MT / 2) + wm * 16 + quad * 4 + r;
        int gn = n0 + wc * (NT / 2) + wn * 16 + ln;
        long long ci = ((long long)((unsigned)gm >> cMsh)) * cMslab +
                       (long long)(gm & cMmask) * ldc +
                       ((long long)((unsigned)gn >> cNsh)) * cNslab + (gn & cNmask);
        float v = alpha * acc[wm][wn][r];
        if (S) v += beta * (float)S[ci];
        C[ci] = (fp16)v;
      }
}

// ---------- mfma6: maskless gload_lds GEMM, dual-base B descriptor ----------
template <int MT, int NT>
__global__ __launch_bounds__(256) void mfma6(
    const fp16* __restrict__ A, int lda,
    const fp16* __restrict__ b0, const fp16* __restrict__ b1, int rsh, int ssh,
    long long z0, long long z1, int ldb,
    fp16* __restrict__ C, int ldc, int cMsh, long long cMslab,
    int K) {
  __shared__ fp16 As[2][MT * 32];
  __shared__ fp16 Bs[2][NT * 32];
  const int tid = threadIdx.x;
  const int gm0 = blockIdx.x * MT, n0 = blockIdx.y * NT;
  const unsigned cMmask = (1u << cMsh) - 1u;
  const int lane = tid & 63, wv = tid >> 6;
  const int wr = wv >> 1, wc = wv & 1;
  const int quad = lane >> 4, ln = lane & 15;
  constexpr int WM = MT / 32, WN = NT / 32;

  const fp16* aSrc[MT / 64];
  const fp16* bSrc[NT / 64];
#pragma unroll
  for (int i = 0; i < MT / 64; ++i) {
    int c = i * 256 + tid;
    int row = c >> 2;
    int lseg = (c & 3) ^ (row & 3);
    aSrc[i] = A + (long long)(gm0 + row) * lda + lseg * 8;
  }
#pragma unroll
  for (int i = 0; i < NT / 64; ++i) {
    int c = i * 256 + tid;
    int row = c >> 2;
    int lseg = (c & 3) ^ (row & 3);
    int gn = n0 + row;
    unsigned b = (unsigned)gn >> rsh;
    unsigned wi = (unsigned)gn & ((1u << rsh) - 1u);
    unsigned sel = wi >> ssh;
    unsigned r = wi & ((1u << ssh) - 1u);
    const fp16* bb = sel ? (b1 + (long long)b * z1) : (b0 + (long long)b * z0);
    bSrc[i] = bb + (long long)r * ldb + lseg * 8;
  }

  f32x4 acc[WM][WN];
#pragma unroll
  for (int i = 0; i < WM; ++i)
#pragma unroll
    for (int j = 0; j < WN; ++j) acc[i][j] = (f32x4){0.f, 0.f, 0.f, 0.f};

  const int sw = (quad ^ (ln & 3)) << 3;

#pragma unroll
  for (int i = 0; i < MT / 64; ++i) gload_lds16(aSrc[i], &As[0][(i * 256 + tid) * 8]);
#pragma unroll
  for (int i = 0; i < NT / 64; ++i) gload_lds16(bSrc[i], &Bs[0][(i * 256 + tid) * 8]);

  const int nk = K >> 5;
  for (int t = 0; t < nk; ++t) {
    const int buf = t & 1;
    __syncthreads();
    if (t + 1 < nk) {
      const int k1 = (t + 1) * 32;
#pragma unroll
      for (int i = 0; i < MT / 64; ++i)
        gload_lds16(aSrc[i] + k1, &As[buf ^ 1][(i * 256 + tid) * 8]);
#pragma unroll
      for (int i = 0; i < NT / 64; ++i)
        gload_lds16(bSrc[i] + k1, &Bs[buf ^ 1][(i * 256 + tid) * 8]);
    }
    f16x8 af[WM], bf[WN];
#pragma unroll
    for (int wm = 0; wm < WM; ++wm) {
      int row = wr * (MT / 2) + wm * 16 + ln;
      af[wm] = *(const f16x8*)&As[buf][row * 32 + sw];
    }
#pragma unroll
    for (int wn = 0; wn < WN; ++wn) {
      int row = wc * (NT / 2) + wn * 16 + ln;
      bf[wn] = *(const f16x8*)&Bs[buf][row * 32 + sw];
    }
#pragma unroll
    for (int wm = 0; wm < WM; ++wm)
#pragma unroll
      for (int wn = 0; wn < WN; ++wn)
        acc[wm][wn] =
            __builtin_amdgcn_mfma_f32_16x16x32_f16(af[wm], bf[wn], acc[wm][wn], 0, 0, 0);
  }
#pragma unroll
  for (int wm = 0; wm < WM; ++wm)
#pragma unroll
    for (int wn = 0; wn < WN; ++wn)
#pragma unroll
      for (int r = 0; r < 4; ++r) {
        int gm = gm0 + wr * (MT / 2) + wm * 16 + quad * 4 + r;
        int gn = n0 + wc * (NT / 2) + wn * 16 + ln;
        long long ci = ((long long)((unsigned)gm >> cMsh)) * cMslab +
                       (long long)(gm & cMmask) * ldc + gn;
        C[ci] = (fp16)acc[wm][wn][r];
      }
}

// ---------- k_zxtfin: ZXt[z][d][n] += w2T@Tmat[z]^T + teXb + seX; zero pad cols ----------
__global__ __launch_bounds__(256) void k_zxtfin(
    const fp16* __restrict__ w2T, const fp16* __restrict__ Tmat,
    fp16* __restrict__ ZXt, const float* __restrict__ teXb, const float* __restrict__ seX) {
  __shared__ fp16 As[64][72];
  __shared__ fp16 Bs[128][72];
  const int z = blockIdx.z;
  const int n0 = blockIdx.y * 128;
  const fp16* Tz = Tmat + (long long)z * 2048 * 64;
  fp16* Cz = ZXt + (long long)z * 64 * 2048;
  const float* tb = teXb + z * 64;
  const int tid = threadIdx.x;
  const int lane = tid & 63, wv = tid >> 6;
  const int wr = wv >> 1, wc = wv & 1;
  const int quad = lane >> 4, ln = lane & 15;
#pragma unroll
  for (int i = 0; i < 2; ++i) {
    int c = tid + 256 * i;
    int row = c >> 3, seg = c & 7;
    *(f16x8*)&As[row][seg * 8] = *(const f16x8*)(w2T + row * 64 + seg * 8);
  }
#pragma unroll
  for (int i = 0; i < 4; ++i) {
    int c = tid + 256 * i;
    int row = c >> 3, seg = c & 7;
    *(f16x8*)&Bs[row][seg * 8] =
        *(const f16x8*)(Tz + (long long)(n0 + row) * 64 + seg * 8);
  }
  __syncthreads();
  f32x4 acc[2][4];
#pragma unroll
  for (int i = 0; i < 2; ++i)
#pragma unroll
    for (int j = 0; j < 4; ++j) acc[i][j] = (f32x4){0.f, 0.f, 0.f, 0.f};
#pragma unroll
  for (int kt = 0; kt < 2; ++kt) {
    f16x8 af[2], bf[4];
#pragma unroll
    for (int wm = 0; wm < 2; ++wm)
      af[wm] = *(const f16x8*)&As[wr * 32 + wm * 16 + ln][kt * 32 + quad * 8];
#pragma unroll
    for (int wn = 0; wn < 4; ++wn)
      bf[wn] = *(const f16x8*)&Bs[wc * 64 + wn * 16 + ln][kt * 32 + quad * 8];
#pragma unroll
    for (int wm = 0; wm < 2; ++wm)
#pragma unroll
      for (int wn = 0; wn < 4; ++wn)
        acc[wm][wn] =
            __builtin_amdgcn_mfma_f32_16x16x32_f16(af[wm], bf[wn], acc[wm][wn], 0, 0, 0);
  }
#pragma unroll
  for (int wm = 0; wm < 2; ++wm)
#pragma unroll
    for (int wn = 0; wn < 4; ++wn)
#pragma unroll
      for (int r = 0; r < 4; ++r) {
        int gm = wr * 32 + wm * 16 + quad * 4 + r;
        int gn = n0 + wc * 64 + wn * 16 + ln;
        long long ci = (long long)gm * 2048 + gn;
        float v = 0.f;
        if (gn < NN)
          v = acc[wm][wn][r] + (float)Cz[ci] + tb[gm] + seX[(long long)gn * 64 + gm];
        Cz[ci] = (fp16)v;
      }
}

// ---------- ConvLSTM conv, mfma4-style with zero-padded 34x34 halo ----------
__global__ __launch_bounds__(256) void k_conv4(
    const fp16* __restrict__ Zfp, const fp16* __restrict__ hp,
    const fp16* __restrict__ wcatT, fp16* __restrict__ gates, int p) {
  __shared__ fp16 As[2][128 * 32];
  __shared__ fp16 Bs[2][64 * 32];
  const int gm0 = blockIdx.x * 128, n0 = blockIdx.y * 64;
  const int tid = threadIdx.x;
  const int lane = tid & 63, wv = tid >> 6;
  const int wr = wv >> 1, wc = wv & 1;
  const int quad = lane >> 4, ln = lane & 15;

  long long aZ[2], aH[2];
#pragma unroll
  for (int i = 0; i < 2; ++i) {
    int c = tid + 256 * i;
    int row = c >> 2;
    int lseg = (c & 3) ^ (row & 3);
    int m = gm0 + row;
    int b = m >> 10, y = (m >> 5) & 31, x = m & 31;
    int pc = (y + 1) * GP + (x + 1);
    aZ[i] = ((long long)(b * PP + p) * GP2 + pc) * 64 + lseg * 8;
    aH[i] = ((long long)b * GP2 + pc) * 64 + lseg * 8;
  }
  const fp16* bBase;
  {
    int row = tid >> 2;
    int lseg = (tid & 3) ^ (row & 3);
    bBase = wcatT + (long long)(n0 + row) * 1152 + lseg * 8;
  }
  f32x4 acc[4][2];
#pragma unroll
  for (int i = 0; i < 4; ++i)
#pragma unroll
    for (int j = 0; j < 2; ++j) acc[i][j] = (f32x4){0.f, 0.f, 0.f, 0.f};

  auto stage = [&](int t, int buf) {
    int tap = (t >> 1) % 9, half = t & 1;
    int srcsel = t >= 18;
    int off = ((tap / 3 - 1) * GP + (tap % 3 - 1)) * 64 + half * 32;
#pragma unroll
    for (int i = 0; i < 2; ++i) {
      const fp16* src = srcsel ? (hp + aH[i] + off) : (Zfp + aZ[i] + off);
      gload_lds16(src, &As[buf][(i * 256 + tid) * 8]);
    }
    gload_lds16(bBase + t * 32, &Bs[buf][tid * 8]);
  };
  stage(0, 0);
  const int sw = (quad ^ (ln & 3)) << 3;
  for (int t = 0; t < 36; ++t) {
    const int buf = t & 1;
    __syncthreads();
    if (t + 1 < 36) stage(t + 1, buf ^ 1);
    f16x8 af[4], bf[2];
#pragma unroll
    for (int wm = 0; wm < 4; ++wm) {
      int row = wr * 64 + wm * 16 + ln;
      af[wm] = *(const f16x8*)&As[buf][row * 32 + sw];
    }
#pragma unroll
    for (int wn = 0; wn < 2; ++wn) {
      int row = wc * 32 + wn * 16 + ln;
      bf[wn] = *(const f16x8*)&Bs[buf][row * 32 + sw];
    }
#pragma unroll
    for (int wm = 0; wm < 4; ++wm)
#pragma unroll
      for (int wn = 0; wn < 2; ++wn)
        acc[wm][wn] =
            __builtin_amdgcn_mfma_f32_16x16x32_f16(af[wm], bf[wn], acc[wm][wn], 0, 0, 0);
  }
#pragma unroll
  for (int wm = 0; wm < 4; ++wm)
#pragma unroll
    for (int wn = 0; wn < 2; ++wn)
#pragma unroll
      for (int r = 0; r < 4; ++r) {
        int gm = gm0 + wr * 64 + wm * 16 + quad * 4 + r;
        int gn = n0 + wc * 32 + wn * 16 + ln;
        gates[(long long)gm * 256 + gn] = (fp16)acc[wm][wn][r];
      }
}

__global__ void k_clstm_update(const fp16* __restrict__ gates, float* __restrict__ c,
                               fp16* __restrict__ h, fp16* __restrict__ ZclT, int p) {
  long long i = (long long)blockIdx.x * 256 + threadIdx.x;
  if (i >= (long long)BB * CC * 64) return;
  int d = (int)(i & 63);
  long long bc = i >> 6;
  int b = (int)(bc >> 10);
  int cell = (int)(bc & 1023);
  const fp16* g = gates + (((long long)b * CC) + cell) * 256;
  float gi = (float)g[d], gf = (float)g[64 + d], gg = (float)g[128 + d],
        go = (float)g[192 + d];
  float hs_f = fminf(fmaxf(0.2f * gf + 0.5f, 0.f), 1.f);
  float hs_i = fminf(fmaxf(0.2f * gi + 0.5f, 0.f), 1.f);
  float hs_o = fminf(fmaxf(0.2f * go + 0.5f, 0.f), 1.f);
  float cv = hs_f * c[i] + hs_i * tanhf(gg);
  c[i] = cv;
  float hv = hs_o * tanhf(cv);
  int pc = ((cell >> 5) + 1) * GP + (cell & 31) + 1;
  h[((long long)b * GP2 + pc) * 64 + d] = (fp16)hv;
  ZclT[(((long long)(b * PP + p)) * 64 + d) * CC + cell] = (fp16)hv;
}

// Tmat[z][n][64] with 2048-row stride per z (pad rows garbage; finisher ignores)
__global__ void k_tmat(const float* __restrict__ X, const float* __restrict__ w1,
                       const float* __restrict__ b1, fp16* __restrict__ T, long long nrows) {
  long long i = (long long)blockIdx.x * 256 + threadIdx.x;
  if (i >= nrows * 64) return;
  int j = (int)(i & 63);
  long long row = i >> 6;
  int z = (int)(row / NN);
  int n = (int)(row - (long long)z * NN);
  T[(((long long)z * 2048) + n) * 64 + j] = (fp16)fmaxf(X[row] * w1[j] + b1[j], 0.f);
}

__global__ void k_trT(const fp16* __restrict__ U0, float* __restrict__ htmp) {
  long long i = (long long)blockIdx.x * 256 + threadIdx.x;
  if (i >= (long long)BB * NN * 64) return;
  int d = (int)(i & 63);
  long long bn = i >> 6;
  int b = (int)(bn / NN);
  int n = (int)(bn % NN);
  htmp[i] = (float)U0[((long long)b * 192 + 64 + d) * 2048 + n];
}

__global__ void k_out(const float* __restrict__ Y, float* __restrict__ out) {
  int i = blockIdx.x * 256 + threadIdx.x;
  if (i >= BB * QQ * NN) return;
  int n = i % NN;
  int bq = i / NN;
  int b = bq / QQ, q = bq % QQ;
  out[i] = Y[((long long)b * NN + n) * 12 + q];
}

// ---------- host helpers ----------
template <typename TA, typename TB, typename TC>
static void launch_gemm(hipStream_t stream, const TA* A, int lda, long long sA,
                        const TB* Bm, int ldb, long long sB, TC* Cm, int ldc, long long sC,
                        const TC* S, long long sS, const float* bias, int M, int Nc, int K,
                        float alpha, float beta, int act, int batch) {
  dim3 g((M + 63) / 64, (Nc + 63) / 64, batch);
  gemm_t<TA, TB, TC><<<g, dim3(256), 0, stream>>>(A, lda, sA, Bm, ldb, sB, Cm, ldc, sC, S,
                                                  sS, bias, M, Nc, K, alpha, beta, act);
}

extern "C" void kernel_launch(void* const* d_in, const int* in_sizes, int n_in,
                              void* d_out, int out_size, void* d_ws, size_t ws_size,
                              hipStream_t stream) {
  char* base = (char*)d_ws;
  size_t off = 0;
  auto alloc_bytes = [&](size_t nb) -> char* {
    char* p = base + off;
    off += (nb + 255) & ~(size_t)255;
    return p;
  };
  auto allocf = [&](size_t n) -> float* { return (float*)alloc_bytes(n * 4); };
  auto alloch = [&](size_t n) -> fp16* { return (fp16*)alloc_bytes(n * 2); };

  const float* X = (const float*)d_in[0];
  const float* Z = (const float*)d_in[1];
  const int* TE = (const int*)d_in[2];
  const float* adj_gg = (const float*)d_in[3];
  const float* adj_gr = (const float*)d_in[4];
  const float* gumbel = (const float*)d_in[5];
  const float* se_x = (const float*)d_in[6];
  const float* se_z = (const float*)d_in[7];
  const float* movement = (const float*)d_in[8];
  auto W = [&](int i) { return (const float*)d_in[i]; };

  // ---- allocations ----
  fp16* wcatT = alloch((size_t)256 * 1152);  // [n][k] pre-transposed conv weights
  fp16* gwT = alloch(128 * 512);
  fp16* cwT = alloch(64 * 512);
  fp16* w2T = alloch(64 * 64);
  fp16* w2mT = alloch(64 * 64);
  float* dinv = allocf(NN);
  fp16* LMall = alloch((size_t)6144 * 2048);  // rows padded to 2048 for maskless mfma4/6
  fp16* mZh = alloch((size_t)CC * CC);
  fp16* agh2 = alloch((size_t)2048 * CC);  // padded to 2048 rows (pad rows zero)
  float* seZ = allocf(CC * 64);
  float* teZ = allocf(BB * PP * 64);
  float* seX = allocf(NN * 64);
  float* teXb = allocf(BB * PP * 64);
  float* mtmp = allocf(NN * 64);
  float* tetmp = allocf(BB * PP * 64);
  fp16* ruT = alloch((size_t)BB * 128 * NN);  // [b][128][2000]
  // pool (4*USL = 50.33MB)
  char* pool = alloc_bytes(50331648);
  fp16* Uall = (fp16*)pool;
  fp16* gates = (fp16*)pool;
  fp16* chh = (fp16*)(pool + 8388608);   // padded h [16][1156][64]
  float* ccc = (float*)(pool + 12582912);
  fp16* Zmix = (fp16*)pool;
  fp16* ZmovT = (fp16*)(pool + 25165824);
  // zpool: Zf_pad [bp][1156][64] (28.4MB) then ZXt [bp][64][2048]
  fp16* zpool = alloch((size_t)BB * PP * 64 * 2048);
  fp16* Zfp = zpool;
  fp16* ZXt = zpool;
  fp16* Zc = alloch((size_t)BB * PP * CC * 64);  // zf1 scratch -> ZclT -> Tmat -> head scratch

  if (off > ws_size) return;

  // optional TnX (hoisted gate x-chebs, 151 MB) — only if workspace allows
  const long long TnXSlab = 2048LL * 12288;
  size_t tnxBytes = ((size_t)3 * TnXSlab * 2 + 255) & ~(size_t)255;
  fp16* TnX = (fp16*)(base + off);
  const bool hoist = (off + tnxBytes) <= ws_size;

  const long long uB = 192LL * 2048;
  const long long USL = 16LL * uB;
  const long long ZXB = 12LL * 64 * 2048;  // per-batch stride of ZXt
  fp16* Lh = LMall;
  fp16* M2h = LMall + 2048LL * 2048;
  fp16* M3h = LMall + 4096LL * 2048;
  const int KCH = 2016;  // chain K (2000 padded to x32; cols 2000..2015 zero)

  // ---- precompute ----
  k_wcatT<<<dim3(1152), dim3(256), 0, stream>>>(wcatT, W(39), W(40));
  k_gru_repackT<<<dim3(256), dim3(256), 0, stream>>>(gwT, W(41), 128);
  k_gru_repackT<<<dim3(128), dim3(256), 0, stream>>>(cwT, W(43), 64);
  k_w2T<<<dim3(16), dim3(256), 0, stream>>>(w2T, W(31));
  k_w2T<<<dim3(16), dim3(256), 0, stream>>>(w2mT, W(33));
  k_dinv<<<dim3(NN), dim3(256), 0, stream>>>(adj_gg, dinv);
  hipMemsetAsync(LMall, 0, (size_t)6144 * 2048 * 2, stream);
  k_L<<<dim3((NN * NN + 255) / 256), dim3(256), 0, stream>>>(adj_gg, dinv, Lh);
  mfma4<64, 128><<<dim3(32, 16, 1), dim3(256), 0, stream>>>(
      Lh, Lh, 31, 31, 0LL, 0LL, 2048, Lh, 2048, 0LL, M2h, 2048, 0LL, 31, 0LL, 31, 0LL,
      (const fp16*)nullptr, 2.f, 0.f, KCH);
  k_subdiag<<<dim3((NN + 255) / 256), dim3(256), 0, stream>>>(M2h);
  mfma4<64, 128><<<dim3(32, 16, 1), dim3(256), 0, stream>>>(
      Lh, Lh, 31, 31, 0LL, 0LL, 2048, M2h, 2048, 0LL, M3h, 2048, 0LL, 31, 0LL, 31, 0LL,
      (const fp16*)Lh, 2.f, -1.f, KCH);
  k_gumbel_softmax<<<dim3(CC), dim3(256), 0, stream>>>(movement, gumbel, mZh);
  k_f2h<<<dim3((NN * CC + 255) / 256), dim3(256), 0, stream>>>(agh2, adj_gr,
                                                               (long long)NN * CC);
  hipMemsetAsync(agh2 + (size_t)NN * CC, 0, (size_t)(2048 - NN) * CC * 2, stream);

  // ---- STEZ / STEX ----
  launch_gemm(stream, se_z, 64, 0LL, W(17), 64, 0LL, mtmp, 64, 0LL, (float*)nullptr, 0LL,
              W(18), CC, 64, 64, 1.f, 0.f, 1, 1);
  launch_gemm(stream, (const float*)mtmp, 64, 0LL, W(19), 64, 0LL, seZ, 64, 0LL,
              (float*)nullptr, 0LL, W(20), CC, 64, 64, 1.f, 0.f, 0, 1);
  k_te<<<dim3((BB * PP * 64 + 255) / 256), dim3(256), 0, stream>>>(TE, W(21), W(22), tetmp);
  launch_gemm(stream, (const float*)tetmp, 64, 0LL, W(23), 64, 0LL, teZ, 64, 0LL,
              (float*)nullptr, 0LL, W(24), BB * PP, 64, 64, 1.f, 0.f, 0, 1);
  launch_gemm(stream, se_x, 64, 0LL, W(9), 64, 0LL, mtmp, 64, 0LL, (float*)nullptr, 0LL,
              W(10), NN, 64, 64, 1.f, 0.f, 1, 1);
  launch_gemm(stream, (const float*)mtmp, 64, 0LL, W(11), 64, 0LL, seX, 64, 0LL,
              (float*)nullptr, 0LL, W(12), NN, 64, 64, 1.f, 0.f, 0, 1);
  k_te<<<dim3((BB * PP * 64 + 255) / 256), dim3(256), 0, stream>>>(TE, W(13), W(14), tetmp);
  launch_gemm(stream, (const float*)tetmp, 64, 0LL, W(15), 64, 0LL, teXb, 64, 0LL,
              (float*)nullptr, 0LL, W(16), BB * PP, 64, 64, 1.f, 0.f, 0, 1);
  k_addb<<<dim3((BB * PP * 64 + 255) / 256), dim3(256), 0, stream>>>(teXb, W(32),
                                                                     BB * PP * 64);

  // ---- Zf = mlp2(Z) + STEZ, scattered into padded 34x34 layout ----
  long long nZ = (long long)BB * PP * CC * 64;
  k_zf1<<<dim3((int)((nZ + 255) / 256)), dim3(256), 0, stream>>>(Z, W(25), W(26), Zc);
  launch_gemm(stream, (const fp16*)Zc, 64, 0LL, W(27), 64, 0LL, (fp16*)pool, 64, 0LL,
              (fp16*)nullptr, 0LL, W(28), BB * PP * CC, 64, 64, 1.f, 0.f, 0, 1);
  hipMemsetAsync(zpool, 0, (size_t)BB * PP * GP2 * 64 * 2, stream);  // zero Zf_pad (halo)
  k_add_stez<<<dim3((int)((nZ + 255) / 256)), dim3(256), 0, stream>>>(Zfp, (fp16*)pool,
                                                                      seZ, teZ);

  // ---- ConvLSTM (writes ZclT into Zc; h in padded chh) ----
  hipMemsetAsync(chh, 0, (size_t)BB * GP2 * 64 * 2, stream);
  hipMemsetAsync(ccc, 0, (size_t)BB * CC * 64 * 4, stream);
  for (int p = 0; p < PP; ++p) {
    k_conv4<<<dim3(BB * CC / 128, 4), dim3(256), 0, stream>>>(Zfp, chh, wcatT, gates, p);
    k_clstm_update<<<dim3((int)(((long long)BB * CC * 64 + 255) / 256)), dim3(256), 0,
                     stream>>>(gates, ccc, chh, Zc, p);
  }

  // ---- movement m1 (mfma4, z-batched) / m2 ----
  mfma4<128, 64><<<dim3(8, 1, 192), dim3(256), 0, stream>>>(
      mZh, mZh, 31, 31, 0LL, 0LL, CC, (const fp16*)Zc, CC, (long long)64 * CC, Zmix, 64,
      (long long)CC * 64, 31, 0LL, 31, 0LL, (const fp16*)nullptr, 1.f, 0.f, CC);
  mfma3<64, 128><<<dim3(1, 8, 192), dim3(256), 0, stream>>>(
      w2mT, 64, 0LL, 31, 0LL, Zmix, 64, (long long)CC * 64, ZmovT, CC, (long long)64 * CC,
      31, 0LL, 31, 0LL, (const fp16*)nullptr, 0LL, 0.f, W(34), 0LL, nullptr, 0, 64, CC, 64,
      1.f, 1);

  // ---- zxt term1: one big GEMM, M = 192*64 = 12288 rows of ZmovT ----
  mfma4<128, 128><<<dim3(96, 16, 1), dim3(256), 0, stream>>>(
      ZmovT, ZmovT, 31, 31, 0LL, 0LL, 1024, agh2, 1024, 0LL, ZXt, 2048, 0LL, 31, 0LL, 31,
      0LL, (const fp16*)nullptr, 1.f, 0.f, 1024);

  // ---- zxt term2 + biases (two halves; Tmat padded to 2048 rows/z in dead Zc) ----
  fp16* Tmat = Zc;
  for (int half = 0; half < 2; ++half) {
    long long z0 = 96LL * half;
    k_tmat<<<dim3((int)((96LL * NN * 64 + 255) / 256)), dim3(256), 0, stream>>>(
        X + z0 * NN, W(29), W(30), Tmat, 96LL * NN);
    k_zxtfin<<<dim3(1, 16, 96), dim3(256), 0, stream>>>(
        w2T, Tmat, ZXt + z0 * 64 * 2048, teXb + z0 * 64, seX);
  }

  // ---- DCGRU ----
  fp16* U0 = Uall;
  fp16* Tn = Uall + USL;        // old path: 3 slabs [2048][2048]; hoisted: TnH 3x[2048][1024]
  fp16* Tn2 = Uall + 3 * USL;   // 3 cand slabs [2048][1024]
  const long long TnSlab = 2048LL * 2048;
  const long long TnHSlab = 2048LL * 1024;
  const long long Tn2Slab = 2048LL * 1024;
  hipMemsetAsync(U0, 0, (size_t)USL * 2, stream);  // zero slab 0 (h/rh rows + pads)

  if (hoist) {
    // TnX[s][node][(b*12+p)*64+c] = LM_s @ x^T for ALL p — ZXt is one contiguous
    // 12288x2048 matrix.
    mfma6<128, 128><<<dim3(48, 96), dim3(256), 0, stream>>>(
        LMall, 2048, ZXt, ZXt, 31, 31, 0LL, 0LL, 2048, TnX, 12288, 11, TnXSlab, KCH);
  }

  for (int p = 0; p < PP; ++p) {
    const fp16* xP = ZXt + (long long)p * 64 * 2048;
    if (hoist) {
      // h-chebs only: TnH[s][n][b*64+c] = LM_s @ h^T
      mfma6<128, 128><<<dim3(48, 8), dim3(256), 0, stream>>>(
          LMall, 2048, U0 + 64 * 2048, U0 + 64 * 2048, 6, 6, uB, uB, 2048, Tn, 1024, 11,
          TnHSlab, KCH);
      mfma7<128, 1><<<dim3(1, 32, BB), dim3(256), 0, stream>>>(
          gwT, U0, uB, 0, xP, ZXB,
          TnX + (long long)p * 64, TnXSlab, 12288, 768,
          Tn, TnHSlab, 1024, 64,
          ruT, NN, (long long)128 * NN, W(42), U0 + 128 * 2048, U0 + 64 * 2048,
          (const fp16*)nullptr, 0LL, 128, NN);
    } else {
      // combined xh chebs: Tn[s][n][z*128+row]
      mfma6<128, 128><<<dim3(48, 16), dim3(256), 0, stream>>>(
          LMall, 2048, xP, U0 + 64 * 2048, 7, 6, ZXB, uB, 2048, Tn, 2048, 11, TnSlab, KCH);
      mfma7<128, 1><<<dim3(1, 32, BB), dim3(256), 0, stream>>>(
          gwT, U0, uB, 0, xP, ZXB,
          Tn, TnSlab, 2048, 128,
          Tn + 64, TnSlab, 2048, 128,
          ruT, NN, (long long)128 * NN, W(42), U0 + 128 * 2048, U0 + 64 * 2048,
          (const fp16*)nullptr, 0LL, 128, NN);
    }
    // cand chebs: Tn2[s][n][z*64+row] = LM_s @ rh^T
    mfma6<128, 128><<<dim3(48, 8), dim3(256), 0, stream>>>(
        LMall, 2048, U0 + 128 * 2048, U0 + 128 * 2048, 6, 6, uB, uB, 2048, Tn2, 1024, 11,
        Tn2Slab, KCH);
    // cnd GEMM; epilogue does h' = u*h + (1-u)*tanh(v) in place in U0 rows 64..127
    if (hoist) {
      mfma7<64, 2><<<dim3(1, 32, BB), dim3(256), 0, stream>>>(
          cwT, U0, uB, 64, xP, ZXB,
          TnX + (long long)p * 64, TnXSlab, 12288, 768,
          Tn2, Tn2Slab, 1024, 64,
          U0 + 64 * 2048, 2048, uB, W(44), (fp16*)nullptr, (const fp16*)nullptr,
          (const fp16*)ruT, (long long)128 * NN, 64, NN);
    } else {
      mfma7<64, 2><<<dim3(1, 32, BB), dim3(256), 0, stream>>>(
          cwT, U0, uB, 64, xP, ZXB,
          Tn, TnSlab, 2048, 128,
          Tn2, Tn2Slab, 1024, 64,
          U0 + 64 * 2048, 2048, uB, W(44), (fp16*)nullptr, (const fp16*)nullptr,
          (const fp16*)ruT, (long long)128 * NN, 64, NN);
    }
  }

  // ---- output head (all scratch in dead Zc; U0 untouched until read) ----
  float* htmp = (float*)Zc;                       // 8.19 MB
  float* out1 = (float*)(Zc + 5120000);           // byte 10.24 MB, 8.19 MB
  float* out2 = (float*)(Zc + 10240000);          // byte 20.48 MB, 1.54 MB
  k_trT<<<dim3((int)(((long long)BB * NN * 64 + 255) / 256)), dim3(256), 0, stream>>>(U0,
                                                                                      htmp);
  launch_gemm(stream, (const float*)htmp, 64, 0LL, W(35), 64, 0LL, out1, 64, 0LL,
              (float*)nullptr, 0LL, W(36), BB * NN, 64, 64, 1.f, 0.f, 1, 1);
  launch_gemm(stream, (const float*)out1, 64, 0LL, W(37), 12, 0LL, out2, 12, 0LL,
              (float*)nullptr, 0LL, W(38), BB * NN, 12, 64, 1.f, 0.f, 0, 1);
  k_out<<<dim3((BB * QQ * NN + 255) / 256), dim3(256), 0, stream>>>(out2, (float*)d_out);
}

// Round 6
// 2937.559 us; speedup vs baseline: 1.8149x; 1.0206x over previous
//
#include <hip/hip_runtime.h>
#include <hip/hip_bf16.h>
#include <math.h>

typedef _Float16 fp16;
typedef _Float16 f16x8 __attribute__((ext_vector_type(8)));
typedef float f32x4 __attribute__((ext_vector_type(4)));

#define BB 16
#define PP 12
#define QQ 12
#define NN 2000
#define CC 1024
#define GP 34   // padded grid side (32 + halo)
#define GP2 1156

static __device__ __forceinline__ float ldf(float v) { return v; }
static __device__ __forceinline__ float ldf(fp16 v) { return (float)v; }
static __device__ __forceinline__ void stf(float* p, float v) { *p = v; }
static __device__ __forceinline__ void stf(fp16* p, float v) { *p = (fp16)v; }

// async global->LDS, 16B per lane (wave-uniform LDS base + lane*16)
static __device__ __forceinline__ void gload_lds16(const fp16* g, fp16* l) {
  __builtin_amdgcn_global_load_lds(
      (const __attribute__((address_space(1))) void*)g,
      (__attribute__((address_space(3))) void*)l, 16, 0, 0);
}

// Swizzle note: logical seg q of row r is stored at slot q ^ ((r>>1)&3).
// With this key the 16 lanes of each quad tile all 8 LDS bank-groups exactly
// twice on ds_read_b128 (2 lanes/bank = free). Staging fetches seg
// (slot ^ (row>>1)&3) so the involution holds on both sides.

// ---------- conversions / repacks ----------
__global__ void k_f2h(fp16* __restrict__ dst, const float* __restrict__ src, long long n) {
  long long i = (long long)blockIdx.x * 256 + threadIdx.x;
  if (i < n) dst[i] = (fp16)src[i];
}

// wcatT[n][kk] = wcat[kk][n], kk<576 from W39, else W40 (each [576][256])
__global__ void k_wcatT(fp16* __restrict__ dst, const float* __restrict__ w39,
                        const float* __restrict__ w40) {
  int i = blockIdx.x * 256 + threadIdx.x;
  if (i >= 1152 * 256) return;
  int n = i & 255, kk = i >> 8;
  float v = (kk < 576) ? w39[kk * 256 + n] : w40[(kk - 576) * 256 + n];
  dst[(long long)n * 1152 + kk] = (fp16)v;
}

// dcgru weights (512,O): row=f*4+t -> Wt[d][t*128+c] = src[(c*4+t)*O+d]
__global__ void k_gru_repackT(fp16* __restrict__ dst, const float* __restrict__ src, int O) {
  int i = blockIdx.x * 256 + threadIdx.x;
  if (i >= O * 512) return;
  int d = i >> 9;
  int kc = i & 511;
  int t = kc >> 7;
  int c = kc & 127;
  dst[i] = (fp16)src[(c * 4 + t) * O + d];
}

// (64,64) -> T[d][k] fp16
__global__ void k_w2T(fp16* __restrict__ dst, const float* __restrict__ src) {
  int i = blockIdx.x * 256 + threadIdx.x;
  if (i >= 4096) return;
  int d = i >> 6, k = i & 63;
  dst[i] = (fp16)src[k * 64 + d];
}

// ---------- laplacian ----------
__global__ void k_dinv(const float* __restrict__ adj, float* __restrict__ dinv) {
  int row = blockIdx.x;
  float s = 0.f;
  for (int j = threadIdx.x; j < NN; j += 256)
    s += fmaxf(adj[(long long)row * NN + j], adj[(long long)j * NN + row]);
  __shared__ float red[256];
  red[threadIdx.x] = s;
  __syncthreads();
  for (int st = 128; st > 0; st >>= 1) {
    if (threadIdx.x < st) red[threadIdx.x] += red[threadIdx.x + st];
    __syncthreads();
  }
  if (threadIdx.x == 0) {
    float d = red[0];
    dinv[row] = d > 0.f ? 1.0f / sqrtf(d) : 0.f;
  }
}

// writes L with row stride 2048 (zero-padded for maskless mfma4)
__global__ void k_L(const float* __restrict__ adj, const float* __restrict__ dinv,
                    fp16* __restrict__ Lh) {
  long long i = (long long)blockIdx.x * 256 + threadIdx.x;
  if (i >= (long long)NN * NN) return;
  int r = (int)(i / NN), c = (int)(i % NN);
  float a = fmaxf(adj[(long long)r * NN + c], adj[(long long)c * NN + r]);
  Lh[(long long)r * 2048 + c] = (fp16)(-dinv[r] * a * dinv[c]);
}

__global__ void k_subdiag(fp16* __restrict__ M2) {
  int i = blockIdx.x * 256 + threadIdx.x;
  if (i >= NN) return;
  M2[(long long)i * 2048 + i] = (fp16)((float)M2[(long long)i * 2048 + i] - 1.0f);
}

// ---------- gumbel softmax -> fp16 ----------
__global__ void k_gumbel_softmax(const float* __restrict__ ml, const float* __restrict__ gn,
                                 fp16* __restrict__ mZ) {
  int row = blockIdx.x;
  __shared__ float buf[CC];
  __shared__ float red[256];
  int t = threadIdx.x;
  float mx = -1e30f;
  for (int j = t; j < CC; j += 256) {
    float u = gn[(long long)row * CC + j];
    float g = -logf(-logf(u + 1e-20f) + 1e-20f);
    float v = ml[(long long)row * CC + j] + g;
    buf[j] = v;
    mx = fmaxf(mx, v);
  }
  red[t] = mx;
  __syncthreads();
  for (int st = 128; st > 0; st >>= 1) {
    if (t < st) red[t] = fmaxf(red[t], red[t + st]);
    __syncthreads();
  }
  mx = red[0];
  __syncthreads();
  float s = 0.f;
  for (int j = t; j < CC; j += 256) {
    float e = expf(buf[j] - mx);
    buf[j] = e;
    s += e;
  }
  red[t] = s;
  __syncthreads();
  for (int st = 128; st > 0; st >>= 1) {
    if (t < st) red[t] += red[t + st];
    __syncthreads();
  }
  float inv = 1.0f / red[0];
  for (int j = t; j < CC; j += 256) mZ[(long long)row * CC + j] = (fp16)(buf[j] * inv);
}

__global__ void k_te(const int* __restrict__ TE, const float* __restrict__ w1,
                     const float* __restrict__ b1, float* __restrict__ tmp) {
  int i = blockIdx.x * 256 + threadIdx.x;
  if (i >= BB * PP * 64) return;
  int j = i & 63;
  int bp = i >> 6;
  int b = bp / PP, p = bp % PP;
  int te0 = TE[(b * (PP + QQ) + p) * 2 + 0];
  int te1 = TE[(b * (PP + QQ) + p) * 2 + 1];
  float v = w1[te0 * 64 + j] + w1[(7 + te1) * 64 + j] + b1[j];
  tmp[i] = fmaxf(v, 0.f);
}

__global__ void k_addb(float* __restrict__ dst, const float* __restrict__ b, int n) {
  int i = blockIdx.x * 256 + threadIdx.x;
  if (i < n) dst[i] += b[i & 63];
}

__global__ void k_zf1(const float* __restrict__ Z, const float* __restrict__ w1,
                      const float* __restrict__ b1, fp16* __restrict__ tmp) {
  long long i = (long long)blockIdx.x * 256 + threadIdx.x;
  if (i >= (long long)BB * PP * CC * 64) return;
  int j = (int)(i & 63);
  long long row = i >> 6;
  float v = Z[row * 2 + 0] * w1[j] + Z[row * 2 + 1] * w1[64 + j] + b1[j];
  tmp[i] = (fp16)fmaxf(v, 0.f);
}

// scatter Zf (unpadded) + STEZ into padded 34x34 grid layout
__global__ void k_add_stez(fp16* __restrict__ dst, const fp16* __restrict__ src,
                           const float* __restrict__ seZ, const float* __restrict__ teZ) {
  long long i = (long long)blockIdx.x * 256 + threadIdx.x;
  if (i >= (long long)BB * PP * CC * 64) return;
  int j = (int)(i & 63);
  long long row = i >> 6;
  int c = (int)(row & 1023);
  int bp = (int)(row >> 10);
  int pc = ((c >> 5) + 1) * GP + (c & 31) + 1;
  dst[((long long)bp * GP2 + pc) * 64 + j] =
      (fp16)((float)src[i] + seZ[c * 64 + j] + teZ[bp * 64 + j]);
}

// ---------- generic fp32-path GEMM (small ops) ----------
template <typename TA, typename TB, typename TC>
__global__ __launch_bounds__(256) void gemm_t(
    const TA* __restrict__ A, int lda, long long sA,
    const TB* __restrict__ Bm, int ldb, long long sB,
    TC* Cm, int ldc, long long sC,
    const TC* S, long long sS,
    const float* __restrict__ bias,
    int M, int Ncols, int K, float alpha, float beta, int act) {
  int bz = blockIdx.z;
  A += (long long)bz * sA;
  Bm += (long long)bz * sB;
  Cm += (long long)bz * sC;
  if (S) S += (long long)bz * sS;
  const int row0 = blockIdx.x * 64, col0 = blockIdx.y * 64;
  __shared__ float As[16][68];
  __shared__ float Bs[16][68];
  int tid = threadIdx.x, tx = tid & 15, ty = tid >> 4;
  float acc[4][4] = {};
  for (int k0 = 0; k0 < K; k0 += 16) {
#pragma unroll
    for (int j = 0; j < 4; ++j) {
      int e = tid + 256 * j;
      int m = e >> 4, kk = e & 15;
      int gm = row0 + m;
      As[kk][m] = (gm < M) ? ldf(A[(long long)gm * lda + k0 + kk]) : 0.f;
    }
#pragma unroll
    for (int j = 0; j < 4; ++j) {
      int e = tid + 256 * j;
      int kk = e >> 6, n = e & 63;
      int gn = col0 + n;
      Bs[kk][n] = (gn < Ncols) ? ldf(Bm[(long long)(k0 + kk) * ldb + gn]) : 0.f;
    }
    __syncthreads();
#pragma unroll
    for (int kk = 0; kk < 16; ++kk) {
      float a[4], bb[4];
#pragma unroll
      for (int i = 0; i < 4; ++i) a[i] = As[kk][ty * 4 + i];
#pragma unroll
      for (int j = 0; j < 4; ++j) bb[j] = Bs[kk][tx * 4 + j];
#pragma unroll
      for (int i = 0; i < 4; ++i)
#pragma unroll
        for (int j = 0; j < 4; ++j) acc[i][j] = fmaf(a[i], bb[j], acc[i][j]);
    }
    __syncthreads();
  }
#pragma unroll
  for (int i = 0; i < 4; ++i) {
    int r = row0 + ty * 4 + i;
    if (r >= M) continue;
#pragma unroll
    for (int j = 0; j < 4; ++j) {
      int cn = col0 + tx * 4 + j;
      if (cn >= Ncols) continue;
      float v = alpha * acc[i][j];
      if (bias) v += bias[cn];
      if (S) v += beta * ldf(S[(long long)r * ldc + cn]);
      if (act == 1) v = fmaxf(v, 0.f);
      else if (act == 2) v = 1.f / (1.f + expf(-v));
      else if (act == 3) v = tanhf(v);
      stf(&Cm[(long long)r * ldc + cn], v);
    }
  }
}

// ---------- mfma7: DCGRU weight GEMMs, mfma4-structure, fused GRU epilogues ----------
// K=512 fixed = 16 k-steps. Double-buffered LDS, gload_lds staging for A and for
// cheb slabs 1..3; slab0 (live xh) transpose-scatter directly into swizzled layout.
// B k-slab s>=1: kin<64 from Xc (x-chebs), kin>=64 from Hc (h/rh-chebs).
// MODE 1 (ru):  C=ruT [z][128][NN]; sigmoid; rows<64 also write rh=r*h into rhOut
// MODE 2 (cnd): tanh; h' = u*h + (1-u)*v written in-place into C (=U0 h-rows)
template <int MT, int MODE>
__global__ __launch_bounds__(256) void mfma7(
    const fp16* __restrict__ A,                       // weights MT x 512
    const fp16* __restrict__ U0base, long long uZ, int bHi,
    const fp16* __restrict__ xB, long long xZ,        // ZXt slab0 x rows (ld 2048)
    const fp16* __restrict__ Xc, long long XcSlab, int Xcld, int Xczmul,
    const fp16* __restrict__ Hc, long long HcSlab, int Hcld, int Hczmul,
    fp16* __restrict__ C, int ldc, long long cBatch,
    const float* __restrict__ bias,
    fp16* __restrict__ rhOut, const fp16* __restrict__ hIn,
    const fp16* __restrict__ uIn, long long uStride,
    int M, int Ncols) {
  __shared__ fp16 As[2][MT * 32];
  __shared__ fp16 Bs[2][64 * 32];
  const int z = blockIdx.z;
  const int n0 = blockIdx.y * 64;
  const fp16* U0z = U0base + (long long)z * uZ;
  const fp16* xBz = xB + (long long)z * xZ;
  C += (long long)z * cBatch;
  if (rhOut) rhOut += (long long)z * uZ;
  if (hIn) hIn += (long long)z * uZ;
  if (uIn) uIn += (long long)z * uStride;
  const int tid = threadIdx.x;
  const int lane = tid & 63, wv = tid >> 6;
  const int wr = wv >> 1, wc = wv & 1;
  const int quad = lane >> 4, ln = lane & 15;
  constexpr int WM = MT / 32;

  // A staging sources (seg pre-swizzled: slot ^ ((row>>1)&3))
  const fp16* aSrc[MT / 64];
#pragma unroll
  for (int i = 0; i < MT / 64; ++i) {
    int c = i * 256 + tid;
    int row = c >> 2;
    int lseg = (c & 3) ^ ((c >> 3) & 3);
    aSrc[i] = A + (long long)row * 512 + lseg * 8;
  }
  // B slab>=1 per-thread geometry
  const int brow = tid >> 2;
  const int blseg = (tid & 3) ^ ((tid >> 3) & 3);
  const long long bnode = n0 + brow;

  f32x4 acc[WM][2];
#pragma unroll
  for (int i = 0; i < WM; ++i)
#pragma unroll
    for (int j = 0; j < 2; ++j) acc[i][j] = (f32x4){0.f, 0.f, 0.f, 0.f};

  auto stage = [&](int t, int buf) {
    const int k0 = t * 32;
#pragma unroll
    for (int i = 0; i < MT / 64; ++i)
      gload_lds16(aSrc[i] + k0, &As[buf][(i * 256 + tid) * 8]);
    if (k0 < 128) {
      // slab0: xh transpose-scatter into swizzled layout
      int kin = k0 + (tid & 31);
      int ngrp = tid >> 5;
      int n = n0 + ngrp * 8;
      const fp16* src = (kin < 64) ? (xBz + (long long)kin * 2048 + n)
                                   : (U0z + (long long)(kin + bHi) * 2048 + n);
      f16x8 v = *(const f16x8*)src;
      int kk = tid & 31;
#pragma unroll
      for (int j = 0; j < 8; ++j) {
        int rn = ngrp * 8 + j;
        Bs[buf][rn * 32 + ((((kk >> 3) ^ ((rn >> 1) & 3)) << 3) | (kk & 7))] = v[j];
      }
    } else {
      int slab = k0 >> 7;
      int kin = (k0 & 127) + blseg * 8;
      const fp16* src;
      if (kin < 64)
        src = Xc + (long long)(slab - 1) * XcSlab + bnode * Xcld +
              (long long)z * Xczmul + kin;
      else
        src = Hc + (long long)(slab - 1) * HcSlab + bnode * Hcld +
              (long long)z * Hczmul + (kin - 64);
      gload_lds16(src, &Bs[buf][tid * 8]);
    }
  };

  const int sw = (quad ^ ((ln >> 1) & 3)) << 3;
  stage(0, 0);
  for (int t = 0; t < 16; ++t) {
    const int buf = t & 1;
    __syncthreads();
    if (t + 1 < 16) stage(t + 1, buf ^ 1);
    f16x8 af[WM], bf[2];
#pragma unroll
    for (int wm = 0; wm < WM; ++wm) {
      int row = wr * (MT / 2) + wm * 16 + ln;
      af[wm] = *(const f16x8*)&As[buf][row * 32 + sw];
    }
#pragma unroll
    for (int wn = 0; wn < 2; ++wn) {
      int row = wc * 32 + wn * 16 + ln;
      bf[wn] = *(const f16x8*)&Bs[buf][row * 32 + sw];
    }
#pragma unroll
    for (int wm = 0; wm < WM; ++wm)
#pragma unroll
      for (int wn = 0; wn < 2; ++wn)
        acc[wm][wn] =
            __builtin_amdgcn_mfma_f32_16x16x32_f16(af[wm], bf[wn], acc[wm][wn], 0, 0, 0);
  }
#pragma unroll
  for (int wm = 0; wm < WM; ++wm) {
#pragma unroll
    for (int wn = 0; wn < 2; ++wn) {
#pragma unroll
      for (int r = 0; r < 4; ++r) {
        int gm = wr * (MT / 2) + wm * 16 + quad * 4 + r;
        int gn = n0 + wc * 32 + wn * 16 + ln;
        if (gm < M && gn < Ncols) {
          float v = acc[wm][wn][r];
          v += bias[gm];
          if (MODE == 1) {
            v = 1.f / (1.f + expf(-v));  // sigmoid
            C[(long long)gm * ldc + gn] = (fp16)v;
            if (gm < 64) {
              float h = (float)hIn[(long long)gm * 2048 + gn];
              rhOut[(long long)gm * 2048 + gn] = (fp16)(v * h);
            }
          } else {
            v = tanhf(v);
            float u = (float)uIn[(long long)(64 + gm) * NN + gn];
            long long ci = (long long)gm * ldc + gn;
            float h = (float)C[ci];
            C[ci] = (fp16)(u * h + (1.f - u) * v);
          }
        }
      }
    }
  }
}

// ---------- mfma3: all-b128 GEMM (kept for movement m2) ----------
template <int MT, int NT>
__global__ __launch_bounds__(256) void mfma3(
    const fp16* __restrict__ A, int lda, long long zA, int aMsh, long long aMslab,
    const fp16* __restrict__ B, int ldb, long long zB,
    fp16* __restrict__ C, int ldc, long long zC, int cMsh, long long cMslab, int cNsh,
    long long cNslab,
    const fp16* __restrict__ S, long long zS, float beta,
    const float* __restrict__ rowBias, long long zRB,
    const float* __restrict__ s2T, int s2ld,
    int M, int Ncols, int K, float alpha, int act) {
  __shared__ fp16 As[MT][40];
  __shared__ fp16 Bs[NT][40];
  const int z = blockIdx.z;
  const int gm0 = blockIdx.x * MT, n0 = blockIdx.y * NT;
  A += (long long)z * zA;
  B += (long long)z * zB;
  C += (long long)z * zC;
  if (S) S += (long long)z * zS;
  const int tid = threadIdx.x;
  const int lane = tid & 63, wv = tid >> 6;
  const int wr = wv >> 1, wc = wv & 1;
  const int quad = lane >> 4, ln = lane & 15;
  const unsigned aMmask = (1u << aMsh) - 1u;
  const unsigned cMmask = (1u << cMsh) - 1u;
  const unsigned cNmask = (1u << cNsh) - 1u;
  constexpr int WM = MT / 32, WN = NT / 32;
  f32x4 acc[WM][WN];
#pragma unroll
  for (int i = 0; i < WM; ++i)
#pragma unroll
    for (int j = 0; j < WN; ++j) acc[i][j] = (f32x4){0.f, 0.f, 0.f, 0.f};

  for (int k0 = 0; k0 < K; k0 += 32) {
#pragma unroll
    for (int i = 0; i < MT / 64; ++i) {
      int c = tid + 256 * i;
      int row = c >> 2, seg = c & 3;
      int gm = gm0 + row;
      int kk0 = k0 + seg * 8;
      const fp16* src = A + ((long long)((unsigned)gm >> aMsh)) * aMslab +
                        (long long)(gm & aMmask) * lda + kk0;
      if (gm < M && kk0 + 8 <= K) {
        *(f16x8*)&As[row][seg * 8] = *(const f16x8*)src;
      } else {
#pragma unroll
        for (int j = 0; j < 8; ++j)
          As[row][seg * 8 + j] = (gm < M && kk0 + j < K) ? src[j] : (fp16)0.f;
      }
    }
#pragma unroll
    for (int i = 0; i < NT / 64; ++i) {
      int c = tid + 256 * i;
      int n = c >> 2, seg = c & 3;
      int gn = n0 + n;
      int kk0 = k0 + seg * 8;
      const fp16* src = B + (long long)gn * ldb + kk0;
      if (gn < Ncols && kk0 + 8 <= K) {
        *(f16x8*)&Bs[n][seg * 8] = *(const f16x8*)src;
      } else {
#pragma unroll
        for (int j = 0; j < 8; ++j)
          Bs[n][seg * 8 + j] = (gn < Ncols && kk0 + j < K) ? src[j] : (fp16)0.f;
      }
    }
    __syncthreads();
    f16x8 af[WM], bf[WN];
#pragma unroll
    for (int wm = 0; wm < WM; ++wm)
      af[wm] = *(const f16x8*)&As[wr * (MT / 2) + wm * 16 + ln][quad * 8];
#pragma unroll
    for (int wn = 0; wn < WN; ++wn)
      bf[wn] = *(const f16x8*)&Bs[wc * (NT / 2) + wn * 16 + ln][quad * 8];
#pragma unroll
    for (int wm = 0; wm < WM; ++wm)
#pragma unroll
      for (int wn = 0; wn < WN; ++wn)
        acc[wm][wn] =
            __builtin_amdgcn_mfma_f32_16x16x32_f16(af[wm], bf[wn], acc[wm][wn], 0, 0, 0);
    __syncthreads();
  }
#pragma unroll
  for (int wm = 0; wm < WM; ++wm) {
#pragma unroll
    for (int wn = 0; wn < WN; ++wn) {
#pragma unroll
      for (int r = 0; r < 4; ++r) {
        int gm = gm0 + wr * (MT / 2) + wm * 16 + quad * 4 + r;
        int gn = n0 + wc * (NT / 2) + wn * 16 + ln;
        if (gm < M && gn < Ncols) {
          float v = alpha * acc[wm][wn][r];
          if (rowBias) v += rowBias[(long long)z * zRB + gm];
          if (s2T) v += s2T[(long long)gn * s2ld + gm];
          long long ci = ((long long)((unsigned)gm >> cMsh)) * cMslab +
                         (long long)(gm & cMmask) * ldc +
                         ((long long)((unsigned)gn >> cNsh)) * cNslab + (gn & cNmask);
          if (S) v += beta * (float)S[ci];
          if (act == 1) v = fmaxf(v, 0.f);
          else if (act == 2) v = 1.f / (1.f + expf(-v));
          else if (act == 3) v = tanhf(v);
          C[ci] = (fp16)v;
        }
      }
    }
  }
}

// ---------- mfma4: maskless gload_lds GEMM, dual-base A descriptor ----------
template <int MT, int NT>
__global__ __launch_bounds__(256) void mfma4(
    const fp16* __restrict__ base0, const fp16* __restrict__ base1, int rsh, int ssh,
    long long z0, long long z1, int lda,
    const fp16* __restrict__ B, int ldb, long long zB,
    fp16* __restrict__ C, int ldc, long long zC, int cMsh, long long cMslab, int cNsh,
    long long cNslab,
    const fp16* __restrict__ S, float alpha, float beta, int K) {
  __shared__ fp16 As[2][MT * 32];
  __shared__ fp16 Bs[2][NT * 32];
  const int tid = threadIdx.x;
  const int z = blockIdx.z;
  const int gm0 = blockIdx.x * MT, n0 = blockIdx.y * NT;
  B += (long long)z * zB;
  C += (long long)z * zC;
  if (S) S += (long long)z * zC;
  const unsigned cMmask = (1u << cMsh) - 1u;
  const unsigned cNmask = (1u << cNsh) - 1u;
  const int lane = tid & 63, wv = tid >> 6;
  const int wr = wv >> 1, wc = wv & 1;
  const int quad = lane >> 4, ln = lane & 15;
  constexpr int WM = MT / 32, WN = NT / 32;

  const fp16* aSrc[MT / 64];
  const fp16* bSrc[NT / 64];
#pragma unroll
  for (int i = 0; i < MT / 64; ++i) {
    int c = i * 256 + tid;
    int row = c >> 2;
    int lseg = (c & 3) ^ ((c >> 3) & 3);
    int gm = gm0 + row;
    unsigned b = (unsigned)gm >> rsh;
    unsigned wi = (unsigned)gm & ((1u << rsh) - 1u);
    unsigned sel = wi >> ssh;
    unsigned r = wi & ((1u << ssh) - 1u);
    const fp16* ab = sel ? (base1 + (long long)b * z1) : (base0 + (long long)b * z0);
    aSrc[i] = ab + (long long)r * lda + lseg * 8;
  }
#pragma unroll
  for (int i = 0; i < NT / 64; ++i) {
    int c = i * 256 + tid;
    int lseg = (c & 3) ^ ((c >> 3) & 3);
    bSrc[i] = B + (long long)(n0 + (c >> 2)) * ldb + lseg * 8;
  }

  f32x4 acc[WM][WN];
#pragma unroll
  for (int i = 0; i < WM; ++i)
#pragma unroll
    for (int j = 0; j < WN; ++j) acc[i][j] = (f32x4){0.f, 0.f, 0.f, 0.f};

  const int sw = (quad ^ ((ln >> 1) & 3)) << 3;

#pragma unroll
  for (int i = 0; i < MT / 64; ++i) gload_lds16(aSrc[i], &As[0][(i * 256 + tid) * 8]);
#pragma unroll
  for (int i = 0; i < NT / 64; ++i) gload_lds16(bSrc[i], &Bs[0][(i * 256 + tid) * 8]);

  const int nk = K >> 5;
  for (int t = 0; t < nk; ++t) {
    const int buf = t & 1;
    __syncthreads();
    if (t + 1 < nk) {
      const int k1 = (t + 1) * 32;
#pragma unroll
      for (int i = 0; i < MT / 64; ++i)
        gload_lds16(aSrc[i] + k1, &As[buf ^ 1][(i * 256 + tid) * 8]);
#pragma unroll
      for (int i = 0; i < NT / 64; ++i)
        gload_lds16(bSrc[i] + k1, &Bs[buf ^ 1][(i * 256 + tid) * 8]);
    }
    f16x8 af[WM], bf[WN];
#pragma unroll
    for (int wm = 0; wm < WM; ++wm) {
      int row = wr * (MT / 2) + wm * 16 + ln;
      af[wm] = *(const f16x8*)&As[buf][row * 32 + sw];
    }
#pragma unroll
    for (int wn = 0; wn < WN; ++wn) {
      int row = wc * (NT / 2) + wn * 16 + ln;
      bf[wn] = *(const f16x8*)&Bs[buf][row * 32 + sw];
    }
#pragma unroll
    for (int wm = 0; wm < WM; ++wm)
#pragma unroll
      for (int wn = 0; wn < WN; ++wn)
        acc[wm][wn] =
            __builtin_amdgcn_mfma_f32_16x16x32_f16(af[wm], bf[wn], acc[wm][wn], 0, 0, 0);
  }
#pragma unroll
  for (int wm = 0; wm < WM; ++wm)
#pragma unroll
    for (int wn = 0; wn < WN; ++wn)
#pragma unroll
      for (int r = 0; r < 4; ++r) {
        int gm = gm0 + wr * (MT / 2) + wm * 16 + quad * 4 + r;
        int gn = n0 + wc * (NT / 2) + wn * 16 + ln;
        long long ci = ((long long)((unsigned)gm >> cMsh)) * cMslab +
                       (long long)(gm & cMmask) * ldc +
                       ((long long)((unsigned)gn >> cNsh)) * cNslab + (gn & cNmask);
        float v = alpha * acc[wm][wn][r];
        if (S) v += beta * (float)S[ci];
        C[ci] = (fp16)v;
      }
}

// ---------- mfma6: maskless gload_lds GEMM, dual-base B descriptor ----------
template <int MT, int NT>
__global__ __launch_bounds__(256) void mfma6(
    const fp16* __restrict__ A, int lda,
    const fp16* __restrict__ b0, const fp16* __restrict__ b1, int rsh, int ssh,
    long long z0, long long z1, int ldb,
    fp16* __restrict__ C, int ldc, int cMsh, long long cMslab,
    int K) {
  __shared__ fp16 As[2][MT * 32];
  __shared__ fp16 Bs[2][NT * 32];
  const int tid = threadIdx.x;
  const int gm0 = blockIdx.x * MT, n0 = blockIdx.y * NT;
  const unsigned cMmask = (1u << cMsh) - 1u;
  const int lane = tid & 63, wv = tid >> 6;
  const int wr = wv >> 1, wc = wv & 1;
  const int quad = lane >> 4, ln = lane & 15;
  constexpr int WM = MT / 32, WN = NT / 32;

  const fp16* aSrc[MT / 64];
  const fp16* bSrc[NT / 64];
#pragma unroll
  for (int i = 0; i < MT / 64; ++i) {
    int c = i * 256 + tid;
    int lseg = (c & 3) ^ ((c >> 3) & 3);
    aSrc[i] = A + (long long)(gm0 + (c >> 2)) * lda + lseg * 8;
  }
#pragma unroll
  for (int i = 0; i < NT / 64; ++i) {
    int c = i * 256 + tid;
    int lseg = (c & 3) ^ ((c >> 3) & 3);
    int gn = n0 + (c >> 2);
    unsigned b = (unsigned)gn >> rsh;
    unsigned wi = (unsigned)gn & ((1u << rsh) - 1u);
    unsigned sel = wi >> ssh;
    unsigned r = wi & ((1u << ssh) - 1u);
    const fp16* bb = sel ? (b1 + (long long)b * z1) : (b0 + (long long)b * z0);
    bSrc[i] = bb + (long long)r * ldb + lseg * 8;
  }

  f32x4 acc[WM][WN];
#pragma unroll
  for (int i = 0; i < WM; ++i)
#pragma unroll
    for (int j = 0; j < WN; ++j) acc[i][j] = (f32x4){0.f, 0.f, 0.f, 0.f};

  const int sw = (quad ^ ((ln >> 1) & 3)) << 3;

#pragma unroll
  for (int i = 0; i < MT / 64; ++i) gload_lds16(aSrc[i], &As[0][(i * 256 + tid) * 8]);
#pragma unroll
  for (int i = 0; i < NT / 64; ++i) gload_lds16(bSrc[i], &Bs[0][(i * 256 + tid) * 8]);

  const int nk = K >> 5;
  for (int t = 0; t < nk; ++t) {
    const int buf = t & 1;
    __syncthreads();
    if (t + 1 < nk) {
      const int k1 = (t + 1) * 32;
#pragma unroll
      for (int i = 0; i < MT / 64; ++i)
        gload_lds16(aSrc[i] + k1, &As[buf ^ 1][(i * 256 + tid) * 8]);
#pragma unroll
      for (int i = 0; i < NT / 64; ++i)
        gload_lds16(bSrc[i] + k1, &Bs[buf ^ 1][(i * 256 + tid) * 8]);
    }
    f16x8 af[WM], bf[WN];
#pragma unroll
    for (int wm = 0; wm < WM; ++wm) {
      int row = wr * (MT / 2) + wm * 16 + ln;
      af[wm] = *(const f16x8*)&As[buf][row * 32 + sw];
    }
#pragma unroll
    for (int wn = 0; wn < WN; ++wn) {
      int row = wc * (NT / 2) + wn * 16 + ln;
      bf[wn] = *(const f16x8*)&Bs[buf][row * 32 + sw];
    }
#pragma unroll
    for (int wm = 0; wm < WM; ++wm)
#pragma unroll
      for (int wn = 0; wn < WN; ++wn)
        acc[wm][wn] =
            __builtin_amdgcn_mfma_f32_16x16x32_f16(af[wm], bf[wn], acc[wm][wn], 0, 0, 0);
  }
#pragma unroll
  for (int wm = 0; wm < WM; ++wm)
#pragma unroll
    for (int wn = 0; wn < WN; ++wn)
#pragma unroll
      for (int r = 0; r < 4; ++r) {
        int gm = gm0 + wr * (MT / 2) + wm * 16 + quad * 4 + r;
        int gn = n0 + wc * (NT / 2) + wn * 16 + ln;
        long long ci = ((long long)((unsigned)gm >> cMsh)) * cMslab +
                       (long long)(gm & cMmask) * ldc + gn;
        C[ci] = (fp16)acc[wm][wn][r];
      }
}

// ---------- k_zxtfin: ZXt[z][d][n] += w2T@Tmat[z]^T + teXb + seX; zero pad cols ----------
__global__ __launch_bounds__(256) void k_zxtfin(
    const fp16* __restrict__ w2T, const fp16* __restrict__ Tmat,
    fp16* __restrict__ ZXt, const float* __restrict__ teXb, const float* __restrict__ seX) {
  __shared__ fp16 As[64][72];
  __shared__ fp16 Bs[128][72];
  const int z = blockIdx.z;
  const int n0 = blockIdx.y * 128;
  const fp16* Tz = Tmat + (long long)z * 2048 * 64;
  fp16* Cz = ZXt + (long long)z * 64 * 2048;
  const float* tb = teXb + z * 64;
  const int tid = threadIdx.x;
  const int lane = tid & 63, wv = tid >> 6;
  const int wr = wv >> 1, wc = wv & 1;
  const int quad = lane >> 4, ln = lane & 15;
#pragma unroll
  for (int i = 0; i < 2; ++i) {
    int c = tid + 256 * i;
    int row = c >> 3, seg = c & 7;
    *(f16x8*)&As[row][seg * 8] = *(const f16x8*)(w2T + row * 64 + seg * 8);
  }
#pragma unroll
  for (int i = 0; i < 4; ++i) {
    int c = tid + 256 * i;
    int row = c >> 3, seg = c & 7;
    *(f16x8*)&Bs[row][seg * 8] =
        *(const f16x8*)(Tz + (long long)(n0 + row) * 64 + seg * 8);
  }
  __syncthreads();
  f32x4 acc[2][4];
#pragma unroll
  for (int i = 0; i < 2; ++i)
#pragma unroll
    for (int j = 0; j < 4; ++j) acc[i][j] = (f32x4){0.f, 0.f, 0.f, 0.f};
#pragma unroll
  for (int kt = 0; kt < 2; ++kt) {
    f16x8 af[2], bf[4];
#pragma unroll
    for (int wm = 0; wm < 2; ++wm)
      af[wm] = *(const f16x8*)&As[wr * 32 + wm * 16 + ln][kt * 32 + quad * 8];
#pragma unroll
    for (int wn = 0; wn < 4; ++wn)
      bf[wn] = *(const f16x8*)&Bs[wc * 64 + wn * 16 + ln][kt * 32 + quad * 8];
#pragma unroll
    for (int wm = 0; wm < 2; ++wm)
#pragma unroll
      for (int wn = 0; wn < 4; ++wn)
        acc[wm][wn] =
            __builtin_amdgcn_mfma_f32_16x16x32_f16(af[wm], bf[wn], acc[wm][wn], 0, 0, 0);
  }
#pragma unroll
  for (int wm = 0; wm < 2; ++wm)
#pragma unroll
    for (int wn = 0; wn < 4; ++wn)
#pragma unroll
      for (int r = 0; r < 4; ++r) {
        int gm = wr * 32 + wm * 16 + quad * 4 + r;
        int gn = n0 + wc * 64 + wn * 16 + ln;
        long long ci = (long long)gm * 2048 + gn;
        float v = 0.f;
        if (gn < NN)
          v = acc[wm][wn][r] + (float)Cz[ci] + tb[gm] + seX[(long long)gn * 64 + gm];
        Cz[ci] = (fp16)v;
      }
}

// ---------- ConvLSTM conv, mfma4-style with zero-padded 34x34 halo ----------
__global__ __launch_bounds__(256) void k_conv4(
    const fp16* __restrict__ Zfp, const fp16* __restrict__ hp,
    const fp16* __restrict__ wcatT, fp16* __restrict__ gates, int p) {
  __shared__ fp16 As[2][128 * 32];
  __shared__ fp16 Bs[2][64 * 32];
  const int gm0 = blockIdx.x * 128, n0 = blockIdx.y * 64;
  const int tid = threadIdx.x;
  const int lane = tid & 63, wv = tid >> 6;
  const int wr = wv >> 1, wc = wv & 1;
  const int quad = lane >> 4, ln = lane & 15;

  long long aZ[2], aH[2];
#pragma unroll
  for (int i = 0; i < 2; ++i) {
    int c = tid + 256 * i;
    int row = c >> 2;
    int lseg = (c & 3) ^ ((c >> 3) & 3);
    int m = gm0 + row;
    int b = m >> 10, y = (m >> 5) & 31, x = m & 31;
    int pc = (y + 1) * GP + (x + 1);
    aZ[i] = ((long long)(b * PP + p) * GP2 + pc) * 64 + lseg * 8;
    aH[i] = ((long long)b * GP2 + pc) * 64 + lseg * 8;
  }
  const fp16* bBase;
  {
    int row = tid >> 2;
    int lseg = (tid & 3) ^ ((tid >> 3) & 3);
    bBase = wcatT + (long long)(n0 + row) * 1152 + lseg * 8;
  }
  f32x4 acc[4][2];
#pragma unroll
  for (int i = 0; i < 4; ++i)
#pragma unroll
    for (int j = 0; j < 2; ++j) acc[i][j] = (f32x4){0.f, 0.f, 0.f, 0.f};

  auto stage = [&](int t, int buf) {
    int tap = (t >> 1) % 9, half = t & 1;
    int srcsel = t >= 18;
    int off = ((tap / 3 - 1) * GP + (tap % 3 - 1)) * 64 + half * 32;
#pragma unroll
    for (int i = 0; i < 2; ++i) {
      const fp16* src = srcsel ? (hp + aH[i] + off) : (Zfp + aZ[i] + off);
      gload_lds16(src, &As[buf][(i * 256 + tid) * 8]);
    }
    gload_lds16(bBase + t * 32, &Bs[buf][tid * 8]);
  };
  stage(0, 0);
  const int sw = (quad ^ ((ln >> 1) & 3)) << 3;
  for (int t = 0; t < 36; ++t) {
    const int buf = t & 1;
    __syncthreads();
    if (t + 1 < 36) stage(t + 1, buf ^ 1);
    f16x8 af[4], bf[2];
#pragma unroll
    for (int wm = 0; wm < 4; ++wm) {
      int row = wr * 64 + wm * 16 + ln;
      af[wm] = *(const f16x8*)&As[buf][row * 32 + sw];
    }
#pragma unroll
    for (int wn = 0; wn < 2; ++wn) {
      int row = wc * 32 + wn * 16 + ln;
      bf[wn] = *(const f16x8*)&Bs[buf][row * 32 + sw];
    }
#pragma unroll
    for (int wm = 0; wm < 4; ++wm)
#pragma unroll
      for (int wn = 0; wn < 2; ++wn)
        acc[wm][wn] =
            __builtin_amdgcn_mfma_f32_16x16x32_f16(af[wm], bf[wn], acc[wm][wn], 0, 0, 0);
  }
#pragma unroll
  for (int wm = 0; wm < 4; ++wm)
#pragma unroll
    for (int wn = 0; wn < 2; ++wn)
#pragma unroll
      for (int r = 0; r < 4; ++r) {
        int gm = gm0 + wr * 64 + wm * 16 + quad * 4 + r;
        int gn = n0 + wc * 32 + wn * 16 + ln;
        gates[(long long)gm * 256 + gn] = (fp16)acc[wm][wn][r];
      }
}

__global__ void k_clstm_update(const fp16* __restrict__ gates, float* __restrict__ c,
                               fp16* __restrict__ h, fp16* __restrict__ ZclT, int p) {
  long long i = (long long)blockIdx.x * 256 + threadIdx.x;
  if (i >= (long long)BB * CC * 64) return;
  int d = (int)(i & 63);
  long long bc = i >> 6;
  int b = (int)(bc >> 10);
  int cell = (int)(bc & 1023);
  const fp16* g = gates + (((long long)b * CC) + cell) * 256;
  float gi = (float)g[d], gf = (float)g[64 + d], gg = (float)g[128 + d],
        go = (float)g[192 + d];
  float hs_f = fminf(fmaxf(0.2f * gf + 0.5f, 0.f), 1.f);
  float hs_i = fminf(fmaxf(0.2f * gi + 0.5f, 0.f), 1.f);
  float hs_o = fminf(fmaxf(0.2f * go + 0.5f, 0.f), 1.f);
  float cv = hs_f * c[i] + hs_i * tanhf(gg);
  c[i] = cv;
  float hv = hs_o * tanhf(cv);
  int pc = ((cell >> 5) + 1) * GP + (cell & 31) + 1;
  h[((long long)b * GP2 + pc) * 64 + d] = (fp16)hv;
  ZclT[(((long long)(b * PP + p)) * 64 + d) * CC + cell] = (fp16)hv;
}

// Tmat[z][n][64] with 2048-row stride per z (pad rows garbage; finisher ignores)
__global__ void k_tmat(const float* __restrict__ X, const float* __restrict__ w1,
                       const float* __restrict__ b1, fp16* __restrict__ T, long long nrows) {
  long long i = (long long)blockIdx.x * 256 + threadIdx.x;
  if (i >= nrows * 64) return;
  int j = (int)(i & 63);
  long long row = i >> 6;
  int z = (int)(row / NN);
  int n = (int)(row - (long long)z * NN);
  T[(((long long)z * 2048) + n) * 64 + j] = (fp16)fmaxf(X[row] * w1[j] + b1[j], 0.f);
}

__global__ void k_trT(const fp16* __restrict__ U0, float* __restrict__ htmp) {
  long long i = (long long)blockIdx.x * 256 + threadIdx.x;
  if (i >= (long long)BB * NN * 64) return;
  int d = (int)(i & 63);
  long long bn = i >> 6;
  int b = (int)(bn / NN);
  int n = (int)(bn % NN);
  htmp[i] = (float)U0[((long long)b * 192 + 64 + d) * 2048 + n];
}

__global__ void k_out(const float* __restrict__ Y, float* __restrict__ out) {
  int i = blockIdx.x * 256 + threadIdx.x;
  if (i >= BB * QQ * NN) return;
  int n = i % NN;
  int bq = i / NN;
  int b = bq / QQ, q = bq % QQ;
  out[i] = Y[((long long)b * NN + n) * 12 + q];
}

// ---------- host helpers ----------
template <typename TA, typename TB, typename TC>
static void launch_gemm(hipStream_t stream, const TA* A, int lda, long long sA,
                        const TB* Bm, int ldb, long long sB, TC* Cm, int ldc, long long sC,
                        const TC* S, long long sS, const float* bias, int M, int Nc, int K,
                        float alpha, float beta, int act, int batch) {
  dim3 g((M + 63) / 64, (Nc + 63) / 64, batch);
  gemm_t<TA, TB, TC><<<g, dim3(256), 0, stream>>>(A, lda, sA, Bm, ldb, sB, Cm, ldc, sC, S,
                                                  sS, bias, M, Nc, K, alpha, beta, act);
}

extern "C" void kernel_launch(void* const* d_in, const int* in_sizes, int n_in,
                              void* d_out, int out_size, void* d_ws, size_t ws_size,
                              hipStream_t stream) {
  char* base = (char*)d_ws;
  size_t off = 0;
  auto alloc_bytes = [&](size_t nb) -> char* {
    char* p = base + off;
    off += (nb + 255) & ~(size_t)255;
    return p;
  };
  auto allocf = [&](size_t n) -> float* { return (float*)alloc_bytes(n * 4); };
  auto alloch = [&](size_t n) -> fp16* { return (fp16*)alloc_bytes(n * 2); };

  const float* X = (const float*)d_in[0];
  const float* Z = (const float*)d_in[1];
  const int* TE = (const int*)d_in[2];
  const float* adj_gg = (const float*)d_in[3];
  const float* adj_gr = (const float*)d_in[4];
  const float* gumbel = (const float*)d_in[5];
  const float* se_x = (const float*)d_in[6];
  const float* se_z = (const float*)d_in[7];
  const float* movement = (const float*)d_in[8];
  auto W = [&](int i) { return (const float*)d_in[i]; };

  // ---- allocations ----
  fp16* wcatT = alloch((size_t)256 * 1152);  // [n][k] pre-transposed conv weights
  fp16* gwT = alloch(128 * 512);
  fp16* cwT = alloch(64 * 512);
  fp16* w2T = alloch(64 * 64);
  fp16* w2mT = alloch(64 * 64);
  float* dinv = allocf(NN);
  fp16* LMall = alloch((size_t)6144 * 2048);  // rows padded to 2048 for maskless mfma4/6
  fp16* mZh = alloch((size_t)CC * CC);
  fp16* agh2 = alloch((size_t)2048 * CC);  // padded to 2048 rows (pad rows zero)
  float* seZ = allocf(CC * 64);
  float* teZ = allocf(BB * PP * 64);
  float* seX = allocf(NN * 64);
  float* teXb = allocf(BB * PP * 64);
  float* mtmp = allocf(NN * 64);
  float* tetmp = allocf(BB * PP * 64);
  fp16* ruT = alloch((size_t)BB * 128 * NN);  // [b][128][2000]
  // pool (4*USL = 50.33MB)
  char* pool = alloc_bytes(50331648);
  fp16* Uall = (fp16*)pool;
  fp16* gates = (fp16*)pool;
  fp16* chh = (fp16*)(pool + 8388608);   // padded h [16][1156][64]
  float* ccc = (float*)(pool + 12582912);
  fp16* Zmix = (fp16*)pool;
  fp16* ZmovT = (fp16*)(pool + 25165824);
  // zpool: Zf_pad [bp][1156][64] (28.4MB) then ZXt [bp][64][2048]
  fp16* zpool = alloch((size_t)BB * PP * 64 * 2048);
  fp16* Zfp = zpool;
  fp16* ZXt = zpool;
  fp16* Zc = alloch((size_t)BB * PP * CC * 64);  // zf1 scratch -> ZclT -> Tmat -> head scratch

  if (off > ws_size) return;

  const long long uB = 192LL * 2048;
  const long long USL = 16LL * uB;
  const long long ZXB = 12LL * 64 * 2048;  // per-batch stride of ZXt
  fp16* Lh = LMall;
  fp16* M2h = LMall + 2048LL * 2048;
  fp16* M3h = LMall + 4096LL * 2048;
  const int KCH = 2016;  // chain K (2000 padded to x32; cols 2000..2015 zero)

  // ---- precompute ----
  k_wcatT<<<dim3(1152), dim3(256), 0, stream>>>(wcatT, W(39), W(40));
  k_gru_repackT<<<dim3(256), dim3(256), 0, stream>>>(gwT, W(41), 128);
  k_gru_repackT<<<dim3(128), dim3(256), 0, stream>>>(cwT, W(43), 64);
  k_w2T<<<dim3(16), dim3(256), 0, stream>>>(w2T, W(31));
  k_w2T<<<dim3(16), dim3(256), 0, stream>>>(w2mT, W(33));
  k_dinv<<<dim3(NN), dim3(256), 0, stream>>>(adj_gg, dinv);
  hipMemsetAsync(LMall, 0, (size_t)6144 * 2048 * 2, stream);
  k_L<<<dim3((NN * NN + 255) / 256), dim3(256), 0, stream>>>(adj_gg, dinv, Lh);
  mfma4<64, 128><<<dim3(32, 16, 1), dim3(256), 0, stream>>>(
      Lh, Lh, 31, 31, 0LL, 0LL, 2048, Lh, 2048, 0LL, M2h, 2048, 0LL, 31, 0LL, 31, 0LL,
      (const fp16*)nullptr, 2.f, 0.f, KCH);
  k_subdiag<<<dim3((NN + 255) / 256), dim3(256), 0, stream>>>(M2h);
  mfma4<64, 128><<<dim3(32, 16, 1), dim3(256), 0, stream>>>(
      Lh, Lh, 31, 31, 0LL, 0LL, 2048, M2h, 2048, 0LL, M3h, 2048, 0LL, 31, 0LL, 31, 0LL,
      (const fp16*)Lh, 2.f, -1.f, KCH);
  k_gumbel_softmax<<<dim3(CC), dim3(256), 0, stream>>>(movement, gumbel, mZh);
  k_f2h<<<dim3((NN * CC + 255) / 256), dim3(256), 0, stream>>>(agh2, adj_gr,
                                                               (long long)NN * CC);
  hipMemsetAsync(agh2 + (size_t)NN * CC, 0, (size_t)(2048 - NN) * CC * 2, stream);

  // ---- STEZ / STEX ----
  launch_gemm(stream, se_z, 64, 0LL, W(17), 64, 0LL, mtmp, 64, 0LL, (float*)nullptr, 0LL,
              W(18), CC, 64, 64, 1.f, 0.f, 1, 1);
  launch_gemm(stream, (const float*)mtmp, 64, 0LL, W(19), 64, 0LL, seZ, 64, 0LL,
              (float*)nullptr, 0LL, W(20), CC, 64, 64, 1.f, 0.f, 0, 1);
  k_te<<<dim3((BB * PP * 64 + 255) / 256), dim3(256), 0, stream>>>(TE, W(21), W(22), tetmp);
  launch_gemm(stream, (const float*)tetmp, 64, 0LL, W(23), 64, 0LL, teZ, 64, 0LL,
              (float*)nullptr, 0LL, W(24), BB * PP, 64, 64, 1.f, 0.f, 0, 1);
  launch_gemm(stream, se_x, 64, 0LL, W(9), 64, 0LL, mtmp, 64, 0LL, (float*)nullptr, 0LL,
              W(10), NN, 64, 64, 1.f, 0.f, 1, 1);
  launch_gemm(stream, (const float*)mtmp, 64, 0LL, W(11), 64, 0LL, seX, 64, 0LL,
              (float*)nullptr, 0LL, W(12), NN, 64, 64, 1.f, 0.f, 0, 1);
  k_te<<<dim3((BB * PP * 64 + 255) / 256), dim3(256), 0, stream>>>(TE, W(13), W(14), tetmp);
  launch_gemm(stream, (const float*)tetmp, 64, 0LL, W(15), 64, 0LL, teXb, 64, 0LL,
              (float*)nullptr, 0LL, W(16), BB * PP, 64, 64, 1.f, 0.f, 0, 1);
  k_addb<<<dim3((BB * PP * 64 + 255) / 256), dim3(256), 0, stream>>>(teXb, W(32),
                                                                     BB * PP * 64);

  // ---- Zf = mlp2(Z) + STEZ, scattered into padded 34x34 layout ----
  long long nZ = (long long)BB * PP * CC * 64;
  k_zf1<<<dim3((int)((nZ + 255) / 256)), dim3(256), 0, stream>>>(Z, W(25), W(26), Zc);
  launch_gemm(stream, (const fp16*)Zc, 64, 0LL, W(27), 64, 0LL, (fp16*)pool, 64, 0LL,
              (fp16*)nullptr, 0LL, W(28), BB * PP * CC, 64, 64, 1.f, 0.f, 0, 1);
  hipMemsetAsync(zpool, 0, (size_t)BB * PP * GP2 * 64 * 2, stream);  // zero Zf_pad (halo)
  k_add_stez<<<dim3((int)((nZ + 255) / 256)), dim3(256), 0, stream>>>(Zfp, (fp16*)pool,
                                                                      seZ, teZ);

  // ---- ConvLSTM (writes ZclT into Zc; h in padded chh) ----
  hipMemsetAsync(chh, 0, (size_t)BB * GP2 * 64 * 2, stream);
  hipMemsetAsync(ccc, 0, (size_t)BB * CC * 64 * 4, stream);
  for (int p = 0; p < PP; ++p) {
    k_conv4<<<dim3(BB * CC / 128, 4), dim3(256), 0, stream>>>(Zfp, chh, wcatT, gates, p);
    k_clstm_update<<<dim3((int)(((long long)BB * CC * 64 + 255) / 256)), dim3(256), 0,
                     stream>>>(gates, ccc, chh, Zc, p);
  }

  // ---- movement m1 (mfma4, z-batched) / m2 ----
  mfma4<128, 64><<<dim3(8, 1, 192), dim3(256), 0, stream>>>(
      mZh, mZh, 31, 31, 0LL, 0LL, CC, (const fp16*)Zc, CC, (long long)64 * CC, Zmix, 64,
      (long long)CC * 64, 31, 0LL, 31, 0LL, (const fp16*)nullptr, 1.f, 0.f, CC);
  mfma3<64, 128><<<dim3(1, 8, 192), dim3(256), 0, stream>>>(
      w2mT, 64, 0LL, 31, 0LL, Zmix, 64, (long long)CC * 64, ZmovT, CC, (long long)64 * CC,
      31, 0LL, 31, 0LL, (const fp16*)nullptr, 0LL, 0.f, W(34), 0LL, nullptr, 0, 64, CC, 64,
      1.f, 1);

  // ---- zxt term1: one big GEMM, M = 192*64 = 12288 rows of ZmovT ----
  mfma4<128, 128><<<dim3(96, 16, 1), dim3(256), 0, stream>>>(
      ZmovT, ZmovT, 31, 31, 0LL, 0LL, 1024, agh2, 1024, 0LL, ZXt, 2048, 0LL, 31, 0LL, 31,
      0LL, (const fp16*)nullptr, 1.f, 0.f, 1024);

  // ---- zxt term2 + biases (two halves; Tmat padded to 2048 rows/z in dead Zc) ----
  fp16* Tmat = Zc;
  for (int half = 0; half < 2; ++half) {
    long long z0 = 96LL * half;
    k_tmat<<<dim3((int)((96LL * NN * 64 + 255) / 256)), dim3(256), 0, stream>>>(
        X + z0 * NN, W(29), W(30), Tmat, 96LL * NN);
    k_zxtfin<<<dim3(1, 16, 96), dim3(256), 0, stream>>>(
        w2T, Tmat, ZXt + z0 * 64 * 2048, teXb + z0 * 64, seX);
  }

  // ---- DCGRU (combined xh chebs; h lives in U0 rows 64..127; x read from ZXt) ----
  fp16* U0 = Uall;
  fp16* Tn = Uall + USL;        // 3 slabs [2048 n][16z*128]
  fp16* Tn2 = Uall + 3 * USL;   // 3 cand slabs [2048 n][16z*64]
  const long long TnSlab = 2048LL * 2048;
  const long long Tn2Slab = 2048LL * 1024;
  hipMemsetAsync(U0, 0, (size_t)USL * 2, stream);  // zero slab 0 (h/rh rows + pads)

  for (int p = 0; p < PP; ++p) {
    const fp16* xP = ZXt + (long long)p * 64 * 2048;
    // combined xh chebs: Tn[s][n][z*128+row]
    mfma6<128, 128><<<dim3(48, 16), dim3(256), 0, stream>>>(
        LMall, 2048, xP, U0 + 64 * 2048, 7, 6, ZXB, uB, 2048, Tn, 2048, 11, TnSlab, KCH);
    // ruT = sigmoid(gwT @ chebs); epilogue writes rh = r*h into U0 rows 128..191
    mfma7<128, 1><<<dim3(1, 32, BB), dim3(256), 0, stream>>>(
        gwT, U0, uB, 0, xP, ZXB,
        Tn, TnSlab, 2048, 128,
        Tn + 64, TnSlab, 2048, 128,
        ruT, NN, (long long)128 * NN, W(42), U0 + 128 * 2048, U0 + 64 * 2048,
        (const fp16*)nullptr, 0LL, 128, NN);
    // cand chebs: Tn2[s][n][z*64+row] = LM_s @ rh^T
    mfma6<128, 128><<<dim3(48, 8), dim3(256), 0, stream>>>(
        LMall, 2048, U0 + 128 * 2048, U0 + 128 * 2048, 6, 6, uB, uB, 2048, Tn2, 1024, 11,
        Tn2Slab, KCH);
    // cnd GEMM; epilogue does h' = u*h + (1-u)*tanh(v) in place in U0 rows 64..127
    mfma7<64, 2><<<dim3(1, 32, BB), dim3(256), 0, stream>>>(
        cwT, U0, uB, 64, xP, ZXB,
        Tn, TnSlab, 2048, 128,
        Tn2, Tn2Slab, 1024, 64,
        U0 + 64 * 2048, 2048, uB, W(44), (fp16*)nullptr, (const fp16*)nullptr,
        (const fp16*)ruT, (long long)128 * NN, 64, NN);
  }

  // ---- output head (all scratch in dead Zc; U0 untouched until read) ----
  float* htmp = (float*)Zc;                       // 8.19 MB
  float* out1 = (float*)(Zc + 5120000);           // byte 10.24 MB, 8.19 MB
  float* out2 = (float*)(Zc + 10240000);          // byte 20.48 MB, 1.54 MB
  k_trT<<<dim3((int)(((long long)BB * NN * 64 + 255) / 256)), dim3(256), 0, stream>>>(U0,
                                                                                      htmp);
  launch_gemm(stream, (const float*)htmp, 64, 0LL, W(35), 64, 0LL, out1, 64, 0LL,
              (float*)nullptr, 0LL, W(36), BB * NN, 64, 64, 1.f, 0.f, 1, 1);
  launch_gemm(stream, (const float*)out1, 64, 0LL, W(37), 12, 0LL, out2, 12, 0LL,
              (float*)nullptr, 0LL, W(38), BB * NN, 12, 64, 1.f, 0.f, 0, 1);
  k_out<<<dim3((BB * QQ * NN + 255) / 256), dim3(256), 0, stream>>>(out2, (float*)d_out);
}

// Round 7
// 2908.093 us; speedup vs baseline: 1.8332x; 1.0101x over previous
//
#include <hip/hip_runtime.h>
#include <hip/hip_bf16.h>
#include <math.h>

typedef _Float16 fp16;
typedef _Float16 f16x8 __attribute__((ext_vector_type(8)));
typedef float f32x4 __attribute__((ext_vector_type(4)));

#define BB 16
#define PP 12
#define QQ 12
#define NN 2000
#define CC 1024
#define GP 34   // padded grid side (32 + halo)
#define GP2 1156

static __device__ __forceinline__ float ldf(float v) { return v; }
static __device__ __forceinline__ float ldf(fp16 v) { return (float)v; }
static __device__ __forceinline__ void stf(float* p, float v) { *p = v; }
static __device__ __forceinline__ void stf(fp16* p, float v) { *p = (fp16)v; }

// async global->LDS, 16B per lane (wave-uniform LDS base + lane*16)
static __device__ __forceinline__ void gload_lds16(const fp16* g, fp16* l) {
  __builtin_amdgcn_global_load_lds(
      (const __attribute__((address_space(1))) void*)g,
      (__attribute__((address_space(3))) void*)l, 16, 0, 0);
}

// Swizzle note (32-wide rows, 4 segs): logical seg q of row r stored at slot
// q ^ ((r>>1)&3) -> 16 lanes of a quad tile all 8 bank-groups twice (free).
// For 64-wide rows (8 segs): slot = q ^ (r&7), same property.

// ---------- conversions / repacks ----------
__global__ void k_f2h(fp16* __restrict__ dst, const float* __restrict__ src, long long n) {
  long long i = (long long)blockIdx.x * 256 + threadIdx.x;
  if (i < n) dst[i] = (fp16)src[i];
}

// wcatT[n][kk] = wcat[kk][n], kk<576 from W39, else W40 (each [576][256])
__global__ void k_wcatT(fp16* __restrict__ dst, const float* __restrict__ w39,
                        const float* __restrict__ w40) {
  int i = blockIdx.x * 256 + threadIdx.x;
  if (i >= 1152 * 256) return;
  int n = i & 255, kk = i >> 8;
  float v = (kk < 576) ? w39[kk * 256 + n] : w40[(kk - 576) * 256 + n];
  dst[(long long)n * 1152 + kk] = (fp16)v;
}

// dcgru weights (512,O): row=f*4+t -> Wt[d][t*128+c] = src[(c*4+t)*O+d]
__global__ void k_gru_repackT(fp16* __restrict__ dst, const float* __restrict__ src, int O) {
  int i = blockIdx.x * 256 + threadIdx.x;
  if (i >= O * 512) return;
  int d = i >> 9;
  int kc = i & 511;
  int t = kc >> 7;
  int c = kc & 127;
  dst[i] = (fp16)src[(c * 4 + t) * O + d];
}

// (64,64) -> T[d][k] fp16
__global__ void k_w2T(fp16* __restrict__ dst, const float* __restrict__ src) {
  int i = blockIdx.x * 256 + threadIdx.x;
  if (i >= 4096) return;
  int d = i >> 6, k = i & 63;
  dst[i] = (fp16)src[k * 64 + d];
}

// generic transpose repack: dst[j][k] (JP x 64 fp16) = src[k*J+j] for j<J else 0
__global__ void k_wT(fp16* __restrict__ dst, const float* __restrict__ src, int J, int JP) {
  int i = blockIdx.x * 256 + threadIdx.x;
  if (i >= JP * 64) return;
  int j = i >> 6, k = i & 63;
  dst[i] = (fp16)((j < J) ? src[k * J + j] : 0.f);
}

// ---------- laplacian ----------
__global__ void k_dinv(const float* __restrict__ adj, float* __restrict__ dinv) {
  int row = blockIdx.x;
  float s = 0.f;
  for (int j = threadIdx.x; j < NN; j += 256)
    s += fmaxf(adj[(long long)row * NN + j], adj[(long long)j * NN + row]);
  __shared__ float red[256];
  red[threadIdx.x] = s;
  __syncthreads();
  for (int st = 128; st > 0; st >>= 1) {
    if (threadIdx.x < st) red[threadIdx.x] += red[threadIdx.x + st];
    __syncthreads();
  }
  if (threadIdx.x == 0) {
    float d = red[0];
    dinv[row] = d > 0.f ? 1.0f / sqrtf(d) : 0.f;
  }
}

// writes L with row stride 2048 (zero-padded for maskless mfma4)
__global__ void k_L(const float* __restrict__ adj, const float* __restrict__ dinv,
                    fp16* __restrict__ Lh) {
  long long i = (long long)blockIdx.x * 256 + threadIdx.x;
  if (i >= (long long)NN * NN) return;
  int r = (int)(i / NN), c = (int)(i % NN);
  float a = fmaxf(adj[(long long)r * NN + c], adj[(long long)c * NN + r]);
  Lh[(long long)r * 2048 + c] = (fp16)(-dinv[r] * a * dinv[c]);
}

__global__ void k_subdiag(fp16* __restrict__ M2) {
  int i = blockIdx.x * 256 + threadIdx.x;
  if (i >= NN) return;
  M2[(long long)i * 2048 + i] = (fp16)((float)M2[(long long)i * 2048 + i] - 1.0f);
}

// ---------- gumbel softmax -> fp16 ----------
__global__ void k_gumbel_softmax(const float* __restrict__ ml, const float* __restrict__ gn,
                                 fp16* __restrict__ mZ) {
  int row = blockIdx.x;
  __shared__ float buf[CC];
  __shared__ float red[256];
  int t = threadIdx.x;
  float mx = -1e30f;
  for (int j = t; j < CC; j += 256) {
    float u = gn[(long long)row * CC + j];
    float g = -logf(-logf(u + 1e-20f) + 1e-20f);
    float v = ml[(long long)row * CC + j] + g;
    buf[j] = v;
    mx = fmaxf(mx, v);
  }
  red[t] = mx;
  __syncthreads();
  for (int st = 128; st > 0; st >>= 1) {
    if (t < st) red[t] = fmaxf(red[t], red[t + st]);
    __syncthreads();
  }
  mx = red[0];
  __syncthreads();
  float s = 0.f;
  for (int j = t; j < CC; j += 256) {
    float e = expf(buf[j] - mx);
    buf[j] = e;
    s += e;
  }
  red[t] = s;
  __syncthreads();
  for (int st = 128; st > 0; st >>= 1) {
    if (t < st) red[t] += red[t + st];
    __syncthreads();
  }
  float inv = 1.0f / red[0];
  for (int j = t; j < CC; j += 256) mZ[(long long)row * CC + j] = (fp16)(buf[j] * inv);
}

__global__ void k_te(const int* __restrict__ TE, const float* __restrict__ w1,
                     const float* __restrict__ b1, float* __restrict__ tmp) {
  int i = blockIdx.x * 256 + threadIdx.x;
  if (i >= BB * PP * 64) return;
  int j = i & 63;
  int bp = i >> 6;
  int b = bp / PP, p = bp % PP;
  int te0 = TE[(b * (PP + QQ) + p) * 2 + 0];
  int te1 = TE[(b * (PP + QQ) + p) * 2 + 1];
  float v = w1[te0 * 64 + j] + w1[(7 + te1) * 64 + j] + b1[j];
  tmp[i] = fmaxf(v, 0.f);
}

__global__ void k_addb(float* __restrict__ dst, const float* __restrict__ b, int n) {
  int i = blockIdx.x * 256 + threadIdx.x;
  if (i < n) dst[i] += b[i & 63];
}

__global__ void k_zf1(const float* __restrict__ Z, const float* __restrict__ w1,
                      const float* __restrict__ b1, fp16* __restrict__ tmp) {
  long long i = (long long)blockIdx.x * 256 + threadIdx.x;
  if (i >= (long long)BB * PP * CC * 64) return;
  int j = (int)(i & 63);
  long long row = i >> 6;
  float v = Z[row * 2 + 0] * w1[j] + Z[row * 2 + 1] * w1[64 + j] + b1[j];
  tmp[i] = (fp16)fmaxf(v, 0.f);
}

// ---------- k_zf2: Zf = (zf1 @ W27) + b28 + seZ + teZ, scattered into padded grid ----------
// M = BB*PP*CC = 196608 rows (grid.x*128), K=64, N=64. Single-shot LDS, swizzled.
__global__ __launch_bounds__(256) void k_zf2(
    const fp16* __restrict__ A, const fp16* __restrict__ w27T,
    const float* __restrict__ b28, const float* __restrict__ seZ,
    const float* __restrict__ teZ, fp16* __restrict__ Zfp) {
  __shared__ fp16 As[128 * 64];
  __shared__ fp16 Bs[64 * 64];
  const int tid = threadIdx.x;
  const int gm0 = blockIdx.x * 128;
  const int lane = tid & 63, wv = tid >> 6;
  const int wr = wv >> 1, wc = wv & 1;
  const int quad = lane >> 4, ln = lane & 15;
#pragma unroll
  for (int i = 0; i < 4; ++i) {
    int c = i * 256 + tid;
    int row = c >> 3;
    int lseg = (c & 7) ^ (row & 7);
    gload_lds16(A + (long long)(gm0 + row) * 64 + lseg * 8, &As[c * 8]);
  }
#pragma unroll
  for (int i = 0; i < 2; ++i) {
    int c = i * 256 + tid;
    int row = c >> 3;
    int lseg = (c & 7) ^ (row & 7);
    gload_lds16(w27T + (long long)row * 64 + lseg * 8, &Bs[c * 8]);
  }
  f32x4 acc[4][2];
#pragma unroll
  for (int i = 0; i < 4; ++i)
#pragma unroll
    for (int j = 0; j < 2; ++j) acc[i][j] = (f32x4){0.f, 0.f, 0.f, 0.f};
  __syncthreads();
#pragma unroll
  for (int kt = 0; kt < 2; ++kt) {
    f16x8 af[4], bf[2];
#pragma unroll
    for (int wm = 0; wm < 4; ++wm) {
      int row = wr * 64 + wm * 16 + ln;
      int slot = (kt * 4 + quad) ^ (row & 7);
      af[wm] = *(const f16x8*)&As[row * 64 + slot * 8];
    }
#pragma unroll
    for (int wn = 0; wn < 2; ++wn) {
      int row = wc * 32 + wn * 16 + ln;
      int slot = (kt * 4 + quad) ^ (row & 7);
      bf[wn] = *(const f16x8*)&Bs[row * 64 + slot * 8];
    }
#pragma unroll
    for (int wm = 0; wm < 4; ++wm)
#pragma unroll
      for (int wn = 0; wn < 2; ++wn)
        acc[wm][wn] =
            __builtin_amdgcn_mfma_f32_16x16x32_f16(af[wm], bf[wn], acc[wm][wn], 0, 0, 0);
  }
#pragma unroll
  for (int wm = 0; wm < 4; ++wm)
#pragma unroll
    for (int wn = 0; wn < 2; ++wn)
#pragma unroll
      for (int r = 0; r < 4; ++r) {
        int gm = gm0 + wr * 64 + wm * 16 + quad * 4 + r;
        int j = wc * 32 + wn * 16 + ln;
        int c = gm & 1023;
        int bp = gm >> 10;
        int pc = ((c >> 5) + 1) * GP + (c & 31) + 1;
        Zfp[((long long)bp * GP2 + pc) * 64 + j] =
            (fp16)(acc[wm][wn][r] + b28[j] + seZ[c * 64 + j] + teZ[bp * 64 + j]);
      }
}

// ---------- k_head: out[b][q][n] = (relu(h@W35+b36)@W37+b38), h from U0 h-rows ----------
// grid (16 n-tiles, 16 b); per block 128 n rows.
__global__ __launch_bounds__(256) void k_head(
    const fp16* __restrict__ U0, const fp16* __restrict__ w35T,
    const float* __restrict__ b36, const fp16* __restrict__ w37T,
    const float* __restrict__ b38, float* __restrict__ out) {
  __shared__ fp16 hT[128 * 72];
  __shared__ fp16 Bs[64 * 64];
  __shared__ fp16 h2[128 * 72];
  const int b = blockIdx.y;
  const int n0 = blockIdx.x * 128;
  const int tid = threadIdx.x;
  const int lane = tid & 63, wv = tid >> 6;
  const int wr = wv >> 1, wc = wv & 1;
  const int quad = lane >> 4, ln = lane & 15;
  const fp16* hbase = U0 + ((long long)b * 192 + 64) * 2048;
  // transpose-load h: task = (d, 8-group of n)
#pragma unroll
  for (int i = 0; i < 4; ++i) {
    int task = i * 256 + tid;
    int d = task >> 4, ng = task & 15;
    f16x8 v = *(const f16x8*)(hbase + (long long)d * 2048 + n0 + ng * 8);
#pragma unroll
    for (int k = 0; k < 8; ++k) hT[(ng * 8 + k) * 72 + d] = v[k];
  }
  // W35T 64x64 -> swizzled slots
#pragma unroll
  for (int i = 0; i < 2; ++i) {
    int c = i * 256 + tid;
    int row = c >> 3, s = c & 7;
    *(f16x8*)&Bs[row * 64 + (s ^ (row & 7)) * 8] =
        *(const f16x8*)(w35T + row * 64 + s * 8);
  }
  __syncthreads();
  f32x4 a1[4][2];
#pragma unroll
  for (int i = 0; i < 4; ++i)
#pragma unroll
    for (int j = 0; j < 2; ++j) a1[i][j] = (f32x4){0.f, 0.f, 0.f, 0.f};
#pragma unroll
  for (int kt = 0; kt < 2; ++kt) {
    f16x8 af[4], bf[2];
#pragma unroll
    for (int wm = 0; wm < 4; ++wm) {
      int row = wr * 64 + wm * 16 + ln;
      af[wm] = *(const f16x8*)&hT[row * 72 + kt * 32 + quad * 8];
    }
#pragma unroll
    for (int wn = 0; wn < 2; ++wn) {
      int row = wc * 32 + wn * 16 + ln;
      int slot = (kt * 4 + quad) ^ (row & 7);
      bf[wn] = *(const f16x8*)&Bs[row * 64 + slot * 8];
    }
#pragma unroll
    for (int wm = 0; wm < 4; ++wm)
#pragma unroll
      for (int wn = 0; wn < 2; ++wn)
        a1[wm][wn] =
            __builtin_amdgcn_mfma_f32_16x16x32_f16(af[wm], bf[wn], a1[wm][wn], 0, 0, 0);
  }
#pragma unroll
  for (int wm = 0; wm < 4; ++wm)
#pragma unroll
    for (int wn = 0; wn < 2; ++wn)
#pragma unroll
      for (int r = 0; r < 4; ++r) {
        int rl = wr * 64 + wm * 16 + quad * 4 + r;
        int j = wc * 32 + wn * 16 + ln;
        h2[rl * 72 + j] = (fp16)fmaxf(a1[wm][wn][r] + b36[j], 0.f);
      }
  __syncthreads();
  // stage2: rows wv*32 + wm*16, cols q = ln (16, write 12)
  f32x4 a2[2];
#pragma unroll
  for (int i = 0; i < 2; ++i) a2[i] = (f32x4){0.f, 0.f, 0.f, 0.f};
#pragma unroll
  for (int kt = 0; kt < 2; ++kt) {
    f16x8 bf = *(const f16x8*)(w37T + ln * 64 + kt * 32 + quad * 8);
#pragma unroll
    for (int wm = 0; wm < 2; ++wm) {
      int row = wv * 32 + wm * 16 + ln;
      f16x8 af = *(const f16x8*)&h2[row * 72 + kt * 32 + quad * 8];
      a2[wm] = __builtin_amdgcn_mfma_f32_16x16x32_f16(af, bf, a2[wm], 0, 0, 0);
    }
  }
#pragma unroll
  for (int wm = 0; wm < 2; ++wm)
#pragma unroll
    for (int r = 0; r < 4; ++r) {
      int nl = wv * 32 + wm * 16 + quad * 4 + r;
      int n = n0 + nl;
      int q = ln;
      if (n < NN && q < 12)
        out[((long long)b * 12 + q) * NN + n] = a2[wm][r] + b38[q];
    }
}

// ---------- generic fp32-path GEMM (small ops) ----------
template <typename TA, typename TB, typename TC>
__global__ __launch_bounds__(256) void gemm_t(
    const TA* __restrict__ A, int lda, long long sA,
    const TB* __restrict__ Bm, int ldb, long long sB,
    TC* Cm, int ldc, long long sC,
    const TC* S, long long sS,
    const float* __restrict__ bias,
    int M, int Ncols, int K, float alpha, float beta, int act) {
  int bz = blockIdx.z;
  A += (long long)bz * sA;
  Bm += (long long)bz * sB;
  Cm += (long long)bz * sC;
  if (S) S += (long long)bz * sS;
  const int row0 = blockIdx.x * 64, col0 = blockIdx.y * 64;
  __shared__ float As[16][68];
  __shared__ float Bs[16][68];
  int tid = threadIdx.x, tx = tid & 15, ty = tid >> 4;
  float acc[4][4] = {};
  for (int k0 = 0; k0 < K; k0 += 16) {
#pragma unroll
    for (int j = 0; j < 4; ++j) {
      int e = tid + 256 * j;
      int m = e >> 4, kk = e & 15;
      int gm = row0 + m;
      As[kk][m] = (gm < M) ? ldf(A[(long long)gm * lda + k0 + kk]) : 0.f;
    }
#pragma unroll
    for (int j = 0; j < 4; ++j) {
      int e = tid + 256 * j;
      int kk = e >> 6, n = e & 63;
      int gn = col0 + n;
      Bs[kk][n] = (gn < Ncols) ? ldf(Bm[(long long)(k0 + kk) * ldb + gn]) : 0.f;
    }
    __syncthreads();
#pragma unroll
    for (int kk = 0; kk < 16; ++kk) {
      float a[4], bb[4];
#pragma unroll
      for (int i = 0; i < 4; ++i) a[i] = As[kk][ty * 4 + i];
#pragma unroll
      for (int j = 0; j < 4; ++j) bb[j] = Bs[kk][tx * 4 + j];
#pragma unroll
      for (int i = 0; i < 4; ++i)
#pragma unroll
        for (int j = 0; j < 4; ++j) acc[i][j] = fmaf(a[i], bb[j], acc[i][j]);
    }
    __syncthreads();
  }
#pragma unroll
  for (int i = 0; i < 4; ++i) {
    int r = row0 + ty * 4 + i;
    if (r >= M) continue;
#pragma unroll
    for (int j = 0; j < 4; ++j) {
      int cn = col0 + tx * 4 + j;
      if (cn >= Ncols) continue;
      float v = alpha * acc[i][j];
      if (bias) v += bias[cn];
      if (S) v += beta * ldf(S[(long long)r * ldc + cn]);
      if (act == 1) v = fmaxf(v, 0.f);
      else if (act == 2) v = 1.f / (1.f + expf(-v));
      else if (act == 3) v = tanhf(v);
      stf(&Cm[(long long)r * ldc + cn], v);
    }
  }
}

// ---------- mfma7: DCGRU weight GEMMs, mfma4-structure, fused GRU epilogues ----------
template <int MT, int MODE>
__global__ __launch_bounds__(256) void mfma7(
    const fp16* __restrict__ A,                       // weights MT x 512
    const fp16* __restrict__ U0base, long long uZ, int bHi,
    const fp16* __restrict__ xB, long long xZ,        // ZXt slab0 x rows (ld 2048)
    const fp16* __restrict__ Xc, long long XcSlab, int Xcld, int Xczmul,
    const fp16* __restrict__ Hc, long long HcSlab, int Hcld, int Hczmul,
    fp16* __restrict__ C, int ldc, long long cBatch,
    const float* __restrict__ bias,
    fp16* __restrict__ rhOut, const fp16* __restrict__ hIn,
    const fp16* __restrict__ uIn, long long uStride,
    int M, int Ncols) {
  __shared__ fp16 As[2][MT * 32];
  __shared__ fp16 Bs[2][64 * 32];
  const int z = blockIdx.z;
  const int n0 = blockIdx.y * 64;
  const fp16* U0z = U0base + (long long)z * uZ;
  const fp16* xBz = xB + (long long)z * xZ;
  C += (long long)z * cBatch;
  if (rhOut) rhOut += (long long)z * uZ;
  if (hIn) hIn += (long long)z * uZ;
  if (uIn) uIn += (long long)z * uStride;
  const int tid = threadIdx.x;
  const int lane = tid & 63, wv = tid >> 6;
  const int wr = wv >> 1, wc = wv & 1;
  const int quad = lane >> 4, ln = lane & 15;
  constexpr int WM = MT / 32;

  const fp16* aSrc[MT / 64];
#pragma unroll
  for (int i = 0; i < MT / 64; ++i) {
    int c = i * 256 + tid;
    int row = c >> 2;
    int lseg = (c & 3) ^ ((c >> 3) & 3);
    aSrc[i] = A + (long long)row * 512 + lseg * 8;
  }
  const int brow = tid >> 2;
  const int blseg = (tid & 3) ^ ((tid >> 3) & 3);
  const long long bnode = n0 + brow;

  f32x4 acc[WM][2];
#pragma unroll
  for (int i = 0; i < WM; ++i)
#pragma unroll
    for (int j = 0; j < 2; ++j) acc[i][j] = (f32x4){0.f, 0.f, 0.f, 0.f};

  auto stage = [&](int t, int buf) {
    const int k0 = t * 32;
#pragma unroll
    for (int i = 0; i < MT / 64; ++i)
      gload_lds16(aSrc[i] + k0, &As[buf][(i * 256 + tid) * 8]);
    if (k0 < 128) {
      int kin = k0 + (tid & 31);
      int ngrp = tid >> 5;
      int n = n0 + ngrp * 8;
      const fp16* src = (kin < 64) ? (xBz + (long long)kin * 2048 + n)
                                   : (U0z + (long long)(kin + bHi) * 2048 + n);
      f16x8 v = *(const f16x8*)src;
      int kk = tid & 31;
#pragma unroll
      for (int j = 0; j < 8; ++j) {
        int rn = ngrp * 8 + j;
        Bs[buf][rn * 32 + ((((kk >> 3) ^ ((rn >> 1) & 3)) << 3) | (kk & 7))] = v[j];
      }
    } else {
      int slab = k0 >> 7;
      int kin = (k0 & 127) + blseg * 8;
      const fp16* src;
      if (kin < 64)
        src = Xc + (long long)(slab - 1) * XcSlab + bnode * Xcld +
              (long long)z * Xczmul + kin;
      else
        src = Hc + (long long)(slab - 1) * HcSlab + bnode * Hcld +
              (long long)z * Hczmul + (kin - 64);
      gload_lds16(src, &Bs[buf][tid * 8]);
    }
  };

  const int sw = (quad ^ ((ln >> 1) & 3)) << 3;
  stage(0, 0);
  for (int t = 0; t < 16; ++t) {
    const int buf = t & 1;
    __syncthreads();
    if (t + 1 < 16) stage(t + 1, buf ^ 1);
    f16x8 af[WM], bf[2];
#pragma unroll
    for (int wm = 0; wm < WM; ++wm) {
      int row = wr * (MT / 2) + wm * 16 + ln;
      af[wm] = *(const f16x8*)&As[buf][row * 32 + sw];
    }
#pragma unroll
    for (int wn = 0; wn < 2; ++wn) {
      int row = wc * 32 + wn * 16 + ln;
      bf[wn] = *(const f16x8*)&Bs[buf][row * 32 + sw];
    }
#pragma unroll
    for (int wm = 0; wm < WM; ++wm)
#pragma unroll
      for (int wn = 0; wn < 2; ++wn)
        acc[wm][wn] =
            __builtin_amdgcn_mfma_f32_16x16x32_f16(af[wm], bf[wn], acc[wm][wn], 0, 0, 0);
  }
#pragma unroll
  for (int wm = 0; wm < WM; ++wm) {
#pragma unroll
    for (int wn = 0; wn < 2; ++wn) {
#pragma unroll
      for (int r = 0; r < 4; ++r) {
        int gm = wr * (MT / 2) + wm * 16 + quad * 4 + r;
        int gn = n0 + wc * 32 + wn * 16 + ln;
        if (gm < M && gn < Ncols) {
          float v = acc[wm][wn][r];
          v += bias[gm];
          if (MODE == 1) {
            v = 1.f / (1.f + expf(-v));  // sigmoid
            C[(long long)gm * ldc + gn] = (fp16)v;
            if (gm < 64) {
              float h = (float)hIn[(long long)gm * 2048 + gn];
              rhOut[(long long)gm * 2048 + gn] = (fp16)(v * h);
            }
          } else {
            v = tanhf(v);
            float u = (float)uIn[(long long)(64 + gm) * NN + gn];
            long long ci = (long long)gm * ldc + gn;
            float h = (float)C[ci];
            C[ci] = (fp16)(u * h + (1.f - u) * v);
          }
        }
      }
    }
  }
}

// ---------- mfma3: all-b128 GEMM (kept for movement m2) ----------
template <int MT, int NT>
__global__ __launch_bounds__(256) void mfma3(
    const fp16* __restrict__ A, int lda, long long zA, int aMsh, long long aMslab,
    const fp16* __restrict__ B, int ldb, long long zB,
    fp16* __restrict__ C, int ldc, long long zC, int cMsh, long long cMslab, int cNsh,
    long long cNslab,
    const fp16* __restrict__ S, long long zS, float beta,
    const float* __restrict__ rowBias, long long zRB,
    const float* __restrict__ s2T, int s2ld,
    int M, int Ncols, int K, float alpha, int act) {
  __shared__ fp16 As[MT][40];
  __shared__ fp16 Bs[NT][40];
  const int z = blockIdx.z;
  const int gm0 = blockIdx.x * MT, n0 = blockIdx.y * NT;
  A += (long long)z * zA;
  B += (long long)z * zB;
  C += (long long)z * zC;
  if (S) S += (long long)z * zS;
  const int tid = threadIdx.x;
  const int lane = tid & 63, wv = tid >> 6;
  const int wr = wv >> 1, wc = wv & 1;
  const int quad = lane >> 4, ln = lane & 15;
  const unsigned aMmask = (1u << aMsh) - 1u;
  const unsigned cMmask = (1u << cMsh) - 1u;
  const unsigned cNmask = (1u << cNsh) - 1u;
  constexpr int WM = MT / 32, WN = NT / 32;
  f32x4 acc[WM][WN];
#pragma unroll
  for (int i = 0; i < WM; ++i)
#pragma unroll
    for (int j = 0; j < WN; ++j) acc[i][j] = (f32x4){0.f, 0.f, 0.f, 0.f};

  for (int k0 = 0; k0 < K; k0 += 32) {
#pragma unroll
    for (int i = 0; i < MT / 64; ++i) {
      int c = tid + 256 * i;
      int row = c >> 2, seg = c & 3;
      int gm = gm0 + row;
      int kk0 = k0 + seg * 8;
      const fp16* src = A + ((long long)((unsigned)gm >> aMsh)) * aMslab +
                        (long long)(gm & aMmask) * lda + kk0;
      if (gm < M && kk0 + 8 <= K) {
        *(f16x8*)&As[row][seg * 8] = *(const f16x8*)src;
      } else {
#pragma unroll
        for (int j = 0; j < 8; ++j)
          As[row][seg * 8 + j] = (gm < M && kk0 + j < K) ? src[j] : (fp16)0.f;
      }
    }
#pragma unroll
    for (int i = 0; i < NT / 64; ++i) {
      int c = tid + 256 * i;
      int n = c >> 2, seg = c & 3;
      int gn = n0 + n;
      int kk0 = k0 + seg * 8;
      const fp16* src = B + (long long)gn * ldb + kk0;
      if (gn < Ncols && kk0 + 8 <= K) {
        *(f16x8*)&Bs[n][seg * 8] = *(const f16x8*)src;
      } else {
#pragma unroll
        for (int j = 0; j < 8; ++j)
          Bs[n][seg * 8 + j] = (gn < Ncols && kk0 + j < K) ? src[j] : (fp16)0.f;
      }
    }
    __syncthreads();
    f16x8 af[WM], bf[WN];
#pragma unroll
    for (int wm = 0; wm < WM; ++wm)
      af[wm] = *(const f16x8*)&As[wr * (MT / 2) + wm * 16 + ln][quad * 8];
#pragma unroll
    for (int wn = 0; wn < WN; ++wn)
      bf[wn] = *(const f16x8*)&Bs[wc * (NT / 2) + wn * 16 + ln][quad * 8];
#pragma unroll
    for (int wm = 0; wm < WM; ++wm)
#pragma unroll
      for (int wn = 0; wn < WN; ++wn)
        acc[wm][wn] =
            __builtin_amdgcn_mfma_f32_16x16x32_f16(af[wm], bf[wn], acc[wm][wn], 0, 0, 0);
    __syncthreads();
  }
#pragma unroll
  for (int wm = 0; wm < WM; ++wm) {
#pragma unroll
    for (int wn = 0; wn < WN; ++wn) {
#pragma unroll
      for (int r = 0; r < 4; ++r) {
        int gm = gm0 + wr * (MT / 2) + wm * 16 + quad * 4 + r;
        int gn = n0 + wc * (NT / 2) + wn * 16 + ln;
        if (gm < M && gn < Ncols) {
          float v = alpha * acc[wm][wn][r];
          if (rowBias) v += rowBias[(long long)z * zRB + gm];
          if (s2T) v += s2T[(long long)gn * s2ld + gm];
          long long ci = ((long long)((unsigned)gm >> cMsh)) * cMslab +
                         (long long)(gm & cMmask) * ldc +
                         ((long long)((unsigned)gn >> cNsh)) * cNslab + (gn & cNmask);
          if (S) v += beta * (float)S[ci];
          if (act == 1) v = fmaxf(v, 0.f);
          else if (act == 2) v = 1.f / (1.f + expf(-v));
          else if (act == 3) v = tanhf(v);
          C[ci] = (fp16)v;
        }
      }
    }
  }
}

// ---------- mfma4: maskless gload_lds GEMM, dual-base A descriptor ----------
template <int MT, int NT>
__global__ __launch_bounds__(256) void mfma4(
    const fp16* __restrict__ base0, const fp16* __restrict__ base1, int rsh, int ssh,
    long long z0, long long z1, int lda,
    const fp16* __restrict__ B, int ldb, long long zB,
    fp16* __restrict__ C, int ldc, long long zC, int cMsh, long long cMslab, int cNsh,
    long long cNslab,
    const fp16* __restrict__ S, float alpha, float beta, int K) {
  __shared__ fp16 As[2][MT * 32];
  __shared__ fp16 Bs[2][NT * 32];
  const int tid = threadIdx.x;
  const int z = blockIdx.z;
  const int gm0 = blockIdx.x * MT, n0 = blockIdx.y * NT;
  B += (long long)z * zB;
  C += (long long)z * zC;
  if (S) S += (long long)z * zC;
  const unsigned cMmask = (1u << cMsh) - 1u;
  const unsigned cNmask = (1u << cNsh) - 1u;
  const int lane = tid & 63, wv = tid >> 6;
  const int wr = wv >> 1, wc = wv & 1;
  const int quad = lane >> 4, ln = lane & 15;
  constexpr int WM = MT / 32, WN = NT / 32;

  const fp16* aSrc[MT / 64];
  const fp16* bSrc[NT / 64];
#pragma unroll
  for (int i = 0; i < MT / 64; ++i) {
    int c = i * 256 + tid;
    int row = c >> 2;
    int lseg = (c & 3) ^ ((c >> 3) & 3);
    int gm = gm0 + row;
    unsigned b = (unsigned)gm >> rsh;
    unsigned wi = (unsigned)gm & ((1u << rsh) - 1u);
    unsigned sel = wi >> ssh;
    unsigned r = wi & ((1u << ssh) - 1u);
    const fp16* ab = sel ? (base1 + (long long)b * z1) : (base0 + (long long)b * z0);
    aSrc[i] = ab + (long long)r * lda + lseg * 8;
  }
#pragma unroll
  for (int i = 0; i < NT / 64; ++i) {
    int c = i * 256 + tid;
    int lseg = (c & 3) ^ ((c >> 3) & 3);
    bSrc[i] = B + (long long)(n0 + (c >> 2)) * ldb + lseg * 8;
  }

  f32x4 acc[WM][WN];
#pragma unroll
  for (int i = 0; i < WM; ++i)
#pragma unroll
    for (int j = 0; j < WN; ++j) acc[i][j] = (f32x4){0.f, 0.f, 0.f, 0.f};

  const int sw = (quad ^ ((ln >> 1) & 3)) << 3;

#pragma unroll
  for (int i = 0; i < MT / 64; ++i) gload_lds16(aSrc[i], &As[0][(i * 256 + tid) * 8]);
#pragma unroll
  for (int i = 0; i < NT / 64; ++i) gload_lds16(bSrc[i], &Bs[0][(i * 256 + tid) * 8]);

  const int nk = K >> 5;
  for (int t = 0; t < nk; ++t) {
    const int buf = t & 1;
    __syncthreads();
    if (t + 1 < nk) {
      const int k1 = (t + 1) * 32;
#pragma unroll
      for (int i = 0; i < MT / 64; ++i)
        gload_lds16(aSrc[i] + k1, &As[buf ^ 1][(i * 256 + tid) * 8]);
#pragma unroll
      for (int i = 0; i < NT / 64; ++i)
        gload_lds16(bSrc[i] + k1, &Bs[buf ^ 1][(i * 256 + tid) * 8]);
    }
    f16x8 af[WM], bf[WN];
#pragma unroll
    for (int wm = 0; wm < WM; ++wm) {
      int row = wr * (MT / 2) + wm * 16 + ln;
      af[wm] = *(const f16x8*)&As[buf][row * 32 + sw];
    }
#pragma unroll
    for (int wn = 0; wn < WN; ++wn) {
      int row = wc * (NT / 2) + wn * 16 + ln;
      bf[wn] = *(const f16x8*)&Bs[buf][row * 32 + sw];
    }
#pragma unroll
    for (int wm = 0; wm < WM; ++wm)
#pragma unroll
      for (int wn = 0; wn < WN; ++wn)
        acc[wm][wn] =
            __builtin_amdgcn_mfma_f32_16x16x32_f16(af[wm], bf[wn], acc[wm][wn], 0, 0, 0);
  }
#pragma unroll
  for (int wm = 0; wm < WM; ++wm)
#pragma unroll
    for (int wn = 0; wn < WN; ++wn)
#pragma unroll
      for (int r = 0; r < 4; ++r) {
        int gm = gm0 + wr * (MT / 2) + wm * 16 + quad * 4 + r;
        int gn = n0 + wc * (NT / 2) + wn * 16 + ln;
        long long ci = ((long long)((unsigned)gm >> cMsh)) * cMslab +
                       (long long)(gm & cMmask) * ldc +
                       ((long long)((unsigned)gn >> cNsh)) * cNslab + (gn & cNmask);
        float v = alpha * acc[wm][wn][r];
        if (S) v += beta * (float)S[ci];
        C[ci] = (fp16)v;
      }
}

// ---------- mfma6: maskless gload_lds GEMM, dual-base B descriptor ----------
template <int MT, int NT>
__global__ __launch_bounds__(256) void mfma6(
    const fp16* __restrict__ A, int lda,
    const fp16* __restrict__ b0, const fp16* __restrict__ b1, int rsh, int ssh,
    long long z0, long long z1, int ldb,
    fp16* __restrict__ C, int ldc, int cMsh, long long cMslab,
    int K) {
  __shared__ fp16 As[2][MT * 32];
  __shared__ fp16 Bs[2][NT * 32];
  const int tid = threadIdx.x;
  const int gm0 = blockIdx.x * MT, n0 = blockIdx.y * NT;
  const unsigned cMmask = (1u << cMsh) - 1u;
  const int lane = tid & 63, wv = tid >> 6;
  const int wr = wv >> 1, wc = wv & 1;
  const int quad = lane >> 4, ln = lane & 15;
  constexpr int WM = MT / 32, WN = NT / 32;

  const fp16* aSrc[MT / 64];
  const fp16* bSrc[NT / 64];
#pragma unroll
  for (int i = 0; i < MT / 64; ++i) {
    int c = i * 256 + tid;
    int lseg = (c & 3) ^ ((c >> 3) & 3);
    aSrc[i] = A + (long long)(gm0 + (c >> 2)) * lda + lseg * 8;
  }
#pragma unroll
  for (int i = 0; i < NT / 64; ++i) {
    int c = i * 256 + tid;
    int lseg = (c & 3) ^ ((c >> 3) & 3);
    int gn = n0 + (c >> 2);
    unsigned b = (unsigned)gn >> rsh;
    unsigned wi = (unsigned)gn & ((1u << rsh) - 1u);
    unsigned sel = wi >> ssh;
    unsigned r = wi & ((1u << ssh) - 1u);
    const fp16* bb = sel ? (b1 + (long long)b * z1) : (b0 + (long long)b * z0);
    bSrc[i] = bb + (long long)r * ldb + lseg * 8;
  }

  f32x4 acc[WM][WN];
#pragma unroll
  for (int i = 0; i < WM; ++i)
#pragma unroll
    for (int j = 0; j < WN; ++j) acc[i][j] = (f32x4){0.f, 0.f, 0.f, 0.f};

  const int sw = (quad ^ ((ln >> 1) & 3)) << 3;

#pragma unroll
  for (int i = 0; i < MT / 64; ++i) gload_lds16(aSrc[i], &As[0][(i * 256 + tid) * 8]);
#pragma unroll
  for (int i = 0; i < NT / 64; ++i) gload_lds16(bSrc[i], &Bs[0][(i * 256 + tid) * 8]);

  const int nk = K >> 5;
  for (int t = 0; t < nk; ++t) {
    const int buf = t & 1;
    __syncthreads();
    if (t + 1 < nk) {
      const int k1 = (t + 1) * 32;
#pragma unroll
      for (int i = 0; i < MT / 64; ++i)
        gload_lds16(aSrc[i] + k1, &As[buf ^ 1][(i * 256 + tid) * 8]);
#pragma unroll
      for (int i = 0; i < NT / 64; ++i)
        gload_lds16(bSrc[i] + k1, &Bs[buf ^ 1][(i * 256 + tid) * 8]);
    }
    f16x8 af[WM], bf[WN];
#pragma unroll
    for (int wm = 0; wm < WM; ++wm) {
      int row = wr * (MT / 2) + wm * 16 + ln;
      af[wm] = *(const f16x8*)&As[buf][row * 32 + sw];
    }
#pragma unroll
    for (int wn = 0; wn < WN; ++wn) {
      int row = wc * (NT / 2) + wn * 16 + ln;
      bf[wn] = *(const f16x8*)&Bs[buf][row * 32 + sw];
    }
#pragma unroll
    for (int wm = 0; wm < WM; ++wm)
#pragma unroll
      for (int wn = 0; wn < WN; ++wn)
        acc[wm][wn] =
            __builtin_amdgcn_mfma_f32_16x16x32_f16(af[wm], bf[wn], acc[wm][wn], 0, 0, 0);
  }
#pragma unroll
  for (int wm = 0; wm < WM; ++wm)
#pragma unroll
    for (int wn = 0; wn < WN; ++wn)
#pragma unroll
      for (int r = 0; r < 4; ++r) {
        int gm = gm0 + wr * (MT / 2) + wm * 16 + quad * 4 + r;
        int gn = n0 + wc * (NT / 2) + wn * 16 + ln;
        long long ci = ((long long)((unsigned)gm >> cMsh)) * cMslab +
                       (long long)(gm & cMmask) * ldc + gn;
        C[ci] = (fp16)acc[wm][wn][r];
      }
}

// ---------- k_zxtfin: ZXt[z][d][n] += w2T@Tmat[z]^T + teXb + seX; zero pad cols ----------
__global__ __launch_bounds__(256) void k_zxtfin(
    const fp16* __restrict__ w2T, const fp16* __restrict__ Tmat,
    fp16* __restrict__ ZXt, const float* __restrict__ teXb, const float* __restrict__ seX) {
  __shared__ fp16 As[64][72];
  __shared__ fp16 Bs[128][72];
  const int z = blockIdx.z;
  const int n0 = blockIdx.y * 128;
  const fp16* Tz = Tmat + (long long)z * 2048 * 64;
  fp16* Cz = ZXt + (long long)z * 64 * 2048;
  const float* tb = teXb + z * 64;
  const int tid = threadIdx.x;
  const int lane = tid & 63, wv = tid >> 6;
  const int wr = wv >> 1, wc = wv & 1;
  const int quad = lane >> 4, ln = lane & 15;
#pragma unroll
  for (int i = 0; i < 2; ++i) {
    int c = tid + 256 * i;
    int row = c >> 3, seg = c & 7;
    *(f16x8*)&As[row][seg * 8] = *(const f16x8*)(w2T + row * 64 + seg * 8);
  }
#pragma unroll
  for (int i = 0; i < 4; ++i) {
    int c = tid + 256 * i;
    int row = c >> 3, seg = c & 7;
    *(f16x8*)&Bs[row][seg * 8] =
        *(const f16x8*)(Tz + (long long)(n0 + row) * 64 + seg * 8);
  }
  __syncthreads();
  f32x4 acc[2][4];
#pragma unroll
  for (int i = 0; i < 2; ++i)
#pragma unroll
    for (int j = 0; j < 4; ++j) acc[i][j] = (f32x4){0.f, 0.f, 0.f, 0.f};
#pragma unroll
  for (int kt = 0; kt < 2; ++kt) {
    f16x8 af[2], bf[4];
#pragma unroll
    for (int wm = 0; wm < 2; ++wm)
      af[wm] = *(const f16x8*)&As[wr * 32 + wm * 16 + ln][kt * 32 + quad * 8];
#pragma unroll
    for (int wn = 0; wn < 4; ++wn)
      bf[wn] = *(const f16x8*)&Bs[wc * 64 + wn * 16 + ln][kt * 32 + quad * 8];
#pragma unroll
    for (int wm = 0; wm < 2; ++wm)
#pragma unroll
      for (int wn = 0; wn < 4; ++wn)
        acc[wm][wn] =
            __builtin_amdgcn_mfma_f32_16x16x32_f16(af[wm], bf[wn], acc[wm][wn], 0, 0, 0);
  }
#pragma unroll
  for (int wm = 0; wm < 2; ++wm)
#pragma unroll
    for (int wn = 0; wn < 4; ++wn)
#pragma unroll
      for (int r = 0; r < 4; ++r) {
        int gm = wr * 32 + wm * 16 + quad * 4 + r;
        int gn = n0 + wc * 64 + wn * 16 + ln;
        long long ci = (long long)gm * 2048 + gn;
        float v = 0.f;
        if (gn < NN)
          v = acc[wm][wn][r] + (float)Cz[ci] + tb[gm] + seX[(long long)gn * 64 + gm];
        Cz[ci] = (fp16)v;
      }
}

// ---------- ConvLSTM conv, mfma4-style with zero-padded 34x34 halo ----------
__global__ __launch_bounds__(256) void k_conv4(
    const fp16* __restrict__ Zfp, const fp16* __restrict__ hp,
    const fp16* __restrict__ wcatT, fp16* __restrict__ gates, int p) {
  __shared__ fp16 As[2][128 * 32];
  __shared__ fp16 Bs[2][64 * 32];
  const int gm0 = blockIdx.x * 128, n0 = blockIdx.y * 64;
  const int tid = threadIdx.x;
  const int lane = tid & 63, wv = tid >> 6;
  const int wr = wv >> 1, wc = wv & 1;
  const int quad = lane >> 4, ln = lane & 15;

  long long aZ[2], aH[2];
#pragma unroll
  for (int i = 0; i < 2; ++i) {
    int c = tid + 256 * i;
    int row = c >> 2;
    int lseg = (c & 3) ^ ((c >> 3) & 3);
    int m = gm0 + row;
    int b = m >> 10, y = (m >> 5) & 31, x = m & 31;
    int pc = (y + 1) * GP + (x + 1);
    aZ[i] = ((long long)(b * PP + p) * GP2 + pc) * 64 + lseg * 8;
    aH[i] = ((long long)b * GP2 + pc) * 64 + lseg * 8;
  }
  const fp16* bBase;
  {
    int row = tid >> 2;
    int lseg = (tid & 3) ^ ((tid >> 3) & 3);
    bBase = wcatT + (long long)(n0 + row) * 1152 + lseg * 8;
  }
  f32x4 acc[4][2];
#pragma unroll
  for (int i = 0; i < 4; ++i)
#pragma unroll
    for (int j = 0; j < 2; ++j) acc[i][j] = (f32x4){0.f, 0.f, 0.f, 0.f};

  auto stage = [&](int t, int buf) {
    int tap = (t >> 1) % 9, half = t & 1;
    int srcsel = t >= 18;
    int off = ((tap / 3 - 1) * GP + (tap % 3 - 1)) * 64 + half * 32;
#pragma unroll
    for (int i = 0; i < 2; ++i) {
      const fp16* src = srcsel ? (hp + aH[i] + off) : (Zfp + aZ[i] + off);
      gload_lds16(src, &As[buf][(i * 256 + tid) * 8]);
    }
    gload_lds16(bBase + t * 32, &Bs[buf][tid * 8]);
  };
  stage(0, 0);
  const int sw = (quad ^ ((ln >> 1) & 3)) << 3;
  for (int t = 0; t < 36; ++t) {
    const int buf = t & 1;
    __syncthreads();
    if (t + 1 < 36) stage(t + 1, buf ^ 1);
    f16x8 af[4], bf[2];
#pragma unroll
    for (int wm = 0; wm < 4; ++wm) {
      int row = wr * 64 + wm * 16 + ln;
      af[wm] = *(const f16x8*)&As[buf][row * 32 + sw];
    }
#pragma unroll
    for (int wn = 0; wn < 2; ++wn) {
      int row = wc * 32 + wn * 16 + ln;
      bf[wn] = *(const f16x8*)&Bs[buf][row * 32 + sw];
    }
#pragma unroll
    for (int wm = 0; wm < 4; ++wm)
#pragma unroll
      for (int wn = 0; wn < 2; ++wn)
        acc[wm][wn] =
            __builtin_amdgcn_mfma_f32_16x16x32_f16(af[wm], bf[wn], acc[wm][wn], 0, 0, 0);
  }
#pragma unroll
  for (int wm = 0; wm < 4; ++wm)
#pragma unroll
    for (int wn = 0; wn < 2; ++wn)
#pragma unroll
      for (int r = 0; r < 4; ++r) {
        int gm = gm0 + wr * 64 + wm * 16 + quad * 4 + r;
        int gn = n0 + wc * 32 + wn * 16 + ln;
        gates[(long long)gm * 256 + gn] = (fp16)acc[wm][wn][r];
      }
}

__global__ void k_clstm_update(const fp16* __restrict__ gates, float* __restrict__ c,
                               fp16* __restrict__ h, fp16* __restrict__ ZclT, int p) {
  long long i = (long long)blockIdx.x * 256 + threadIdx.x;
  if (i >= (long long)BB * CC * 64) return;
  int d = (int)(i & 63);
  long long bc = i >> 6;
  int b = (int)(bc >> 10);
  int cell = (int)(bc & 1023);
  const fp16* g = gates + (((long long)b * CC) + cell) * 256;
  float gi = (float)g[d], gf = (float)g[64 + d], gg = (float)g[128 + d],
        go = (float)g[192 + d];
  float hs_f = fminf(fmaxf(0.2f * gf + 0.5f, 0.f), 1.f);
  float hs_i = fminf(fmaxf(0.2f * gi + 0.5f, 0.f), 1.f);
  float hs_o = fminf(fmaxf(0.2f * go + 0.5f, 0.f), 1.f);
  float cv = hs_f * c[i] + hs_i * tanhf(gg);
  c[i] = cv;
  float hv = hs_o * tanhf(cv);
  int pc = ((cell >> 5) + 1) * GP + (cell & 31) + 1;
  h[((long long)b * GP2 + pc) * 64 + d] = (fp16)hv;
  ZclT[(((long long)(b * PP + p)) * 64 + d) * CC + cell] = (fp16)hv;
}

// Tmat[z][n][64] with 2048-row stride per z (pad rows garbage; finisher ignores)
__global__ void k_tmat(const float* __restrict__ X, const float* __restrict__ w1,
                       const float* __restrict__ b1, fp16* __restrict__ T, long long nrows) {
  long long i = (long long)blockIdx.x * 256 + threadIdx.x;
  if (i >= nrows * 64) return;
  int j = (int)(i & 63);
  long long row = i >> 6;
  int z = (int)(row / NN);
  int n = (int)(row - (long long)z * NN);
  T[(((long long)z * 2048) + n) * 64 + j] = (fp16)fmaxf(X[row] * w1[j] + b1[j], 0.f);
}

// ---------- host helpers ----------
template <typename TA, typename TB, typename TC>
static void launch_gemm(hipStream_t stream, const TA* A, int lda, long long sA,
                        const TB* Bm, int ldb, long long sB, TC* Cm, int ldc, long long sC,
                        const TC* S, long long sS, const float* bias, int M, int Nc, int K,
                        float alpha, float beta, int act, int batch) {
  dim3 g((M + 63) / 64, (Nc + 63) / 64, batch);
  gemm_t<TA, TB, TC><<<g, dim3(256), 0, stream>>>(A, lda, sA, Bm, ldb, sB, Cm, ldc, sC, S,
                                                  sS, bias, M, Nc, K, alpha, beta, act);
}

extern "C" void kernel_launch(void* const* d_in, const int* in_sizes, int n_in,
                              void* d_out, int out_size, void* d_ws, size_t ws_size,
                              hipStream_t stream) {
  char* base = (char*)d_ws;
  size_t off = 0;
  auto alloc_bytes = [&](size_t nb) -> char* {
    char* p = base + off;
    off += (nb + 255) & ~(size_t)255;
    return p;
  };
  auto allocf = [&](size_t n) -> float* { return (float*)alloc_bytes(n * 4); };
  auto alloch = [&](size_t n) -> fp16* { return (fp16*)alloc_bytes(n * 2); };

  const float* X = (const float*)d_in[0];
  const float* Z = (const float*)d_in[1];
  const int* TE = (const int*)d_in[2];
  const float* adj_gg = (const float*)d_in[3];
  const float* adj_gr = (const float*)d_in[4];
  const float* gumbel = (const float*)d_in[5];
  const float* se_x = (const float*)d_in[6];
  const float* se_z = (const float*)d_in[7];
  const float* movement = (const float*)d_in[8];
  auto W = [&](int i) { return (const float*)d_in[i]; };

  // ---- allocations ----
  fp16* wcatT = alloch((size_t)256 * 1152);  // [n][k] pre-transposed conv weights
  fp16* gwT = alloch(128 * 512);
  fp16* cwT = alloch(64 * 512);
  fp16* w2T = alloch(64 * 64);
  fp16* w2mT = alloch(64 * 64);
  fp16* w27T = alloch(64 * 64);
  fp16* w35T = alloch(64 * 64);
  fp16* w37T = alloch(16 * 64);
  float* dinv = allocf(NN);
  fp16* LMall = alloch((size_t)6144 * 2048);  // rows padded to 2048 for maskless mfma4/6
  fp16* mZh = alloch((size_t)CC * CC);
  fp16* agh2 = alloch((size_t)2048 * CC);  // padded to 2048 rows (pad rows zero)
  float* seZ = allocf(CC * 64);
  float* teZ = allocf(BB * PP * 64);
  float* seX = allocf(NN * 64);
  float* teXb = allocf(BB * PP * 64);
  float* mtmp = allocf(NN * 64);
  float* tetmp = allocf(BB * PP * 64);
  fp16* ruT = alloch((size_t)BB * 128 * NN);  // [b][128][2000]
  // pool (4*USL = 50.33MB)
  char* pool = alloc_bytes(50331648);
  fp16* Uall = (fp16*)pool;
  fp16* gates = (fp16*)pool;
  fp16* chh = (fp16*)(pool + 8388608);   // padded h [16][1156][64]
  float* ccc = (float*)(pool + 12582912);
  fp16* Zmix = (fp16*)pool;
  fp16* ZmovT = (fp16*)(pool + 25165824);
  // zpool: Zf_pad [bp][1156][64] (28.4MB) then ZXt [bp][64][2048]
  fp16* zpool = alloch((size_t)BB * PP * 64 * 2048);
  fp16* Zfp = zpool;
  fp16* ZXt = zpool;
  fp16* Zc = alloch((size_t)BB * PP * CC * 64);  // zf1 scratch -> ZclT -> Tmat

  if (off > ws_size) return;

  const long long uB = 192LL * 2048;
  const long long USL = 16LL * uB;
  const long long ZXB = 12LL * 64 * 2048;  // per-batch stride of ZXt
  fp16* Lh = LMall;
  fp16* M2h = LMall + 2048LL * 2048;
  fp16* M3h = LMall + 4096LL * 2048;
  const int KCH = 2016;  // chain K (2000 padded to x32; cols 2000..2015 zero)

  // ---- precompute ----
  k_wcatT<<<dim3(1152), dim3(256), 0, stream>>>(wcatT, W(39), W(40));
  k_gru_repackT<<<dim3(256), dim3(256), 0, stream>>>(gwT, W(41), 128);
  k_gru_repackT<<<dim3(128), dim3(256), 0, stream>>>(cwT, W(43), 64);
  k_w2T<<<dim3(16), dim3(256), 0, stream>>>(w2T, W(31));
  k_w2T<<<dim3(16), dim3(256), 0, stream>>>(w2mT, W(33));
  k_wT<<<dim3(16), dim3(256), 0, stream>>>(w27T, W(27), 64, 64);
  k_wT<<<dim3(16), dim3(256), 0, stream>>>(w35T, W(35), 64, 64);
  k_wT<<<dim3(4), dim3(256), 0, stream>>>(w37T, W(37), 12, 16);
  k_dinv<<<dim3(NN), dim3(256), 0, stream>>>(adj_gg, dinv);
  hipMemsetAsync(LMall, 0, (size_t)6144 * 2048 * 2, stream);
  k_L<<<dim3((NN * NN + 255) / 256), dim3(256), 0, stream>>>(adj_gg, dinv, Lh);
  mfma4<64, 128><<<dim3(32, 16, 1), dim3(256), 0, stream>>>(
      Lh, Lh, 31, 31, 0LL, 0LL, 2048, Lh, 2048, 0LL, M2h, 2048, 0LL, 31, 0LL, 31, 0LL,
      (const fp16*)nullptr, 2.f, 0.f, KCH);
  k_subdiag<<<dim3((NN + 255) / 256), dim3(256), 0, stream>>>(M2h);
  mfma4<64, 128><<<dim3(32, 16, 1), dim3(256), 0, stream>>>(
      Lh, Lh, 31, 31, 0LL, 0LL, 2048, M2h, 2048, 0LL, M3h, 2048, 0LL, 31, 0LL, 31, 0LL,
      (const fp16*)Lh, 2.f, -1.f, KCH);
  k_gumbel_softmax<<<dim3(CC), dim3(256), 0, stream>>>(movement, gumbel, mZh);
  k_f2h<<<dim3((NN * CC + 255) / 256), dim3(256), 0, stream>>>(agh2, adj_gr,
                                                               (long long)NN * CC);
  hipMemsetAsync(agh2 + (size_t)NN * CC, 0, (size_t)(2048 - NN) * CC * 2, stream);

  // ---- STEZ / STEX ----
  launch_gemm(stream, se_z, 64, 0LL, W(17), 64, 0LL, mtmp, 64, 0LL, (float*)nullptr, 0LL,
              W(18), CC, 64, 64, 1.f, 0.f, 1, 1);
  launch_gemm(stream, (const float*)mtmp, 64, 0LL, W(19), 64, 0LL, seZ, 64, 0LL,
              (float*)nullptr, 0LL, W(20), CC, 64, 64, 1.f, 0.f, 0, 1);
  k_te<<<dim3((BB * PP * 64 + 255) / 256), dim3(256), 0, stream>>>(TE, W(21), W(22), tetmp);
  launch_gemm(stream, (const float*)tetmp, 64, 0LL, W(23), 64, 0LL, teZ, 64, 0LL,
              (float*)nullptr, 0LL, W(24), BB * PP, 64, 64, 1.f, 0.f, 0, 1);
  launch_gemm(stream, se_x, 64, 0LL, W(9), 64, 0LL, mtmp, 64, 0LL, (float*)nullptr, 0LL,
              W(10), NN, 64, 64, 1.f, 0.f, 1, 1);
  launch_gemm(stream, (const float*)mtmp, 64, 0LL, W(11), 64, 0LL, seX, 64, 0LL,
              (float*)nullptr, 0LL, W(12), NN, 64, 64, 1.f, 0.f, 0, 1);
  k_te<<<dim3((BB * PP * 64 + 255) / 256), dim3(256), 0, stream>>>(TE, W(13), W(14), tetmp);
  launch_gemm(stream, (const float*)tetmp, 64, 0LL, W(15), 64, 0LL, teXb, 64, 0LL,
              (float*)nullptr, 0LL, W(16), BB * PP, 64, 64, 1.f, 0.f, 0, 1);
  k_addb<<<dim3((BB * PP * 64 + 255) / 256), dim3(256), 0, stream>>>(teXb, W(32),
                                                                     BB * PP * 64);

  // ---- Zf = mlp2(Z) + STEZ, fused GEMM + scatter into padded 34x34 layout ----
  long long nZ = (long long)BB * PP * CC * 64;
  k_zf1<<<dim3((int)((nZ + 255) / 256)), dim3(256), 0, stream>>>(Z, W(25), W(26), Zc);
  hipMemsetAsync(zpool, 0, (size_t)BB * PP * GP2 * 64 * 2, stream);  // zero Zf_pad (halo)
  k_zf2<<<dim3(1536), dim3(256), 0, stream>>>((const fp16*)Zc, w27T, W(28), seZ, teZ, Zfp);

  // ---- ConvLSTM (writes ZclT into Zc; h in padded chh) ----
  hipMemsetAsync(chh, 0, (size_t)BB * GP2 * 64 * 2, stream);
  hipMemsetAsync(ccc, 0, (size_t)BB * CC * 64 * 4, stream);
  for (int p = 0; p < PP; ++p) {
    k_conv4<<<dim3(BB * CC / 128, 4), dim3(256), 0, stream>>>(Zfp, chh, wcatT, gates, p);
    k_clstm_update<<<dim3((int)(((long long)BB * CC * 64 + 255) / 256)), dim3(256), 0,
                     stream>>>(gates, ccc, chh, Zc, p);
  }

  // ---- movement m1 (mfma4, z-batched) / m2 ----
  mfma4<128, 64><<<dim3(8, 1, 192), dim3(256), 0, stream>>>(
      mZh, mZh, 31, 31, 0LL, 0LL, CC, (const fp16*)Zc, CC, (long long)64 * CC, Zmix, 64,
      (long long)CC * 64, 31, 0LL, 31, 0LL, (const fp16*)nullptr, 1.f, 0.f, CC);
  mfma3<64, 128><<<dim3(1, 8, 192), dim3(256), 0, stream>>>(
      w2mT, 64, 0LL, 31, 0LL, Zmix, 64, (long long)CC * 64, ZmovT, CC, (long long)64 * CC,
      31, 0LL, 31, 0LL, (const fp16*)nullptr, 0LL, 0.f, W(34), 0LL, nullptr, 0, 64, CC, 64,
      1.f, 1);

  // ---- zxt term1: one big GEMM, M = 192*64 = 12288 rows of ZmovT ----
  mfma4<128, 128><<<dim3(96, 16, 1), dim3(256), 0, stream>>>(
      ZmovT, ZmovT, 31, 31, 0LL, 0LL, 1024, agh2, 1024, 0LL, ZXt, 2048, 0LL, 31, 0LL, 31,
      0LL, (const fp16*)nullptr, 1.f, 0.f, 1024);

  // ---- zxt term2 + biases (two halves; Tmat padded to 2048 rows/z in dead Zc) ----
  fp16* Tmat = Zc;
  for (int half = 0; half < 2; ++half) {
    long long z0 = 96LL * half;
    k_tmat<<<dim3((int)((96LL * NN * 64 + 255) / 256)), dim3(256), 0, stream>>>(
        X + z0 * NN, W(29), W(30), Tmat, 96LL * NN);
    k_zxtfin<<<dim3(1, 16, 96), dim3(256), 0, stream>>>(
        w2T, Tmat, ZXt + z0 * 64 * 2048, teXb + z0 * 64, seX);
  }

  // ---- DCGRU (combined xh chebs; h lives in U0 rows 64..127; x read from ZXt) ----
  fp16* U0 = Uall;
  fp16* Tn = Uall + USL;        // 3 slabs [2048 n][16z*128]
  fp16* Tn2 = Uall + 3 * USL;   // 3 cand slabs [2048 n][16z*64]
  const long long TnSlab = 2048LL * 2048;
  const long long Tn2Slab = 2048LL * 1024;
  hipMemsetAsync(U0, 0, (size_t)USL * 2, stream);  // zero slab 0 (h/rh rows + pads)

  for (int p = 0; p < PP; ++p) {
    const fp16* xP = ZXt + (long long)p * 64 * 2048;
    // combined xh chebs: Tn[s][n][z*128+row]
    mfma6<128, 128><<<dim3(48, 16), dim3(256), 0, stream>>>(
        LMall, 2048, xP, U0 + 64 * 2048, 7, 6, ZXB, uB, 2048, Tn, 2048, 11, TnSlab, KCH);
    // ruT = sigmoid(gwT @ chebs); epilogue writes rh = r*h into U0 rows 128..191
    mfma7<128, 1><<<dim3(1, 32, BB), dim3(256), 0, stream>>>(
        gwT, U0, uB, 0, xP, ZXB,
        Tn, TnSlab, 2048, 128,
        Tn + 64, TnSlab, 2048, 128,
        ruT, NN, (long long)128 * NN, W(42), U0 + 128 * 2048, U0 + 64 * 2048,
        (const fp16*)nullptr, 0LL, 128, NN);
    // cand chebs: Tn2[s][n][z*64+row] = LM_s @ rh^T
    mfma6<128, 128><<<dim3(48, 8), dim3(256), 0, stream>>>(
        LMall, 2048, U0 + 128 * 2048, U0 + 128 * 2048, 6, 6, uB, uB, 2048, Tn2, 1024, 11,
        Tn2Slab, KCH);
    // cnd GEMM; epilogue does h' = u*h + (1-u)*tanh(v) in place in U0 rows 64..127
    mfma7<64, 2><<<dim3(1, 32, BB), dim3(256), 0, stream>>>(
        cwT, U0, uB, 64, xP, ZXB,
        Tn, TnSlab, 2048, 128,
        Tn2, Tn2Slab, 1024, 64,
        U0 + 64 * 2048, 2048, uB, W(44), (fp16*)nullptr, (const fp16*)nullptr,
        (const fp16*)ruT, (long long)128 * NN, 64, NN);
  }

  // ---- output head: fused transpose + MLP2 -> d_out ----
  k_head<<<dim3(16, 16), dim3(256), 0, stream>>>(U0, w35T, W(36), w37T, W(38),
                                                 (float*)d_out);
}

// Round 8
// 2866.471 us; speedup vs baseline: 1.8599x; 1.0145x over previous
//
#include <hip/hip_runtime.h>
#include <hip/hip_bf16.h>
#include <math.h>

typedef _Float16 fp16;
typedef _Float16 f16x8 __attribute__((ext_vector_type(8)));
typedef float f32x4 __attribute__((ext_vector_type(4)));

#define BB 16
#define PP 12
#define QQ 12
#define NN 2000
#define CC 1024
#define GP 34   // padded grid side (32 + halo)
#define GP2 1156

static __device__ __forceinline__ float ldf(float v) { return v; }
static __device__ __forceinline__ float ldf(fp16 v) { return (float)v; }
static __device__ __forceinline__ void stf(float* p, float v) { *p = v; }
static __device__ __forceinline__ void stf(fp16* p, float v) { *p = (fp16)v; }

// async global->LDS, 16B per lane (wave-uniform LDS base + lane*16)
static __device__ __forceinline__ void gload_lds16(const fp16* g, fp16* l) {
  __builtin_amdgcn_global_load_lds(
      (const __attribute__((address_space(1))) void*)g,
      (__attribute__((address_space(3))) void*)l, 16, 0, 0);
}

// Swizzle note (32-wide rows, 4 segs): logical seg q of row r stored at slot
// q ^ ((r>>1)&3) -> 16 lanes of a quad tile all 8 bank-groups twice (free).
// For 64-wide rows (8 segs): slot = q ^ (r&7), same property.

// ---------- conversions / repacks ----------
__global__ void k_f2h(fp16* __restrict__ dst, const float* __restrict__ src, long long n) {
  long long i = (long long)blockIdx.x * 256 + threadIdx.x;
  if (i < n) dst[i] = (fp16)src[i];
}

// wcatT[n][kk] = wcat[kk][n], kk<576 from W39, else W40 (each [576][256])
__global__ void k_wcatT(fp16* __restrict__ dst, const float* __restrict__ w39,
                        const float* __restrict__ w40) {
  int i = blockIdx.x * 256 + threadIdx.x;
  if (i >= 1152 * 256) return;
  int n = i & 255, kk = i >> 8;
  float v = (kk < 576) ? w39[kk * 256 + n] : w40[(kk - 576) * 256 + n];
  dst[(long long)n * 1152 + kk] = (fp16)v;
}

// dcgru weights (512,O): row=f*4+t -> Wt[d][t*128+c] = src[(c*4+t)*O+d]
__global__ void k_gru_repackT(fp16* __restrict__ dst, const float* __restrict__ src, int O) {
  int i = blockIdx.x * 256 + threadIdx.x;
  if (i >= O * 512) return;
  int d = i >> 9;
  int kc = i & 511;
  int t = kc >> 7;
  int c = kc & 127;
  dst[i] = (fp16)src[(c * 4 + t) * O + d];
}

// (64,64) -> T[d][k] fp16
__global__ void k_w2T(fp16* __restrict__ dst, const float* __restrict__ src) {
  int i = blockIdx.x * 256 + threadIdx.x;
  if (i >= 4096) return;
  int d = i >> 6, k = i & 63;
  dst[i] = (fp16)src[k * 64 + d];
}

// generic transpose repack: dst[j][k] (JP x 64 fp16) = src[k*J+j] for j<J else 0
__global__ void k_wT(fp16* __restrict__ dst, const float* __restrict__ src, int J, int JP) {
  int i = blockIdx.x * 256 + threadIdx.x;
  if (i >= JP * 64) return;
  int j = i >> 6, k = i & 63;
  dst[i] = (fp16)((j < J) ? src[k * J + j] : 0.f);
}

// ---------- laplacian ----------
__global__ void k_dinv(const float* __restrict__ adj, float* __restrict__ dinv) {
  int row = blockIdx.x;
  float s = 0.f;
  for (int j = threadIdx.x; j < NN; j += 256)
    s += fmaxf(adj[(long long)row * NN + j], adj[(long long)j * NN + row]);
  __shared__ float red[256];
  red[threadIdx.x] = s;
  __syncthreads();
  for (int st = 128; st > 0; st >>= 1) {
    if (threadIdx.x < st) red[threadIdx.x] += red[threadIdx.x + st];
    __syncthreads();
  }
  if (threadIdx.x == 0) {
    float d = red[0];
    dinv[row] = d > 0.f ? 1.0f / sqrtf(d) : 0.f;
  }
}

// writes L with row stride 2048 (zero-padded for maskless mfma4)
__global__ void k_L(const float* __restrict__ adj, const float* __restrict__ dinv,
                    fp16* __restrict__ Lh) {
  long long i = (long long)blockIdx.x * 256 + threadIdx.x;
  if (i >= (long long)NN * NN) return;
  int r = (int)(i / NN), c = (int)(i % NN);
  float a = fmaxf(adj[(long long)r * NN + c], adj[(long long)c * NN + r]);
  Lh[(long long)r * 2048 + c] = (fp16)(-dinv[r] * a * dinv[c]);
}

__global__ void k_subdiag(fp16* __restrict__ M2) {
  int i = blockIdx.x * 256 + threadIdx.x;
  if (i >= NN) return;
  M2[(long long)i * 2048 + i] = (fp16)((float)M2[(long long)i * 2048 + i] - 1.0f);
}

// ---------- gumbel softmax -> fp16 ----------
__global__ void k_gumbel_softmax(const float* __restrict__ ml, const float* __restrict__ gn,
                                 fp16* __restrict__ mZ) {
  int row = blockIdx.x;
  __shared__ float buf[CC];
  __shared__ float red[256];
  int t = threadIdx.x;
  float mx = -1e30f;
  for (int j = t; j < CC; j += 256) {
    float u = gn[(long long)row * CC + j];
    float g = -logf(-logf(u + 1e-20f) + 1e-20f);
    float v = ml[(long long)row * CC + j] + g;
    buf[j] = v;
    mx = fmaxf(mx, v);
  }
  red[t] = mx;
  __syncthreads();
  for (int st = 128; st > 0; st >>= 1) {
    if (t < st) red[t] = fmaxf(red[t], red[t + st]);
    __syncthreads();
  }
  mx = red[0];
  __syncthreads();
  float s = 0.f;
  for (int j = t; j < CC; j += 256) {
    float e = expf(buf[j] - mx);
    buf[j] = e;
    s += e;
  }
  red[t] = s;
  __syncthreads();
  for (int st = 128; st > 0; st >>= 1) {
    if (t < st) red[t] += red[t + st];
    __syncthreads();
  }
  float inv = 1.0f / red[0];
  for (int j = t; j < CC; j += 256) mZ[(long long)row * CC + j] = (fp16)(buf[j] * inv);
}

__global__ void k_te(const int* __restrict__ TE, const float* __restrict__ w1,
                     const float* __restrict__ b1, float* __restrict__ tmp) {
  int i = blockIdx.x * 256 + threadIdx.x;
  if (i >= BB * PP * 64) return;
  int j = i & 63;
  int bp = i >> 6;
  int b = bp / PP, p = bp % PP;
  int te0 = TE[(b * (PP + QQ) + p) * 2 + 0];
  int te1 = TE[(b * (PP + QQ) + p) * 2 + 1];
  float v = w1[te0 * 64 + j] + w1[(7 + te1) * 64 + j] + b1[j];
  tmp[i] = fmaxf(v, 0.f);
}

__global__ void k_addb(float* __restrict__ dst, const float* __restrict__ b, int n) {
  int i = blockIdx.x * 256 + threadIdx.x;
  if (i < n) dst[i] += b[i & 63];
}

// ---------- k_zf2f: Zf = (relu(Z@W25+b26) @ W27) + b28 + seZ + teZ -> padded grid ----------
// Layer-1 is rank-2: compute A-tile in-register, ds_write swizzled. M=196608, K=64, N=64.
__global__ __launch_bounds__(256) void k_zf2f(
    const float* __restrict__ Z, const float* __restrict__ w25,
    const float* __restrict__ b26, const fp16* __restrict__ w27T,
    const float* __restrict__ b28, const float* __restrict__ seZ,
    const float* __restrict__ teZ, fp16* __restrict__ Zfp) {
  __shared__ fp16 As[128 * 64];
  __shared__ fp16 Bs[64 * 64];
  const int tid = threadIdx.x;
  const int gm0 = blockIdx.x * 128;
  const int lane = tid & 63, wv = tid >> 6;
  const int wr = wv >> 1, wc = wv & 1;
  const int quad = lane >> 4, ln = lane & 15;
  // A compute: 4 tasks x 8 elems, write to swizzled slot
#pragma unroll
  for (int i = 0; i < 4; ++i) {
    int c = i * 256 + tid;
    int row = c >> 3, seg = c & 7;
    float z0v = Z[(long long)(gm0 + row) * 2 + 0];
    float z1v = Z[(long long)(gm0 + row) * 2 + 1];
    fp16 tmp[8];
#pragma unroll
    for (int e = 0; e < 8; ++e) {
      int j = seg * 8 + e;
      tmp[e] = (fp16)fmaxf(z0v * w25[j] + z1v * w25[64 + j] + b26[j], 0.f);
    }
    *(f16x8*)&As[row * 64 + ((seg ^ (row & 7)) * 8)] = *(f16x8*)tmp;
  }
#pragma unroll
  for (int i = 0; i < 2; ++i) {
    int c = i * 256 + tid;
    int row = c >> 3;
    int lseg = (c & 7) ^ (row & 7);
    gload_lds16(w27T + (long long)row * 64 + lseg * 8, &Bs[c * 8]);
  }
  f32x4 acc[4][2];
#pragma unroll
  for (int i = 0; i < 4; ++i)
#pragma unroll
    for (int j = 0; j < 2; ++j) acc[i][j] = (f32x4){0.f, 0.f, 0.f, 0.f};
  __syncthreads();
#pragma unroll
  for (int kt = 0; kt < 2; ++kt) {
    f16x8 af[4], bf[2];
#pragma unroll
    for (int wm = 0; wm < 4; ++wm) {
      int row = wr * 64 + wm * 16 + ln;
      int slot = (kt * 4 + quad) ^ (row & 7);
      af[wm] = *(const f16x8*)&As[row * 64 + slot * 8];
    }
#pragma unroll
    for (int wn = 0; wn < 2; ++wn) {
      int row = wc * 32 + wn * 16 + ln;
      int slot = (kt * 4 + quad) ^ (row & 7);
      bf[wn] = *(const f16x8*)&Bs[row * 64 + slot * 8];
    }
#pragma unroll
    for (int wm = 0; wm < 4; ++wm)
#pragma unroll
      for (int wn = 0; wn < 2; ++wn)
        acc[wm][wn] =
            __builtin_amdgcn_mfma_f32_16x16x32_f16(af[wm], bf[wn], acc[wm][wn], 0, 0, 0);
  }
#pragma unroll
  for (int wm = 0; wm < 4; ++wm)
#pragma unroll
    for (int wn = 0; wn < 2; ++wn)
#pragma unroll
      for (int r = 0; r < 4; ++r) {
        int gm = gm0 + wr * 64 + wm * 16 + quad * 4 + r;
        int j = wc * 32 + wn * 16 + ln;
        int c = gm & 1023;
        int bp = gm >> 10;
        int pc = ((c >> 5) + 1) * GP + (c & 31) + 1;
        Zfp[((long long)bp * GP2 + pc) * 64 + j] =
            (fp16)(acc[wm][wn][r] + b28[j] + seZ[c * 64 + j] + teZ[bp * 64 + j]);
      }
}

// ---------- k_head: out[b][q][n] = (relu(h@W35+b36)@W37+b38), h from U0 h-rows ----------
__global__ __launch_bounds__(256) void k_head(
    const fp16* __restrict__ U0, const fp16* __restrict__ w35T,
    const float* __restrict__ b36, const fp16* __restrict__ w37T,
    const float* __restrict__ b38, float* __restrict__ out) {
  __shared__ fp16 hT[128 * 72];
  __shared__ fp16 Bs[64 * 64];
  __shared__ fp16 h2[128 * 72];
  const int b = blockIdx.y;
  const int n0 = blockIdx.x * 128;
  const int tid = threadIdx.x;
  const int lane = tid & 63, wv = tid >> 6;
  const int wr = wv >> 1, wc = wv & 1;
  const int quad = lane >> 4, ln = lane & 15;
  const fp16* hbase = U0 + ((long long)b * 192 + 64) * 2048;
#pragma unroll
  for (int i = 0; i < 4; ++i) {
    int task = i * 256 + tid;
    int d = task >> 4, ng = task & 15;
    f16x8 v = *(const f16x8*)(hbase + (long long)d * 2048 + n0 + ng * 8);
#pragma unroll
    for (int k = 0; k < 8; ++k) hT[(ng * 8 + k) * 72 + d] = v[k];
  }
#pragma unroll
  for (int i = 0; i < 2; ++i) {
    int c = i * 256 + tid;
    int row = c >> 3, s = c & 7;
    *(f16x8*)&Bs[row * 64 + (s ^ (row & 7)) * 8] =
        *(const f16x8*)(w35T + row * 64 + s * 8);
  }
  __syncthreads();
  f32x4 a1[4][2];
#pragma unroll
  for (int i = 0; i < 4; ++i)
#pragma unroll
    for (int j = 0; j < 2; ++j) a1[i][j] = (f32x4){0.f, 0.f, 0.f, 0.f};
#pragma unroll
  for (int kt = 0; kt < 2; ++kt) {
    f16x8 af[4], bf[2];
#pragma unroll
    for (int wm = 0; wm < 4; ++wm) {
      int row = wr * 64 + wm * 16 + ln;
      af[wm] = *(const f16x8*)&hT[row * 72 + kt * 32 + quad * 8];
    }
#pragma unroll
    for (int wn = 0; wn < 2; ++wn) {
      int row = wc * 32 + wn * 16 + ln;
      int slot = (kt * 4 + quad) ^ (row & 7);
      bf[wn] = *(const f16x8*)&Bs[row * 64 + slot * 8];
    }
#pragma unroll
    for (int wm = 0; wm < 4; ++wm)
#pragma unroll
      for (int wn = 0; wn < 2; ++wn)
        a1[wm][wn] =
            __builtin_amdgcn_mfma_f32_16x16x32_f16(af[wm], bf[wn], a1[wm][wn], 0, 0, 0);
  }
#pragma unroll
  for (int wm = 0; wm < 4; ++wm)
#pragma unroll
    for (int wn = 0; wn < 2; ++wn)
#pragma unroll
      for (int r = 0; r < 4; ++r) {
        int rl = wr * 64 + wm * 16 + quad * 4 + r;
        int j = wc * 32 + wn * 16 + ln;
        h2[rl * 72 + j] = (fp16)fmaxf(a1[wm][wn][r] + b36[j], 0.f);
      }
  __syncthreads();
  f32x4 a2[2];
#pragma unroll
  for (int i = 0; i < 2; ++i) a2[i] = (f32x4){0.f, 0.f, 0.f, 0.f};
#pragma unroll
  for (int kt = 0; kt < 2; ++kt) {
    f16x8 bf = *(const f16x8*)(w37T + ln * 64 + kt * 32 + quad * 8);
#pragma unroll
    for (int wm = 0; wm < 2; ++wm) {
      int row = wv * 32 + wm * 16 + ln;
      f16x8 af = *(const f16x8*)&h2[row * 72 + kt * 32 + quad * 8];
      a2[wm] = __builtin_amdgcn_mfma_f32_16x16x32_f16(af, bf, a2[wm], 0, 0, 0);
    }
  }
#pragma unroll
  for (int wm = 0; wm < 2; ++wm)
#pragma unroll
    for (int r = 0; r < 4; ++r) {
      int nl = wv * 32 + wm * 16 + quad * 4 + r;
      int n = n0 + nl;
      int q = ln;
      if (n < NN && q < 12)
        out[((long long)b * 12 + q) * NN + n] = a2[wm][r] + b38[q];
    }
}

// ---------- generic fp32-path GEMM (small ops) ----------
template <typename TA, typename TB, typename TC>
__global__ __launch_bounds__(256) void gemm_t(
    const TA* __restrict__ A, int lda, long long sA,
    const TB* __restrict__ Bm, int ldb, long long sB,
    TC* Cm, int ldc, long long sC,
    const TC* S, long long sS,
    const float* __restrict__ bias,
    int M, int Ncols, int K, float alpha, float beta, int act) {
  int bz = blockIdx.z;
  A += (long long)bz * sA;
  Bm += (long long)bz * sB;
  Cm += (long long)bz * sC;
  if (S) S += (long long)bz * sS;
  const int row0 = blockIdx.x * 64, col0 = blockIdx.y * 64;
  __shared__ float As[16][68];
  __shared__ float Bs[16][68];
  int tid = threadIdx.x, tx = tid & 15, ty = tid >> 4;
  float acc[4][4] = {};
  for (int k0 = 0; k0 < K; k0 += 16) {
#pragma unroll
    for (int j = 0; j < 4; ++j) {
      int e = tid + 256 * j;
      int m = e >> 4, kk = e & 15;
      int gm = row0 + m;
      As[kk][m] = (gm < M) ? ldf(A[(long long)gm * lda + k0 + kk]) : 0.f;
    }
#pragma unroll
    for (int j = 0; j < 4; ++j) {
      int e = tid + 256 * j;
      int kk = e >> 6, n = e & 63;
      int gn = col0 + n;
      Bs[kk][n] = (gn < Ncols) ? ldf(Bm[(long long)(k0 + kk) * ldb + gn]) : 0.f;
    }
    __syncthreads();
#pragma unroll
    for (int kk = 0; kk < 16; ++kk) {
      float a[4], bb[4];
#pragma unroll
      for (int i = 0; i < 4; ++i) a[i] = As[kk][ty * 4 + i];
#pragma unroll
      for (int j = 0; j < 4; ++j) bb[j] = Bs[kk][tx * 4 + j];
#pragma unroll
      for (int i = 0; i < 4; ++i)
#pragma unroll
        for (int j = 0; j < 4; ++j) acc[i][j] = fmaf(a[i], bb[j], acc[i][j]);
    }
    __syncthreads();
  }
#pragma unroll
  for (int i = 0; i < 4; ++i) {
    int r = row0 + ty * 4 + i;
    if (r >= M) continue;
#pragma unroll
    for (int j = 0; j < 4; ++j) {
      int cn = col0 + tx * 4 + j;
      if (cn >= Ncols) continue;
      float v = alpha * acc[i][j];
      if (bias) v += bias[cn];
      if (S) v += beta * ldf(S[(long long)r * ldc + cn]);
      if (act == 1) v = fmaxf(v, 0.f);
      else if (act == 2) v = 1.f / (1.f + expf(-v));
      else if (act == 3) v = tanhf(v);
      stf(&Cm[(long long)r * ldc + cn], v);
    }
  }
}

// ---------- mfma7: DCGRU weight GEMMs, mfma4-structure, fused GRU epilogues ----------
template <int MT, int MODE>
__global__ __launch_bounds__(256) void mfma7(
    const fp16* __restrict__ A,                       // weights MT x 512
    const fp16* __restrict__ U0base, long long uZ, int bHi,
    const fp16* __restrict__ xB, long long xZ,        // ZXt slab0 x rows (ld 2048)
    const fp16* __restrict__ Xc, long long XcSlab, int Xcld, int Xczmul,
    const fp16* __restrict__ Hc, long long HcSlab, int Hcld, int Hczmul,
    fp16* __restrict__ C, int ldc, long long cBatch,
    const float* __restrict__ bias,
    fp16* __restrict__ rhOut, const fp16* __restrict__ hIn,
    const fp16* __restrict__ uIn, long long uStride,
    int M, int Ncols) {
  __shared__ fp16 As[2][MT * 32];
  __shared__ fp16 Bs[2][64 * 32];
  const int z = blockIdx.z;
  const int n0 = blockIdx.y * 64;
  const fp16* U0z = U0base + (long long)z * uZ;
  const fp16* xBz = xB + (long long)z * xZ;
  C += (long long)z * cBatch;
  if (rhOut) rhOut += (long long)z * uZ;
  if (hIn) hIn += (long long)z * uZ;
  if (uIn) uIn += (long long)z * uStride;
  const int tid = threadIdx.x;
  const int lane = tid & 63, wv = tid >> 6;
  const int wr = wv >> 1, wc = wv & 1;
  const int quad = lane >> 4, ln = lane & 15;
  constexpr int WM = MT / 32;

  const fp16* aSrc[MT / 64];
#pragma unroll
  for (int i = 0; i < MT / 64; ++i) {
    int c = i * 256 + tid;
    int row = c >> 2;
    int lseg = (c & 3) ^ ((c >> 3) & 3);
    aSrc[i] = A + (long long)row * 512 + lseg * 8;
  }
  const int brow = tid >> 2;
  const int blseg = (tid & 3) ^ ((tid >> 3) & 3);
  const long long bnode = n0 + brow;

  f32x4 acc[WM][2];
#pragma unroll
  for (int i = 0; i < WM; ++i)
#pragma unroll
    for (int j = 0; j < 2; ++j) acc[i][j] = (f32x4){0.f, 0.f, 0.f, 0.f};

  auto stage = [&](int t, int buf) {
    const int k0 = t * 32;
#pragma unroll
    for (int i = 0; i < MT / 64; ++i)
      gload_lds16(aSrc[i] + k0, &As[buf][(i * 256 + tid) * 8]);
    if (k0 < 128) {
      int kin = k0 + (tid & 31);
      int ngrp = tid >> 5;
      int n = n0 + ngrp * 8;
      const fp16* src = (kin < 64) ? (xBz + (long long)kin * 2048 + n)
                                   : (U0z + (long long)(kin + bHi) * 2048 + n);
      f16x8 v = *(const f16x8*)src;
      int kk = tid & 31;
#pragma unroll
      for (int j = 0; j < 8; ++j) {
        int rn = ngrp * 8 + j;
        Bs[buf][rn * 32 + ((((kk >> 3) ^ ((rn >> 1) & 3)) << 3) | (kk & 7))] = v[j];
      }
    } else {
      int slab = k0 >> 7;
      int kin = (k0 & 127) + blseg * 8;
      const fp16* src;
      if (kin < 64)
        src = Xc + (long long)(slab - 1) * XcSlab + bnode * Xcld +
              (long long)z * Xczmul + kin;
      else
        src = Hc + (long long)(slab - 1) * HcSlab + bnode * Hcld +
              (long long)z * Hczmul + (kin - 64);
      gload_lds16(src, &Bs[buf][tid * 8]);
    }
  };

  const int sw = (quad ^ ((ln >> 1) & 3)) << 3;
  stage(0, 0);
  for (int t = 0; t < 16; ++t) {
    const int buf = t & 1;
    __syncthreads();
    if (t + 1 < 16) stage(t + 1, buf ^ 1);
    f16x8 af[WM], bf[2];
#pragma unroll
    for (int wm = 0; wm < WM; ++wm) {
      int row = wr * (MT / 2) + wm * 16 + ln;
      af[wm] = *(const f16x8*)&As[buf][row * 32 + sw];
    }
#pragma unroll
    for (int wn = 0; wn < 2; ++wn) {
      int row = wc * 32 + wn * 16 + ln;
      bf[wn] = *(const f16x8*)&Bs[buf][row * 32 + sw];
    }
#pragma unroll
    for (int wm = 0; wm < WM; ++wm)
#pragma unroll
      for (int wn = 0; wn < 2; ++wn)
        acc[wm][wn] =
            __builtin_amdgcn_mfma_f32_16x16x32_f16(af[wm], bf[wn], acc[wm][wn], 0, 0, 0);
  }
#pragma unroll
  for (int wm = 0; wm < WM; ++wm) {
#pragma unroll
    for (int wn = 0; wn < 2; ++wn) {
#pragma unroll
      for (int r = 0; r < 4; ++r) {
        int gm = wr * (MT / 2) + wm * 16 + quad * 4 + r;
        int gn = n0 + wc * 32 + wn * 16 + ln;
        if (gm < M && gn < Ncols) {
          float v = acc[wm][wn][r];
          v += bias[gm];
          if (MODE == 1) {
            v = 1.f / (1.f + expf(-v));  // sigmoid
            C[(long long)gm * ldc + gn] = (fp16)v;
            if (gm < 64) {
              float h = (float)hIn[(long long)gm * 2048 + gn];
              rhOut[(long long)gm * 2048 + gn] = (fp16)(v * h);
            }
          } else {
            v = tanhf(v);
            float u = (float)uIn[(long long)(64 + gm) * NN + gn];
            long long ci = (long long)gm * ldc + gn;
            float h = (float)C[ci];
            C[ci] = (fp16)(u * h + (1.f - u) * v);
          }
        }
      }
    }
  }
}

// ---------- mfma3: all-b128 GEMM (kept for movement m2) ----------
template <int MT, int NT>
__global__ __launch_bounds__(256) void mfma3(
    const fp16* __restrict__ A, int lda, long long zA, int aMsh, long long aMslab,
    const fp16* __restrict__ B, int ldb, long long zB,
    fp16* __restrict__ C, int ldc, long long zC, int cMsh, long long cMslab, int cNsh,
    long long cNslab,
    const fp16* __restrict__ S, long long zS, float beta,
    const float* __restrict__ rowBias, long long zRB,
    const float* __restrict__ s2T, int s2ld,
    int M, int Ncols, int K, float alpha, int act) {
  __shared__ fp16 As[MT][40];
  __shared__ fp16 Bs[NT][40];
  const int z = blockIdx.z;
  const int gm0 = blockIdx.x * MT, n0 = blockIdx.y * NT;
  A += (long long)z * zA;
  B += (long long)z * zB;
  C += (long long)z * zC;
  if (S) S += (long long)z * zS;
  const int tid = threadIdx.x;
  const int lane = tid & 63, wv = tid >> 6;
  const int wr = wv >> 1, wc = wv & 1;
  const int quad = lane >> 4, ln = lane & 15;
  const unsigned aMmask = (1u << aMsh) - 1u;
  const unsigned cMmask = (1u << cMsh) - 1u;
  const unsigned cNmask = (1u << cNsh) - 1u;
  constexpr int WM = MT / 32, WN = NT / 32;
  f32x4 acc[WM][WN];
#pragma unroll
  for (int i = 0; i < WM; ++i)
#pragma unroll
    for (int j = 0; j < WN; ++j) acc[i][j] = (f32x4){0.f, 0.f, 0.f, 0.f};

  for (int k0 = 0; k0 < K; k0 += 32) {
#pragma unroll
    for (int i = 0; i < MT / 64; ++i) {
      int c = tid + 256 * i;
      int row = c >> 2, seg = c & 3;
      int gm = gm0 + row;
      int kk0 = k0 + seg * 8;
      const fp16* src = A + ((long long)((unsigned)gm >> aMsh)) * aMslab +
                        (long long)(gm & aMmask) * lda + kk0;
      if (gm < M && kk0 + 8 <= K) {
        *(f16x8*)&As[row][seg * 8] = *(const f16x8*)src;
      } else {
#pragma unroll
        for (int j = 0; j < 8; ++j)
          As[row][seg * 8 + j] = (gm < M && kk0 + j < K) ? src[j] : (fp16)0.f;
      }
    }
#pragma unroll
    for (int i = 0; i < NT / 64; ++i) {
      int c = tid + 256 * i;
      int n = c >> 2, seg = c & 3;
      int gn = n0 + n;
      int kk0 = k0 + seg * 8;
      const fp16* src = B + (long long)gn * ldb + kk0;
      if (gn < Ncols && kk0 + 8 <= K) {
        *(f16x8*)&Bs[n][seg * 8] = *(const f16x8*)src;
      } else {
#pragma unroll
        for (int j = 0; j < 8; ++j)
          Bs[n][seg * 8 + j] = (gn < Ncols && kk0 + j < K) ? src[j] : (fp16)0.f;
      }
    }
    __syncthreads();
    f16x8 af[WM], bf[WN];
#pragma unroll
    for (int wm = 0; wm < WM; ++wm)
      af[wm] = *(const f16x8*)&As[wr * (MT / 2) + wm * 16 + ln][quad * 8];
#pragma unroll
    for (int wn = 0; wn < WN; ++wn)
      bf[wn] = *(const f16x8*)&Bs[wc * (NT / 2) + wn * 16 + ln][quad * 8];
#pragma unroll
    for (int wm = 0; wm < WM; ++wm)
#pragma unroll
      for (int wn = 0; wn < WN; ++wn)
        acc[wm][wn] =
            __builtin_amdgcn_mfma_f32_16x16x32_f16(af[wm], bf[wn], acc[wm][wn], 0, 0, 0);
    __syncthreads();
  }
#pragma unroll
  for (int wm = 0; wm < WM; ++wm) {
#pragma unroll
    for (int wn = 0; wn < WN; ++wn) {
#pragma unroll
      for (int r = 0; r < 4; ++r) {
        int gm = gm0 + wr * (MT / 2) + wm * 16 + quad * 4 + r;
        int gn = n0 + wc * (NT / 2) + wn * 16 + ln;
        if (gm < M && gn < Ncols) {
          float v = alpha * acc[wm][wn][r];
          if (rowBias) v += rowBias[(long long)z * zRB + gm];
          if (s2T) v += s2T[(long long)gn * s2ld + gm];
          long long ci = ((long long)((unsigned)gm >> cMsh)) * cMslab +
                         (long long)(gm & cMmask) * ldc +
                         ((long long)((unsigned)gn >> cNsh)) * cNslab + (gn & cNmask);
          if (S) v += beta * (float)S[ci];
          if (act == 1) v = fmaxf(v, 0.f);
          else if (act == 2) v = 1.f / (1.f + expf(-v));
          else if (act == 3) v = tanhf(v);
          C[ci] = (fp16)v;
        }
      }
    }
  }
}

// ---------- mfma4: maskless gload_lds GEMM, dual-base A descriptor ----------
template <int MT, int NT>
__global__ __launch_bounds__(256) void mfma4(
    const fp16* __restrict__ base0, const fp16* __restrict__ base1, int rsh, int ssh,
    long long z0, long long z1, int lda,
    const fp16* __restrict__ B, int ldb, long long zB,
    fp16* __restrict__ C, int ldc, long long zC, int cMsh, long long cMslab, int cNsh,
    long long cNslab,
    const fp16* __restrict__ S, float alpha, float beta, int K) {
  __shared__ fp16 As[2][MT * 32];
  __shared__ fp16 Bs[2][NT * 32];
  const int tid = threadIdx.x;
  const int z = blockIdx.z;
  const int gm0 = blockIdx.x * MT, n0 = blockIdx.y * NT;
  B += (long long)z * zB;
  C += (long long)z * zC;
  if (S) S += (long long)z * zC;
  const unsigned cMmask = (1u << cMsh) - 1u;
  const unsigned cNmask = (1u << cNsh) - 1u;
  const int lane = tid & 63, wv = tid >> 6;
  const int wr = wv >> 1, wc = wv & 1;
  const int quad = lane >> 4, ln = lane & 15;
  constexpr int WM = MT / 32, WN = NT / 32;

  const fp16* aSrc[MT / 64];
  const fp16* bSrc[NT / 64];
#pragma unroll
  for (int i = 0; i < MT / 64; ++i) {
    int c = i * 256 + tid;
    int row = c >> 2;
    int lseg = (c & 3) ^ ((c >> 3) & 3);
    int gm = gm0 + row;
    unsigned b = (unsigned)gm >> rsh;
    unsigned wi = (unsigned)gm & ((1u << rsh) - 1u);
    unsigned sel = wi >> ssh;
    unsigned r = wi & ((1u << ssh) - 1u);
    const fp16* ab = sel ? (base1 + (long long)b * z1) : (base0 + (long long)b * z0);
    aSrc[i] = ab + (long long)r * lda + lseg * 8;
  }
#pragma unroll
  for (int i = 0; i < NT / 64; ++i) {
    int c = i * 256 + tid;
    int lseg = (c & 3) ^ ((c >> 3) & 3);
    bSrc[i] = B + (long long)(n0 + (c >> 2)) * ldb + lseg * 8;
  }

  f32x4 acc[WM][WN];
#pragma unroll
  for (int i = 0; i < WM; ++i)
#pragma unroll
    for (int j = 0; j < WN; ++j) acc[i][j] = (f32x4){0.f, 0.f, 0.f, 0.f};

  const int sw = (quad ^ ((ln >> 1) & 3)) << 3;

#pragma unroll
  for (int i = 0; i < MT / 64; ++i) gload_lds16(aSrc[i], &As[0][(i * 256 + tid) * 8]);
#pragma unroll
  for (int i = 0; i < NT / 64; ++i) gload_lds16(bSrc[i], &Bs[0][(i * 256 + tid) * 8]);

  const int nk = K >> 5;
  for (int t = 0; t < nk; ++t) {
    const int buf = t & 1;
    __syncthreads();
    if (t + 1 < nk) {
      const int k1 = (t + 1) * 32;
#pragma unroll
      for (int i = 0; i < MT / 64; ++i)
        gload_lds16(aSrc[i] + k1, &As[buf ^ 1][(i * 256 + tid) * 8]);
#pragma unroll
      for (int i = 0; i < NT / 64; ++i)
        gload_lds16(bSrc[i] + k1, &Bs[buf ^ 1][(i * 256 + tid) * 8]);
    }
    f16x8 af[WM], bf[WN];
#pragma unroll
    for (int wm = 0; wm < WM; ++wm) {
      int row = wr * (MT / 2) + wm * 16 + ln;
      af[wm] = *(const f16x8*)&As[buf][row * 32 + sw];
    }
#pragma unroll
    for (int wn = 0; wn < WN; ++wn) {
      int row = wc * (NT / 2) + wn * 16 + ln;
      bf[wn] = *(const f16x8*)&Bs[buf][row * 32 + sw];
    }
#pragma unroll
    for (int wm = 0; wm < WM; ++wm)
#pragma unroll
      for (int wn = 0; wn < WN; ++wn)
        acc[wm][wn] =
            __builtin_amdgcn_mfma_f32_16x16x32_f16(af[wm], bf[wn], acc[wm][wn], 0, 0, 0);
  }
#pragma unroll
  for (int wm = 0; wm < WM; ++wm)
#pragma unroll
    for (int wn = 0; wn < WN; ++wn)
#pragma unroll
      for (int r = 0; r < 4; ++r) {
        int gm = gm0 + wr * (MT / 2) + wm * 16 + quad * 4 + r;
        int gn = n0 + wc * (NT / 2) + wn * 16 + ln;
        long long ci = ((long long)((unsigned)gm >> cMsh)) * cMslab +
                       (long long)(gm & cMmask) * ldc +
                       ((long long)((unsigned)gn >> cNsh)) * cNslab + (gn & cNmask);
        float v = alpha * acc[wm][wn][r];
        if (S) v += beta * (float)S[ci];
        C[ci] = (fp16)v;
      }
}

// ---------- mfma6: maskless gload_lds GEMM, dual-base B descriptor ----------
template <int MT, int NT>
__global__ __launch_bounds__(256) void mfma6(
    const fp16* __restrict__ A, int lda,
    const fp16* __restrict__ b0, const fp16* __restrict__ b1, int rsh, int ssh,
    long long z0, long long z1, int ldb,
    fp16* __restrict__ C, int ldc, int cMsh, long long cMslab,
    int K) {
  __shared__ fp16 As[2][MT * 32];
  __shared__ fp16 Bs[2][NT * 32];
  const int tid = threadIdx.x;
  const int gm0 = blockIdx.x * MT, n0 = blockIdx.y * NT;
  const unsigned cMmask = (1u << cMsh) - 1u;
  const int lane = tid & 63, wv = tid >> 6;
  const int wr = wv >> 1, wc = wv & 1;
  const int quad = lane >> 4, ln = lane & 15;
  constexpr int WM = MT / 32, WN = NT / 32;

  const fp16* aSrc[MT / 64];
  const fp16* bSrc[NT / 64];
#pragma unroll
  for (int i = 0; i < MT / 64; ++i) {
    int c = i * 256 + tid;
    int lseg = (c & 3) ^ ((c >> 3) & 3);
    aSrc[i] = A + (long long)(gm0 + (c >> 2)) * lda + lseg * 8;
  }
#pragma unroll
  for (int i = 0; i < NT / 64; ++i) {
    int c = i * 256 + tid;
    int lseg = (c & 3) ^ ((c >> 3) & 3);
    int gn = n0 + (c >> 2);
    unsigned b = (unsigned)gn >> rsh;
    unsigned wi = (unsigned)gn & ((1u << rsh) - 1u);
    unsigned sel = wi >> ssh;
    unsigned r = wi & ((1u << ssh) - 1u);
    const fp16* bb = sel ? (b1 + (long long)b * z1) : (b0 + (long long)b * z0);
    bSrc[i] = bb + (long long)r * ldb + lseg * 8;
  }

  f32x4 acc[WM][WN];
#pragma unroll
  for (int i = 0; i < WM; ++i)
#pragma unroll
    for (int j = 0; j < WN; ++j) acc[i][j] = (f32x4){0.f, 0.f, 0.f, 0.f};

  const int sw = (quad ^ ((ln >> 1) & 3)) << 3;

#pragma unroll
  for (int i = 0; i < MT / 64; ++i) gload_lds16(aSrc[i], &As[0][(i * 256 + tid) * 8]);
#pragma unroll
  for (int i = 0; i < NT / 64; ++i) gload_lds16(bSrc[i], &Bs[0][(i * 256 + tid) * 8]);

  const int nk = K >> 5;
  for (int t = 0; t < nk; ++t) {
    const int buf = t & 1;
    __syncthreads();
    if (t + 1 < nk) {
      const int k1 = (t + 1) * 32;
#pragma unroll
      for (int i = 0; i < MT / 64; ++i)
        gload_lds16(aSrc[i] + k1, &As[buf ^ 1][(i * 256 + tid) * 8]);
#pragma unroll
      for (int i = 0; i < NT / 64; ++i)
        gload_lds16(bSrc[i] + k1, &Bs[buf ^ 1][(i * 256 + tid) * 8]);
    }
    f16x8 af[WM], bf[WN];
#pragma unroll
    for (int wm = 0; wm < WM; ++wm) {
      int row = wr * (MT / 2) + wm * 16 + ln;
      af[wm] = *(const f16x8*)&As[buf][row * 32 + sw];
    }
#pragma unroll
    for (int wn = 0; wn < WN; ++wn) {
      int row = wc * (NT / 2) + wn * 16 + ln;
      bf[wn] = *(const f16x8*)&Bs[buf][row * 32 + sw];
    }
#pragma unroll
    for (int wm = 0; wm < WM; ++wm)
#pragma unroll
      for (int wn = 0; wn < WN; ++wn)
        acc[wm][wn] =
            __builtin_amdgcn_mfma_f32_16x16x32_f16(af[wm], bf[wn], acc[wm][wn], 0, 0, 0);
  }
#pragma unroll
  for (int wm = 0; wm < WM; ++wm)
#pragma unroll
    for (int wn = 0; wn < WN; ++wn)
#pragma unroll
      for (int r = 0; r < 4; ++r) {
        int gm = gm0 + wr * (MT / 2) + wm * 16 + quad * 4 + r;
        int gn = n0 + wc * (NT / 2) + wn * 16 + ln;
        long long ci = ((long long)((unsigned)gm >> cMsh)) * cMslab +
                       (long long)(gm & cMmask) * ldc + gn;
        C[ci] = (fp16)acc[wm][wn][r];
      }
}

// ---------- k_zxtfin2: ZXt[z][d][n] += w2T@relu(x*w29+b30)^T + teXb + seX ----------
// Tmat layer computed in-register (rank-1). z over 192; zero pad cols >= NN.
__global__ __launch_bounds__(256) void k_zxtfin2(
    const fp16* __restrict__ w2T, const float* __restrict__ X,
    const float* __restrict__ w29, const float* __restrict__ b30,
    fp16* __restrict__ ZXt, const float* __restrict__ teXb,
    const float* __restrict__ seX) {
  __shared__ fp16 As[64][72];
  __shared__ fp16 Bs[128][72];
  const int z = blockIdx.z;
  const int n0 = blockIdx.y * 128;
  fp16* Cz = ZXt + (long long)z * 64 * 2048;
  const float* tb = teXb + z * 64;
  const int tid = threadIdx.x;
  const int lane = tid & 63, wv = tid >> 6;
  const int wr = wv >> 1, wc = wv & 1;
  const int quad = lane >> 4, ln = lane & 15;
#pragma unroll
  for (int i = 0; i < 2; ++i) {
    int c = tid + 256 * i;
    int row = c >> 3, seg = c & 7;
    *(f16x8*)&As[row][seg * 8] = *(const f16x8*)(w2T + row * 64 + seg * 8);
  }
  // Bs compute: Tmat row n = relu(X[z][n] * w29 + b30)
#pragma unroll
  for (int i = 0; i < 4; ++i) {
    int c = tid + 256 * i;
    int row = c >> 3, seg = c & 7;
    int n = n0 + row;
    float xv = (n < NN) ? X[(long long)z * NN + n] : 0.f;
    fp16 tmp[8];
#pragma unroll
    for (int e = 0; e < 8; ++e) {
      int j = seg * 8 + e;
      tmp[e] = (fp16)fmaxf(xv * w29[j] + b30[j], 0.f);
    }
    *(f16x8*)&Bs[row][seg * 8] = *(f16x8*)tmp;
  }
  __syncthreads();
  f32x4 acc[2][4];
#pragma unroll
  for (int i = 0; i < 2; ++i)
#pragma unroll
    for (int j = 0; j < 4; ++j) acc[i][j] = (f32x4){0.f, 0.f, 0.f, 0.f};
#pragma unroll
  for (int kt = 0; kt < 2; ++kt) {
    f16x8 af[2], bf[4];
#pragma unroll
    for (int wm = 0; wm < 2; ++wm)
      af[wm] = *(const f16x8*)&As[wr * 32 + wm * 16 + ln][kt * 32 + quad * 8];
#pragma unroll
    for (int wn = 0; wn < 4; ++wn)
      bf[wn] = *(const f16x8*)&Bs[wc * 64 + wn * 16 + ln][kt * 32 + quad * 8];
#pragma unroll
    for (int wm = 0; wm < 2; ++wm)
#pragma unroll
      for (int wn = 0; wn < 4; ++wn)
        acc[wm][wn] =
            __builtin_amdgcn_mfma_f32_16x16x32_f16(af[wm], bf[wn], acc[wm][wn], 0, 0, 0);
  }
#pragma unroll
  for (int wm = 0; wm < 2; ++wm)
#pragma unroll
    for (int wn = 0; wn < 4; ++wn)
#pragma unroll
      for (int r = 0; r < 4; ++r) {
        int gm = wr * 32 + wm * 16 + quad * 4 + r;
        int gn = n0 + wc * 64 + wn * 16 + ln;
        long long ci = (long long)gm * 2048 + gn;
        float v = 0.f;
        if (gn < NN)
          v = acc[wm][wn][r] + (float)Cz[ci] + tb[gm] + seX[(long long)gn * 64 + gm];
        Cz[ci] = (fp16)v;
      }
}

// ---------- ConvLSTM conv, mfma4-style with zero-padded 34x34 halo ----------
__global__ __launch_bounds__(256) void k_conv4(
    const fp16* __restrict__ Zfp, const fp16* __restrict__ hp,
    const fp16* __restrict__ wcatT, fp16* __restrict__ gates, int p) {
  __shared__ fp16 As[2][128 * 32];
  __shared__ fp16 Bs[2][64 * 32];
  const int gm0 = blockIdx.x * 128, n0 = blockIdx.y * 64;
  const int tid = threadIdx.x;
  const int lane = tid & 63, wv = tid >> 6;
  const int wr = wv >> 1, wc = wv & 1;
  const int quad = lane >> 4, ln = lane & 15;

  long long aZ[2], aH[2];
#pragma unroll
  for (int i = 0; i < 2; ++i) {
    int c = tid + 256 * i;
    int row = c >> 2;
    int lseg = (c & 3) ^ ((c >> 3) & 3);
    int m = gm0 + row;
    int b = m >> 10, y = (m >> 5) & 31, x = m & 31;
    int pc = (y + 1) * GP + (x + 1);
    aZ[i] = ((long long)(b * PP + p) * GP2 + pc) * 64 + lseg * 8;
    aH[i] = ((long long)b * GP2 + pc) * 64 + lseg * 8;
  }
  const fp16* bBase;
  {
    int row = tid >> 2;
    int lseg = (tid & 3) ^ ((tid >> 3) & 3);
    bBase = wcatT + (long long)(n0 + row) * 1152 + lseg * 8;
  }
  f32x4 acc[4][2];
#pragma unroll
  for (int i = 0; i < 4; ++i)
#pragma unroll
    for (int j = 0; j < 2; ++j) acc[i][j] = (f32x4){0.f, 0.f, 0.f, 0.f};

  auto stage = [&](int t, int buf) {
    int tap = (t >> 1) % 9, half = t & 1;
    int srcsel = t >= 18;
    int off = ((tap / 3 - 1) * GP + (tap % 3 - 1)) * 64 + half * 32;
#pragma unroll
    for (int i = 0; i < 2; ++i) {
      const fp16* src = srcsel ? (hp + aH[i] + off) : (Zfp + aZ[i] + off);
      gload_lds16(src, &As[buf][(i * 256 + tid) * 8]);
    }
    gload_lds16(bBase + t * 32, &Bs[buf][tid * 8]);
  };
  stage(0, 0);
  const int sw = (quad ^ ((ln >> 1) & 3)) << 3;
  for (int t = 0; t < 36; ++t) {
    const int buf = t & 1;
    __syncthreads();
    if (t + 1 < 36) stage(t + 1, buf ^ 1);
    f16x8 af[4], bf[2];
#pragma unroll
    for (int wm = 0; wm < 4; ++wm) {
      int row = wr * 64 + wm * 16 + ln;
      af[wm] = *(const f16x8*)&As[buf][row * 32 + sw];
    }
#pragma unroll
    for (int wn = 0; wn < 2; ++wn) {
      int row = wc * 32 + wn * 16 + ln;
      bf[wn] = *(const f16x8*)&Bs[buf][row * 32 + sw];
    }
#pragma unroll
    for (int wm = 0; wm < 4; ++wm)
#pragma unroll
      for (int wn = 0; wn < 2; ++wn)
        acc[wm][wn] =
            __builtin_amdgcn_mfma_f32_16x16x32_f16(af[wm], bf[wn], acc[wm][wn], 0, 0, 0);
  }
#pragma unroll
  for (int wm = 0; wm < 4; ++wm)
#pragma unroll
    for (int wn = 0; wn < 2; ++wn)
#pragma unroll
      for (int r = 0; r < 4; ++r) {
        int gm = gm0 + wr * 64 + wm * 16 + quad * 4 + r;
        int gn = n0 + wc * 32 + wn * 16 + ln;
        gates[(long long)gm * 256 + gn] = (fp16)acc[wm][wn][r];
      }
}

__global__ void k_clstm_update(const fp16* __restrict__ gates, float* __restrict__ c,
                               fp16* __restrict__ h, fp16* __restrict__ ZclT, int p) {
  long long i = (long long)blockIdx.x * 256 + threadIdx.x;
  if (i >= (long long)BB * CC * 64) return;
  int d = (int)(i & 63);
  long long bc = i >> 6;
  int b = (int)(bc >> 10);
  int cell = (int)(bc & 1023);
  const fp16* g = gates + (((long long)b * CC) + cell) * 256;
  float gi = (float)g[d], gf = (float)g[64 + d], gg = (float)g[128 + d],
        go = (float)g[192 + d];
  float hs_f = fminf(fmaxf(0.2f * gf + 0.5f, 0.f), 1.f);
  float hs_i = fminf(fmaxf(0.2f * gi + 0.5f, 0.f), 1.f);
  float hs_o = fminf(fmaxf(0.2f * go + 0.5f, 0.f), 1.f);
  float cv = hs_f * c[i] + hs_i * tanhf(gg);
  c[i] = cv;
  float hv = hs_o * tanhf(cv);
  int pc = ((cell >> 5) + 1) * GP + (cell & 31) + 1;
  h[((long long)b * GP2 + pc) * 64 + d] = (fp16)hv;
  ZclT[(((long long)(b * PP + p)) * 64 + d) * CC + cell] = (fp16)hv;
}

// ---------- host helpers ----------
template <typename TA, typename TB, typename TC>
static void launch_gemm(hipStream_t stream, const TA* A, int lda, long long sA,
                        const TB* Bm, int ldb, long long sB, TC* Cm, int ldc, long long sC,
                        const TC* S, long long sS, const float* bias, int M, int Nc, int K,
                        float alpha, float beta, int act, int batch) {
  dim3 g((M + 63) / 64, (Nc + 63) / 64, batch);
  gemm_t<TA, TB, TC><<<g, dim3(256), 0, stream>>>(A, lda, sA, Bm, ldb, sB, Cm, ldc, sC, S,
                                                  sS, bias, M, Nc, K, alpha, beta, act);
}

extern "C" void kernel_launch(void* const* d_in, const int* in_sizes, int n_in,
                              void* d_out, int out_size, void* d_ws, size_t ws_size,
                              hipStream_t stream) {
  char* base = (char*)d_ws;
  size_t off = 0;
  auto alloc_bytes = [&](size_t nb) -> char* {
    char* p = base + off;
    off += (nb + 255) & ~(size_t)255;
    return p;
  };
  auto allocf = [&](size_t n) -> float* { return (float*)alloc_bytes(n * 4); };
  auto alloch = [&](size_t n) -> fp16* { return (fp16*)alloc_bytes(n * 2); };

  const float* X = (const float*)d_in[0];
  const float* Z = (const float*)d_in[1];
  const int* TE = (const int*)d_in[2];
  const float* adj_gg = (const float*)d_in[3];
  const float* adj_gr = (const float*)d_in[4];
  const float* gumbel = (const float*)d_in[5];
  const float* se_x = (const float*)d_in[6];
  const float* se_z = (const float*)d_in[7];
  const float* movement = (const float*)d_in[8];
  auto W = [&](int i) { return (const float*)d_in[i]; };

  // ---- allocations ----
  fp16* wcatT = alloch((size_t)256 * 1152);  // [n][k] pre-transposed conv weights
  fp16* gwT = alloch(128 * 512);
  fp16* cwT = alloch(64 * 512);
  fp16* w2T = alloch(64 * 64);
  fp16* w2mT = alloch(64 * 64);
  fp16* w27T = alloch(64 * 64);
  fp16* w35T = alloch(64 * 64);
  fp16* w37T = alloch(16 * 64);
  float* dinv = allocf(NN);
  fp16* LMall = alloch((size_t)6144 * 2048);  // rows padded to 2048 for maskless mfma4/6
  fp16* mZh = alloch((size_t)CC * CC);
  fp16* agh2 = alloch((size_t)2048 * CC);  // padded to 2048 rows (pad rows zero)
  float* seZ = allocf(CC * 64);
  float* teZ = allocf(BB * PP * 64);
  float* seX = allocf(NN * 64);
  float* teXb = allocf(BB * PP * 64);
  float* mtmp = allocf(NN * 64);
  float* tetmp = allocf(BB * PP * 64);
  fp16* ruT = alloch((size_t)BB * 128 * NN);  // [b][128][2000]
  // pool (4*USL = 50.33MB)
  char* pool = alloc_bytes(50331648);
  fp16* Uall = (fp16*)pool;
  fp16* gates = (fp16*)pool;
  fp16* chh = (fp16*)(pool + 8388608);   // padded h [16][1156][64]
  float* ccc = (float*)(pool + 12582912);
  fp16* Zmix = (fp16*)pool;
  fp16* ZmovT = (fp16*)(pool + 25165824);
  // zpool: Zf_pad [bp][1156][64] (28.4MB) then ZXt [bp][64][2048]
  fp16* zpool = alloch((size_t)BB * PP * 64 * 2048);
  fp16* Zfp = zpool;
  fp16* ZXt = zpool;
  fp16* Zc = alloch((size_t)BB * PP * CC * 64);  // ZclT (conv output, movement m1 input)

  if (off > ws_size) return;

  const long long uB = 192LL * 2048;
  const long long USL = 16LL * uB;
  const long long ZXB = 12LL * 64 * 2048;  // per-batch stride of ZXt
  fp16* Lh = LMall;
  fp16* M2h = LMall + 2048LL * 2048;
  fp16* M3h = LMall + 4096LL * 2048;
  const int KCH = 2016;  // chain K (2000 padded to x32; cols 2000..2015 zero)

  // ---- precompute ----
  k_wcatT<<<dim3(1152), dim3(256), 0, stream>>>(wcatT, W(39), W(40));
  k_gru_repackT<<<dim3(256), dim3(256), 0, stream>>>(gwT, W(41), 128);
  k_gru_repackT<<<dim3(128), dim3(256), 0, stream>>>(cwT, W(43), 64);
  k_w2T<<<dim3(16), dim3(256), 0, stream>>>(w2T, W(31));
  k_w2T<<<dim3(16), dim3(256), 0, stream>>>(w2mT, W(33));
  k_wT<<<dim3(16), dim3(256), 0, stream>>>(w27T, W(27), 64, 64);
  k_wT<<<dim3(16), dim3(256), 0, stream>>>(w35T, W(35), 64, 64);
  k_wT<<<dim3(4), dim3(256), 0, stream>>>(w37T, W(37), 12, 16);
  k_dinv<<<dim3(NN), dim3(256), 0, stream>>>(adj_gg, dinv);
  hipMemsetAsync(LMall, 0, (size_t)6144 * 2048 * 2, stream);
  k_L<<<dim3((NN * NN + 255) / 256), dim3(256), 0, stream>>>(adj_gg, dinv, Lh);
  mfma4<64, 128><<<dim3(32, 16, 1), dim3(256), 0, stream>>>(
      Lh, Lh, 31, 31, 0LL, 0LL, 2048, Lh, 2048, 0LL, M2h, 2048, 0LL, 31, 0LL, 31, 0LL,
      (const fp16*)nullptr, 2.f, 0.f, KCH);
  k_subdiag<<<dim3((NN + 255) / 256), dim3(256), 0, stream>>>(M2h);
  mfma4<64, 128><<<dim3(32, 16, 1), dim3(256), 0, stream>>>(
      Lh, Lh, 31, 31, 0LL, 0LL, 2048, M2h, 2048, 0LL, M3h, 2048, 0LL, 31, 0LL, 31, 0LL,
      (const fp16*)Lh, 2.f, -1.f, KCH);
  k_gumbel_softmax<<<dim3(CC), dim3(256), 0, stream>>>(movement, gumbel, mZh);
  k_f2h<<<dim3((NN * CC + 255) / 256), dim3(256), 0, stream>>>(agh2, adj_gr,
                                                               (long long)NN * CC);
  hipMemsetAsync(agh2 + (size_t)NN * CC, 0, (size_t)(2048 - NN) * CC * 2, stream);

  // ---- STEZ / STEX ----
  launch_gemm(stream, se_z, 64, 0LL, W(17), 64, 0LL, mtmp, 64, 0LL, (float*)nullptr, 0LL,
              W(18), CC, 64, 64, 1.f, 0.f, 1, 1);
  launch_gemm(stream, (const float*)mtmp, 64, 0LL, W(19), 64, 0LL, seZ, 64, 0LL,
              (float*)nullptr, 0LL, W(20), CC, 64, 64, 1.f, 0.f, 0, 1);
  k_te<<<dim3((BB * PP * 64 + 255) / 256), dim3(256), 0, stream>>>(TE, W(21), W(22), tetmp);
  launch_gemm(stream, (const float*)tetmp, 64, 0LL, W(23), 64, 0LL, teZ, 64, 0LL,
              (float*)nullptr, 0LL, W(24), BB * PP, 64, 64, 1.f, 0.f, 0, 1);
  launch_gemm(stream, se_x, 64, 0LL, W(9), 64, 0LL, mtmp, 64, 0LL, (float*)nullptr, 0LL,
              W(10), NN, 64, 64, 1.f, 0.f, 1, 1);
  launch_gemm(stream, (const float*)mtmp, 64, 0LL, W(11), 64, 0LL, seX, 64, 0LL,
              (float*)nullptr, 0LL, W(12), NN, 64, 64, 1.f, 0.f, 0, 1);
  k_te<<<dim3((BB * PP * 64 + 255) / 256), dim3(256), 0, stream>>>(TE, W(13), W(14), tetmp);
  launch_gemm(stream, (const float*)tetmp, 64, 0LL, W(15), 64, 0LL, teXb, 64, 0LL,
              (float*)nullptr, 0LL, W(16), BB * PP, 64, 64, 1.f, 0.f, 0, 1);
  k_addb<<<dim3((BB * PP * 64 + 255) / 256), dim3(256), 0, stream>>>(teXb, W(32),
                                                                     BB * PP * 64);

  // ---- Zf = mlp2(Z) + STEZ, fully fused -> padded 34x34 layout ----
  hipMemsetAsync(zpool, 0, (size_t)BB * PP * GP2 * 64 * 2, stream);  // zero Zf_pad (halo)
  k_zf2f<<<dim3(1536), dim3(256), 0, stream>>>(Z, W(25), W(26), w27T, W(28), seZ, teZ,
                                               Zfp);

  // ---- ConvLSTM (writes ZclT into Zc; h in padded chh) ----
  hipMemsetAsync(chh, 0, (size_t)BB * GP2 * 64 * 2, stream);
  hipMemsetAsync(ccc, 0, (size_t)BB * CC * 64 * 4, stream);
  for (int p = 0; p < PP; ++p) {
    k_conv4<<<dim3(BB * CC / 128, 4), dim3(256), 0, stream>>>(Zfp, chh, wcatT, gates, p);
    k_clstm_update<<<dim3((int)(((long long)BB * CC * 64 + 255) / 256)), dim3(256), 0,
                     stream>>>(gates, ccc, chh, Zc, p);
  }

  // ---- movement m1 (mfma4, z-batched) / m2 ----
  mfma4<128, 64><<<dim3(8, 1, 192), dim3(256), 0, stream>>>(
      mZh, mZh, 31, 31, 0LL, 0LL, CC, (const fp16*)Zc, CC, (long long)64 * CC, Zmix, 64,
      (long long)CC * 64, 31, 0LL, 31, 0LL, (const fp16*)nullptr, 1.f, 0.f, CC);
  mfma3<64, 128><<<dim3(1, 8, 192), dim3(256), 0, stream>>>(
      w2mT, 64, 0LL, 31, 0LL, Zmix, 64, (long long)CC * 64, ZmovT, CC, (long long)64 * CC,
      31, 0LL, 31, 0LL, (const fp16*)nullptr, 0LL, 0.f, W(34), 0LL, nullptr, 0, 64, CC, 64,
      1.f, 1);

  // ---- zxt term1: one big GEMM, M = 192*64 = 12288 rows of ZmovT ----
  mfma4<128, 128><<<dim3(96, 16, 1), dim3(256), 0, stream>>>(
      ZmovT, ZmovT, 31, 31, 0LL, 0LL, 1024, agh2, 1024, 0LL, ZXt, 2048, 0LL, 31, 0LL, 31,
      0LL, (const fp16*)nullptr, 1.f, 0.f, 1024);

  // ---- zxt term2 + biases, Tmat computed in-kernel (single launch, z=192) ----
  k_zxtfin2<<<dim3(1, 16, 192), dim3(256), 0, stream>>>(w2T, X, W(29), W(30), ZXt, teXb,
                                                        seX);

  // ---- DCGRU (combined xh chebs; h lives in U0 rows 64..127; x read from ZXt) ----
  fp16* U0 = Uall;
  fp16* Tn = Uall + USL;        // 3 slabs [2048 n][16z*128]
  fp16* Tn2 = Uall + 3 * USL;   // 3 cand slabs [2048 n][16z*64]
  const long long TnSlab = 2048LL * 2048;
  const long long Tn2Slab = 2048LL * 1024;
  hipMemsetAsync(U0, 0, (size_t)USL * 2, stream);  // zero slab 0 (h/rh rows + pads)

  for (int p = 0; p < PP; ++p) {
    const fp16* xP = ZXt + (long long)p * 64 * 2048;
    // combined xh chebs: Tn[s][n][z*128+row]
    mfma6<128, 128><<<dim3(48, 16), dim3(256), 0, stream>>>(
        LMall, 2048, xP, U0 + 64 * 2048, 7, 6, ZXB, uB, 2048, Tn, 2048, 11, TnSlab, KCH);
    // ruT = sigmoid(gwT @ chebs); epilogue writes rh = r*h into U0 rows 128..191
    mfma7<128, 1><<<dim3(1, 32, BB), dim3(256), 0, stream>>>(
        gwT, U0, uB, 0, xP, ZXB,
        Tn, TnSlab, 2048, 128,
        Tn + 64, TnSlab, 2048, 128,
        ruT, NN, (long long)128 * NN, W(42), U0 + 128 * 2048, U0 + 64 * 2048,
        (const fp16*)nullptr, 0LL, 128, NN);
    // cand chebs: Tn2[s][n][z*64+row] = LM_s @ rh^T  (MT=64: 768 blocks = 3/CU)
    mfma6<64, 128><<<dim3(96, 8), dim3(256), 0, stream>>>(
        LMall, 2048, U0 + 128 * 2048, U0 + 128 * 2048, 6, 6, uB, uB, 2048, Tn2, 1024, 11,
        Tn2Slab, KCH);
    // cnd GEMM; epilogue does h' = u*h + (1-u)*tanh(v) in place in U0 rows 64..127
    mfma7<64, 2><<<dim3(1, 32, BB), dim3(256), 0, stream>>>(
        cwT, U0, uB, 64, xP, ZXB,
        Tn, TnSlab, 2048, 128,
        Tn2, Tn2Slab, 1024, 64,
        U0 + 64 * 2048, 2048, uB, W(44), (fp16*)nullptr, (const fp16*)nullptr,
        (const fp16*)ruT, (long long)128 * NN, 64, NN);
  }

  // ---- output head: fused transpose + MLP2 -> d_out ----
  k_head<<<dim3(16, 16), dim3(256), 0, stream>>>(U0, w35T, W(36), w37T, W(38),
                                                 (float*)d_out);
}

// Round 9
// 2783.660 us; speedup vs baseline: 1.9152x; 1.0297x over previous
//
#include <hip/hip_runtime.h>
#include <hip/hip_bf16.h>
#include <math.h>

typedef _Float16 fp16;
typedef _Float16 f16x8 __attribute__((ext_vector_type(8)));
typedef float f32x4 __attribute__((ext_vector_type(4)));

#define BB 16
#define PP 12
#define QQ 12
#define NN 2000
#define CC 1024
#define GP 34   // padded grid side (32 + halo)
#define GP2 1156

// async global->LDS, 16B per lane (wave-uniform LDS base + lane*16)
static __device__ __forceinline__ void gload_lds16(const fp16* g, fp16* l) {
  __builtin_amdgcn_global_load_lds(
      (const __attribute__((address_space(1))) void*)g,
      (__attribute__((address_space(3))) void*)l, 16, 0, 0);
}

// Swizzle note (32-wide rows, 4 segs): logical seg q of row r stored at slot
// q ^ ((r>>1)&3) -> 16 lanes of a quad tile all 8 bank-groups twice (free).
// For 64-wide rows (8 segs): slot = q ^ (r&7), same property.

// ---------- conversions / repacks ----------
__global__ void k_f2h(fp16* __restrict__ dst, const float* __restrict__ src, long long n) {
  long long i = (long long)blockIdx.x * 256 + threadIdx.x;
  if (i < n) dst[i] = (fp16)src[i];
}

// wcatT[n][kk] = wcat[kk][n], kk<576 from W39, else W40 (each [576][256])
__global__ void k_wcatT(fp16* __restrict__ dst, const float* __restrict__ w39,
                        const float* __restrict__ w40) {
  int i = blockIdx.x * 256 + threadIdx.x;
  if (i >= 1152 * 256) return;
  int n = i & 255, kk = i >> 8;
  float v = (kk < 576) ? w39[kk * 256 + n] : w40[(kk - 576) * 256 + n];
  dst[(long long)n * 1152 + kk] = (fp16)v;
}

// dcgru weights (512,O): row=f*4+t -> Wt[d][t*128+c] = src[(c*4+t)*O+d]
__global__ void k_gru_repackT(fp16* __restrict__ dst, const float* __restrict__ src, int O) {
  int i = blockIdx.x * 256 + threadIdx.x;
  if (i >= O * 512) return;
  int d = i >> 9;
  int kc = i & 511;
  int t = kc >> 7;
  int c = kc & 127;
  dst[i] = (fp16)src[(c * 4 + t) * O + d];
}

// (64,64) -> T[d][k] fp16
__global__ void k_w2T(fp16* __restrict__ dst, const float* __restrict__ src) {
  int i = blockIdx.x * 256 + threadIdx.x;
  if (i >= 4096) return;
  int d = i >> 6, k = i & 63;
  dst[i] = (fp16)src[k * 64 + d];
}

// generic transpose repack: dst[j][k] (JP x 64 fp16) = src[k*J+j] for j<J else 0
__global__ void k_wT(fp16* __restrict__ dst, const float* __restrict__ src, int J, int JP) {
  int i = blockIdx.x * 256 + threadIdx.x;
  if (i >= JP * 64) return;
  int j = i >> 6, k = i & 63;
  dst[i] = (fp16)((j < J) ? src[k * J + j] : 0.f);
}

// ---------- laplacian ----------
__global__ void k_dinv(const float* __restrict__ adj, float* __restrict__ dinv) {
  int row = blockIdx.x;
  float s = 0.f;
  for (int j = threadIdx.x; j < NN; j += 256)
    s += fmaxf(adj[(long long)row * NN + j], adj[(long long)j * NN + row]);
  __shared__ float red[256];
  red[threadIdx.x] = s;
  __syncthreads();
  for (int st = 128; st > 0; st >>= 1) {
    if (threadIdx.x < st) red[threadIdx.x] += red[threadIdx.x + st];
    __syncthreads();
  }
  if (threadIdx.x == 0) {
    float d = red[0];
    dinv[row] = d > 0.f ? 1.0f / sqrtf(d) : 0.f;
  }
}

// writes L with row stride 2048 (zero-padded for maskless mfma4)
__global__ void k_L(const float* __restrict__ adj, const float* __restrict__ dinv,
                    fp16* __restrict__ Lh) {
  long long i = (long long)blockIdx.x * 256 + threadIdx.x;
  if (i >= (long long)NN * NN) return;
  int r = (int)(i / NN), c = (int)(i % NN);
  float a = fmaxf(adj[(long long)r * NN + c], adj[(long long)c * NN + r]);
  Lh[(long long)r * 2048 + c] = (fp16)(-dinv[r] * a * dinv[c]);
}

__global__ void k_subdiag(fp16* __restrict__ M2) {
  int i = blockIdx.x * 256 + threadIdx.x;
  if (i >= NN) return;
  M2[(long long)i * 2048 + i] = (fp16)((float)M2[(long long)i * 2048 + i] - 1.0f);
}

// ---------- gumbel softmax -> fp16 ----------
__global__ void k_gumbel_softmax(const float* __restrict__ ml, const float* __restrict__ gn,
                                 fp16* __restrict__ mZ) {
  int row = blockIdx.x;
  __shared__ float buf[CC];
  __shared__ float red[256];
  int t = threadIdx.x;
  float mx = -1e30f;
  for (int j = t; j < CC; j += 256) {
    float u = gn[(long long)row * CC + j];
    float g = -logf(-logf(u + 1e-20f) + 1e-20f);
    float v = ml[(long long)row * CC + j] + g;
    buf[j] = v;
    mx = fmaxf(mx, v);
  }
  red[t] = mx;
  __syncthreads();
  for (int st = 128; st > 0; st >>= 1) {
    if (t < st) red[t] = fmaxf(red[t], red[t + st]);
    __syncthreads();
  }
  mx = red[0];
  __syncthreads();
  float s = 0.f;
  for (int j = t; j < CC; j += 256) {
    float e = expf(buf[j] - mx);
    buf[j] = e;
    s += e;
  }
  red[t] = s;
  __syncthreads();
  for (int st = 128; st > 0; st >>= 1) {
    if (t < st) red[t] += red[t + st];
    __syncthreads();
  }
  float inv = 1.0f / red[0];
  for (int j = t; j < CC; j += 256) mZ[(long long)row * CC + j] = (fp16)(buf[j] * inv);
}

// ---------- k_mlp2: fused 2-layer MLP (STE paths) ----------
// MODE 0: stage1 = relu(A@W1 + b1) via MFMA (A float [M][64], w1T fp16 [64][64])
// MODE 1: stage1 = relu(w1f[te0] + w1f[7+te1] + b1) computed directly from TE
// stage2: out = stage1 @ W2 + b2 (+ eb). out float [M][64] and/or outT fp16 [64][2048].
template <int MODE>
__global__ __launch_bounds__(256) void k_mlp2(
    const float* __restrict__ A, const int* __restrict__ TE,
    const float* __restrict__ w1f, const float* __restrict__ b1,
    const fp16* __restrict__ w1T, const fp16* __restrict__ w2T,
    const float* __restrict__ b2, const float* __restrict__ eb,
    float* __restrict__ out, fp16* __restrict__ outT, int M) {
  __shared__ fp16 hT[128 * 72];
  __shared__ fp16 Bs[64 * 64];
  __shared__ fp16 h2[128 * 72];
  const int m0 = blockIdx.x * 128;
  const int tid = threadIdx.x;
  const int lane = tid & 63, wv = tid >> 6;
  const int wr = wv >> 1, wc = wv & 1;
  const int quad = lane >> 4, ln = lane & 15;
#pragma unroll
  for (int i = 0; i < 4; ++i) {
    int c = i * 256 + tid;
    int row = c >> 3, seg = c & 7;
    int gm = m0 + row;
    fp16 tmp[8];
    if (MODE == 0) {
#pragma unroll
      for (int e = 0; e < 8; ++e)
        tmp[e] = (gm < M) ? (fp16)A[(long long)gm * 64 + seg * 8 + e] : (fp16)0.f;
      *(f16x8*)&hT[row * 72 + seg * 8] = *(f16x8*)tmp;
    } else {
      if (gm < M) {
        int b = gm / PP, p = gm - b * PP;
        int te0 = TE[(b * (PP + QQ) + p) * 2 + 0];
        int te1 = TE[(b * (PP + QQ) + p) * 2 + 1];
#pragma unroll
        for (int e = 0; e < 8; ++e) {
          int j = seg * 8 + e;
          tmp[e] =
              (fp16)fmaxf(w1f[te0 * 64 + j] + w1f[(7 + te1) * 64 + j] + b1[j], 0.f);
        }
      } else {
#pragma unroll
        for (int e = 0; e < 8; ++e) tmp[e] = (fp16)0.f;
      }
      *(f16x8*)&h2[row * 72 + seg * 8] = *(f16x8*)tmp;
    }
  }
  {
    const fp16* wsrc = (MODE == 0) ? w1T : w2T;
#pragma unroll
    for (int i = 0; i < 2; ++i) {
      int c = i * 256 + tid;
      int row = c >> 3, s = c & 7;
      *(f16x8*)&Bs[row * 64 + ((s ^ (row & 7)) * 8)] =
          *(const f16x8*)(wsrc + row * 64 + s * 8);
    }
  }
  __syncthreads();
  if (MODE == 0) {
    f32x4 a1[4][2];
#pragma unroll
    for (int i = 0; i < 4; ++i)
#pragma unroll
      for (int j = 0; j < 2; ++j) a1[i][j] = (f32x4){0.f, 0.f, 0.f, 0.f};
#pragma unroll
    for (int kt = 0; kt < 2; ++kt) {
      f16x8 af[4], bf[2];
#pragma unroll
      for (int wm = 0; wm < 4; ++wm) {
        int row = wr * 64 + wm * 16 + ln;
        af[wm] = *(const f16x8*)&hT[row * 72 + kt * 32 + quad * 8];
      }
#pragma unroll
      for (int wn = 0; wn < 2; ++wn) {
        int row = wc * 32 + wn * 16 + ln;
        int slot = (kt * 4 + quad) ^ (row & 7);
        bf[wn] = *(const f16x8*)&Bs[row * 64 + slot * 8];
      }
#pragma unroll
      for (int wm = 0; wm < 4; ++wm)
#pragma unroll
        for (int wn = 0; wn < 2; ++wn)
          a1[wm][wn] =
              __builtin_amdgcn_mfma_f32_16x16x32_f16(af[wm], bf[wn], a1[wm][wn], 0, 0, 0);
    }
    __syncthreads();  // all Bs/hT reads done
#pragma unroll
    for (int wm = 0; wm < 4; ++wm)
#pragma unroll
      for (int wn = 0; wn < 2; ++wn)
#pragma unroll
        for (int r = 0; r < 4; ++r) {
          int rl = wr * 64 + wm * 16 + quad * 4 + r;
          int j = wc * 32 + wn * 16 + ln;
          h2[rl * 72 + j] = (fp16)fmaxf(a1[wm][wn][r] + b1[j], 0.f);
        }
#pragma unroll
    for (int i = 0; i < 2; ++i) {
      int c = i * 256 + tid;
      int row = c >> 3, s = c & 7;
      *(f16x8*)&Bs[row * 64 + ((s ^ (row & 7)) * 8)] =
          *(const f16x8*)(w2T + row * 64 + s * 8);
    }
    __syncthreads();
  }
  // stage 2
  f32x4 a2[4][2];
#pragma unroll
  for (int i = 0; i < 4; ++i)
#pragma unroll
    for (int j = 0; j < 2; ++j) a2[i][j] = (f32x4){0.f, 0.f, 0.f, 0.f};
#pragma unroll
  for (int kt = 0; kt < 2; ++kt) {
    f16x8 af[4], bf[2];
#pragma unroll
    for (int wm = 0; wm < 4; ++wm) {
      int row = wr * 64 + wm * 16 + ln;
      af[wm] = *(const f16x8*)&h2[row * 72 + kt * 32 + quad * 8];
    }
#pragma unroll
    for (int wn = 0; wn < 2; ++wn) {
      int row = wc * 32 + wn * 16 + ln;
      int slot = (kt * 4 + quad) ^ (row & 7);
      bf[wn] = *(const f16x8*)&Bs[row * 64 + slot * 8];
    }
#pragma unroll
    for (int wm = 0; wm < 4; ++wm)
#pragma unroll
      for (int wn = 0; wn < 2; ++wn)
        a2[wm][wn] =
            __builtin_amdgcn_mfma_f32_16x16x32_f16(af[wm], bf[wn], a2[wm][wn], 0, 0, 0);
  }
#pragma unroll
  for (int wm = 0; wm < 4; ++wm)
#pragma unroll
    for (int wn = 0; wn < 2; ++wn)
#pragma unroll
      for (int r = 0; r < 4; ++r) {
        int gm = m0 + wr * 64 + wm * 16 + quad * 4 + r;
        int j = wc * 32 + wn * 16 + ln;
        if (gm < M) {
          float v = a2[wm][wn][r] + b2[j];
          if (eb) v += eb[j];
          if (out) out[(long long)gm * 64 + j] = v;
          if (outT) outT[(long long)j * 2048 + gm] = (fp16)v;
        }
      }
}

// ---------- k_zf2f: Zf = (relu(Z@W25+b26) @ W27) + b28 + seZ + teZ -> padded grid ----------
__global__ __launch_bounds__(256) void k_zf2f(
    const float* __restrict__ Z, const float* __restrict__ w25,
    const float* __restrict__ b26, const fp16* __restrict__ w27T,
    const float* __restrict__ b28, const float* __restrict__ seZ,
    const float* __restrict__ teZ, fp16* __restrict__ Zfp) {
  __shared__ fp16 As[128 * 64];
  __shared__ fp16 Bs[64 * 64];
  const int tid = threadIdx.x;
  const int gm0 = blockIdx.x * 128;
  const int lane = tid & 63, wv = tid >> 6;
  const int wr = wv >> 1, wc = wv & 1;
  const int quad = lane >> 4, ln = lane & 15;
#pragma unroll
  for (int i = 0; i < 4; ++i) {
    int c = i * 256 + tid;
    int row = c >> 3, seg = c & 7;
    float z0v = Z[(long long)(gm0 + row) * 2 + 0];
    float z1v = Z[(long long)(gm0 + row) * 2 + 1];
    fp16 tmp[8];
#pragma unroll
    for (int e = 0; e < 8; ++e) {
      int j = seg * 8 + e;
      tmp[e] = (fp16)fmaxf(z0v * w25[j] + z1v * w25[64 + j] + b26[j], 0.f);
    }
    *(f16x8*)&As[row * 64 + ((seg ^ (row & 7)) * 8)] = *(f16x8*)tmp;
  }
#pragma unroll
  for (int i = 0; i < 2; ++i) {
    int c = i * 256 + tid;
    int row = c >> 3;
    int lseg = (c & 7) ^ (row & 7);
    gload_lds16(w27T + (long long)row * 64 + lseg * 8, &Bs[c * 8]);
  }
  f32x4 acc[4][2];
#pragma unroll
  for (int i = 0; i < 4; ++i)
#pragma unroll
    for (int j = 0; j < 2; ++j) acc[i][j] = (f32x4){0.f, 0.f, 0.f, 0.f};
  __syncthreads();
#pragma unroll
  for (int kt = 0; kt < 2; ++kt) {
    f16x8 af[4], bf[2];
#pragma unroll
    for (int wm = 0; wm < 4; ++wm) {
      int row = wr * 64 + wm * 16 + ln;
      int slot = (kt * 4 + quad) ^ (row & 7);
      af[wm] = *(const f16x8*)&As[row * 64 + slot * 8];
    }
#pragma unroll
    for (int wn = 0; wn < 2; ++wn) {
      int row = wc * 32 + wn * 16 + ln;
      int slot = (kt * 4 + quad) ^ (row & 7);
      bf[wn] = *(const f16x8*)&Bs[row * 64 + slot * 8];
    }
#pragma unroll
    for (int wm = 0; wm < 4; ++wm)
#pragma unroll
      for (int wn = 0; wn < 2; ++wn)
        acc[wm][wn] =
            __builtin_amdgcn_mfma_f32_16x16x32_f16(af[wm], bf[wn], acc[wm][wn], 0, 0, 0);
  }
#pragma unroll
  for (int wm = 0; wm < 4; ++wm)
#pragma unroll
    for (int wn = 0; wn < 2; ++wn)
#pragma unroll
      for (int r = 0; r < 4; ++r) {
        int gm = gm0 + wr * 64 + wm * 16 + quad * 4 + r;
        int j = wc * 32 + wn * 16 + ln;
        int c = gm & 1023;
        int bp = gm >> 10;
        int pc = ((c >> 5) + 1) * GP + (c & 31) + 1;
        Zfp[((long long)bp * GP2 + pc) * 64 + j] =
            (fp16)(acc[wm][wn][r] + b28[j] + seZ[c * 64 + j] + teZ[bp * 64 + j]);
      }
}

// ---------- k_head: out[b][q][n] = (relu(h@W35+b36)@W37+b38), h from U0 h-rows ----------
__global__ __launch_bounds__(256) void k_head(
    const fp16* __restrict__ U0, const fp16* __restrict__ w35T,
    const float* __restrict__ b36, const fp16* __restrict__ w37T,
    const float* __restrict__ b38, float* __restrict__ out) {
  __shared__ fp16 hT[128 * 72];
  __shared__ fp16 Bs[64 * 64];
  __shared__ fp16 h2[128 * 72];
  const int b = blockIdx.y;
  const int n0 = blockIdx.x * 128;
  const int tid = threadIdx.x;
  const int lane = tid & 63, wv = tid >> 6;
  const int wr = wv >> 1, wc = wv & 1;
  const int quad = lane >> 4, ln = lane & 15;
  const fp16* hbase = U0 + ((long long)b * 192 + 64) * 2048;
#pragma unroll
  for (int i = 0; i < 4; ++i) {
    int task = i * 256 + tid;
    int d = task >> 4, ng = task & 15;
    f16x8 v = *(const f16x8*)(hbase + (long long)d * 2048 + n0 + ng * 8);
#pragma unroll
    for (int k = 0; k < 8; ++k) hT[(ng * 8 + k) * 72 + d] = v[k];
  }
#pragma unroll
  for (int i = 0; i < 2; ++i) {
    int c = i * 256 + tid;
    int row = c >> 3, s = c & 7;
    *(f16x8*)&Bs[row * 64 + (s ^ (row & 7)) * 8] =
        *(const f16x8*)(w35T + row * 64 + s * 8);
  }
  __syncthreads();
  f32x4 a1[4][2];
#pragma unroll
  for (int i = 0; i < 4; ++i)
#pragma unroll
    for (int j = 0; j < 2; ++j) a1[i][j] = (f32x4){0.f, 0.f, 0.f, 0.f};
#pragma unroll
  for (int kt = 0; kt < 2; ++kt) {
    f16x8 af[4], bf[2];
#pragma unroll
    for (int wm = 0; wm < 4; ++wm) {
      int row = wr * 64 + wm * 16 + ln;
      af[wm] = *(const f16x8*)&hT[row * 72 + kt * 32 + quad * 8];
    }
#pragma unroll
    for (int wn = 0; wn < 2; ++wn) {
      int row = wc * 32 + wn * 16 + ln;
      int slot = (kt * 4 + quad) ^ (row & 7);
      bf[wn] = *(const f16x8*)&Bs[row * 64 + slot * 8];
    }
#pragma unroll
    for (int wm = 0; wm < 4; ++wm)
#pragma unroll
      for (int wn = 0; wn < 2; ++wn)
        a1[wm][wn] =
            __builtin_amdgcn_mfma_f32_16x16x32_f16(af[wm], bf[wn], a1[wm][wn], 0, 0, 0);
  }
#pragma unroll
  for (int wm = 0; wm < 4; ++wm)
#pragma unroll
    for (int wn = 0; wn < 2; ++wn)
#pragma unroll
      for (int r = 0; r < 4; ++r) {
        int rl = wr * 64 + wm * 16 + quad * 4 + r;
        int j = wc * 32 + wn * 16 + ln;
        h2[rl * 72 + j] = (fp16)fmaxf(a1[wm][wn][r] + b36[j], 0.f);
      }
  __syncthreads();
  f32x4 a2[2];
#pragma unroll
  for (int i = 0; i < 2; ++i) a2[i] = (f32x4){0.f, 0.f, 0.f, 0.f};
#pragma unroll
  for (int kt = 0; kt < 2; ++kt) {
    f16x8 bf = *(const f16x8*)(w37T + ln * 64 + kt * 32 + quad * 8);
#pragma unroll
    for (int wm = 0; wm < 2; ++wm) {
      int row = wv * 32 + wm * 16 + ln;
      f16x8 af = *(const f16x8*)&h2[row * 72 + kt * 32 + quad * 8];
      a2[wm] = __builtin_amdgcn_mfma_f32_16x16x32_f16(af, bf, a2[wm], 0, 0, 0);
    }
  }
#pragma unroll
  for (int wm = 0; wm < 2; ++wm)
#pragma unroll
    for (int r = 0; r < 4; ++r) {
      int nl = wv * 32 + wm * 16 + quad * 4 + r;
      int n = n0 + nl;
      int q = ln;
      if (n < NN && q < 12)
        out[((long long)b * 12 + q) * NN + n] = a2[wm][r] + b38[q];
    }
}

// ---------- mfma7: DCGRU weight GEMMs, mfma4-structure, fused GRU epilogues ----------
template <int MT, int MODE>
__global__ __launch_bounds__(256) void mfma7(
    const fp16* __restrict__ A,                       // weights MT x 512
    const fp16* __restrict__ U0base, long long uZ, int bHi,
    const fp16* __restrict__ xB, long long xZ,        // ZXt slab0 x rows (ld 2048)
    const fp16* __restrict__ Xc, long long XcSlab, int Xcld, int Xczmul,
    const fp16* __restrict__ Hc, long long HcSlab, int Hcld, int Hczmul,
    fp16* __restrict__ C, int ldc, long long cBatch,
    const float* __restrict__ bias,
    fp16* __restrict__ rhOut, const fp16* __restrict__ hIn,
    const fp16* __restrict__ uIn, long long uStride,
    int M, int Ncols) {
  __shared__ fp16 As[2][MT * 32];
  __shared__ fp16 Bs[2][64 * 32];
  const int z = blockIdx.z;
  const int n0 = blockIdx.y * 64;
  const fp16* U0z = U0base + (long long)z * uZ;
  const fp16* xBz = xB + (long long)z * xZ;
  C += (long long)z * cBatch;
  if (rhOut) rhOut += (long long)z * uZ;
  if (hIn) hIn += (long long)z * uZ;
  if (uIn) uIn += (long long)z * uStride;
  const int tid = threadIdx.x;
  const int lane = tid & 63, wv = tid >> 6;
  const int wr = wv >> 1, wc = wv & 1;
  const int quad = lane >> 4, ln = lane & 15;
  constexpr int WM = MT / 32;

  const fp16* aSrc[MT / 64];
#pragma unroll
  for (int i = 0; i < MT / 64; ++i) {
    int c = i * 256 + tid;
    int row = c >> 2;
    int lseg = (c & 3) ^ ((c >> 3) & 3);
    aSrc[i] = A + (long long)row * 512 + lseg * 8;
  }
  const int brow = tid >> 2;
  const int blseg = (tid & 3) ^ ((tid >> 3) & 3);
  const long long bnode = n0 + brow;

  f32x4 acc[WM][2];
#pragma unroll
  for (int i = 0; i < WM; ++i)
#pragma unroll
    for (int j = 0; j < 2; ++j) acc[i][j] = (f32x4){0.f, 0.f, 0.f, 0.f};

  auto stage = [&](int t, int buf) {
    const int k0 = t * 32;
#pragma unroll
    for (int i = 0; i < MT / 64; ++i)
      gload_lds16(aSrc[i] + k0, &As[buf][(i * 256 + tid) * 8]);
    if (k0 < 128) {
      int kin = k0 + (tid & 31);
      int ngrp = tid >> 5;
      int n = n0 + ngrp * 8;
      const fp16* src = (kin < 64) ? (xBz + (long long)kin * 2048 + n)
                                   : (U0z + (long long)(kin + bHi) * 2048 + n);
      f16x8 v = *(const f16x8*)src;
      int kk = tid & 31;
#pragma unroll
      for (int j = 0; j < 8; ++j) {
        int rn = ngrp * 8 + j;
        Bs[buf][rn * 32 + ((((kk >> 3) ^ ((rn >> 1) & 3)) << 3) | (kk & 7))] = v[j];
      }
    } else {
      int slab = k0 >> 7;
      int kin = (k0 & 127) + blseg * 8;
      const fp16* src;
      if (kin < 64)
        src = Xc + (long long)(slab - 1) * XcSlab + bnode * Xcld +
              (long long)z * Xczmul + kin;
      else
        src = Hc + (long long)(slab - 1) * HcSlab + bnode * Hcld +
              (long long)z * Hczmul + (kin - 64);
      gload_lds16(src, &Bs[buf][tid * 8]);
    }
  };

  const int sw = (quad ^ ((ln >> 1) & 3)) << 3;
  stage(0, 0);
  for (int t = 0; t < 16; ++t) {
    const int buf = t & 1;
    __syncthreads();
    if (t + 1 < 16) stage(t + 1, buf ^ 1);
    f16x8 af[WM], bf[2];
#pragma unroll
    for (int wm = 0; wm < WM; ++wm) {
      int row = wr * (MT / 2) + wm * 16 + ln;
      af[wm] = *(const f16x8*)&As[buf][row * 32 + sw];
    }
#pragma unroll
    for (int wn = 0; wn < 2; ++wn) {
      int row = wc * 32 + wn * 16 + ln;
      bf[wn] = *(const f16x8*)&Bs[buf][row * 32 + sw];
    }
#pragma unroll
    for (int wm = 0; wm < WM; ++wm)
#pragma unroll
      for (int wn = 0; wn < 2; ++wn)
        acc[wm][wn] =
            __builtin_amdgcn_mfma_f32_16x16x32_f16(af[wm], bf[wn], acc[wm][wn], 0, 0, 0);
  }
#pragma unroll
  for (int wm = 0; wm < WM; ++wm) {
#pragma unroll
    for (int wn = 0; wn < 2; ++wn) {
#pragma unroll
      for (int r = 0; r < 4; ++r) {
        int gm = wr * (MT / 2) + wm * 16 + quad * 4 + r;
        int gn = n0 + wc * 32 + wn * 16 + ln;
        if (gm < M && gn < Ncols) {
          float v = acc[wm][wn][r];
          v += bias[gm];
          if (MODE == 1) {
            v = 1.f / (1.f + expf(-v));  // sigmoid
            C[(long long)gm * ldc + gn] = (fp16)v;
            if (gm < 64) {
              float h = (float)hIn[(long long)gm * 2048 + gn];
              rhOut[(long long)gm * 2048 + gn] = (fp16)(v * h);
            }
          } else {
            v = tanhf(v);
            float u = (float)uIn[(long long)(64 + gm) * NN + gn];
            long long ci = (long long)gm * ldc + gn;
            float h = (float)C[ci];
            C[ci] = (fp16)(u * h + (1.f - u) * v);
          }
        }
      }
    }
  }
}

// ---------- mfma3: all-b128 GEMM (kept for movement m2) ----------
template <int MT, int NT>
__global__ __launch_bounds__(256) void mfma3(
    const fp16* __restrict__ A, int lda, long long zA, int aMsh, long long aMslab,
    const fp16* __restrict__ B, int ldb, long long zB,
    fp16* __restrict__ C, int ldc, long long zC, int cMsh, long long cMslab, int cNsh,
    long long cNslab,
    const fp16* __restrict__ S, long long zS, float beta,
    const float* __restrict__ rowBias, long long zRB,
    const float* __restrict__ s2T, int s2ld,
    int M, int Ncols, int K, float alpha, int act) {
  __shared__ fp16 As[MT][40];
  __shared__ fp16 Bs[NT][40];
  const int z = blockIdx.z;
  const int gm0 = blockIdx.x * MT, n0 = blockIdx.y * NT;
  A += (long long)z * zA;
  B += (long long)z * zB;
  C += (long long)z * zC;
  if (S) S += (long long)z * zS;
  const int tid = threadIdx.x;
  const int lane = tid & 63, wv = tid >> 6;
  const int wr = wv >> 1, wc = wv & 1;
  const int quad = lane >> 4, ln = lane & 15;
  const unsigned aMmask = (1u << aMsh) - 1u;
  const unsigned cMmask = (1u << cMsh) - 1u;
  const unsigned cNmask = (1u << cNsh) - 1u;
  constexpr int WM = MT / 32, WN = NT / 32;
  f32x4 acc[WM][WN];
#pragma unroll
  for (int i = 0; i < WM; ++i)
#pragma unroll
    for (int j = 0; j < WN; ++j) acc[i][j] = (f32x4){0.f, 0.f, 0.f, 0.f};

  for (int k0 = 0; k0 < K; k0 += 32) {
#pragma unroll
    for (int i = 0; i < MT / 64; ++i) {
      int c = tid + 256 * i;
      int row = c >> 2, seg = c & 3;
      int gm = gm0 + row;
      int kk0 = k0 + seg * 8;
      const fp16* src = A + ((long long)((unsigned)gm >> aMsh)) * aMslab +
                        (long long)(gm & aMmask) * lda + kk0;
      if (gm < M && kk0 + 8 <= K) {
        *(f16x8*)&As[row][seg * 8] = *(const f16x8*)src;
      } else {
#pragma unroll
        for (int j = 0; j < 8; ++j)
          As[row][seg * 8 + j] = (gm < M && kk0 + j < K) ? src[j] : (fp16)0.f;
      }
    }
#pragma unroll
    for (int i = 0; i < NT / 64; ++i) {
      int c = tid + 256 * i;
      int n = c >> 2, seg = c & 3;
      int gn = n0 + n;
      int kk0 = k0 + seg * 8;
      const fp16* src = B + (long long)gn * ldb + kk0;
      if (gn < Ncols && kk0 + 8 <= K) {
        *(f16x8*)&Bs[n][seg * 8] = *(const f16x8*)src;
      } else {
#pragma unroll
        for (int j = 0; j < 8; ++j)
          Bs[n][seg * 8 + j] = (gn < Ncols && kk0 + j < K) ? src[j] : (fp16)0.f;
      }
    }
    __syncthreads();
    f16x8 af[WM], bf[WN];
#pragma unroll
    for (int wm = 0; wm < WM; ++wm)
      af[wm] = *(const f16x8*)&As[wr * (MT / 2) + wm * 16 + ln][quad * 8];
#pragma unroll
    for (int wn = 0; wn < WN; ++wn)
      bf[wn] = *(const f16x8*)&Bs[wc * (NT / 2) + wn * 16 + ln][quad * 8];
#pragma unroll
    for (int wm = 0; wm < WM; ++wm)
#pragma unroll
      for (int wn = 0; wn < WN; ++wn)
        acc[wm][wn] =
            __builtin_amdgcn_mfma_f32_16x16x32_f16(af[wm], bf[wn], acc[wm][wn], 0, 0, 0);
    __syncthreads();
  }
#pragma unroll
  for (int wm = 0; wm < WM; ++wm) {
#pragma unroll
    for (int wn = 0; wn < WN; ++wn) {
#pragma unroll
      for (int r = 0; r < 4; ++r) {
        int gm = gm0 + wr * (MT / 2) + wm * 16 + quad * 4 + r;
        int gn = n0 + wc * (NT / 2) + wn * 16 + ln;
        if (gm < M && gn < Ncols) {
          float v = alpha * acc[wm][wn][r];
          if (rowBias) v += rowBias[(long long)z * zRB + gm];
          if (s2T) v += s2T[(long long)gn * s2ld + gm];
          long long ci = ((long long)((unsigned)gm >> cMsh)) * cMslab +
                         (long long)(gm & cMmask) * ldc +
                         ((long long)((unsigned)gn >> cNsh)) * cNslab + (gn & cNmask);
          if (S) v += beta * (float)S[ci];
          if (act == 1) v = fmaxf(v, 0.f);
          else if (act == 2) v = 1.f / (1.f + expf(-v));
          else if (act == 3) v = tanhf(v);
          C[ci] = (fp16)v;
        }
      }
    }
  }
}

// ---------- mfma4: maskless gload_lds GEMM, dual-base A descriptor ----------
template <int MT, int NT>
__global__ __launch_bounds__(256) void mfma4(
    const fp16* __restrict__ base0, const fp16* __restrict__ base1, int rsh, int ssh,
    long long z0, long long z1, int lda,
    const fp16* __restrict__ B, int ldb, long long zB,
    fp16* __restrict__ C, int ldc, long long zC, int cMsh, long long cMslab, int cNsh,
    long long cNslab,
    const fp16* __restrict__ S, float alpha, float beta, int K) {
  __shared__ fp16 As[2][MT * 32];
  __shared__ fp16 Bs[2][NT * 32];
  const int tid = threadIdx.x;
  const int z = blockIdx.z;
  const int gm0 = blockIdx.x * MT, n0 = blockIdx.y * NT;
  B += (long long)z * zB;
  C += (long long)z * zC;
  if (S) S += (long long)z * zC;
  const unsigned cMmask = (1u << cMsh) - 1u;
  const unsigned cNmask = (1u << cNsh) - 1u;
  const int lane = tid & 63, wv = tid >> 6;
  const int wr = wv >> 1, wc = wv & 1;
  const int quad = lane >> 4, ln = lane & 15;
  constexpr int WM = MT / 32, WN = NT / 32;

  const fp16* aSrc[MT / 64];
  const fp16* bSrc[NT / 64];
#pragma unroll
  for (int i = 0; i < MT / 64; ++i) {
    int c = i * 256 + tid;
    int row = c >> 2;
    int lseg = (c & 3) ^ ((c >> 3) & 3);
    int gm = gm0 + row;
    unsigned b = (unsigned)gm >> rsh;
    unsigned wi = (unsigned)gm & ((1u << rsh) - 1u);
    unsigned sel = wi >> ssh;
    unsigned r = wi & ((1u << ssh) - 1u);
    const fp16* ab = sel ? (base1 + (long long)b * z1) : (base0 + (long long)b * z0);
    aSrc[i] = ab + (long long)r * lda + lseg * 8;
  }
#pragma unroll
  for (int i = 0; i < NT / 64; ++i) {
    int c = i * 256 + tid;
    int lseg = (c & 3) ^ ((c >> 3) & 3);
    bSrc[i] = B + (long long)(n0 + (c >> 2)) * ldb + lseg * 8;
  }

  f32x4 acc[WM][WN];
#pragma unroll
  for (int i = 0; i < WM; ++i)
#pragma unroll
    for (int j = 0; j < WN; ++j) acc[i][j] = (f32x4){0.f, 0.f, 0.f, 0.f};

  const int sw = (quad ^ ((ln >> 1) & 3)) << 3;

#pragma unroll
  for (int i = 0; i < MT / 64; ++i) gload_lds16(aSrc[i], &As[0][(i * 256 + tid) * 8]);
#pragma unroll
  for (int i = 0; i < NT / 64; ++i) gload_lds16(bSrc[i], &Bs[0][(i * 256 + tid) * 8]);

  const int nk = K >> 5;
  for (int t = 0; t < nk; ++t) {
    const int buf = t & 1;
    __syncthreads();
    if (t + 1 < nk) {
      const int k1 = (t + 1) * 32;
#pragma unroll
      for (int i = 0; i < MT / 64; ++i)
        gload_lds16(aSrc[i] + k1, &As[buf ^ 1][(i * 256 + tid) * 8]);
#pragma unroll
      for (int i = 0; i < NT / 64; ++i)
        gload_lds16(bSrc[i] + k1, &Bs[buf ^ 1][(i * 256 + tid) * 8]);
    }
    f16x8 af[WM], bf[WN];
#pragma unroll
    for (int wm = 0; wm < WM; ++wm) {
      int row = wr * (MT / 2) + wm * 16 + ln;
      af[wm] = *(const f16x8*)&As[buf][row * 32 + sw];
    }
#pragma unroll
    for (int wn = 0; wn < WN; ++wn) {
      int row = wc * (NT / 2) + wn * 16 + ln;
      bf[wn] = *(const f16x8*)&Bs[buf][row * 32 + sw];
    }
#pragma unroll
    for (int wm = 0; wm < WM; ++wm)
#pragma unroll
      for (int wn = 0; wn < WN; ++wn)
        acc[wm][wn] =
            __builtin_amdgcn_mfma_f32_16x16x32_f16(af[wm], bf[wn], acc[wm][wn], 0, 0, 0);
  }
#pragma unroll
  for (int wm = 0; wm < WM; ++wm)
#pragma unroll
    for (int wn = 0; wn < WN; ++wn)
#pragma unroll
      for (int r = 0; r < 4; ++r) {
        int gm = gm0 + wr * (MT / 2) + wm * 16 + quad * 4 + r;
        int gn = n0 + wc * (NT / 2) + wn * 16 + ln;
        long long ci = ((long long)((unsigned)gm >> cMsh)) * cMslab +
                       (long long)(gm & cMmask) * ldc +
                       ((long long)((unsigned)gn >> cNsh)) * cNslab + (gn & cNmask);
        float v = alpha * acc[wm][wn][r];
        if (S) v += beta * (float)S[ci];
        C[ci] = (fp16)v;
      }
}

// ---------- mfma6: maskless gload_lds GEMM, dual-base B descriptor ----------
template <int MT, int NT>
__global__ __launch_bounds__(256) void mfma6(
    const fp16* __restrict__ A, int lda,
    const fp16* __restrict__ b0, const fp16* __restrict__ b1, int rsh, int ssh,
    long long z0, long long z1, int ldb,
    fp16* __restrict__ C, int ldc, int cMsh, long long cMslab,
    int K) {
  __shared__ fp16 As[2][MT * 32];
  __shared__ fp16 Bs[2][NT * 32];
  const int tid = threadIdx.x;
  const int gm0 = blockIdx.x * MT, n0 = blockIdx.y * NT;
  const unsigned cMmask = (1u << cMsh) - 1u;
  const int lane = tid & 63, wv = tid >> 6;
  const int wr = wv >> 1, wc = wv & 1;
  const int quad = lane >> 4, ln = lane & 15;
  constexpr int WM = MT / 32, WN = NT / 32;

  const fp16* aSrc[MT / 64];
  const fp16* bSrc[NT / 64];
#pragma unroll
  for (int i = 0; i < MT / 64; ++i) {
    int c = i * 256 + tid;
    int lseg = (c & 3) ^ ((c >> 3) & 3);
    aSrc[i] = A + (long long)(gm0 + (c >> 2)) * lda + lseg * 8;
  }
#pragma unroll
  for (int i = 0; i < NT / 64; ++i) {
    int c = i * 256 + tid;
    int lseg = (c & 3) ^ ((c >> 3) & 3);
    int gn = n0 + (c >> 2);
    unsigned b = (unsigned)gn >> rsh;
    unsigned wi = (unsigned)gn & ((1u << rsh) - 1u);
    unsigned sel = wi >> ssh;
    unsigned r = wi & ((1u << ssh) - 1u);
    const fp16* bb = sel ? (b1 + (long long)b * z1) : (b0 + (long long)b * z0);
    bSrc[i] = bb + (long long)r * ldb + lseg * 8;
  }

  f32x4 acc[WM][WN];
#pragma unroll
  for (int i = 0; i < WM; ++i)
#pragma unroll
    for (int j = 0; j < WN; ++j) acc[i][j] = (f32x4){0.f, 0.f, 0.f, 0.f};

  const int sw = (quad ^ ((ln >> 1) & 3)) << 3;

#pragma unroll
  for (int i = 0; i < MT / 64; ++i) gload_lds16(aSrc[i], &As[0][(i * 256 + tid) * 8]);
#pragma unroll
  for (int i = 0; i < NT / 64; ++i) gload_lds16(bSrc[i], &Bs[0][(i * 256 + tid) * 8]);

  const int nk = K >> 5;
  for (int t = 0; t < nk; ++t) {
    const int buf = t & 1;
    __syncthreads();
    if (t + 1 < nk) {
      const int k1 = (t + 1) * 32;
#pragma unroll
      for (int i = 0; i < MT / 64; ++i)
        gload_lds16(aSrc[i] + k1, &As[buf ^ 1][(i * 256 + tid) * 8]);
#pragma unroll
      for (int i = 0; i < NT / 64; ++i)
        gload_lds16(bSrc[i] + k1, &Bs[buf ^ 1][(i * 256 + tid) * 8]);
    }
    f16x8 af[WM], bf[WN];
#pragma unroll
    for (int wm = 0; wm < WM; ++wm) {
      int row = wr * (MT / 2) + wm * 16 + ln;
      af[wm] = *(const f16x8*)&As[buf][row * 32 + sw];
    }
#pragma unroll
    for (int wn = 0; wn < WN; ++wn) {
      int row = wc * (NT / 2) + wn * 16 + ln;
      bf[wn] = *(const f16x8*)&Bs[buf][row * 32 + sw];
    }
#pragma unroll
    for (int wm = 0; wm < WM; ++wm)
#pragma unroll
      for (int wn = 0; wn < WN; ++wn)
        acc[wm][wn] =
            __builtin_amdgcn_mfma_f32_16x16x32_f16(af[wm], bf[wn], acc[wm][wn], 0, 0, 0);
  }
#pragma unroll
  for (int wm = 0; wm < WM; ++wm)
#pragma unroll
    for (int wn = 0; wn < WN; ++wn)
#pragma unroll
      for (int r = 0; r < 4; ++r) {
        int gm = gm0 + wr * (MT / 2) + wm * 16 + quad * 4 + r;
        int gn = n0 + wc * (NT / 2) + wn * 16 + ln;
        long long ci = ((long long)((unsigned)gm >> cMsh)) * cMslab +
                       (long long)(gm & cMmask) * ldc + gn;
        C[ci] = (fp16)acc[wm][wn][r];
      }
}

// ---------- k_zxtfin2w: ZXt[z][d][n] = w2T@relu(x*w29+b30)^T + teXb + seXT (WRITE) ----------
// Pure write (no readback); term1 GEMM adds its contribution afterwards via S.
__global__ __launch_bounds__(256) void k_zxtfin2w(
    const fp16* __restrict__ w2T, const float* __restrict__ X,
    const float* __restrict__ w29, const float* __restrict__ b30,
    fp16* __restrict__ ZXt, const float* __restrict__ teXb,
    const fp16* __restrict__ seXT) {
  __shared__ fp16 As[64][72];
  __shared__ fp16 Bs[128][72];
  const int z = blockIdx.z;
  const int n0 = blockIdx.y * 128;
  fp16* Cz = ZXt + (long long)z * 64 * 2048;
  const float* tb = teXb + z * 64;
  const int tid = threadIdx.x;
  const int lane = tid & 63, wv = tid >> 6;
  const int wr = wv >> 1, wc = wv & 1;
  const int quad = lane >> 4, ln = lane & 15;
#pragma unroll
  for (int i = 0; i < 2; ++i) {
    int c = tid + 256 * i;
    int row = c >> 3, seg = c & 7;
    *(f16x8*)&As[row][seg * 8] = *(const f16x8*)(w2T + row * 64 + seg * 8);
  }
#pragma unroll
  for (int i = 0; i < 4; ++i) {
    int c = tid + 256 * i;
    int row = c >> 3, seg = c & 7;
    int n = n0 + row;
    float xv = (n < NN) ? X[(long long)z * NN + n] : 0.f;
    fp16 tmp[8];
#pragma unroll
    for (int e = 0; e < 8; ++e) {
      int j = seg * 8 + e;
      tmp[e] = (fp16)fmaxf(xv * w29[j] + b30[j], 0.f);
    }
    *(f16x8*)&Bs[row][seg * 8] = *(f16x8*)tmp;
  }
  __syncthreads();
  f32x4 acc[2][4];
#pragma unroll
  for (int i = 0; i < 2; ++i)
#pragma unroll
    for (int j = 0; j < 4; ++j) acc[i][j] = (f32x4){0.f, 0.f, 0.f, 0.f};
#pragma unroll
  for (int kt = 0; kt < 2; ++kt) {
    f16x8 af[2], bf[4];
#pragma unroll
    for (int wm = 0; wm < 2; ++wm)
      af[wm] = *(const f16x8*)&As[wr * 32 + wm * 16 + ln][kt * 32 + quad * 8];
#pragma unroll
    for (int wn = 0; wn < 4; ++wn)
      bf[wn] = *(const f16x8*)&Bs[wc * 64 + wn * 16 + ln][kt * 32 + quad * 8];
#pragma unroll
    for (int wm = 0; wm < 2; ++wm)
#pragma unroll
      for (int wn = 0; wn < 4; ++wn)
        acc[wm][wn] =
            __builtin_amdgcn_mfma_f32_16x16x32_f16(af[wm], bf[wn], acc[wm][wn], 0, 0, 0);
  }
#pragma unroll
  for (int wm = 0; wm < 2; ++wm)
#pragma unroll
    for (int wn = 0; wn < 4; ++wn)
#pragma unroll
      for (int r = 0; r < 4; ++r) {
        int gm = wr * 32 + wm * 16 + quad * 4 + r;
        int gn = n0 + wc * 64 + wn * 16 + ln;
        float v = 0.f;
        if (gn < NN)
          v = acc[wm][wn][r] + tb[gm] + (float)seXT[(long long)gm * 2048 + gn];
        Cz[(long long)gm * 2048 + gn] = (fp16)v;
      }
}

// ---------- ConvLSTM conv, mfma4-style with zero-padded 34x34 halo ----------
__global__ __launch_bounds__(256) void k_conv4(
    const fp16* __restrict__ Zfp, const fp16* __restrict__ hp,
    const fp16* __restrict__ wcatT, fp16* __restrict__ gates, int p) {
  __shared__ fp16 As[2][128 * 32];
  __shared__ fp16 Bs[2][64 * 32];
  const int gm0 = blockIdx.x * 128, n0 = blockIdx.y * 64;
  const int tid = threadIdx.x;
  const int lane = tid & 63, wv = tid >> 6;
  const int wr = wv >> 1, wc = wv & 1;
  const int quad = lane >> 4, ln = lane & 15;

  long long aZ[2], aH[2];
#pragma unroll
  for (int i = 0; i < 2; ++i) {
    int c = tid + 256 * i;
    int row = c >> 2;
    int lseg = (c & 3) ^ ((c >> 3) & 3);
    int m = gm0 + row;
    int b = m >> 10, y = (m >> 5) & 31, x = m & 31;
    int pc = (y + 1) * GP + (x + 1);
    aZ[i] = ((long long)(b * PP + p) * GP2 + pc) * 64 + lseg * 8;
    aH[i] = ((long long)b * GP2 + pc) * 64 + lseg * 8;
  }
  const fp16* bBase;
  {
    int row = tid >> 2;
    int lseg = (tid & 3) ^ ((tid >> 3) & 3);
    bBase = wcatT + (long long)(n0 + row) * 1152 + lseg * 8;
  }
  f32x4 acc[4][2];
#pragma unroll
  for (int i = 0; i < 4; ++i)
#pragma unroll
    for (int j = 0; j < 2; ++j) acc[i][j] = (f32x4){0.f, 0.f, 0.f, 0.f};

  auto stage = [&](int t, int buf) {
    int tap = (t >> 1) % 9, half = t & 1;
    int srcsel = t >= 18;
    int off = ((tap / 3 - 1) * GP + (tap % 3 - 1)) * 64 + half * 32;
#pragma unroll
    for (int i = 0; i < 2; ++i) {
      const fp16* src = srcsel ? (hp + aH[i] + off) : (Zfp + aZ[i] + off);
      gload_lds16(src, &As[buf][(i * 256 + tid) * 8]);
    }
    gload_lds16(bBase + t * 32, &Bs[buf][tid * 8]);
  };
  stage(0, 0);
  const int sw = (quad ^ ((ln >> 1) & 3)) << 3;
  for (int t = 0; t < 36; ++t) {
    const int buf = t & 1;
    __syncthreads();
    if (t + 1 < 36) stage(t + 1, buf ^ 1);
    f16x8 af[4], bf[2];
#pragma unroll
    for (int wm = 0; wm < 4; ++wm) {
      int row = wr * 64 + wm * 16 + ln;
      af[wm] = *(const f16x8*)&As[buf][row * 32 + sw];
    }
#pragma unroll
    for (int wn = 0; wn < 2; ++wn) {
      int row = wc * 32 + wn * 16 + ln;
      bf[wn] = *(const f16x8*)&Bs[buf][row * 32 + sw];
    }
#pragma unroll
    for (int wm = 0; wm < 4; ++wm)
#pragma unroll
      for (int wn = 0; wn < 2; ++wn)
        acc[wm][wn] =
            __builtin_amdgcn_mfma_f32_16x16x32_f16(af[wm], bf[wn], acc[wm][wn], 0, 0, 0);
  }
#pragma unroll
  for (int wm = 0; wm < 4; ++wm)
#pragma unroll
    for (int wn = 0; wn < 2; ++wn)
#pragma unroll
      for (int r = 0; r < 4; ++r) {
        int gm = gm0 + wr * 64 + wm * 16 + quad * 4 + r;
        int gn = n0 + wc * 32 + wn * 16 + ln;
        gates[(long long)gm * 256 + gn] = (fp16)acc[wm][wn][r];
      }
}

__global__ void k_clstm_update(const fp16* __restrict__ gates, float* __restrict__ c,
                               fp16* __restrict__ h, fp16* __restrict__ ZclT, int p) {
  long long i = (long long)blockIdx.x * 256 + threadIdx.x;
  if (i >= (long long)BB * CC * 64) return;
  int d = (int)(i & 63);
  long long bc = i >> 6;
  int b = (int)(bc >> 10);
  int cell = (int)(bc & 1023);
  const fp16* g = gates + (((long long)b * CC) + cell) * 256;
  float gi = (float)g[d], gf = (float)g[64 + d], gg = (float)g[128 + d],
        go = (float)g[192 + d];
  float hs_f = fminf(fmaxf(0.2f * gf + 0.5f, 0.f), 1.f);
  float hs_i = fminf(fmaxf(0.2f * gi + 0.5f, 0.f), 1.f);
  float hs_o = fminf(fmaxf(0.2f * go + 0.5f, 0.f), 1.f);
  float cv = hs_f * c[i] + hs_i * tanhf(gg);
  c[i] = cv;
  float hv = hs_o * tanhf(cv);
  int pc = ((cell >> 5) + 1) * GP + (cell & 31) + 1;
  h[((long long)b * GP2 + pc) * 64 + d] = (fp16)hv;
  ZclT[(((long long)(b * PP + p)) * 64 + d) * CC + cell] = (fp16)hv;
}

extern "C" void kernel_launch(void* const* d_in, const int* in_sizes, int n_in,
                              void* d_out, int out_size, void* d_ws, size_t ws_size,
                              hipStream_t stream) {
  char* base = (char*)d_ws;
  size_t off = 0;
  auto alloc_bytes = [&](size_t nb) -> char* {
    char* p = base + off;
    off += (nb + 255) & ~(size_t)255;
    return p;
  };
  auto allocf = [&](size_t n) -> float* { return (float*)alloc_bytes(n * 4); };
  auto alloch = [&](size_t n) -> fp16* { return (fp16*)alloc_bytes(n * 2); };

  const float* X = (const float*)d_in[0];
  const float* Z = (const float*)d_in[1];
  const int* TE = (const int*)d_in[2];
  const float* adj_gg = (const float*)d_in[3];
  const float* adj_gr = (const float*)d_in[4];
  const float* gumbel = (const float*)d_in[5];
  const float* se_x = (const float*)d_in[6];
  const float* se_z = (const float*)d_in[7];
  const float* movement = (const float*)d_in[8];
  auto W = [&](int i) { return (const float*)d_in[i]; };

  // ---- allocations ----
  fp16* wcatT = alloch((size_t)256 * 1152);  // [n][k] pre-transposed conv weights
  fp16* gwT = alloch(128 * 512);
  fp16* cwT = alloch(64 * 512);
  fp16* w2T = alloch(64 * 64);
  fp16* w2mT = alloch(64 * 64);
  fp16* w27T = alloch(64 * 64);
  fp16* w35T = alloch(64 * 64);
  fp16* w37T = alloch(16 * 64);
  fp16* w9T = alloch(64 * 64);
  fp16* w11T = alloch(64 * 64);
  fp16* w17T = alloch(64 * 64);
  fp16* w19T = alloch(64 * 64);
  fp16* w15T = alloch(64 * 64);
  fp16* w23T = alloch(64 * 64);
  float* dinv = allocf(NN);
  fp16* LMall = alloch((size_t)6144 * 2048);  // rows padded to 2048 for maskless mfma4/6
  fp16* mZh = alloch((size_t)CC * CC);
  fp16* agh2 = alloch((size_t)2048 * CC);  // padded to 2048 rows (pad rows zero)
  float* seZ = allocf(CC * 64);
  float* teZ = allocf(BB * PP * 64);
  fp16* seXT = alloch((size_t)64 * 2048);  // transposed seX, fp16
  float* teXb = allocf(BB * PP * 64);
  fp16* ruT = alloch((size_t)BB * 128 * NN);  // [b][128][2000]
  // pool (4*USL = 50.33MB)
  char* pool = alloc_bytes(50331648);
  fp16* Uall = (fp16*)pool;
  fp16* gates = (fp16*)pool;
  fp16* chh = (fp16*)(pool + 8388608);   // padded h [16][1156][64]
  float* ccc = (float*)(pool + 12582912);
  fp16* Zmix = (fp16*)pool;
  fp16* ZmovT = (fp16*)(pool + 25165824);
  // zpool: Zf_pad [bp][1156][64] (28.4MB) then ZXt [bp][64][2048]
  fp16* zpool = alloch((size_t)BB * PP * 64 * 2048);
  fp16* Zfp = zpool;
  fp16* ZXt = zpool;
  fp16* Zc = alloch((size_t)BB * PP * CC * 64);  // ZclT (conv output, movement m1 input)

  if (off > ws_size) return;

  const long long uB = 192LL * 2048;
  const long long USL = 16LL * uB;
  const long long ZXB = 12LL * 64 * 2048;  // per-batch stride of ZXt
  fp16* Lh = LMall;
  fp16* M2h = LMall + 2048LL * 2048;
  fp16* M3h = LMall + 4096LL * 2048;
  const int KCH = 2016;  // chain K (2000 padded to x32; cols 2000..2015 zero)

  // ---- precompute ----
  k_wcatT<<<dim3(1152), dim3(256), 0, stream>>>(wcatT, W(39), W(40));
  k_gru_repackT<<<dim3(256), dim3(256), 0, stream>>>(gwT, W(41), 128);
  k_gru_repackT<<<dim3(128), dim3(256), 0, stream>>>(cwT, W(43), 64);
  k_w2T<<<dim3(16), dim3(256), 0, stream>>>(w2T, W(31));
  k_w2T<<<dim3(16), dim3(256), 0, stream>>>(w2mT, W(33));
  k_wT<<<dim3(16), dim3(256), 0, stream>>>(w27T, W(27), 64, 64);
  k_wT<<<dim3(16), dim3(256), 0, stream>>>(w35T, W(35), 64, 64);
  k_wT<<<dim3(4), dim3(256), 0, stream>>>(w37T, W(37), 12, 16);
  k_wT<<<dim3(16), dim3(256), 0, stream>>>(w9T, W(9), 64, 64);
  k_wT<<<dim3(16), dim3(256), 0, stream>>>(w11T, W(11), 64, 64);
  k_wT<<<dim3(16), dim3(256), 0, stream>>>(w17T, W(17), 64, 64);
  k_wT<<<dim3(16), dim3(256), 0, stream>>>(w19T, W(19), 64, 64);
  k_wT<<<dim3(16), dim3(256), 0, stream>>>(w15T, W(15), 64, 64);
  k_wT<<<dim3(16), dim3(256), 0, stream>>>(w23T, W(23), 64, 64);
  k_dinv<<<dim3(NN), dim3(256), 0, stream>>>(adj_gg, dinv);
  hipMemsetAsync(LMall, 0, (size_t)6144 * 2048 * 2, stream);
  k_L<<<dim3((NN * NN + 255) / 256), dim3(256), 0, stream>>>(adj_gg, dinv, Lh);
  mfma4<64, 128><<<dim3(32, 16, 1), dim3(256), 0, stream>>>(
      Lh, Lh, 31, 31, 0LL, 0LL, 2048, Lh, 2048, 0LL, M2h, 2048, 0LL, 31, 0LL, 31, 0LL,
      (const fp16*)nullptr, 2.f, 0.f, KCH);
  k_subdiag<<<dim3((NN + 255) / 256), dim3(256), 0, stream>>>(M2h);
  mfma4<64, 128><<<dim3(32, 16, 1), dim3(256), 0, stream>>>(
      Lh, Lh, 31, 31, 0LL, 0LL, 2048, M2h, 2048, 0LL, M3h, 2048, 0LL, 31, 0LL, 31, 0LL,
      (const fp16*)Lh, 2.f, -1.f, KCH);
  k_gumbel_softmax<<<dim3(CC), dim3(256), 0, stream>>>(movement, gumbel, mZh);
  k_f2h<<<dim3((NN * CC + 255) / 256), dim3(256), 0, stream>>>(agh2, adj_gr,
                                                               (long long)NN * CC);
  hipMemsetAsync(agh2 + (size_t)NN * CC, 0, (size_t)(2048 - NN) * CC * 2, stream);

  // ---- STE paths, fully fused ----
  k_mlp2<0><<<dim3(8), dim3(256), 0, stream>>>(se_z, (const int*)nullptr,
                                               (const float*)nullptr, W(18), w17T, w19T,
                                               W(20), (const float*)nullptr, seZ,
                                               (fp16*)nullptr, CC);
  k_mlp2<0><<<dim3(16), dim3(256), 0, stream>>>(se_x, (const int*)nullptr,
                                                (const float*)nullptr, W(10), w9T, w11T,
                                                W(12), (const float*)nullptr,
                                                (float*)nullptr, seXT, NN);
  k_mlp2<1><<<dim3(2), dim3(256), 0, stream>>>((const float*)nullptr, TE, W(21), W(22),
                                               (const fp16*)nullptr, w23T, W(24),
                                               (const float*)nullptr, teZ, (fp16*)nullptr,
                                               BB * PP);
  k_mlp2<1><<<dim3(2), dim3(256), 0, stream>>>((const float*)nullptr, TE, W(13), W(14),
                                               (const fp16*)nullptr, w15T, W(16), W(32),
                                               teXb, (fp16*)nullptr, BB * PP);

  // ---- Zf = mlp2(Z) + STEZ, fully fused -> padded 34x34 layout ----
  hipMemsetAsync(zpool, 0, (size_t)BB * PP * GP2 * 64 * 2, stream);  // zero Zf_pad (halo)
  k_zf2f<<<dim3(1536), dim3(256), 0, stream>>>(Z, W(25), W(26), w27T, W(28), seZ, teZ,
                                               Zfp);

  // ---- ConvLSTM (writes ZclT into Zc; h in padded chh) ----
  hipMemsetAsync(chh, 0, (size_t)BB * GP2 * 64 * 2, stream);
  hipMemsetAsync(ccc, 0, (size_t)BB * CC * 64 * 4, stream);
  for (int p = 0; p < PP; ++p) {
    k_conv4<<<dim3(BB * CC / 128, 4), dim3(256), 0, stream>>>(Zfp, chh, wcatT, gates, p);
    k_clstm_update<<<dim3((int)(((long long)BB * CC * 64 + 255) / 256)), dim3(256), 0,
                     stream>>>(gates, ccc, chh, Zc, p);
  }

  // ---- movement m1 (mfma4, z-batched) / m2 ----
  mfma4<128, 64><<<dim3(8, 1, 192), dim3(256), 0, stream>>>(
      mZh, mZh, 31, 31, 0LL, 0LL, CC, (const fp16*)Zc, CC, (long long)64 * CC, Zmix, 64,
      (long long)CC * 64, 31, 0LL, 31, 0LL, (const fp16*)nullptr, 1.f, 0.f, CC);
  mfma3<64, 128><<<dim3(1, 8, 192), dim3(256), 0, stream>>>(
      w2mT, 64, 0LL, 31, 0LL, Zmix, 64, (long long)CC * 64, ZmovT, CC, (long long)64 * CC,
      31, 0LL, 31, 0LL, (const fp16*)nullptr, 0LL, 0.f, W(34), 0LL, nullptr, 0, 64, CC, 64,
      1.f, 1);

  // ---- zxt term2 + biases FIRST (pure write into ZXt; Zfp dead after conv) ----
  k_zxtfin2w<<<dim3(1, 16, 192), dim3(256), 0, stream>>>(w2T, X, W(29), W(30), ZXt, teXb,
                                                         seXT);

  // ---- zxt term1: one big GEMM with S-add of term2 (in-place) ----
  mfma4<128, 128><<<dim3(96, 16, 1), dim3(256), 0, stream>>>(
      ZmovT, ZmovT, 31, 31, 0LL, 0LL, 1024, agh2, 1024, 0LL, ZXt, 2048, 0LL, 31, 0LL, 31,
      0LL, (const fp16*)ZXt, 1.f, 1.f, 1024);

  // ---- DCGRU (combined xh chebs; h lives in U0 rows 64..127; x read from ZXt) ----
  fp16* U0 = Uall;
  fp16* Tn = Uall + USL;        // 3 slabs [2048 n][16z*128]
  fp16* Tn2 = Uall + 3 * USL;   // 3 cand slabs [2048 n][16z*64]
  const long long TnSlab = 2048LL * 2048;
  const long long Tn2Slab = 2048LL * 1024;
  hipMemsetAsync(U0, 0, (size_t)USL * 2, stream);  // zero slab 0 (h/rh rows + pads)

  for (int p = 0; p < PP; ++p) {
    const fp16* xP = ZXt + (long long)p * 64 * 2048;
    // combined xh chebs: Tn[s][n][z*128+row]
    mfma6<128, 128><<<dim3(48, 16), dim3(256), 0, stream>>>(
        LMall, 2048, xP, U0 + 64 * 2048, 7, 6, ZXB, uB, 2048, Tn, 2048, 11, TnSlab, KCH);
    // ruT = sigmoid(gwT @ chebs); epilogue writes rh = r*h into U0 rows 128..191
    mfma7<128, 1><<<dim3(1, 32, BB), dim3(256), 0, stream>>>(
        gwT, U0, uB, 0, xP, ZXB,
        Tn, TnSlab, 2048, 128,
        Tn + 64, TnSlab, 2048, 128,
        ruT, NN, (long long)128 * NN, W(42), U0 + 128 * 2048, U0 + 64 * 2048,
        (const fp16*)nullptr, 0LL, 128, NN);
    // cand chebs: Tn2[s][n][z*64+row] = LM_s @ rh^T  (MT=64: 768 blocks = 3/CU)
    mfma6<64, 128><<<dim3(96, 8), dim3(256), 0, stream>>>(
        LMall, 2048, U0 + 128 * 2048, U0 + 128 * 2048, 6, 6, uB, uB, 2048, Tn2, 1024, 11,
        Tn2Slab, KCH);
    // cnd GEMM; epilogue does h' = u*h + (1-u)*tanh(v) in place in U0 rows 64..127
    mfma7<64, 2><<<dim3(1, 32, BB), dim3(256), 0, stream>>>(
        cwT, U0, uB, 64, xP, ZXB,
        Tn, TnSlab, 2048, 128,
        Tn2, Tn2Slab, 1024, 64,
        U0 + 64 * 2048, 2048, uB, W(44), (fp16*)nullptr, (const fp16*)nullptr,
        (const fp16*)ruT, (long long)128 * NN, 64, NN);
  }

  // ---- output head: fused transpose + MLP2 -> d_out ----
  k_head<<<dim3(16, 16), dim3(256), 0, stream>>>(U0, w35T, W(36), w37T, W(38),
                                                 (float*)d_out);
}